// Round 13
// baseline (474.911 us; speedup 1.0000x reference)
//
#include <hip/hip_runtime.h>
#include <hip/hip_bf16.h>

typedef __hip_bfloat16 bf16;
typedef __attribute__((ext_vector_type(8))) short short8v;   // 8 bf16 = 4 VGPRs (MFMA A/B frag)
typedef __attribute__((ext_vector_type(4))) float f32x4;     // MFMA C/D frag

#define NN 4096
#define NE 32768
#define HH 128
#define MAXZ 100
#define TPB 8    // edges per block, TNE edge kernel
#define NB 2     // nodes per block in node-side kernels (grid 2048 = 8 blocks/CU)

// ENVIRONMENT FACTS (r0-r12): float tensors are FLOAT32; runtime detector kept as
// insurance. MFMA msg-edge path hardware-validated r10. NB=2 best (r11/r12).
// r12 lesson: node kernels are issue-slot-bound (VALUBusy 57%, HBM 4%) — this
// round halves weight-load instruction count via k-pair float2 packing with
// EXACT add-order preservation (absmax must stay 0.00206089).

__device__ __forceinline__ float b2f(bf16 v){ return __bfloat162float(v); }
__device__ __forceinline__ float ldf(const float* p, size_t i){ return p[i]; }
__device__ __forceinline__ float ldf(const bf16*  p, size_t i){ return __bfloat162float(p[i]); }
__device__ __forceinline__ float siluf(float x){ return x / (1.0f + __expf(-x)); }
__device__ __forceinline__ unsigned short f2bu(float x){
  bf16 h = __float2bfloat16(x);
  return *reinterpret_cast<unsigned short*>(&h);
}

// dtype detect: flag[0]=1 if float inputs are f32, 0 if bf16.
__global__ void __launch_bounds__(256) k_detect(const unsigned int* __restrict__ w, int* __restrict__ flag){
  __shared__ int cnt[256];
  int t = threadIdx.x;
  int c = 0;
  for (int i = t; i < 4096; i += 256){
    unsigned int lo = w[i] & 0xffffu;
    int e = (int)((lo >> 7) & 0xffu);
    c += (e >= 110 && e <= 132) ? 1 : 0;
  }
  cnt[t] = c; __syncthreads();
  for (int off=128; off>=1; off>>=1){ if (t<off) cnt[t]+=cnt[t+off]; __syncthreads(); }
  if (t==0) flag[0] = (cnt[0] < 2048) ? 1 : 0;
}

// ---------------- CSR build ----------------
__global__ void __launch_bounds__(256) k_count(const int* __restrict__ dst, int* __restrict__ counts){
  int e = blockIdx.x*256 + threadIdx.x;
  if (e < NE) atomicAdd(&counts[dst[e]], 1);
}

__global__ void __launch_bounds__(1024) k_scan(const int* __restrict__ counts, int* __restrict__ offsets, int* __restrict__ cursor){
  __shared__ int lds[1024];
  int t = threadIdx.x;
  int c0 = counts[4*t+0], c1 = counts[4*t+1], c2 = counts[4*t+2], c3 = counts[4*t+3];
  int s1 = c0+c1, s2 = s1+c2, s3 = s2+c3;
  lds[t] = s3;
  __syncthreads();
  for (int off=1; off<1024; off<<=1){
    int v = lds[t];
    int add = (t>=off)? lds[t-off] : 0;
    __syncthreads();
    lds[t] = v + add;
    __syncthreads();
  }
  int incl = lds[t];
  int base = incl - s3;
  offsets[4*t+0]=base;    offsets[4*t+1]=base+c0; offsets[4*t+2]=base+s1; offsets[4*t+3]=base+s2;
  cursor [4*t+0]=base;    cursor [4*t+1]=base+c0; cursor [4*t+2]=base+s1; cursor [4*t+3]=base+s2;
  if (t==1023) offsets[4096]=incl;
}

__global__ void __launch_bounds__(256) k_fill(const int* __restrict__ dst, int* __restrict__ cursor, int* __restrict__ csr){
  int e = blockIdx.x*256 + threadIdx.x;
  if (e < NE){ int p = atomicAdd(&cursor[dst[e]], 1); csr[p] = e; }
}

// ---------------- edge geometry ----------------
template<typename T>
__device__ __forceinline__ void geom_impl(const T* ew, const T* evec,
    const int* src, const int* dst, float* gC, float* gV){
  int e = blockIdx.x*256 + threadIdx.x;
  if (e >= NE) return;
  float d = ldf(ew, e);
  float c = 0.5f*(cosf(d*0.6283185307179586f)+1.0f);
  c = (d < 5.0f) ? c : 0.0f;
  gC[e] = c;
  float x = ldf(evec, (size_t)e*3+0), y = ldf(evec, (size_t)e*3+1), z = ldf(evec, (size_t)e*3+2);
  if (src[e] != dst[e]){
    float n = sqrtf(x*x+y*y+z*z);
    float inv = 1.0f/fmaxf(n, 1e-12f);
    x*=inv; y*=inv; z*=inv;
  }
  gV[e*3+0]=x; gV[e*3+1]=y; gV[e*3+2]=z;
}
__global__ void __launch_bounds__(256) k_geom(const void* ew, const void* evec,
    const int* __restrict__ src, const int* __restrict__ dst,
    float* __restrict__ gC, float* __restrict__ gV, const int* __restrict__ flag){
  if (flag[0]) geom_impl<float>((const float*)ew, (const float*)evec, src, dst, gC, gV);
  else         geom_impl<bf16 >((const bf16* )ew, (const bf16* )evec, src, dst, gC, gV);
}

// ---------------- per-z embedding products ----------------
template<typename T>
__device__ __forceinline__ void zemb_impl(const T* emb, const T* emb2_w,
    float* P1z, float* P2z, float* Zr){
  int zv = blockIdx.x, h = threadIdx.x;
  Zr[h] = ldf(emb, (size_t)zv*HH + h);
  __syncthreads();
  float p1=0.f, p2=0.f;
  for (int r=0;r<128;++r){
    float x = Zr[r];
    p1 += x*ldf(emb2_w, (size_t)r*HH+h);
    p2 += x*ldf(emb2_w, (size_t)(r+128)*HH+h);
  }
  P1z[zv*HH+h]=p1; P2z[zv*HH+h]=p2;
}
__global__ void __launch_bounds__(128) k_zemb(const void* emb, const void* emb2_w,
    float* __restrict__ P1z, float* __restrict__ P2z, const int* __restrict__ flag){
  __shared__ float Zr[128];
  if (flag[0]) zemb_impl<float>((const float*)emb, (const float*)emb2_w, P1z, P2z, Zr);
  else         zemb_impl<bf16 >((const bf16* )emb, (const bf16* )emb2_w, P1z, P2z, Zr);
}

// ---------------- convert edge_attr -> bf16 ----------------
__global__ void __launch_bounds__(256) k_cvt_attr(const void* in, unsigned short* __restrict__ out,
                                                  const int* __restrict__ flag){
  int i = blockIdx.x*256 + threadIdx.x;
  if (flag[0]) out[i] = f2bu(((const float*)in)[i]);
  else         out[i] = ((const unsigned short*)in)[i];
}

// ---------------- weight repack into MFMA B-fragment layout ----------------
struct PackDescs {
  const void*     base[6];
  long            eoff[6];
  unsigned short* out[6];
  int K[6]; int N[6];
};
template<typename T>
__device__ __forceinline__ void pack_impl(const PackDescs& d){
  int y = blockIdx.y;
  int K = d.K[y], N = d.N[y];
  int ktiles = K>>5, ntiles = N>>4;
  int total = ktiles*ntiles*64;
  int idx = blockIdx.x*256 + threadIdx.x;
  if (idx >= total) return;
  int lane = idx & 63, tile = idx >> 6;
  int kt = tile % ktiles, nt = tile / ktiles;
  const T* W = (const T*)d.base[y] + d.eoff[y];
  int n = nt*16 + (lane&15), k0 = kt*32 + (lane>>4)*8;
  unsigned int t[8];
  #pragma unroll
  for (int j=0;j<8;++j) t[j] = f2bu(ldf(W, (size_t)(k0+j)*N + n));
  uint4 v;
  v.x = t[0] | (t[1]<<16);
  v.y = t[2] | (t[3]<<16);
  v.z = t[4] | (t[5]<<16);
  v.w = t[6] | (t[7]<<16);
  *reinterpret_cast<uint4*>(d.out[y] + ((size_t)tile*64 + lane)*8) = v;
}
__global__ void __launch_bounds__(256) k_pack(PackDescs d, const int* __restrict__ flag){
  if (flag[0]) pack_impl<float>(d);
  else         pack_impl<bf16 >(d);
}

// ---------------- pack 15 cmix matrices (128x128) into float2 k-pairs ----------------
// out[m][r2*128+h] = (W_m[2*r2][h], W_m[2*r2+1][h]).  m: 0-2 tne_lt, 3-8 lx, 9-14 lt.
template<typename T>
__device__ __forceinline__ void packf2_impl(const T* tlt, const T* lx, const T* lt, float2* out){
  int m = blockIdx.y;
  int idx = blockIdx.x*256 + threadIdx.x;   // < 8192
  int r2 = idx >> 7, h = idx & 127;
  const T* W;
  if (m < 3)      W = tlt + (size_t)m*16384;
  else if (m < 9) W = lx  + (size_t)(m-3)*16384;
  else            W = lt  + (size_t)(m-9)*16384;
  float2 v;
  v.x = ldf(W, (size_t)(2*r2)*128 + h);
  v.y = ldf(W, (size_t)(2*r2+1)*128 + h);
  out[(size_t)m*8192 + idx] = v;
}
__global__ void __launch_bounds__(256) k_packf2(const void* tlt, const void* lx, const void* lt,
                                                float2* __restrict__ out, const int* __restrict__ flag){
  if (flag[0]) packf2_impl<float>((const float*)tlt, (const float*)lx, (const float*)lt, out);
  else         packf2_impl<bf16 >((const bf16* )tlt, (const bf16* )lx, (const bf16* )lt, out);
}

// ---------------- pack s1_w (256x384) -> P(float2: cols 3h,3h+1), Q(float: col 3h+2) ----------------
template<typename T>
__device__ __forceinline__ void packs1_impl(const T* W, float2* P, float* Q){
  int idx = blockIdx.x*256 + threadIdx.x;   // < 256*128
  int r = idx >> 7, h = idx & 127;
  float2 v;
  v.x = ldf(W, (size_t)r*384 + 3*h);
  v.y = ldf(W, (size_t)r*384 + 3*h+1);
  P[idx] = v;
  Q[idx] = ldf(W, (size_t)r*384 + 3*h+2);
}
__global__ void __launch_bounds__(256) k_packs1(const void* W, float2* __restrict__ P, float* __restrict__ Q,
                                                const int* __restrict__ flag){
  if (flag[0]) packs1_impl<float>((const float*)W, P, Q);
  else         packs1_impl<bf16 >((const bf16* )W, P, Q);
}

// ---------------- TNE edge coefficients -> eabuf bf16 [E][3][128] ----------------
template<typename T>
__device__ __forceinline__ void tne_edge_impl(
  const T* eattr, const int* src, const int* dst, const int* z,
  const T* dp1_w, const T* dp1_b, const T* dp2_w, const T* dp2_b,
  const T* dp3_w, const T* dp3_b, const T* emb2_b,
  const float* P1z, const float* P2z, const float* gC, bf16* eabuf,
  float (*attr)[32], int* zd, int* zs)
{
  int e0 = blockIdx.x*TPB;
  int h  = threadIdx.x;
  for (int i=h; i<TPB*32; i+=128) attr[i>>5][i&31] = ldf(eattr, (size_t)e0*32 + i);
  if (h < TPB){ int e=e0+h; zd[h]=z[dst[e]]; zs[h]=z[src[e]]; }
  __syncthreads();
  float w1[TPB], w2[TPB], w3[TPB];
  float b1v=ldf(dp1_b,h), b2v=ldf(dp2_b,h), b3v=ldf(dp3_b,h);
  #pragma unroll
  for (int e=0;e<TPB;++e){ w1[e]=b1v; w2[e]=b2v; w3[e]=b3v; }
  for (int r=0;r<32;++r){
    float u1=ldf(dp1_w,(size_t)r*HH+h), u2=ldf(dp2_w,(size_t)r*HH+h), u3=ldf(dp3_w,(size_t)r*HH+h);
    #pragma unroll
    for (int e=0;e<TPB;++e){ float a=attr[e][r]; w1[e]+=a*u1; w2[e]+=a*u2; w3[e]+=a*u3; }
  }
  float eb = ldf(emb2_b,h);
  #pragma unroll
  for (int e=0;e<TPB;++e){
    float zij = P1z[zd[e]*HH+h] + P2z[zs[e]*HH+h] + eb;
    float c = gC[e0+e];
    bf16* p = eabuf + (size_t)(e0+e)*384;
    p[h]     = __float2bfloat16(zij*w1[e]*c);
    p[128+h] = __float2bfloat16(zij*w2[e]*c);
    p[256+h] = __float2bfloat16(zij*w3[e]*c);
  }
}
__global__ void __launch_bounds__(128) k_tne_edge(
  const void* eattr, const int* __restrict__ src, const int* __restrict__ dst, const int* __restrict__ z,
  const void* dp1_w, const void* dp1_b, const void* dp2_w, const void* dp2_b,
  const void* dp3_w, const void* dp3_b, const void* emb2_b,
  const float* __restrict__ P1z, const float* __restrict__ P2z,
  const float* __restrict__ gC, bf16* __restrict__ eabuf, const int* __restrict__ flag)
{
  __shared__ float attr[TPB][32];
  __shared__ int zd[TPB], zs[TPB];
  if (flag[0]) tne_edge_impl<float>((const float*)eattr, src, dst, z,
      (const float*)dp1_w, (const float*)dp1_b, (const float*)dp2_w, (const float*)dp2_b,
      (const float*)dp3_w, (const float*)dp3_b, (const float*)emb2_b, P1z, P2z, gC, eabuf, attr, zd, zs);
  else tne_edge_impl<bf16>((const bf16*)eattr, src, dst, z,
      (const bf16*)dp1_w, (const bf16*)dp1_b, (const bf16*)dp2_w, (const bf16*)dp2_b,
      (const bf16*)dp3_w, (const bf16*)dp3_b, (const bf16*)emb2_b, P1z, P2z, gC, eabuf, attr, zd, zs);
}

// ---------------- TNE node: NB nodes/block, packed weights ----------------
template<typename T>
__device__ __forceinline__ void tne_node_impl(
  const int* offsets, const int* csr, const float* gV, const bf16* eabuf,
  const T* ln_g, const T* ln_b,
  const float2* ltp,            // packed tne_lt (3 matrices: +0, +8192, +16384)
  const T* s0_w, const T* s0_b,
  const float2* s1P, const float* s1Q, const T* s1_b, float* X9,
  float (*sm)[10][128], float* red, float (*lnv)[128], float (*h1s)[256])
{
  int n0 = blockIdx.x*NB, h = threadIdx.x;
  float tnv[NB];
  #pragma unroll
  for (int nn=0;nn<NB;++nn){
    int n = n0+nn;
    float a=0, v0=0,v1=0,v2=0, s0=0,s1=0,s2=0,s3=0,s4=0,s5=0;
    int beg = offsets[n], end = offsets[n+1];
    for (int i=beg;i<end;++i){
      int e = csr[i];
      const bf16* p = eabuf + (size_t)e*384;
      float c1 = b2f(p[h]), c2 = b2f(p[128+h]), c3 = b2f(p[256+h]);
      float vx = gV[e*3+0], vy = gV[e*3+1], vz = gV[e*3+2];
      float tr3 = (vx*vx+vy*vy+vz*vz)*(1.0f/3.0f);
      a  += c1;
      v0 += c2*vx; v1 += c2*vy; v2 += c2*vz;
      s0 += c3*(vx*vx - tr3); s1 += c3*vx*vy;          s2 += c3*vx*vz;
      s3 += c3*(vy*vy - tr3); s4 += c3*vy*vz;          s5 += c3*(vz*vz - tr3);
    }
    sm[nn][0][h]=a; sm[nn][1][h]=v0; sm[nn][2][h]=v1; sm[nn][3][h]=v2;
    sm[nn][4][h]=s0; sm[nn][5][h]=s1; sm[nn][6][h]=s2; sm[nn][7][h]=s3; sm[nn][8][h]=s4; sm[nn][9][h]=s5;
    tnv[nn] = 3.0f*a*a + 2.0f*(v0*v0+v1*v1+v2*v2)
            + s0*s0 + s3*s3 + s5*s5 + 2.0f*(s1*s1 + s2*s2 + s4*s4);
  }
  float gg = ldf(ln_g,h), bb = ldf(ln_b,h);
  #pragma unroll
  for (int nn=0;nn<NB;++nn){
    __syncthreads();
    red[h] = tnv[nn]; __syncthreads();
    for (int off=64; off>=1; off>>=1){ if (h<off) red[h]+=red[h+off]; __syncthreads(); }
    float mean = red[0]*(1.0f/128.0f);
    __syncthreads();
    float dm = tnv[nn] - mean;
    red[h] = dm*dm; __syncthreads();
    for (int off=64; off>=1; off>>=1){ if (h<off) red[h]+=red[h+off]; __syncthreads(); }
    float var = red[0]*(1.0f/128.0f);
    lnv[nn][h] = dm*rsqrtf(var+1e-5f)*gg + bb;
  }
  __syncthreads();
  // fsc stage 1: 128 -> 256 (cols 2h, 2h+1)
  {
    float ba = ldf(s0_b,2*h), bc = ldf(s0_b,2*h+1);
    float a0[NB], a1[NB];
    #pragma unroll
    for (int nn=0;nn<NB;++nn){ a0[nn]=ba; a1[nn]=bc; }
    for (int r=0;r<128;++r){
      float u0, u1;
      if constexpr (sizeof(T)==4){
        float2 u = *reinterpret_cast<const float2*>((const float*)s0_w + (size_t)r*256 + 2*h);
        u0 = u.x; u1 = u.y;
      } else {
        u0 = ldf(s0_w,(size_t)r*256+2*h); u1 = ldf(s0_w,(size_t)r*256+2*h+1);
      }
      #pragma unroll
      for (int nn=0;nn<NB;++nn){ float x = lnv[nn][r]; a0[nn]+=x*u0; a1[nn]+=x*u1; }
    }
    #pragma unroll
    for (int nn=0;nn<NB;++nn){ h1s[nn][2*h] = siluf(a0[nn]); h1s[nn][2*h+1] = siluf(a1[nn]); }
  }
  __syncthreads();
  // fsc stage 2: 256 -> 384 via packed P/Q (same values, same order)
  float f0[NB], f1[NB], f2[NB];
  {
    float b0 = ldf(s1_b,3*h), b1 = ldf(s1_b,3*h+1), b2 = ldf(s1_b,3*h+2);
    #pragma unroll
    for (int nn=0;nn<NB;++nn){ f0[nn]=b0; f1[nn]=b1; f2[nn]=b2; }
    for (int r=0;r<256;++r){
      float2 p = s1P[(size_t)r*128+h];
      float  q = s1Q[(size_t)r*128+h];
      #pragma unroll
      for (int nn=0;nn<NB;++nn){ float x = h1s[nn][r]; f0[nn]+=x*p.x; f1[nn]+=x*p.y; f2[nn]+=x*q; }
    }
    #pragma unroll
    for (int nn=0;nn<NB;++nn){ f0[nn]=siluf(f0[nn]); f1[nn]=siluf(f1[nn]); f2[nn]=siluf(f2[nn]); }
  }
  // cmix batched over NB nodes, k-pair packed weights (exact order: .x add then .y add)
  float am[NB]={0};
  float wm0[NB]={0}, wm1[NB]={0}, wm2[NB]={0};
  float t0[NB]={0}, t1[NB]={0}, t2[NB]={0};
  float t3[NB]={0}, t4[NB]={0}, t5[NB]={0};
  for (int r2=0;r2<64;++r2){
    float2 w0 = ltp[(size_t)r2*128+h];
    float2 w1 = ltp[(size_t)8192 + r2*128+h];
    float2 w2 = ltp[(size_t)16384 + r2*128+h];
    #pragma unroll
    for (int nn=0;nn<NB;++nn){
      float2 c0 = *reinterpret_cast<const float2*>(&sm[nn][0][2*r2]);
      am[nn]  += c0.x*w0.x; am[nn]  += c0.y*w0.y;
      float2 c1 = *reinterpret_cast<const float2*>(&sm[nn][1][2*r2]);
      wm0[nn] += c1.x*w1.x; wm0[nn] += c1.y*w1.y;
      float2 c2 = *reinterpret_cast<const float2*>(&sm[nn][2][2*r2]);
      wm1[nn] += c2.x*w1.x; wm1[nn] += c2.y*w1.y;
      float2 c3 = *reinterpret_cast<const float2*>(&sm[nn][3][2*r2]);
      wm2[nn] += c3.x*w1.x; wm2[nn] += c3.y*w1.y;
      float2 c4 = *reinterpret_cast<const float2*>(&sm[nn][4][2*r2]);
      t0[nn] += c4.x*w2.x; t0[nn] += c4.y*w2.y;
      float2 c5 = *reinterpret_cast<const float2*>(&sm[nn][5][2*r2]);
      t1[nn] += c5.x*w2.x; t1[nn] += c5.y*w2.y;
      float2 c6 = *reinterpret_cast<const float2*>(&sm[nn][6][2*r2]);
      t2[nn] += c6.x*w2.x; t2[nn] += c6.y*w2.y;
      float2 c7 = *reinterpret_cast<const float2*>(&sm[nn][7][2*r2]);
      t3[nn] += c7.x*w2.x; t3[nn] += c7.y*w2.y;
      float2 c8 = *reinterpret_cast<const float2*>(&sm[nn][8][2*r2]);
      t4[nn] += c8.x*w2.x; t4[nn] += c8.y*w2.y;
      float2 c9 = *reinterpret_cast<const float2*>(&sm[nn][9][2*r2]);
      t5[nn] += c9.x*w2.x; t5[nn] += c9.y*w2.y;
    }
  }
  #pragma unroll
  for (int nn=0;nn<NB;++nn){
    float x00 = f0[nn]*am[nn] + f2[nn]*t0[nn];
    float x01 = -f1[nn]*wm2[nn] + f2[nn]*t1[nn];
    float x02 =  f1[nn]*wm1[nn] + f2[nn]*t2[nn];
    float x10 =  f1[nn]*wm2[nn] + f2[nn]*t1[nn];
    float x11 = f0[nn]*am[nn] + f2[nn]*t3[nn];
    float x12 = -f1[nn]*wm0[nn] + f2[nn]*t4[nn];
    float x20 = -f1[nn]*wm1[nn] + f2[nn]*t2[nn];
    float x21 =  f1[nn]*wm0[nn] + f2[nn]*t4[nn];
    float x22 = f0[nn]*am[nn] + f2[nn]*t5[nn];
    float* xp = X9 + (size_t)(n0+nn)*1152;
    xp[0*128+h]=x00; xp[1*128+h]=x01; xp[2*128+h]=x02;
    xp[3*128+h]=x10; xp[4*128+h]=x11; xp[5*128+h]=x12;
    xp[6*128+h]=x20; xp[7*128+h]=x21; xp[8*128+h]=x22;
  }
}
__global__ void __launch_bounds__(128) k_tne_node(
  const int* __restrict__ offsets, const int* __restrict__ csr,
  const float* __restrict__ gV, const bf16* __restrict__ eabuf,
  const void* ln_g, const void* ln_b, const float2* __restrict__ ltp,
  const void* s0_w, const void* s0_b,
  const float2* __restrict__ s1P, const float* __restrict__ s1Q, const void* s1_b,
  float* __restrict__ X9, const int* __restrict__ flag)
{
  __shared__ float sm[NB][10][128];
  __shared__ float red[128];
  __shared__ float lnv[NB][128];
  __shared__ float h1s[NB][256];
  if (flag[0]) tne_node_impl<float>(offsets, csr, gV, eabuf,
      (const float*)ln_g, (const float*)ln_b, ltp,
      (const float*)s0_w, (const float*)s0_b, s1P, s1Q, (const float*)s1_b, X9, sm, red, lnv, h1s);
  else tne_node_impl<bf16>(offsets, csr, gV, eabuf,
      (const bf16*)ln_g, (const bf16*)ln_b, ltp,
      (const bf16*)s0_w, (const bf16*)s0_b, s1P, s1Q, (const bf16*)s1_b, X9, sm, red, lnv, h1s);
}

// ---------------- msg edge MLP via MFMA (r10-validated, untouched) ----------------
template<typename T>
__device__ __forceinline__ void mfma_impl(
  const unsigned short* eattr_c, const float* gC,
  const unsigned short* p0, const unsigned short* p1, const unsigned short* p2,
  const T* b0, const T* b1, const T* b2,
  unsigned short* eabuf, unsigned short (*h1p)[2048], unsigned short (*h2p)[4096])
{
  int wid  = threadIdx.x >> 6;
  int lane = threadIdx.x & 63;
  int e0 = blockIdx.x*32 + wid*16;
  int m = lane & 15, g = lane >> 4;
  float cc[4];
  #pragma unroll
  for (int r=0;r<4;++r) cc[r] = gC[e0 + g*4 + r];
  short8v a1 = *reinterpret_cast<const short8v*>(eattr_c + (size_t)(e0+m)*32 + g*8);
  #pragma unroll
  for (int nt=0; nt<8; ++nt){
    float bias = ldf(b0, nt*16+m);
    f32x4 acc = {bias,bias,bias,bias};
    short8v b = *reinterpret_cast<const short8v*>(p0 + ((size_t)nt*64 + lane)*8);
    acc = __builtin_amdgcn_mfma_f32_16x16x32_bf16(a1, b, acc, 0,0,0);
    #pragma unroll
    for (int r=0;r<4;++r){
      int n = nt*16 + m, row = g*4 + r;
      h1p[wid][(n>>5)*512 + (((n>>3)&3)*16+row)*8 + (n&7)] = f2bu(siluf(acc[r]));
    }
  }
  __syncthreads();
  short8v a2[4];
  #pragma unroll
  for (int ks=0; ks<4; ++ks) a2[ks] = *reinterpret_cast<const short8v*>(&h1p[wid][ks*512 + lane*8]);
  for (int nt=0; nt<16; ++nt){
    float bias = ldf(b1, nt*16+m);
    f32x4 acc = {bias,bias,bias,bias};
    #pragma unroll
    for (int ks=0; ks<4; ++ks){
      short8v b = *reinterpret_cast<const short8v*>(p1 + ((size_t)(nt*4+ks)*64 + lane)*8);
      acc = __builtin_amdgcn_mfma_f32_16x16x32_bf16(a2[ks], b, acc, 0,0,0);
    }
    #pragma unroll
    for (int r=0;r<4;++r){
      int n = nt*16 + m, row = g*4 + r;
      h2p[wid][(n>>5)*512 + (((n>>3)&3)*16+row)*8 + (n&7)] = f2bu(siluf(acc[r]));
    }
  }
  __syncthreads();
  short8v a3[8];
  #pragma unroll
  for (int ks=0; ks<8; ++ks) a3[ks] = *reinterpret_cast<const short8v*>(&h2p[wid][ks*512 + lane*8]);
  for (int nt=0; nt<24; ++nt){
    float bias = ldf(b2, nt*16+m);
    f32x4 acc = {bias,bias,bias,bias};
    #pragma unroll
    for (int ks=0; ks<8; ++ks){
      short8v b = *reinterpret_cast<const short8v*>(p2 + ((size_t)(nt*8+ks)*64 + lane)*8);
      acc = __builtin_amdgcn_mfma_f32_16x16x32_bf16(a3[ks], b, acc, 0,0,0);
    }
    #pragma unroll
    for (int r=0;r<4;++r){
      int n = nt*16 + m, row = g*4 + r;
      float v = siluf(acc[r]) * cc[r];
      eabuf[(size_t)(e0+row)*384 + (n%3)*128 + (n/3)] = f2bu(v);
    }
  }
}
__global__ void __launch_bounds__(128) k_msg_edge_mfma(
  const unsigned short* __restrict__ eattr_c, const float* __restrict__ gC,
  const unsigned short* __restrict__ p0, const unsigned short* __restrict__ p1,
  const unsigned short* __restrict__ p2,
  const void* b0, const void* b1, const void* b2, long boff0, long boff1, long boff2,
  unsigned short* __restrict__ eabuf, const int* __restrict__ flag)
{
  __shared__ __align__(16) unsigned short h1p[2][2048];
  __shared__ __align__(16) unsigned short h2p[2][4096];
  if (flag[0]) mfma_impl<float>(eattr_c, gC, p0, p1, p2,
      (const float*)b0 + boff0, (const float*)b1 + boff1, (const float*)b2 + boff2, eabuf, h1p, h2p);
  else mfma_impl<bf16>(eattr_c, gC, p0, p1, p2,
      (const bf16*)b0 + boff0, (const bf16*)b1 + boff1, (const bf16*)b2 + boff2, eabuf, h1p, h2p);
}

// ---------------- msg node prep (NB nodes/block, packed lx) ----------------
__device__ __forceinline__ void prep_impl(
  float* X9, const float2* lxp, bf16* Y10, float (*sm)[10][128])
{
  int n0 = blockIdx.x*NB, h = threadIdx.x;
  #pragma unroll
  for (int nn=0;nn<NB;++nn){
    float* xp = X9 + (size_t)(n0+nn)*1152;
    float x00=xp[0*128+h], x01=xp[1*128+h], x02=xp[2*128+h];
    float x10=xp[3*128+h], x11=xp[4*128+h], x12=xp[5*128+h];
    float x20=xp[6*128+h], x21=xp[7*128+h], x22=xp[8*128+h];
    float tn = x00*x00+x01*x01+x02*x02+x10*x10+x11*x11+x12*x12+x20*x20+x21*x21+x22*x22;
    float inv = 1.0f/(tn+1.0f);
    x00*=inv; x01*=inv; x02*=inv; x10*=inv; x11*=inv; x12*=inv; x20*=inv; x21*=inv; x22*=inv;
    // Reference REBINDS X to normalized before the update (r3 fix).
    xp[0*128+h]=x00; xp[1*128+h]=x01; xp[2*128+h]=x02;
    xp[3*128+h]=x10; xp[4*128+h]=x11; xp[5*128+h]=x12;
    xp[6*128+h]=x20; xp[7*128+h]=x21; xp[8*128+h]=x22;
    float a = (x00+x11+x22)*(1.0f/3.0f);
    sm[nn][0][h]=a;
    sm[nn][1][h]=0.5f*(x21-x12);
    sm[nn][2][h]=0.5f*(x02-x20);
    sm[nn][3][h]=0.5f*(x10-x01);
    sm[nn][4][h]=x00-a;
    sm[nn][5][h]=0.5f*(x01+x10);
    sm[nn][6][h]=0.5f*(x02+x20);
    sm[nn][7][h]=x11-a;
    sm[nn][8][h]=0.5f*(x12+x21);
    sm[nn][9][h]=x22-a;
  }
  __syncthreads();
  float A[NB]={0};
  float V0[NB]={0}, V1[NB]={0}, V2[NB]={0};
  float S0[NB]={0}, S1[NB]={0}, S2[NB]={0};
  float S3[NB]={0}, S4[NB]={0}, S5[NB]={0};
  for (int r2=0;r2<64;++r2){
    float2 w0 = lxp[(size_t)r2*128+h];
    float2 w1 = lxp[(size_t)8192 + r2*128+h];
    float2 w2 = lxp[(size_t)16384 + r2*128+h];
    #pragma unroll
    for (int nn=0;nn<NB;++nn){
      float2 c0 = *reinterpret_cast<const float2*>(&sm[nn][0][2*r2]);
      A[nn]  += c0.x*w0.x; A[nn]  += c0.y*w0.y;
      float2 c1 = *reinterpret_cast<const float2*>(&sm[nn][1][2*r2]);
      V0[nn] += c1.x*w1.x; V0[nn] += c1.y*w1.y;
      float2 c2 = *reinterpret_cast<const float2*>(&sm[nn][2][2*r2]);
      V1[nn] += c2.x*w1.x; V1[nn] += c2.y*w1.y;
      float2 c3 = *reinterpret_cast<const float2*>(&sm[nn][3][2*r2]);
      V2[nn] += c3.x*w1.x; V2[nn] += c3.y*w1.y;
      float2 c4 = *reinterpret_cast<const float2*>(&sm[nn][4][2*r2]);
      S0[nn] += c4.x*w2.x; S0[nn] += c4.y*w2.y;
      float2 c5 = *reinterpret_cast<const float2*>(&sm[nn][5][2*r2]);
      S1[nn] += c5.x*w2.x; S1[nn] += c5.y*w2.y;
      float2 c6 = *reinterpret_cast<const float2*>(&sm[nn][6][2*r2]);
      S2[nn] += c6.x*w2.x; S2[nn] += c6.y*w2.y;
      float2 c7 = *reinterpret_cast<const float2*>(&sm[nn][7][2*r2]);
      S3[nn] += c7.x*w2.x; S3[nn] += c7.y*w2.y;
      float2 c8 = *reinterpret_cast<const float2*>(&sm[nn][8][2*r2]);
      S4[nn] += c8.x*w2.x; S4[nn] += c8.y*w2.y;
      float2 c9 = *reinterpret_cast<const float2*>(&sm[nn][9][2*r2]);
      S5[nn] += c9.x*w2.x; S5[nn] += c9.y*w2.y;
    }
  }
  #pragma unroll
  for (int nn=0;nn<NB;++nn){
    bf16* yp = Y10 + (size_t)(n0+nn)*1280;
    yp[0*128+h]=__float2bfloat16(A[nn]);
    yp[1*128+h]=__float2bfloat16(V0[nn]); yp[2*128+h]=__float2bfloat16(V1[nn]); yp[3*128+h]=__float2bfloat16(V2[nn]);
    yp[4*128+h]=__float2bfloat16(S0[nn]); yp[5*128+h]=__float2bfloat16(S1[nn]); yp[6*128+h]=__float2bfloat16(S2[nn]);
    yp[7*128+h]=__float2bfloat16(S3[nn]); yp[8*128+h]=__float2bfloat16(S4[nn]); yp[9*128+h]=__float2bfloat16(S5[nn]);
  }
}
__global__ void __launch_bounds__(128) k_msg_prep(
  float* __restrict__ X9, const float2* __restrict__ lxp, bf16* __restrict__ Y10)
{
  __shared__ float sm[NB][10][128];
  prep_impl(X9, lxp, Y10, sm);
}

// ---------------- msg scatter+AB+decompose + packed lt cmix + dX update ----------------
template<typename T>
__device__ __forceinline__ void sf_impl(
  const int* offsets, const int* csr, const int* srcA,
  const bf16* eabuf, const bf16* Y10, const float2* ltp,
  float* X9, T* out, int write_out, float (*sm)[10][128])
{
  int n0 = blockIdx.x*NB, h = threadIdx.x;
  #pragma unroll
  for (int nn=0;nn<NB;++nn){
    int n = n0+nn;
    float am=0, vm0=0,vm1=0,vm2=0, smm0=0,smm1=0,smm2=0,smm3=0,smm4=0,smm5=0;
    int beg = offsets[n], end = offsets[n+1];
    for (int i=beg;i<end;++i){
      int e = csr[i]; int s = srcA[e];
      const bf16* ep = eabuf + (size_t)e*384;
      float e0 = b2f(ep[h]), e1 = b2f(ep[128+h]), e2 = b2f(ep[256+h]);
      const bf16* yp = Y10 + (size_t)s*1280;
      am   += e0*b2f(yp[0*128+h]);
      vm0  += e1*b2f(yp[1*128+h]); vm1 += e1*b2f(yp[2*128+h]); vm2 += e1*b2f(yp[3*128+h]);
      smm0 += e2*b2f(yp[4*128+h]); smm1 += e2*b2f(yp[5*128+h]); smm2 += e2*b2f(yp[6*128+h]);
      smm3 += e2*b2f(yp[7*128+h]); smm4 += e2*b2f(yp[8*128+h]); smm5 += e2*b2f(yp[9*128+h]);
    }
    const bf16* yp = Y10 + (size_t)n*1280;
    float aY=b2f(yp[0*128+h]), u0=b2f(yp[1*128+h]), u1=b2f(yp[2*128+h]), u2=b2f(yp[3*128+h]);
    float q0=b2f(yp[4*128+h]), q1=b2f(yp[5*128+h]), q2=b2f(yp[6*128+h]);
    float q3=b2f(yp[7*128+h]), q4=b2f(yp[8*128+h]), q5=b2f(yp[9*128+h]);
    float m00=am+smm0,   m01=-vm2+smm1, m02= vm1+smm2;
    float m10= vm2+smm1, m11=am+smm3,  m12=-vm0+smm4;
    float m20=-vm1+smm2, m21= vm0+smm4, m22=am+smm5;
    float y00=aY+q0,  y01=-u2+q1, y02= u1+q2;
    float y10= u2+q1, y11=aY+q3,  y12=-u0+q4;
    float y20=-u1+q2, y21= u0+q4, y22=aY+q5;
    float ab00 = m00*y00+m01*y10+m02*y20 + y00*m00+y01*m10+y02*m20;
    float ab01 = m00*y01+m01*y11+m02*y21 + y00*m01+y01*m11+y02*m21;
    float ab02 = m00*y02+m01*y12+m02*y22 + y00*m02+y01*m12+y02*m22;
    float ab10 = m10*y00+m11*y10+m12*y20 + y10*m00+y11*m10+y12*m20;
    float ab11 = m10*y01+m11*y11+m12*y21 + y10*m01+y11*m11+y12*m21;
    float ab12 = m10*y02+m11*y12+m12*y22 + y10*m02+y11*m12+y12*m22;
    float ab20 = m20*y00+m21*y10+m22*y20 + y20*m00+y21*m10+y22*m20;
    float ab21 = m20*y01+m21*y11+m22*y21 + y20*m01+y21*m11+y22*m21;
    float ab22 = m20*y02+m21*y12+m22*y22 + y20*m02+y21*m12+y22*m22;
    float a2 = (ab00+ab11+ab22)*(1.0f/3.0f);
    float w0 = 0.5f*(ab21-ab12), w1 = 0.5f*(ab02-ab20), w2 = 0.5f*(ab10-ab01);
    float t0 = ab00-a2, t1 = 0.5f*(ab01+ab10), t2 = 0.5f*(ab02+ab20);
    float t3 = ab11-a2, t4 = 0.5f*(ab12+ab21), t5 = ab22-a2;
    float dnm = ab00*ab00+ab01*ab01+ab02*ab02+ab10*ab10+ab11*ab11+ab12*ab12
              + ab20*ab20+ab21*ab21+ab22*ab22 + 1.0f;
    float inv = 1.0f/dnm;
    sm[nn][0][h]=a2*inv; sm[nn][1][h]=w0*inv; sm[nn][2][h]=w1*inv; sm[nn][3][h]=w2*inv;
    sm[nn][4][h]=t0*inv; sm[nn][5][h]=t1*inv; sm[nn][6][h]=t2*inv;
    sm[nn][7][h]=t3*inv; sm[nn][8][h]=t4*inv; sm[nn][9][h]=t5*inv;
  }
  __syncthreads();
  float at[NB]={0};
  float vt0[NB]={0}, vt1[NB]={0}, vt2[NB]={0};
  float st0[NB]={0}, st1[NB]={0}, st2[NB]={0};
  float st3[NB]={0}, st4[NB]={0}, st5[NB]={0};
  for (int r2=0;r2<64;++r2){
    float2 ww0 = ltp[(size_t)r2*128+h];
    float2 ww1 = ltp[(size_t)8192 + r2*128+h];
    float2 ww2 = ltp[(size_t)16384 + r2*128+h];
    #pragma unroll
    for (int nn=0;nn<NB;++nn){
      float2 c0 = *reinterpret_cast<const float2*>(&sm[nn][0][2*r2]);
      at[nn]  += c0.x*ww0.x; at[nn]  += c0.y*ww0.y;
      float2 c1 = *reinterpret_cast<const float2*>(&sm[nn][1][2*r2]);
      vt0[nn] += c1.x*ww1.x; vt0[nn] += c1.y*ww1.y;
      float2 c2 = *reinterpret_cast<const float2*>(&sm[nn][2][2*r2]);
      vt1[nn] += c2.x*ww1.x; vt1[nn] += c2.y*ww1.y;
      float2 c3 = *reinterpret_cast<const float2*>(&sm[nn][3][2*r2]);
      vt2[nn] += c3.x*ww1.x; vt2[nn] += c3.y*ww1.y;
      float2 c4 = *reinterpret_cast<const float2*>(&sm[nn][4][2*r2]);
      st0[nn] += c4.x*ww2.x; st0[nn] += c4.y*ww2.y;
      float2 c5 = *reinterpret_cast<const float2*>(&sm[nn][5][2*r2]);
      st1[nn] += c5.x*ww2.x; st1[nn] += c5.y*ww2.y;
      float2 c6 = *reinterpret_cast<const float2*>(&sm[nn][6][2*r2]);
      st2[nn] += c6.x*ww2.x; st2[nn] += c6.y*ww2.y;
      float2 c7 = *reinterpret_cast<const float2*>(&sm[nn][7][2*r2]);
      st3[nn] += c7.x*ww2.x; st3[nn] += c7.y*ww2.y;
      float2 c8 = *reinterpret_cast<const float2*>(&sm[nn][8][2*r2]);
      st4[nn] += c8.x*ww2.x; st4[nn] += c8.y*ww2.y;
      float2 c9 = *reinterpret_cast<const float2*>(&sm[nn][9][2*r2]);
      st5[nn] += c9.x*ww2.x; st5[nn] += c9.y*ww2.y;
    }
  }
  #pragma unroll
  for (int nn=0;nn<NB;++nn){
    int n = n0+nn;
    float d00=at[nn]+st0[nn],   d01=-vt2[nn]+st1[nn], d02= vt1[nn]+st2[nn];
    float d10= vt2[nn]+st1[nn], d11=at[nn]+st3[nn],  d12=-vt0[nn]+st4[nn];
    float d20=-vt1[nn]+st2[nn], d21= vt0[nn]+st4[nn], d22=at[nn]+st5[nn];
    float g00 = d00 + d00*d00+d01*d10+d02*d20;
    float g01 = d01 + d00*d01+d01*d11+d02*d21;
    float g02 = d02 + d00*d02+d01*d12+d02*d22;
    float g10 = d10 + d10*d00+d11*d10+d12*d20;
    float g11 = d11 + d10*d01+d11*d11+d12*d21;
    float g12 = d12 + d10*d02+d11*d12+d12*d22;
    float g20 = d20 + d20*d00+d21*d10+d22*d20;
    float g21 = d21 + d20*d01+d21*d11+d22*d21;
    float g22 = d22 + d20*d02+d21*d12+d22*d22;
    float* xp = X9 + (size_t)n*1152;
    float x00=xp[0*128+h]+g00, x01=xp[1*128+h]+g01, x02=xp[2*128+h]+g02;
    float x10=xp[3*128+h]+g10, x11=xp[4*128+h]+g11, x12=xp[5*128+h]+g12;
    float x20=xp[6*128+h]+g20, x21=xp[7*128+h]+g21, x22=xp[8*128+h]+g22;
    if (write_out){
      if (sizeof(T)==4){
        float* of = (float*)out + ((size_t)n*128 + h)*9;
        of[0]=x00; of[1]=x01; of[2]=x02; of[3]=x10; of[4]=x11; of[5]=x12; of[6]=x20; of[7]=x21; of[8]=x22;
      } else {
        bf16* ob = (bf16*)out + ((size_t)n*128 + h)*9;
        ob[0]=__float2bfloat16(x00); ob[1]=__float2bfloat16(x01); ob[2]=__float2bfloat16(x02);
        ob[3]=__float2bfloat16(x10); ob[4]=__float2bfloat16(x11); ob[5]=__float2bfloat16(x12);
        ob[6]=__float2bfloat16(x20); ob[7]=__float2bfloat16(x21); ob[8]=__float2bfloat16(x22);
      }
    } else {
      xp[0*128+h]=x00; xp[1*128+h]=x01; xp[2*128+h]=x02;
      xp[3*128+h]=x10; xp[4*128+h]=x11; xp[5*128+h]=x12;
      xp[6*128+h]=x20; xp[7*128+h]=x21; xp[8*128+h]=x22;
    }
  }
}
__global__ void __launch_bounds__(128) k_msg_sf(
  const int* __restrict__ offsets, const int* __restrict__ csr, const int* __restrict__ srcA,
  const bf16* __restrict__ eabuf, const bf16* __restrict__ Y10,
  const float2* __restrict__ ltp, float* __restrict__ X9, void* __restrict__ out,
  const int* __restrict__ flag, int write_out)
{
  __shared__ float sm[NB][10][128];
  if (flag[0]) sf_impl<float>(offsets, csr, srcA, eabuf, Y10, ltp, X9, (float*)out, write_out, sm);
  else         sf_impl<bf16 >(offsets, csr, srcA, eabuf, Y10, ltp, X9, (bf16* )out, write_out, sm);
}

extern "C" void kernel_launch(void* const* d_in, const int* in_sizes, int n_in,
                              void* d_out, int out_size, void* d_ws, size_t ws_size,
                              hipStream_t stream)
{
  (void)in_sizes; (void)n_in; (void)out_size; (void)ws_size;
  const int* z    = (const int*)d_in[0];
  const int* eidx = (const int*)d_in[1];
  const int* src  = eidx;
  const int* dst  = eidx + NE;

  // Workspace: ~59.5 MiB (proven budget >= 74 MiB).
  char* w = (char*)d_ws;
  int* flag    = (int*)w;   w += 64;
  int* counts  = (int*)w;   w += (size_t)NN*4;
  int* offsets = (int*)w;   w += (size_t)(NN+1)*4 + 60;
  int* cursor  = (int*)w;   w += (size_t)NN*4;
  int* csr     = (int*)w;   w += (size_t)NE*4;
  float* gC    = (float*)w; w += (size_t)NE*4;
  float* gV    = (float*)w; w += (size_t)NE*12;
  float* P1z   = (float*)w; w += (size_t)MAXZ*HH*4;
  float* P2z   = (float*)w; w += (size_t)MAXZ*HH*4;
  bf16* eabuf  = (bf16*)w;  w += (size_t)NE*384*2;
  float* X9    = (float*)w; w += (size_t)NN*1152*4;
  bf16* Y10    = (bf16*)w;  w += (size_t)NN*1280*2;
  unsigned short* eattr_c = (unsigned short*)w; w += (size_t)NE*32*2;
  unsigned short* pw0[2]; unsigned short* pw1[2]; unsigned short* pw2[2];
  for (int l=0;l<2;++l){
    pw0[l] = (unsigned short*)w; w += 8*64*8*2;
    pw1[l] = (unsigned short*)w; w += 64*64*8*2;
    pw2[l] = (unsigned short*)w; w += 192*64*8*2;
  }
  float2* cmixp = (float2*)w; w += (size_t)15*8192*8;   // 983 KB: 0-2 tne_lt, 3-8 lx, 9-14 lt
  float2* s1P   = (float2*)w; w += (size_t)256*128*8;   // 262 KB
  float*  s1Q   = (float*)w;  w += (size_t)256*128*4;   // 131 KB

  k_detect<<<1, 256, 0, stream>>>((const unsigned int*)d_in[4], flag);
  hipMemsetAsync(counts, 0, (size_t)NN*4, stream);
  k_count<<<NE/256, 256, 0, stream>>>(dst, counts);
  k_scan<<<1, 1024, 0, stream>>>(counts, offsets, cursor);
  k_fill<<<NE/256, 256, 0, stream>>>(dst, cursor, csr);
  k_geom<<<NE/256, 256, 0, stream>>>(d_in[2], d_in[3], src, dst, gC, gV, flag);
  k_zemb<<<MAXZ, 128, 0, stream>>>(d_in[5], d_in[12], P1z, P2z, flag);
  k_cvt_attr<<<NE*32/256, 256, 0, stream>>>(d_in[4], eattr_c, flag);
  k_packf2<<<dim3(32, 15), 256, 0, stream>>>(d_in[14], d_in[27], d_in[28], cmixp, flag);
  k_packs1<<<128, 256, 0, stream>>>(d_in[17], s1P, s1Q, flag);

  PackDescs pd;
  for (int l=0;l<2;++l){
    pd.base[l*3+0] = d_in[21]; pd.eoff[l*3+0] = (long)l*32*128;
    pd.base[l*3+1] = d_in[23]; pd.eoff[l*3+1] = (long)l*128*256;
    pd.base[l*3+2] = d_in[25]; pd.eoff[l*3+2] = (long)l*256*384;
    pd.out[l*3+0] = pw0[l]; pd.K[l*3+0]=32;  pd.N[l*3+0]=128;
    pd.out[l*3+1] = pw1[l]; pd.K[l*3+1]=128; pd.N[l*3+1]=256;
    pd.out[l*3+2] = pw2[l]; pd.K[l*3+2]=256; pd.N[l*3+2]=384;
  }
  k_pack<<<dim3(48, 6), 256, 0, stream>>>(pd, flag);

  k_tne_edge<<<NE/TPB, 128, 0, stream>>>(d_in[4], src, dst, z,
      d_in[6], d_in[7], d_in[8], d_in[9], d_in[10], d_in[11], d_in[13],
      P1z, P2z, gC, eabuf, flag);
  k_tne_node<<<NN/NB, 128, 0, stream>>>(offsets, csr, gV, eabuf,
      d_in[19], d_in[20], cmixp, d_in[15], d_in[16], s1P, s1Q, d_in[18], X9, flag);

  for (int l=0; l<2; ++l){
    k_msg_edge_mfma<<<NE/32, 128, 0, stream>>>(eattr_c, gC, pw0[l], pw1[l], pw2[l],
        d_in[22], d_in[24], d_in[26], (long)l*128, (long)l*256, (long)l*384,
        (unsigned short*)eabuf, flag);
    k_msg_prep<<<NN/NB, 128, 0, stream>>>(X9, cmixp + (size_t)(3 + l*3)*8192, Y10);
    k_msg_sf<<<NN/NB, 128, 0, stream>>>(offsets, csr, src, eabuf, Y10,
        cmixp + (size_t)(9 + l*3)*8192, X9, d_out, flag, (l==1)?1:0);
  }
}

// Round 14
// 454.109 us; speedup vs baseline: 1.0458x; 1.0458x over previous
//
#include <hip/hip_runtime.h>
#include <hip/hip_bf16.h>

typedef __hip_bfloat16 bf16;
typedef __attribute__((ext_vector_type(8))) short short8v;   // 8 bf16 = 4 VGPRs (MFMA A/B frag)
typedef __attribute__((ext_vector_type(4))) float f32x4;     // MFMA C/D frag

#define NN 4096
#define NE 32768
#define HH 128
#define MAXZ 100
#define TPB 8    // edges per block, TNE edge kernel
#define NB 2     // nodes per block in node-side kernels (grid 2048 = 8 blocks/CU)

// ENVIRONMENT FACTS (r0-r13): float tensors are FLOAT32; runtime detector kept.
// MFMA msg-edge path hardware-validated r10. NB=2 best (r11/r12).
// r13 lesson: node kernels are LATENCY-bound on the CSR eabuf gather (36.5MB at
// 317GB/s, VALUBusy<50%), NOT weight-issue-bound — float2 weight packing reverted.
// r14: 4-edge-unrolled gathers (same FP order => absmax must stay 0.00206089).

__device__ __forceinline__ float b2f(bf16 v){ return __bfloat162float(v); }
__device__ __forceinline__ float ldf(const float* p, size_t i){ return p[i]; }
__device__ __forceinline__ float ldf(const bf16*  p, size_t i){ return __bfloat162float(p[i]); }
__device__ __forceinline__ float siluf(float x){ return x / (1.0f + __expf(-x)); }
__device__ __forceinline__ unsigned short f2bu(float x){
  bf16 h = __float2bfloat16(x);
  return *reinterpret_cast<unsigned short*>(&h);
}

// dtype detect: flag[0]=1 if float inputs are f32, 0 if bf16.
__global__ void __launch_bounds__(256) k_detect(const unsigned int* __restrict__ w, int* __restrict__ flag){
  __shared__ int cnt[256];
  int t = threadIdx.x;
  int c = 0;
  for (int i = t; i < 4096; i += 256){
    unsigned int lo = w[i] & 0xffffu;
    int e = (int)((lo >> 7) & 0xffu);
    c += (e >= 110 && e <= 132) ? 1 : 0;
  }
  cnt[t] = c; __syncthreads();
  for (int off=128; off>=1; off>>=1){ if (t<off) cnt[t]+=cnt[t+off]; __syncthreads(); }
  if (t==0) flag[0] = (cnt[0] < 2048) ? 1 : 0;
}

// ---------------- CSR build ----------------
__global__ void __launch_bounds__(256) k_count(const int* __restrict__ dst, int* __restrict__ counts){
  int e = blockIdx.x*256 + threadIdx.x;
  if (e < NE) atomicAdd(&counts[dst[e]], 1);
}

__global__ void __launch_bounds__(1024) k_scan(const int* __restrict__ counts, int* __restrict__ offsets, int* __restrict__ cursor){
  __shared__ int lds[1024];
  int t = threadIdx.x;
  int c0 = counts[4*t+0], c1 = counts[4*t+1], c2 = counts[4*t+2], c3 = counts[4*t+3];
  int s1 = c0+c1, s2 = s1+c2, s3 = s2+c3;
  lds[t] = s3;
  __syncthreads();
  for (int off=1; off<1024; off<<=1){
    int v = lds[t];
    int add = (t>=off)? lds[t-off] : 0;
    __syncthreads();
    lds[t] = v + add;
    __syncthreads();
  }
  int incl = lds[t];
  int base = incl - s3;
  offsets[4*t+0]=base;    offsets[4*t+1]=base+c0; offsets[4*t+2]=base+s1; offsets[4*t+3]=base+s2;
  cursor [4*t+0]=base;    cursor [4*t+1]=base+c0; cursor [4*t+2]=base+s1; cursor [4*t+3]=base+s2;
  if (t==1023) offsets[4096]=incl;
}

__global__ void __launch_bounds__(256) k_fill(const int* __restrict__ dst, int* __restrict__ cursor, int* __restrict__ csr){
  int e = blockIdx.x*256 + threadIdx.x;
  if (e < NE){ int p = atomicAdd(&cursor[dst[e]], 1); csr[p] = e; }
}

// ---------------- edge geometry ----------------
template<typename T>
__device__ __forceinline__ void geom_impl(const T* ew, const T* evec,
    const int* src, const int* dst, float* gC, float* gV){
  int e = blockIdx.x*256 + threadIdx.x;
  if (e >= NE) return;
  float d = ldf(ew, e);
  float c = 0.5f*(cosf(d*0.6283185307179586f)+1.0f);
  c = (d < 5.0f) ? c : 0.0f;
  gC[e] = c;
  float x = ldf(evec, (size_t)e*3+0), y = ldf(evec, (size_t)e*3+1), z = ldf(evec, (size_t)e*3+2);
  if (src[e] != dst[e]){
    float n = sqrtf(x*x+y*y+z*z);
    float inv = 1.0f/fmaxf(n, 1e-12f);
    x*=inv; y*=inv; z*=inv;
  }
  gV[e*3+0]=x; gV[e*3+1]=y; gV[e*3+2]=z;
}
__global__ void __launch_bounds__(256) k_geom(const void* ew, const void* evec,
    const int* __restrict__ src, const int* __restrict__ dst,
    float* __restrict__ gC, float* __restrict__ gV, const int* __restrict__ flag){
  if (flag[0]) geom_impl<float>((const float*)ew, (const float*)evec, src, dst, gC, gV);
  else         geom_impl<bf16 >((const bf16* )ew, (const bf16* )evec, src, dst, gC, gV);
}

// ---------------- per-z embedding products ----------------
template<typename T>
__device__ __forceinline__ void zemb_impl(const T* emb, const T* emb2_w,
    float* P1z, float* P2z, float* Zr){
  int zv = blockIdx.x, h = threadIdx.x;
  Zr[h] = ldf(emb, (size_t)zv*HH + h);
  __syncthreads();
  float p1=0.f, p2=0.f;
  for (int r=0;r<128;++r){
    float x = Zr[r];
    p1 += x*ldf(emb2_w, (size_t)r*HH+h);
    p2 += x*ldf(emb2_w, (size_t)(r+128)*HH+h);
  }
  P1z[zv*HH+h]=p1; P2z[zv*HH+h]=p2;
}
__global__ void __launch_bounds__(128) k_zemb(const void* emb, const void* emb2_w,
    float* __restrict__ P1z, float* __restrict__ P2z, const int* __restrict__ flag){
  __shared__ float Zr[128];
  if (flag[0]) zemb_impl<float>((const float*)emb, (const float*)emb2_w, P1z, P2z, Zr);
  else         zemb_impl<bf16 >((const bf16* )emb, (const bf16* )emb2_w, P1z, P2z, Zr);
}

// ---------------- convert edge_attr -> bf16 ----------------
__global__ void __launch_bounds__(256) k_cvt_attr(const void* in, unsigned short* __restrict__ out,
                                                  const int* __restrict__ flag){
  int i = blockIdx.x*256 + threadIdx.x;
  if (flag[0]) out[i] = f2bu(((const float*)in)[i]);
  else         out[i] = ((const unsigned short*)in)[i];
}

// ---------------- weight repack into MFMA B-fragment layout ----------------
struct PackDescs {
  const void*     base[6];
  long            eoff[6];
  unsigned short* out[6];
  int K[6]; int N[6];
};
template<typename T>
__device__ __forceinline__ void pack_impl(const PackDescs& d){
  int y = blockIdx.y;
  int K = d.K[y], N = d.N[y];
  int ktiles = K>>5, ntiles = N>>4;
  int total = ktiles*ntiles*64;
  int idx = blockIdx.x*256 + threadIdx.x;
  if (idx >= total) return;
  int lane = idx & 63, tile = idx >> 6;
  int kt = tile % ktiles, nt = tile / ktiles;
  const T* W = (const T*)d.base[y] + d.eoff[y];
  int n = nt*16 + (lane&15), k0 = kt*32 + (lane>>4)*8;
  unsigned int t[8];
  #pragma unroll
  for (int j=0;j<8;++j) t[j] = f2bu(ldf(W, (size_t)(k0+j)*N + n));
  uint4 v;
  v.x = t[0] | (t[1]<<16);
  v.y = t[2] | (t[3]<<16);
  v.z = t[4] | (t[5]<<16);
  v.w = t[6] | (t[7]<<16);
  *reinterpret_cast<uint4*>(d.out[y] + ((size_t)tile*64 + lane)*8) = v;
}
__global__ void __launch_bounds__(256) k_pack(PackDescs d, const int* __restrict__ flag){
  if (flag[0]) pack_impl<float>(d);
  else         pack_impl<bf16 >(d);
}

// ---------------- TNE edge coefficients -> eabuf bf16 [E][3][128] ----------------
template<typename T>
__device__ __forceinline__ void tne_edge_impl(
  const T* eattr, const int* src, const int* dst, const int* z,
  const T* dp1_w, const T* dp1_b, const T* dp2_w, const T* dp2_b,
  const T* dp3_w, const T* dp3_b, const T* emb2_b,
  const float* P1z, const float* P2z, const float* gC, bf16* eabuf,
  float (*attr)[32], int* zd, int* zs)
{
  int e0 = blockIdx.x*TPB;
  int h  = threadIdx.x;
  for (int i=h; i<TPB*32; i+=128) attr[i>>5][i&31] = ldf(eattr, (size_t)e0*32 + i);
  if (h < TPB){ int e=e0+h; zd[h]=z[dst[e]]; zs[h]=z[src[e]]; }
  __syncthreads();
  float w1[TPB], w2[TPB], w3[TPB];
  float b1v=ldf(dp1_b,h), b2v=ldf(dp2_b,h), b3v=ldf(dp3_b,h);
  #pragma unroll
  for (int e=0;e<TPB;++e){ w1[e]=b1v; w2[e]=b2v; w3[e]=b3v; }
  for (int r=0;r<32;++r){
    float u1=ldf(dp1_w,(size_t)r*HH+h), u2=ldf(dp2_w,(size_t)r*HH+h), u3=ldf(dp3_w,(size_t)r*HH+h);
    #pragma unroll
    for (int e=0;e<TPB;++e){ float a=attr[e][r]; w1[e]+=a*u1; w2[e]+=a*u2; w3[e]+=a*u3; }
  }
  float eb = ldf(emb2_b,h);
  #pragma unroll
  for (int e=0;e<TPB;++e){
    float zij = P1z[zd[e]*HH+h] + P2z[zs[e]*HH+h] + eb;
    float c = gC[e0+e];
    bf16* p = eabuf + (size_t)(e0+e)*384;
    p[h]     = __float2bfloat16(zij*w1[e]*c);
    p[128+h] = __float2bfloat16(zij*w2[e]*c);
    p[256+h] = __float2bfloat16(zij*w3[e]*c);
  }
}
__global__ void __launch_bounds__(128) k_tne_edge(
  const void* eattr, const int* __restrict__ src, const int* __restrict__ dst, const int* __restrict__ z,
  const void* dp1_w, const void* dp1_b, const void* dp2_w, const void* dp2_b,
  const void* dp3_w, const void* dp3_b, const void* emb2_b,
  const float* __restrict__ P1z, const float* __restrict__ P2z,
  const float* __restrict__ gC, bf16* __restrict__ eabuf, const int* __restrict__ flag)
{
  __shared__ float attr[TPB][32];
  __shared__ int zd[TPB], zs[TPB];
  if (flag[0]) tne_edge_impl<float>((const float*)eattr, src, dst, z,
      (const float*)dp1_w, (const float*)dp1_b, (const float*)dp2_w, (const float*)dp2_b,
      (const float*)dp3_w, (const float*)dp3_b, (const float*)emb2_b, P1z, P2z, gC, eabuf, attr, zd, zs);
  else tne_edge_impl<bf16>((const bf16*)eattr, src, dst, z,
      (const bf16*)dp1_w, (const bf16*)dp1_b, (const bf16*)dp2_w, (const bf16*)dp2_b,
      (const bf16*)dp3_w, (const bf16*)dp3_b, (const bf16*)emb2_b, P1z, P2z, gC, eabuf, attr, zd, zs);
}

// ---------------- TNE node: NB nodes/block, 4-edge-unrolled gather ----------------
template<typename T>
__device__ __forceinline__ void tne_node_impl(
  const int* offsets, const int* csr, const float* gV, const bf16* eabuf,
  const T* ln_g, const T* ln_b, const T* tne_lt,
  const T* s0_w, const T* s0_b, const T* s1_w, const T* s1_b, float* X9,
  float (*sm)[10][128], float* red, float (*lnv)[128], float (*h1s)[256])
{
  int n0 = blockIdx.x*NB, h = threadIdx.x;
  float tnv[NB];
  #pragma unroll
  for (int nn=0;nn<NB;++nn){
    int n = n0+nn;
    float a=0, v0=0,v1=0,v2=0, s0=0,s1=0,s2=0,s3=0,s4=0,s5=0;
    int beg = offsets[n], end = offsets[n+1];
    int i = beg;
    // 4-edge unroll: issue all 24 gather loads, then accumulate edge-by-edge
    // in the SAME serial order (bit-identical FP sequence).
    for (; i+4 <= end; i += 4){
      int ea[4];
      #pragma unroll
      for (int u=0;u<4;++u) ea[u] = csr[i+u];
      float c1[4],c2[4],c3[4],vx[4],vy[4],vz[4];
      #pragma unroll
      for (int u=0;u<4;++u){
        const bf16* p = eabuf + (size_t)ea[u]*384;
        c1[u]=b2f(p[h]); c2[u]=b2f(p[128+h]); c3[u]=b2f(p[256+h]);
        vx[u]=gV[ea[u]*3+0]; vy[u]=gV[ea[u]*3+1]; vz[u]=gV[ea[u]*3+2];
      }
      #pragma unroll
      for (int u=0;u<4;++u){
        float tr3 = (vx[u]*vx[u]+vy[u]*vy[u]+vz[u]*vz[u])*(1.0f/3.0f);
        a  += c1[u];
        v0 += c2[u]*vx[u]; v1 += c2[u]*vy[u]; v2 += c2[u]*vz[u];
        s0 += c3[u]*(vx[u]*vx[u] - tr3); s1 += c3[u]*vx[u]*vy[u]; s2 += c3[u]*vx[u]*vz[u];
        s3 += c3[u]*(vy[u]*vy[u] - tr3); s4 += c3[u]*vy[u]*vz[u]; s5 += c3[u]*(vz[u]*vz[u] - tr3);
      }
    }
    for (; i<end; ++i){
      int e = csr[i];
      const bf16* p = eabuf + (size_t)e*384;
      float c1 = b2f(p[h]), c2 = b2f(p[128+h]), c3 = b2f(p[256+h]);
      float vx = gV[e*3+0], vy = gV[e*3+1], vz = gV[e*3+2];
      float tr3 = (vx*vx+vy*vy+vz*vz)*(1.0f/3.0f);
      a  += c1;
      v0 += c2*vx; v1 += c2*vy; v2 += c2*vz;
      s0 += c3*(vx*vx - tr3); s1 += c3*vx*vy;          s2 += c3*vx*vz;
      s3 += c3*(vy*vy - tr3); s4 += c3*vy*vz;          s5 += c3*(vz*vz - tr3);
    }
    sm[nn][0][h]=a; sm[nn][1][h]=v0; sm[nn][2][h]=v1; sm[nn][3][h]=v2;
    sm[nn][4][h]=s0; sm[nn][5][h]=s1; sm[nn][6][h]=s2; sm[nn][7][h]=s3; sm[nn][8][h]=s4; sm[nn][9][h]=s5;
    tnv[nn] = 3.0f*a*a + 2.0f*(v0*v0+v1*v1+v2*v2)
            + s0*s0 + s3*s3 + s5*s5 + 2.0f*(s1*s1 + s2*s2 + s4*s4);
  }
  float gg = ldf(ln_g,h), bb = ldf(ln_b,h);
  #pragma unroll
  for (int nn=0;nn<NB;++nn){
    __syncthreads();
    red[h] = tnv[nn]; __syncthreads();
    for (int off=64; off>=1; off>>=1){ if (h<off) red[h]+=red[h+off]; __syncthreads(); }
    float mean = red[0]*(1.0f/128.0f);
    __syncthreads();
    float dm = tnv[nn] - mean;
    red[h] = dm*dm; __syncthreads();
    for (int off=64; off>=1; off>>=1){ if (h<off) red[h]+=red[h+off]; __syncthreads(); }
    float var = red[0]*(1.0f/128.0f);
    lnv[nn][h] = dm*rsqrtf(var+1e-5f)*gg + bb;
  }
  __syncthreads();
  {
    float ba = ldf(s0_b,2*h), bc = ldf(s0_b,2*h+1);
    float a0[NB], a1[NB];
    #pragma unroll
    for (int nn=0;nn<NB;++nn){ a0[nn]=ba; a1[nn]=bc; }
    for (int r=0;r<128;++r){
      float u0 = ldf(s0_w,(size_t)r*256+2*h), u1 = ldf(s0_w,(size_t)r*256+2*h+1);
      #pragma unroll
      for (int nn=0;nn<NB;++nn){ float x = lnv[nn][r]; a0[nn]+=x*u0; a1[nn]+=x*u1; }
    }
    #pragma unroll
    for (int nn=0;nn<NB;++nn){ h1s[nn][2*h] = siluf(a0[nn]); h1s[nn][2*h+1] = siluf(a1[nn]); }
  }
  __syncthreads();
  float f0[NB], f1[NB], f2[NB];
  {
    float b0 = ldf(s1_b,3*h), b1 = ldf(s1_b,3*h+1), b2 = ldf(s1_b,3*h+2);
    #pragma unroll
    for (int nn=0;nn<NB;++nn){ f0[nn]=b0; f1[nn]=b1; f2[nn]=b2; }
    for (int r=0;r<256;++r){
      float u0 = ldf(s1_w,(size_t)r*384+3*h), u1 = ldf(s1_w,(size_t)r*384+3*h+1), u2 = ldf(s1_w,(size_t)r*384+3*h+2);
      #pragma unroll
      for (int nn=0;nn<NB;++nn){ float x = h1s[nn][r]; f0[nn]+=x*u0; f1[nn]+=x*u1; f2[nn]+=x*u2; }
    }
    #pragma unroll
    for (int nn=0;nn<NB;++nn){ f0[nn]=siluf(f0[nn]); f1[nn]=siluf(f1[nn]); f2[nn]=siluf(f2[nn]); }
  }
  float am[NB]={0};
  float wm0[NB]={0}, wm1[NB]={0}, wm2[NB]={0};
  float t0[NB]={0}, t1[NB]={0}, t2[NB]={0};
  float t3[NB]={0}, t4[NB]={0}, t5[NB]={0};
  for (int r=0;r<128;++r){
    float w0 = ldf(tne_lt,(size_t)r*128+h);
    float w1 = ldf(tne_lt,(size_t)16384+r*128+h);
    float w2 = ldf(tne_lt,(size_t)32768+r*128+h);
    #pragma unroll
    for (int nn=0;nn<NB;++nn){
      am[nn]  += sm[nn][0][r]*w0;
      wm0[nn] += sm[nn][1][r]*w1; wm1[nn] += sm[nn][2][r]*w1; wm2[nn] += sm[nn][3][r]*w1;
      t0[nn] += sm[nn][4][r]*w2; t1[nn] += sm[nn][5][r]*w2; t2[nn] += sm[nn][6][r]*w2;
      t3[nn] += sm[nn][7][r]*w2; t4[nn] += sm[nn][8][r]*w2; t5[nn] += sm[nn][9][r]*w2;
    }
  }
  #pragma unroll
  for (int nn=0;nn<NB;++nn){
    float x00 = f0[nn]*am[nn] + f2[nn]*t0[nn];
    float x01 = -f1[nn]*wm2[nn] + f2[nn]*t1[nn];
    float x02 =  f1[nn]*wm1[nn] + f2[nn]*t2[nn];
    float x10 =  f1[nn]*wm2[nn] + f2[nn]*t1[nn];
    float x11 = f0[nn]*am[nn] + f2[nn]*t3[nn];
    float x12 = -f1[nn]*wm0[nn] + f2[nn]*t4[nn];
    float x20 = -f1[nn]*wm1[nn] + f2[nn]*t2[nn];
    float x21 =  f1[nn]*wm0[nn] + f2[nn]*t4[nn];
    float x22 = f0[nn]*am[nn] + f2[nn]*t5[nn];
    float* xp = X9 + (size_t)(n0+nn)*1152;
    xp[0*128+h]=x00; xp[1*128+h]=x01; xp[2*128+h]=x02;
    xp[3*128+h]=x10; xp[4*128+h]=x11; xp[5*128+h]=x12;
    xp[6*128+h]=x20; xp[7*128+h]=x21; xp[8*128+h]=x22;
  }
}
__global__ void __launch_bounds__(128) k_tne_node(
  const int* __restrict__ offsets, const int* __restrict__ csr,
  const float* __restrict__ gV, const bf16* __restrict__ eabuf,
  const void* ln_g, const void* ln_b, const void* tne_lt,
  const void* s0_w, const void* s0_b, const void* s1_w, const void* s1_b,
  float* __restrict__ X9, const int* __restrict__ flag)
{
  __shared__ float sm[NB][10][128];
  __shared__ float red[128];
  __shared__ float lnv[NB][128];
  __shared__ float h1s[NB][256];
  if (flag[0]) tne_node_impl<float>(offsets, csr, gV, eabuf,
      (const float*)ln_g, (const float*)ln_b, (const float*)tne_lt,
      (const float*)s0_w, (const float*)s0_b, (const float*)s1_w, (const float*)s1_b, X9, sm, red, lnv, h1s);
  else tne_node_impl<bf16>(offsets, csr, gV, eabuf,
      (const bf16*)ln_g, (const bf16*)ln_b, (const bf16*)tne_lt,
      (const bf16*)s0_w, (const bf16*)s0_b, (const bf16*)s1_w, (const bf16*)s1_b, X9, sm, red, lnv, h1s);
}

// ---------------- msg edge MLP via MFMA (r10-validated, untouched) ----------------
template<typename T>
__device__ __forceinline__ void mfma_impl(
  const unsigned short* eattr_c, const float* gC,
  const unsigned short* p0, const unsigned short* p1, const unsigned short* p2,
  const T* b0, const T* b1, const T* b2,
  unsigned short* eabuf, unsigned short (*h1p)[2048], unsigned short (*h2p)[4096])
{
  int wid  = threadIdx.x >> 6;
  int lane = threadIdx.x & 63;
  int e0 = blockIdx.x*32 + wid*16;
  int m = lane & 15, g = lane >> 4;
  float cc[4];
  #pragma unroll
  for (int r=0;r<4;++r) cc[r] = gC[e0 + g*4 + r];
  short8v a1 = *reinterpret_cast<const short8v*>(eattr_c + (size_t)(e0+m)*32 + g*8);
  #pragma unroll
  for (int nt=0; nt<8; ++nt){
    float bias = ldf(b0, nt*16+m);
    f32x4 acc = {bias,bias,bias,bias};
    short8v b = *reinterpret_cast<const short8v*>(p0 + ((size_t)nt*64 + lane)*8);
    acc = __builtin_amdgcn_mfma_f32_16x16x32_bf16(a1, b, acc, 0,0,0);
    #pragma unroll
    for (int r=0;r<4;++r){
      int n = nt*16 + m, row = g*4 + r;
      h1p[wid][(n>>5)*512 + (((n>>3)&3)*16+row)*8 + (n&7)] = f2bu(siluf(acc[r]));
    }
  }
  __syncthreads();
  short8v a2[4];
  #pragma unroll
  for (int ks=0; ks<4; ++ks) a2[ks] = *reinterpret_cast<const short8v*>(&h1p[wid][ks*512 + lane*8]);
  for (int nt=0; nt<16; ++nt){
    float bias = ldf(b1, nt*16+m);
    f32x4 acc = {bias,bias,bias,bias};
    #pragma unroll
    for (int ks=0; ks<4; ++ks){
      short8v b = *reinterpret_cast<const short8v*>(p1 + ((size_t)(nt*4+ks)*64 + lane)*8);
      acc = __builtin_amdgcn_mfma_f32_16x16x32_bf16(a2[ks], b, acc, 0,0,0);
    }
    #pragma unroll
    for (int r=0;r<4;++r){
      int n = nt*16 + m, row = g*4 + r;
      h2p[wid][(n>>5)*512 + (((n>>3)&3)*16+row)*8 + (n&7)] = f2bu(siluf(acc[r]));
    }
  }
  __syncthreads();
  short8v a3[8];
  #pragma unroll
  for (int ks=0; ks<8; ++ks) a3[ks] = *reinterpret_cast<const short8v*>(&h2p[wid][ks*512 + lane*8]);
  for (int nt=0; nt<24; ++nt){
    float bias = ldf(b2, nt*16+m);
    f32x4 acc = {bias,bias,bias,bias};
    #pragma unroll
    for (int ks=0; ks<8; ++ks){
      short8v b = *reinterpret_cast<const short8v*>(p2 + ((size_t)(nt*8+ks)*64 + lane)*8);
      acc = __builtin_amdgcn_mfma_f32_16x16x32_bf16(a3[ks], b, acc, 0,0,0);
    }
    #pragma unroll
    for (int r=0;r<4;++r){
      int n = nt*16 + m, row = g*4 + r;
      float v = siluf(acc[r]) * cc[r];
      eabuf[(size_t)(e0+row)*384 + (n%3)*128 + (n/3)] = f2bu(v);
    }
  }
}
__global__ void __launch_bounds__(128) k_msg_edge_mfma(
  const unsigned short* __restrict__ eattr_c, const float* __restrict__ gC,
  const unsigned short* __restrict__ p0, const unsigned short* __restrict__ p1,
  const unsigned short* __restrict__ p2,
  const void* b0, const void* b1, const void* b2, long boff0, long boff1, long boff2,
  unsigned short* __restrict__ eabuf, const int* __restrict__ flag)
{
  __shared__ __align__(16) unsigned short h1p[2][2048];
  __shared__ __align__(16) unsigned short h2p[2][4096];
  if (flag[0]) mfma_impl<float>(eattr_c, gC, p0, p1, p2,
      (const float*)b0 + boff0, (const float*)b1 + boff1, (const float*)b2 + boff2, eabuf, h1p, h2p);
  else mfma_impl<bf16>(eattr_c, gC, p0, p1, p2,
      (const bf16*)b0 + boff0, (const bf16*)b1 + boff1, (const bf16*)b2 + boff2, eabuf, h1p, h2p);
}

// ---------------- msg node prep (NB nodes/block) ----------------
template<typename T>
__device__ __forceinline__ void prep_impl(
  float* X9, const T* lx, bf16* Y10, float (*sm)[10][128])
{
  int n0 = blockIdx.x*NB, h = threadIdx.x;
  #pragma unroll
  for (int nn=0;nn<NB;++nn){
    float* xp = X9 + (size_t)(n0+nn)*1152;
    float x00=xp[0*128+h], x01=xp[1*128+h], x02=xp[2*128+h];
    float x10=xp[3*128+h], x11=xp[4*128+h], x12=xp[5*128+h];
    float x20=xp[6*128+h], x21=xp[7*128+h], x22=xp[8*128+h];
    float tn = x00*x00+x01*x01+x02*x02+x10*x10+x11*x11+x12*x12+x20*x20+x21*x21+x22*x22;
    float inv = 1.0f/(tn+1.0f);
    x00*=inv; x01*=inv; x02*=inv; x10*=inv; x11*=inv; x12*=inv; x20*=inv; x21*=inv; x22*=inv;
    // Reference REBINDS X to normalized before the update (r3 fix).
    xp[0*128+h]=x00; xp[1*128+h]=x01; xp[2*128+h]=x02;
    xp[3*128+h]=x10; xp[4*128+h]=x11; xp[5*128+h]=x12;
    xp[6*128+h]=x20; xp[7*128+h]=x21; xp[8*128+h]=x22;
    float a = (x00+x11+x22)*(1.0f/3.0f);
    sm[nn][0][h]=a;
    sm[nn][1][h]=0.5f*(x21-x12);
    sm[nn][2][h]=0.5f*(x02-x20);
    sm[nn][3][h]=0.5f*(x10-x01);
    sm[nn][4][h]=x00-a;
    sm[nn][5][h]=0.5f*(x01+x10);
    sm[nn][6][h]=0.5f*(x02+x20);
    sm[nn][7][h]=x11-a;
    sm[nn][8][h]=0.5f*(x12+x21);
    sm[nn][9][h]=x22-a;
  }
  __syncthreads();
  float A[NB]={0};
  float V0[NB]={0}, V1[NB]={0}, V2[NB]={0};
  float S0[NB]={0}, S1[NB]={0}, S2[NB]={0};
  float S3[NB]={0}, S4[NB]={0}, S5[NB]={0};
  for (int r=0;r<128;++r){
    float w0 = ldf(lx,(size_t)r*128+h), w1 = ldf(lx,(size_t)16384+r*128+h), w2 = ldf(lx,(size_t)32768+r*128+h);
    #pragma unroll
    for (int nn=0;nn<NB;++nn){
      A[nn]  += sm[nn][0][r]*w0;
      V0[nn] += sm[nn][1][r]*w1; V1[nn] += sm[nn][2][r]*w1; V2[nn] += sm[nn][3][r]*w1;
      S0[nn] += sm[nn][4][r]*w2; S1[nn] += sm[nn][5][r]*w2; S2[nn] += sm[nn][6][r]*w2;
      S3[nn] += sm[nn][7][r]*w2; S4[nn] += sm[nn][8][r]*w2; S5[nn] += sm[nn][9][r]*w2;
    }
  }
  #pragma unroll
  for (int nn=0;nn<NB;++nn){
    bf16* yp = Y10 + (size_t)(n0+nn)*1280;
    yp[0*128+h]=__float2bfloat16(A[nn]);
    yp[1*128+h]=__float2bfloat16(V0[nn]); yp[2*128+h]=__float2bfloat16(V1[nn]); yp[3*128+h]=__float2bfloat16(V2[nn]);
    yp[4*128+h]=__float2bfloat16(S0[nn]); yp[5*128+h]=__float2bfloat16(S1[nn]); yp[6*128+h]=__float2bfloat16(S2[nn]);
    yp[7*128+h]=__float2bfloat16(S3[nn]); yp[8*128+h]=__float2bfloat16(S4[nn]); yp[9*128+h]=__float2bfloat16(S5[nn]);
  }
}
__global__ void __launch_bounds__(128) k_msg_prep(
  float* __restrict__ X9, const void* lx, long lxoff, bf16* __restrict__ Y10,
  const int* __restrict__ flag)
{
  __shared__ float sm[NB][10][128];
  if (flag[0]) prep_impl<float>(X9, (const float*)lx + lxoff, Y10, sm);
  else         prep_impl<bf16 >(X9, (const bf16* )lx + lxoff, Y10, sm);
}

// ---------------- msg scatter+AB+decompose + NB-batched lt cmix + dX update ----------------
template<typename T>
__device__ __forceinline__ void sf_impl(
  const int* offsets, const int* csr, const int* srcA,
  const bf16* eabuf, const bf16* Y10, const T* lt,
  float* X9, T* out, int write_out, float (*sm)[10][128])
{
  int n0 = blockIdx.x*NB, h = threadIdx.x;
  #pragma unroll
  for (int nn=0;nn<NB;++nn){
    int n = n0+nn;
    float am=0, vm0=0,vm1=0,vm2=0, smm0=0,smm1=0,smm2=0,smm3=0,smm4=0,smm5=0;
    int beg = offsets[n], end = offsets[n+1];
    int i = beg;
    // 4-edge unroll: issue all 52 gather loads, then accumulate edge-by-edge
    // in the SAME serial order (bit-identical FP sequence).
    for (; i+4 <= end; i += 4){
      int ee[4], ss[4];
      #pragma unroll
      for (int u=0;u<4;++u){ ee[u] = csr[i+u]; }
      #pragma unroll
      for (int u=0;u<4;++u){ ss[u] = srcA[ee[u]]; }
      float e0a[4], e1a[4], e2a[4];
      float y0[4],y1[4],y2[4],y3[4],y4[4],y5[4],y6[4],y7[4],y8[4],y9[4];
      #pragma unroll
      for (int u=0;u<4;++u){
        const bf16* ep = eabuf + (size_t)ee[u]*384;
        e0a[u]=b2f(ep[h]); e1a[u]=b2f(ep[128+h]); e2a[u]=b2f(ep[256+h]);
        const bf16* yp = Y10 + (size_t)ss[u]*1280;
        y0[u]=b2f(yp[0*128+h]); y1[u]=b2f(yp[1*128+h]); y2[u]=b2f(yp[2*128+h]);
        y3[u]=b2f(yp[3*128+h]); y4[u]=b2f(yp[4*128+h]); y5[u]=b2f(yp[5*128+h]);
        y6[u]=b2f(yp[6*128+h]); y7[u]=b2f(yp[7*128+h]); y8[u]=b2f(yp[8*128+h]);
        y9[u]=b2f(yp[9*128+h]);
      }
      #pragma unroll
      for (int u=0;u<4;++u){
        am   += e0a[u]*y0[u];
        vm0  += e1a[u]*y1[u]; vm1 += e1a[u]*y2[u]; vm2 += e1a[u]*y3[u];
        smm0 += e2a[u]*y4[u]; smm1 += e2a[u]*y5[u]; smm2 += e2a[u]*y6[u];
        smm3 += e2a[u]*y7[u]; smm4 += e2a[u]*y8[u]; smm5 += e2a[u]*y9[u];
      }
    }
    for (; i<end; ++i){
      int e = csr[i]; int s = srcA[e];
      const bf16* ep = eabuf + (size_t)e*384;
      float e0 = b2f(ep[h]), e1 = b2f(ep[128+h]), e2 = b2f(ep[256+h]);
      const bf16* yp = Y10 + (size_t)s*1280;
      am   += e0*b2f(yp[0*128+h]);
      vm0  += e1*b2f(yp[1*128+h]); vm1 += e1*b2f(yp[2*128+h]); vm2 += e1*b2f(yp[3*128+h]);
      smm0 += e2*b2f(yp[4*128+h]); smm1 += e2*b2f(yp[5*128+h]); smm2 += e2*b2f(yp[6*128+h]);
      smm3 += e2*b2f(yp[7*128+h]); smm4 += e2*b2f(yp[8*128+h]); smm5 += e2*b2f(yp[9*128+h]);
    }
    const bf16* yp = Y10 + (size_t)n*1280;
    float aY=b2f(yp[0*128+h]), u0=b2f(yp[1*128+h]), u1=b2f(yp[2*128+h]), u2=b2f(yp[3*128+h]);
    float q0=b2f(yp[4*128+h]), q1=b2f(yp[5*128+h]), q2=b2f(yp[6*128+h]);
    float q3=b2f(yp[7*128+h]), q4=b2f(yp[8*128+h]), q5=b2f(yp[9*128+h]);
    float m00=am+smm0,   m01=-vm2+smm1, m02= vm1+smm2;
    float m10= vm2+smm1, m11=am+smm3,  m12=-vm0+smm4;
    float m20=-vm1+smm2, m21= vm0+smm4, m22=am+smm5;
    float y00=aY+q0,  y01=-u2+q1, y02= u1+q2;
    float y10= u2+q1, y11=aY+q3,  y12=-u0+q4;
    float y20=-u1+q2, y21= u0+q4, y22=aY+q5;
    float ab00 = m00*y00+m01*y10+m02*y20 + y00*m00+y01*m10+y02*m20;
    float ab01 = m00*y01+m01*y11+m02*y21 + y00*m01+y01*m11+y02*m21;
    float ab02 = m00*y02+m01*y12+m02*y22 + y00*m02+y01*m12+y02*m22;
    float ab10 = m10*y00+m11*y10+m12*y20 + y10*m00+y11*m10+y12*m20;
    float ab11 = m10*y01+m11*y11+m12*y21 + y10*m01+y11*m11+y12*m21;
    float ab12 = m10*y02+m11*y12+m12*y22 + y10*m02+y11*m12+y12*m22;
    float ab20 = m20*y00+m21*y10+m22*y20 + y20*m00+y21*m10+y22*m20;
    float ab21 = m20*y01+m21*y11+m22*y21 + y20*m01+y21*m11+y22*m21;
    float ab22 = m20*y02+m21*y12+m22*y22 + y20*m02+y21*m12+y22*m22;
    float a2 = (ab00+ab11+ab22)*(1.0f/3.0f);
    float w0 = 0.5f*(ab21-ab12), w1 = 0.5f*(ab02-ab20), w2 = 0.5f*(ab10-ab01);
    float t0 = ab00-a2, t1 = 0.5f*(ab01+ab10), t2 = 0.5f*(ab02+ab20);
    float t3 = ab11-a2, t4 = 0.5f*(ab12+ab21), t5 = ab22-a2;
    float dnm = ab00*ab00+ab01*ab01+ab02*ab02+ab10*ab10+ab11*ab11+ab12*ab12
              + ab20*ab20+ab21*ab21+ab22*ab22 + 1.0f;
    float inv = 1.0f/dnm;
    sm[nn][0][h]=a2*inv; sm[nn][1][h]=w0*inv; sm[nn][2][h]=w1*inv; sm[nn][3][h]=w2*inv;
    sm[nn][4][h]=t0*inv; sm[nn][5][h]=t1*inv; sm[nn][6][h]=t2*inv;
    sm[nn][7][h]=t3*inv; sm[nn][8][h]=t4*inv; sm[nn][9][h]=t5*inv;
  }
  __syncthreads();
  float at[NB]={0};
  float vt0[NB]={0}, vt1[NB]={0}, vt2[NB]={0};
  float st0[NB]={0}, st1[NB]={0}, st2[NB]={0};
  float st3[NB]={0}, st4[NB]={0}, st5[NB]={0};
  for (int r=0;r<128;++r){
    float ww0 = ldf(lt,(size_t)r*128+h);
    float ww1 = ldf(lt,(size_t)16384+r*128+h);
    float ww2 = ldf(lt,(size_t)32768+r*128+h);
    #pragma unroll
    for (int nn=0;nn<NB;++nn){
      at[nn]  += sm[nn][0][r]*ww0;
      vt0[nn] += sm[nn][1][r]*ww1; vt1[nn] += sm[nn][2][r]*ww1; vt2[nn] += sm[nn][3][r]*ww1;
      st0[nn] += sm[nn][4][r]*ww2; st1[nn] += sm[nn][5][r]*ww2; st2[nn] += sm[nn][6][r]*ww2;
      st3[nn] += sm[nn][7][r]*ww2; st4[nn] += sm[nn][8][r]*ww2; st5[nn] += sm[nn][9][r]*ww2;
    }
  }
  #pragma unroll
  for (int nn=0;nn<NB;++nn){
    int n = n0+nn;
    float d00=at[nn]+st0[nn],   d01=-vt2[nn]+st1[nn], d02= vt1[nn]+st2[nn];
    float d10= vt2[nn]+st1[nn], d11=at[nn]+st3[nn],  d12=-vt0[nn]+st4[nn];
    float d20=-vt1[nn]+st2[nn], d21= vt0[nn]+st4[nn], d22=at[nn]+st5[nn];
    float g00 = d00 + d00*d00+d01*d10+d02*d20;
    float g01 = d01 + d00*d01+d01*d11+d02*d21;
    float g02 = d02 + d00*d02+d01*d12+d02*d22;
    float g10 = d10 + d10*d00+d11*d10+d12*d20;
    float g11 = d11 + d10*d01+d11*d11+d12*d21;
    float g12 = d12 + d10*d02+d11*d12+d12*d22;
    float g20 = d20 + d20*d00+d21*d10+d22*d20;
    float g21 = d21 + d20*d01+d21*d11+d22*d21;
    float g22 = d22 + d20*d02+d21*d12+d22*d22;
    float* xp = X9 + (size_t)n*1152;
    float x00=xp[0*128+h]+g00, x01=xp[1*128+h]+g01, x02=xp[2*128+h]+g02;
    float x10=xp[3*128+h]+g10, x11=xp[4*128+h]+g11, x12=xp[5*128+h]+g12;
    float x20=xp[6*128+h]+g20, x21=xp[7*128+h]+g21, x22=xp[8*128+h]+g22;
    if (write_out){
      if (sizeof(T)==4){
        float* of = (float*)out + ((size_t)n*128 + h)*9;
        of[0]=x00; of[1]=x01; of[2]=x02; of[3]=x10; of[4]=x11; of[5]=x12; of[6]=x20; of[7]=x21; of[8]=x22;
      } else {
        bf16* ob = (bf16*)out + ((size_t)n*128 + h)*9;
        ob[0]=__float2bfloat16(x00); ob[1]=__float2bfloat16(x01); ob[2]=__float2bfloat16(x02);
        ob[3]=__float2bfloat16(x10); ob[4]=__float2bfloat16(x11); ob[5]=__float2bfloat16(x12);
        ob[6]=__float2bfloat16(x20); ob[7]=__float2bfloat16(x21); ob[8]=__float2bfloat16(x22);
      }
    } else {
      xp[0*128+h]=x00; xp[1*128+h]=x01; xp[2*128+h]=x02;
      xp[3*128+h]=x10; xp[4*128+h]=x11; xp[5*128+h]=x12;
      xp[6*128+h]=x20; xp[7*128+h]=x21; xp[8*128+h]=x22;
    }
  }
}
__global__ void __launch_bounds__(128) k_msg_sf(
  const int* __restrict__ offsets, const int* __restrict__ csr, const int* __restrict__ srcA,
  const bf16* __restrict__ eabuf, const bf16* __restrict__ Y10,
  const void* lt, long ltoff, float* __restrict__ X9, void* __restrict__ out,
  const int* __restrict__ flag, int write_out)
{
  __shared__ float sm[NB][10][128];
  if (flag[0]) sf_impl<float>(offsets, csr, srcA, eabuf, Y10, (const float*)lt + ltoff, X9, (float*)out, write_out, sm);
  else         sf_impl<bf16 >(offsets, csr, srcA, eabuf, Y10, (const bf16* )lt + ltoff, X9, (bf16* )out, write_out, sm);
}

extern "C" void kernel_launch(void* const* d_in, const int* in_sizes, int n_in,
                              void* d_out, int out_size, void* d_ws, size_t ws_size,
                              hipStream_t stream)
{
  (void)in_sizes; (void)n_in; (void)out_size; (void)ws_size;
  const int* z    = (const int*)d_in[0];
  const int* eidx = (const int*)d_in[1];
  const int* src  = eidx;
  const int* dst  = eidx + NE;

  // Workspace: ~58 MiB (proven budget >= 74 MiB).
  char* w = (char*)d_ws;
  int* flag    = (int*)w;   w += 64;
  int* counts  = (int*)w;   w += (size_t)NN*4;
  int* offsets = (int*)w;   w += (size_t)(NN+1)*4 + 60;
  int* cursor  = (int*)w;   w += (size_t)NN*4;
  int* csr     = (int*)w;   w += (size_t)NE*4;
  float* gC    = (float*)w; w += (size_t)NE*4;
  float* gV    = (float*)w; w += (size_t)NE*12;
  float* P1z   = (float*)w; w += (size_t)MAXZ*HH*4;
  float* P2z   = (float*)w; w += (size_t)MAXZ*HH*4;
  bf16* eabuf  = (bf16*)w;  w += (size_t)NE*384*2;
  float* X9    = (float*)w; w += (size_t)NN*1152*4;
  bf16* Y10    = (bf16*)w;  w += (size_t)NN*1280*2;
  unsigned short* eattr_c = (unsigned short*)w; w += (size_t)NE*32*2;
  unsigned short* pw0[2]; unsigned short* pw1[2]; unsigned short* pw2[2];
  for (int l=0;l<2;++l){
    pw0[l] = (unsigned short*)w; w += 8*64*8*2;
    pw1[l] = (unsigned short*)w; w += 64*64*8*2;
    pw2[l] = (unsigned short*)w; w += 192*64*8*2;
  }

  k_detect<<<1, 256, 0, stream>>>((const unsigned int*)d_in[4], flag);
  hipMemsetAsync(counts, 0, (size_t)NN*4, stream);
  k_count<<<NE/256, 256, 0, stream>>>(dst, counts);
  k_scan<<<1, 1024, 0, stream>>>(counts, offsets, cursor);
  k_fill<<<NE/256, 256, 0, stream>>>(dst, cursor, csr);
  k_geom<<<NE/256, 256, 0, stream>>>(d_in[2], d_in[3], src, dst, gC, gV, flag);
  k_zemb<<<MAXZ, 128, 0, stream>>>(d_in[5], d_in[12], P1z, P2z, flag);
  k_cvt_attr<<<NE*32/256, 256, 0, stream>>>(d_in[4], eattr_c, flag);

  PackDescs pd;
  for (int l=0;l<2;++l){
    pd.base[l*3+0] = d_in[21]; pd.eoff[l*3+0] = (long)l*32*128;
    pd.base[l*3+1] = d_in[23]; pd.eoff[l*3+1] = (long)l*128*256;
    pd.base[l*3+2] = d_in[25]; pd.eoff[l*3+2] = (long)l*256*384;
    pd.out[l*3+0] = pw0[l]; pd.K[l*3+0]=32;  pd.N[l*3+0]=128;
    pd.out[l*3+1] = pw1[l]; pd.K[l*3+1]=128; pd.N[l*3+1]=256;
    pd.out[l*3+2] = pw2[l]; pd.K[l*3+2]=256; pd.N[l*3+2]=384;
  }
  k_pack<<<dim3(48, 6), 256, 0, stream>>>(pd, flag);

  k_tne_edge<<<NE/TPB, 128, 0, stream>>>(d_in[4], src, dst, z,
      d_in[6], d_in[7], d_in[8], d_in[9], d_in[10], d_in[11], d_in[13],
      P1z, P2z, gC, eabuf, flag);
  k_tne_node<<<NN/NB, 128, 0, stream>>>(offsets, csr, gV, eabuf,
      d_in[19], d_in[20], d_in[14], d_in[15], d_in[16], d_in[17], d_in[18], X9, flag);

  for (int l=0; l<2; ++l){
    k_msg_edge_mfma<<<NE/32, 128, 0, stream>>>(eattr_c, gC, pw0[l], pw1[l], pw2[l],
        d_in[22], d_in[24], d_in[26], (long)l*128, (long)l*256, (long)l*384,
        (unsigned short*)eabuf, flag);
    k_msg_prep<<<NN/NB, 128, 0, stream>>>(X9, d_in[27], (long)l*3*128*128, Y10, flag);
    k_msg_sf<<<NN/NB, 128, 0, stream>>>(offsets, csr, src, eabuf, Y10,
        d_in[28], (long)l*3*128*128, X9, d_out, flag, (l==1)?1:0);
  }
}

// Round 15
// 453.435 us; speedup vs baseline: 1.0474x; 1.0015x over previous
//
#include <hip/hip_runtime.h>
#include <hip/hip_bf16.h>

typedef __hip_bfloat16 bf16;
typedef __attribute__((ext_vector_type(8))) short short8v;   // 8 bf16 = 4 VGPRs (MFMA A/B frag)
typedef __attribute__((ext_vector_type(4))) float f32x4;     // MFMA C/D frag

#define NN 4096
#define NE 32768
#define HH 128
#define MAXZ 100
#define TPB 8    // edges per block, TNE edge kernel
#define NB 2     // nodes per block in node-side kernels (grid 2048 = 8 blocks/CU)

// ENVIRONMENT FACTS (r0-r14): float tensors are FLOAT32; runtime detector kept.
// MFMA msg-edge path hardware-validated r10. NB=2 best. r13/r14 lesson: node
// kernels were latency-bound on the RANDOM csr->eabuf gather; r15 stores eabuf
// in CSR order (scatter on write side) so consumers stream sequentially.
// Accumulation order unchanged => absmax must stay 0.00206089.

__device__ __forceinline__ float b2f(bf16 v){ return __bfloat162float(v); }
__device__ __forceinline__ float ldf(const float* p, size_t i){ return p[i]; }
__device__ __forceinline__ float ldf(const bf16*  p, size_t i){ return __bfloat162float(p[i]); }
__device__ __forceinline__ float siluf(float x){ return x / (1.0f + __expf(-x)); }
__device__ __forceinline__ unsigned short f2bu(float x){
  bf16 h = __float2bfloat16(x);
  return *reinterpret_cast<unsigned short*>(&h);
}

// dtype detect: flag[0]=1 if float inputs are f32, 0 if bf16.
__global__ void __launch_bounds__(256) k_detect(const unsigned int* __restrict__ w, int* __restrict__ flag){
  __shared__ int cnt[256];
  int t = threadIdx.x;
  int c = 0;
  for (int i = t; i < 4096; i += 256){
    unsigned int lo = w[i] & 0xffffu;
    int e = (int)((lo >> 7) & 0xffu);
    c += (e >= 110 && e <= 132) ? 1 : 0;
  }
  cnt[t] = c; __syncthreads();
  for (int off=128; off>=1; off>>=1){ if (t<off) cnt[t]+=cnt[t+off]; __syncthreads(); }
  if (t==0) flag[0] = (cnt[0] < 2048) ? 1 : 0;
}

// ---------------- CSR build ----------------
__global__ void __launch_bounds__(256) k_count(const int* __restrict__ dst, int* __restrict__ counts){
  int e = blockIdx.x*256 + threadIdx.x;
  if (e < NE) atomicAdd(&counts[dst[e]], 1);
}

__global__ void __launch_bounds__(1024) k_scan(const int* __restrict__ counts, int* __restrict__ offsets, int* __restrict__ cursor){
  __shared__ int lds[1024];
  int t = threadIdx.x;
  int c0 = counts[4*t+0], c1 = counts[4*t+1], c2 = counts[4*t+2], c3 = counts[4*t+3];
  int s1 = c0+c1, s2 = s1+c2, s3 = s2+c3;
  lds[t] = s3;
  __syncthreads();
  for (int off=1; off<1024; off<<=1){
    int v = lds[t];
    int add = (t>=off)? lds[t-off] : 0;
    __syncthreads();
    lds[t] = v + add;
    __syncthreads();
  }
  int incl = lds[t];
  int base = incl - s3;
  offsets[4*t+0]=base;    offsets[4*t+1]=base+c0; offsets[4*t+2]=base+s1; offsets[4*t+3]=base+s2;
  cursor [4*t+0]=base;    cursor [4*t+1]=base+c0; cursor [4*t+2]=base+s1; cursor [4*t+3]=base+s2;
  if (t==1023) offsets[4096]=incl;
}

// fill: also record pos[e] (CSR slot of edge e) and csrc[p] (src node of CSR slot p)
__global__ void __launch_bounds__(256) k_fill(const int* __restrict__ dst, const int* __restrict__ src,
                                              int* __restrict__ cursor, int* __restrict__ csr,
                                              int* __restrict__ pos, int* __restrict__ csrc){
  int e = blockIdx.x*256 + threadIdx.x;
  if (e < NE){
    int p = atomicAdd(&cursor[dst[e]], 1);
    csr[p] = e;
    pos[e] = p;
    csrc[p] = src[e];
  }
}

// ---------------- edge geometry (gV written in CSR order) ----------------
template<typename T>
__device__ __forceinline__ void geom_impl(const T* ew, const T* evec,
    const int* src, const int* dst, const int* pos, float* gC, float* gVp){
  int e = blockIdx.x*256 + threadIdx.x;
  if (e >= NE) return;
  float d = ldf(ew, e);
  float c = 0.5f*(cosf(d*0.6283185307179586f)+1.0f);
  c = (d < 5.0f) ? c : 0.0f;
  gC[e] = c;
  float x = ldf(evec, (size_t)e*3+0), y = ldf(evec, (size_t)e*3+1), z = ldf(evec, (size_t)e*3+2);
  if (src[e] != dst[e]){
    float n = sqrtf(x*x+y*y+z*z);
    float inv = 1.0f/fmaxf(n, 1e-12f);
    x*=inv; y*=inv; z*=inv;
  }
  int p = pos[e];
  gVp[p*3+0]=x; gVp[p*3+1]=y; gVp[p*3+2]=z;
}
__global__ void __launch_bounds__(256) k_geom(const void* ew, const void* evec,
    const int* __restrict__ src, const int* __restrict__ dst, const int* __restrict__ pos,
    float* __restrict__ gC, float* __restrict__ gVp, const int* __restrict__ flag){
  if (flag[0]) geom_impl<float>((const float*)ew, (const float*)evec, src, dst, pos, gC, gVp);
  else         geom_impl<bf16 >((const bf16* )ew, (const bf16* )evec, src, dst, pos, gC, gVp);
}

// ---------------- per-z embedding products ----------------
template<typename T>
__device__ __forceinline__ void zemb_impl(const T* emb, const T* emb2_w,
    float* P1z, float* P2z, float* Zr){
  int zv = blockIdx.x, h = threadIdx.x;
  Zr[h] = ldf(emb, (size_t)zv*HH + h);
  __syncthreads();
  float p1=0.f, p2=0.f;
  for (int r=0;r<128;++r){
    float x = Zr[r];
    p1 += x*ldf(emb2_w, (size_t)r*HH+h);
    p2 += x*ldf(emb2_w, (size_t)(r+128)*HH+h);
  }
  P1z[zv*HH+h]=p1; P2z[zv*HH+h]=p2;
}
__global__ void __launch_bounds__(128) k_zemb(const void* emb, const void* emb2_w,
    float* __restrict__ P1z, float* __restrict__ P2z, const int* __restrict__ flag){
  __shared__ float Zr[128];
  if (flag[0]) zemb_impl<float>((const float*)emb, (const float*)emb2_w, P1z, P2z, Zr);
  else         zemb_impl<bf16 >((const bf16* )emb, (const bf16* )emb2_w, P1z, P2z, Zr);
}

// ---------------- convert edge_attr -> bf16 ----------------
__global__ void __launch_bounds__(256) k_cvt_attr(const void* in, unsigned short* __restrict__ out,
                                                  const int* __restrict__ flag){
  int i = blockIdx.x*256 + threadIdx.x;
  if (flag[0]) out[i] = f2bu(((const float*)in)[i]);
  else         out[i] = ((const unsigned short*)in)[i];
}

// ---------------- weight repack into MFMA B-fragment layout ----------------
struct PackDescs {
  const void*     base[6];
  long            eoff[6];
  unsigned short* out[6];
  int K[6]; int N[6];
};
template<typename T>
__device__ __forceinline__ void pack_impl(const PackDescs& d){
  int y = blockIdx.y;
  int K = d.K[y], N = d.N[y];
  int ktiles = K>>5, ntiles = N>>4;
  int total = ktiles*ntiles*64;
  int idx = blockIdx.x*256 + threadIdx.x;
  if (idx >= total) return;
  int lane = idx & 63, tile = idx >> 6;
  int kt = tile % ktiles, nt = tile / ktiles;
  const T* W = (const T*)d.base[y] + d.eoff[y];
  int n = nt*16 + (lane&15), k0 = kt*32 + (lane>>4)*8;
  unsigned int t[8];
  #pragma unroll
  for (int j=0;j<8;++j) t[j] = f2bu(ldf(W, (size_t)(k0+j)*N + n));
  uint4 v;
  v.x = t[0] | (t[1]<<16);
  v.y = t[2] | (t[3]<<16);
  v.z = t[4] | (t[5]<<16);
  v.w = t[6] | (t[7]<<16);
  *reinterpret_cast<uint4*>(d.out[y] + ((size_t)tile*64 + lane)*8) = v;
}
__global__ void __launch_bounds__(256) k_pack(PackDescs d, const int* __restrict__ flag){
  if (flag[0]) pack_impl<float>(d);
  else         pack_impl<bf16 >(d);
}

// ---------------- TNE edge coefficients -> eabuf bf16 (CSR-ordered rows) ----------------
template<typename T>
__device__ __forceinline__ void tne_edge_impl(
  const T* eattr, const int* src, const int* dst, const int* z, const int* pos,
  const T* dp1_w, const T* dp1_b, const T* dp2_w, const T* dp2_b,
  const T* dp3_w, const T* dp3_b, const T* emb2_b,
  const float* P1z, const float* P2z, const float* gC, bf16* eabuf,
  float (*attr)[32], int* zd, int* zs, int* ppos)
{
  int e0 = blockIdx.x*TPB;
  int h  = threadIdx.x;
  for (int i=h; i<TPB*32; i+=128) attr[i>>5][i&31] = ldf(eattr, (size_t)e0*32 + i);
  if (h < TPB){ int e=e0+h; zd[h]=z[dst[e]]; zs[h]=z[src[e]]; ppos[h]=pos[e]; }
  __syncthreads();
  float w1[TPB], w2[TPB], w3[TPB];
  float b1v=ldf(dp1_b,h), b2v=ldf(dp2_b,h), b3v=ldf(dp3_b,h);
  #pragma unroll
  for (int e=0;e<TPB;++e){ w1[e]=b1v; w2[e]=b2v; w3[e]=b3v; }
  for (int r=0;r<32;++r){
    float u1=ldf(dp1_w,(size_t)r*HH+h), u2=ldf(dp2_w,(size_t)r*HH+h), u3=ldf(dp3_w,(size_t)r*HH+h);
    #pragma unroll
    for (int e=0;e<TPB;++e){ float a=attr[e][r]; w1[e]+=a*u1; w2[e]+=a*u2; w3[e]+=a*u3; }
  }
  float eb = ldf(emb2_b,h);
  #pragma unroll
  for (int e=0;e<TPB;++e){
    float zij = P1z[zd[e]*HH+h] + P2z[zs[e]*HH+h] + eb;
    float c = gC[e0+e];
    bf16* p = eabuf + (size_t)ppos[e]*384;
    p[h]     = __float2bfloat16(zij*w1[e]*c);
    p[128+h] = __float2bfloat16(zij*w2[e]*c);
    p[256+h] = __float2bfloat16(zij*w3[e]*c);
  }
}
__global__ void __launch_bounds__(128) k_tne_edge(
  const void* eattr, const int* __restrict__ src, const int* __restrict__ dst,
  const int* __restrict__ z, const int* __restrict__ pos,
  const void* dp1_w, const void* dp1_b, const void* dp2_w, const void* dp2_b,
  const void* dp3_w, const void* dp3_b, const void* emb2_b,
  const float* __restrict__ P1z, const float* __restrict__ P2z,
  const float* __restrict__ gC, bf16* __restrict__ eabuf, const int* __restrict__ flag)
{
  __shared__ float attr[TPB][32];
  __shared__ int zd[TPB], zs[TPB], ppos[TPB];
  if (flag[0]) tne_edge_impl<float>((const float*)eattr, src, dst, z, pos,
      (const float*)dp1_w, (const float*)dp1_b, (const float*)dp2_w, (const float*)dp2_b,
      (const float*)dp3_w, (const float*)dp3_b, (const float*)emb2_b, P1z, P2z, gC, eabuf, attr, zd, zs, ppos);
  else tne_edge_impl<bf16>((const bf16*)eattr, src, dst, z, pos,
      (const bf16*)dp1_w, (const bf16*)dp1_b, (const bf16*)dp2_w, (const bf16*)dp2_b,
      (const bf16*)dp3_w, (const bf16*)dp3_b, (const bf16*)emb2_b, P1z, P2z, gC, eabuf, attr, zd, zs, ppos);
}

// ---------------- TNE node: NB nodes/block, SEQUENTIAL eabuf/gVp reads ----------------
template<typename T>
__device__ __forceinline__ void tne_node_impl(
  const int* offsets, const float* gVp, const bf16* eabuf,
  const T* ln_g, const T* ln_b, const T* tne_lt,
  const T* s0_w, const T* s0_b, const T* s1_w, const T* s1_b, float* X9,
  float (*sm)[10][128], float* red, float (*lnv)[128], float (*h1s)[256])
{
  int n0 = blockIdx.x*NB, h = threadIdx.x;
  float tnv[NB];
  #pragma unroll
  for (int nn=0;nn<NB;++nn){
    int n = n0+nn;
    float a=0, v0=0,v1=0,v2=0, s0=0,s1=0,s2=0,s3=0,s4=0,s5=0;
    int beg = offsets[n], end = offsets[n+1];
    int i = beg;
    for (; i+4 <= end; i += 4){
      float c1[4],c2[4],c3[4],vx[4],vy[4],vz[4];
      #pragma unroll
      for (int u=0;u<4;++u){
        const bf16* p = eabuf + (size_t)(i+u)*384;
        c1[u]=b2f(p[h]); c2[u]=b2f(p[128+h]); c3[u]=b2f(p[256+h]);
        vx[u]=gVp[(i+u)*3+0]; vy[u]=gVp[(i+u)*3+1]; vz[u]=gVp[(i+u)*3+2];
      }
      #pragma unroll
      for (int u=0;u<4;++u){
        float tr3 = (vx[u]*vx[u]+vy[u]*vy[u]+vz[u]*vz[u])*(1.0f/3.0f);
        a  += c1[u];
        v0 += c2[u]*vx[u]; v1 += c2[u]*vy[u]; v2 += c2[u]*vz[u];
        s0 += c3[u]*(vx[u]*vx[u] - tr3); s1 += c3[u]*vx[u]*vy[u]; s2 += c3[u]*vx[u]*vz[u];
        s3 += c3[u]*(vy[u]*vy[u] - tr3); s4 += c3[u]*vy[u]*vz[u]; s5 += c3[u]*(vz[u]*vz[u] - tr3);
      }
    }
    for (; i<end; ++i){
      const bf16* p = eabuf + (size_t)i*384;
      float c1 = b2f(p[h]), c2 = b2f(p[128+h]), c3 = b2f(p[256+h]);
      float vx = gVp[i*3+0], vy = gVp[i*3+1], vz = gVp[i*3+2];
      float tr3 = (vx*vx+vy*vy+vz*vz)*(1.0f/3.0f);
      a  += c1;
      v0 += c2*vx; v1 += c2*vy; v2 += c2*vz;
      s0 += c3*(vx*vx - tr3); s1 += c3*vx*vy;          s2 += c3*vx*vz;
      s3 += c3*(vy*vy - tr3); s4 += c3*vy*vz;          s5 += c3*(vz*vz - tr3);
    }
    sm[nn][0][h]=a; sm[nn][1][h]=v0; sm[nn][2][h]=v1; sm[nn][3][h]=v2;
    sm[nn][4][h]=s0; sm[nn][5][h]=s1; sm[nn][6][h]=s2; sm[nn][7][h]=s3; sm[nn][8][h]=s4; sm[nn][9][h]=s5;
    tnv[nn] = 3.0f*a*a + 2.0f*(v0*v0+v1*v1+v2*v2)
            + s0*s0 + s3*s3 + s5*s5 + 2.0f*(s1*s1 + s2*s2 + s4*s4);
  }
  float gg = ldf(ln_g,h), bb = ldf(ln_b,h);
  #pragma unroll
  for (int nn=0;nn<NB;++nn){
    __syncthreads();
    red[h] = tnv[nn]; __syncthreads();
    for (int off=64; off>=1; off>>=1){ if (h<off) red[h]+=red[h+off]; __syncthreads(); }
    float mean = red[0]*(1.0f/128.0f);
    __syncthreads();
    float dm = tnv[nn] - mean;
    red[h] = dm*dm; __syncthreads();
    for (int off=64; off>=1; off>>=1){ if (h<off) red[h]+=red[h+off]; __syncthreads(); }
    float var = red[0]*(1.0f/128.0f);
    lnv[nn][h] = dm*rsqrtf(var+1e-5f)*gg + bb;
  }
  __syncthreads();
  {
    float ba = ldf(s0_b,2*h), bc = ldf(s0_b,2*h+1);
    float a0[NB], a1[NB];
    #pragma unroll
    for (int nn=0;nn<NB;++nn){ a0[nn]=ba; a1[nn]=bc; }
    for (int r=0;r<128;++r){
      float u0 = ldf(s0_w,(size_t)r*256+2*h), u1 = ldf(s0_w,(size_t)r*256+2*h+1);
      #pragma unroll
      for (int nn=0;nn<NB;++nn){ float x = lnv[nn][r]; a0[nn]+=x*u0; a1[nn]+=x*u1; }
    }
    #pragma unroll
    for (int nn=0;nn<NB;++nn){ h1s[nn][2*h] = siluf(a0[nn]); h1s[nn][2*h+1] = siluf(a1[nn]); }
  }
  __syncthreads();
  float f0[NB], f1[NB], f2[NB];
  {
    float b0 = ldf(s1_b,3*h), b1 = ldf(s1_b,3*h+1), b2 = ldf(s1_b,3*h+2);
    #pragma unroll
    for (int nn=0;nn<NB;++nn){ f0[nn]=b0; f1[nn]=b1; f2[nn]=b2; }
    for (int r=0;r<256;++r){
      float u0 = ldf(s1_w,(size_t)r*384+3*h), u1 = ldf(s1_w,(size_t)r*384+3*h+1), u2 = ldf(s1_w,(size_t)r*384+3*h+2);
      #pragma unroll
      for (int nn=0;nn<NB;++nn){ float x = h1s[nn][r]; f0[nn]+=x*u0; f1[nn]+=x*u1; f2[nn]+=x*u2; }
    }
    #pragma unroll
    for (int nn=0;nn<NB;++nn){ f0[nn]=siluf(f0[nn]); f1[nn]=siluf(f1[nn]); f2[nn]=siluf(f2[nn]); }
  }
  float am[NB]={0};
  float wm0[NB]={0}, wm1[NB]={0}, wm2[NB]={0};
  float t0[NB]={0}, t1[NB]={0}, t2[NB]={0};
  float t3[NB]={0}, t4[NB]={0}, t5[NB]={0};
  for (int r=0;r<128;++r){
    float w0 = ldf(tne_lt,(size_t)r*128+h);
    float w1 = ldf(tne_lt,(size_t)16384+r*128+h);
    float w2 = ldf(tne_lt,(size_t)32768+r*128+h);
    #pragma unroll
    for (int nn=0;nn<NB;++nn){
      am[nn]  += sm[nn][0][r]*w0;
      wm0[nn] += sm[nn][1][r]*w1; wm1[nn] += sm[nn][2][r]*w1; wm2[nn] += sm[nn][3][r]*w1;
      t0[nn] += sm[nn][4][r]*w2; t1[nn] += sm[nn][5][r]*w2; t2[nn] += sm[nn][6][r]*w2;
      t3[nn] += sm[nn][7][r]*w2; t4[nn] += sm[nn][8][r]*w2; t5[nn] += sm[nn][9][r]*w2;
    }
  }
  #pragma unroll
  for (int nn=0;nn<NB;++nn){
    float x00 = f0[nn]*am[nn] + f2[nn]*t0[nn];
    float x01 = -f1[nn]*wm2[nn] + f2[nn]*t1[nn];
    float x02 =  f1[nn]*wm1[nn] + f2[nn]*t2[nn];
    float x10 =  f1[nn]*wm2[nn] + f2[nn]*t1[nn];
    float x11 = f0[nn]*am[nn] + f2[nn]*t3[nn];
    float x12 = -f1[nn]*wm0[nn] + f2[nn]*t4[nn];
    float x20 = -f1[nn]*wm1[nn] + f2[nn]*t2[nn];
    float x21 =  f1[nn]*wm0[nn] + f2[nn]*t4[nn];
    float x22 = f0[nn]*am[nn] + f2[nn]*t5[nn];
    float* xp = X9 + (size_t)(n0+nn)*1152;
    xp[0*128+h]=x00; xp[1*128+h]=x01; xp[2*128+h]=x02;
    xp[3*128+h]=x10; xp[4*128+h]=x11; xp[5*128+h]=x12;
    xp[6*128+h]=x20; xp[7*128+h]=x21; xp[8*128+h]=x22;
  }
}
__global__ void __launch_bounds__(128) k_tne_node(
  const int* __restrict__ offsets, const float* __restrict__ gVp, const bf16* __restrict__ eabuf,
  const void* ln_g, const void* ln_b, const void* tne_lt,
  const void* s0_w, const void* s0_b, const void* s1_w, const void* s1_b,
  float* __restrict__ X9, const int* __restrict__ flag)
{
  __shared__ float sm[NB][10][128];
  __shared__ float red[128];
  __shared__ float lnv[NB][128];
  __shared__ float h1s[NB][256];
  if (flag[0]) tne_node_impl<float>(offsets, gVp, eabuf,
      (const float*)ln_g, (const float*)ln_b, (const float*)tne_lt,
      (const float*)s0_w, (const float*)s0_b, (const float*)s1_w, (const float*)s1_b, X9, sm, red, lnv, h1s);
  else tne_node_impl<bf16>(offsets, gVp, eabuf,
      (const bf16*)ln_g, (const bf16*)ln_b, (const bf16*)tne_lt,
      (const bf16*)s0_w, (const bf16*)s0_b, (const bf16*)s1_w, (const bf16*)s1_b, X9, sm, red, lnv, h1s);
}

// ---------------- msg edge MLP via MFMA (r10-validated math; CSR-ordered output) ----------------
template<typename T>
__device__ __forceinline__ void mfma_impl(
  const unsigned short* eattr_c, const float* gC, const int* pos,
  const unsigned short* p0, const unsigned short* p1, const unsigned short* p2,
  const T* b0, const T* b1, const T* b2,
  unsigned short* eabuf, unsigned short (*h1p)[2048], unsigned short (*h2p)[4096],
  int (*spos)[16])
{
  int wid  = threadIdx.x >> 6;
  int lane = threadIdx.x & 63;
  int e0 = blockIdx.x*32 + wid*16;
  int m = lane & 15, g = lane >> 4;
  if (lane < 16) spos[wid][lane] = pos[e0 + lane];   // same-wave LDS write/read
  float cc[4];
  #pragma unroll
  for (int r=0;r<4;++r) cc[r] = gC[e0 + g*4 + r];
  short8v a1 = *reinterpret_cast<const short8v*>(eattr_c + (size_t)(e0+m)*32 + g*8);
  #pragma unroll
  for (int nt=0; nt<8; ++nt){
    float bias = ldf(b0, nt*16+m);
    f32x4 acc = {bias,bias,bias,bias};
    short8v b = *reinterpret_cast<const short8v*>(p0 + ((size_t)nt*64 + lane)*8);
    acc = __builtin_amdgcn_mfma_f32_16x16x32_bf16(a1, b, acc, 0,0,0);
    #pragma unroll
    for (int r=0;r<4;++r){
      int n = nt*16 + m, row = g*4 + r;
      h1p[wid][(n>>5)*512 + (((n>>3)&3)*16+row)*8 + (n&7)] = f2bu(siluf(acc[r]));
    }
  }
  __syncthreads();
  short8v a2[4];
  #pragma unroll
  for (int ks=0; ks<4; ++ks) a2[ks] = *reinterpret_cast<const short8v*>(&h1p[wid][ks*512 + lane*8]);
  for (int nt=0; nt<16; ++nt){
    float bias = ldf(b1, nt*16+m);
    f32x4 acc = {bias,bias,bias,bias};
    #pragma unroll
    for (int ks=0; ks<4; ++ks){
      short8v b = *reinterpret_cast<const short8v*>(p1 + ((size_t)(nt*4+ks)*64 + lane)*8);
      acc = __builtin_amdgcn_mfma_f32_16x16x32_bf16(a2[ks], b, acc, 0,0,0);
    }
    #pragma unroll
    for (int r=0;r<4;++r){
      int n = nt*16 + m, row = g*4 + r;
      h2p[wid][(n>>5)*512 + (((n>>3)&3)*16+row)*8 + (n&7)] = f2bu(siluf(acc[r]));
    }
  }
  __syncthreads();
  short8v a3[8];
  #pragma unroll
  for (int ks=0; ks<8; ++ks) a3[ks] = *reinterpret_cast<const short8v*>(&h2p[wid][ks*512 + lane*8]);
  for (int nt=0; nt<24; ++nt){
    float bias = ldf(b2, nt*16+m);
    f32x4 acc = {bias,bias,bias,bias};
    #pragma unroll
    for (int ks=0; ks<8; ++ks){
      short8v b = *reinterpret_cast<const short8v*>(p2 + ((size_t)(nt*8+ks)*64 + lane)*8);
      acc = __builtin_amdgcn_mfma_f32_16x16x32_bf16(a3[ks], b, acc, 0,0,0);
    }
    #pragma unroll
    for (int r=0;r<4;++r){
      int n = nt*16 + m, row = g*4 + r;
      float v = siluf(acc[r]) * cc[r];
      eabuf[(size_t)spos[wid][row]*384 + (n%3)*128 + (n/3)] = f2bu(v);
    }
  }
}
__global__ void __launch_bounds__(128) k_msg_edge_mfma(
  const unsigned short* __restrict__ eattr_c, const float* __restrict__ gC,
  const int* __restrict__ pos,
  const unsigned short* __restrict__ p0, const unsigned short* __restrict__ p1,
  const unsigned short* __restrict__ p2,
  const void* b0, const void* b1, const void* b2, long boff0, long boff1, long boff2,
  unsigned short* __restrict__ eabuf, const int* __restrict__ flag)
{
  __shared__ __align__(16) unsigned short h1p[2][2048];
  __shared__ __align__(16) unsigned short h2p[2][4096];
  __shared__ int spos[2][16];
  if (flag[0]) mfma_impl<float>(eattr_c, gC, pos, p0, p1, p2,
      (const float*)b0 + boff0, (const float*)b1 + boff1, (const float*)b2 + boff2, eabuf, h1p, h2p, spos);
  else mfma_impl<bf16>(eattr_c, gC, pos, p0, p1, p2,
      (const bf16*)b0 + boff0, (const bf16*)b1 + boff1, (const bf16*)b2 + boff2, eabuf, h1p, h2p, spos);
}

// ---------------- msg node prep (NB nodes/block) ----------------
template<typename T>
__device__ __forceinline__ void prep_impl(
  float* X9, const T* lx, bf16* Y10, float (*sm)[10][128])
{
  int n0 = blockIdx.x*NB, h = threadIdx.x;
  #pragma unroll
  for (int nn=0;nn<NB;++nn){
    float* xp = X9 + (size_t)(n0+nn)*1152;
    float x00=xp[0*128+h], x01=xp[1*128+h], x02=xp[2*128+h];
    float x10=xp[3*128+h], x11=xp[4*128+h], x12=xp[5*128+h];
    float x20=xp[6*128+h], x21=xp[7*128+h], x22=xp[8*128+h];
    float tn = x00*x00+x01*x01+x02*x02+x10*x10+x11*x11+x12*x12+x20*x20+x21*x21+x22*x22;
    float inv = 1.0f/(tn+1.0f);
    x00*=inv; x01*=inv; x02*=inv; x10*=inv; x11*=inv; x12*=inv; x20*=inv; x21*=inv; x22*=inv;
    // Reference REBINDS X to normalized before the update (r3 fix).
    xp[0*128+h]=x00; xp[1*128+h]=x01; xp[2*128+h]=x02;
    xp[3*128+h]=x10; xp[4*128+h]=x11; xp[5*128+h]=x12;
    xp[6*128+h]=x20; xp[7*128+h]=x21; xp[8*128+h]=x22;
    float a = (x00+x11+x22)*(1.0f/3.0f);
    sm[nn][0][h]=a;
    sm[nn][1][h]=0.5f*(x21-x12);
    sm[nn][2][h]=0.5f*(x02-x20);
    sm[nn][3][h]=0.5f*(x10-x01);
    sm[nn][4][h]=x00-a;
    sm[nn][5][h]=0.5f*(x01+x10);
    sm[nn][6][h]=0.5f*(x02+x20);
    sm[nn][7][h]=x11-a;
    sm[nn][8][h]=0.5f*(x12+x21);
    sm[nn][9][h]=x22-a;
  }
  __syncthreads();
  float A[NB]={0};
  float V0[NB]={0}, V1[NB]={0}, V2[NB]={0};
  float S0[NB]={0}, S1[NB]={0}, S2[NB]={0};
  float S3[NB]={0}, S4[NB]={0}, S5[NB]={0};
  for (int r=0;r<128;++r){
    float w0 = ldf(lx,(size_t)r*128+h), w1 = ldf(lx,(size_t)16384+r*128+h), w2 = ldf(lx,(size_t)32768+r*128+h);
    #pragma unroll
    for (int nn=0;nn<NB;++nn){
      A[nn]  += sm[nn][0][r]*w0;
      V0[nn] += sm[nn][1][r]*w1; V1[nn] += sm[nn][2][r]*w1; V2[nn] += sm[nn][3][r]*w1;
      S0[nn] += sm[nn][4][r]*w2; S1[nn] += sm[nn][5][r]*w2; S2[nn] += sm[nn][6][r]*w2;
      S3[nn] += sm[nn][7][r]*w2; S4[nn] += sm[nn][8][r]*w2; S5[nn] += sm[nn][9][r]*w2;
    }
  }
  #pragma unroll
  for (int nn=0;nn<NB;++nn){
    bf16* yp = Y10 + (size_t)(n0+nn)*1280;
    yp[0*128+h]=__float2bfloat16(A[nn]);
    yp[1*128+h]=__float2bfloat16(V0[nn]); yp[2*128+h]=__float2bfloat16(V1[nn]); yp[3*128+h]=__float2bfloat16(V2[nn]);
    yp[4*128+h]=__float2bfloat16(S0[nn]); yp[5*128+h]=__float2bfloat16(S1[nn]); yp[6*128+h]=__float2bfloat16(S2[nn]);
    yp[7*128+h]=__float2bfloat16(S3[nn]); yp[8*128+h]=__float2bfloat16(S4[nn]); yp[9*128+h]=__float2bfloat16(S5[nn]);
  }
}
__global__ void __launch_bounds__(128) k_msg_prep(
  float* __restrict__ X9, const void* lx, long lxoff, bf16* __restrict__ Y10,
  const int* __restrict__ flag)
{
  __shared__ float sm[NB][10][128];
  if (flag[0]) prep_impl<float>(X9, (const float*)lx + lxoff, Y10, sm);
  else         prep_impl<bf16 >(X9, (const bf16* )lx + lxoff, Y10, sm);
}

// ---------------- msg scatter (sequential eabuf, Y10 gather via csrc) + AB + cmix + dX ----------------
template<typename T>
__device__ __forceinline__ void sf_impl(
  const int* offsets, const int* csrc,
  const bf16* eabuf, const bf16* Y10, const T* lt,
  float* X9, T* out, int write_out, float (*sm)[10][128])
{
  int n0 = blockIdx.x*NB, h = threadIdx.x;
  #pragma unroll
  for (int nn=0;nn<NB;++nn){
    int n = n0+nn;
    float am=0, vm0=0,vm1=0,vm2=0, smm0=0,smm1=0,smm2=0,smm3=0,smm4=0,smm5=0;
    int beg = offsets[n], end = offsets[n+1];
    int i = beg;
    for (; i+4 <= end; i += 4){
      int ss[4];
      #pragma unroll
      for (int u=0;u<4;++u){ ss[u] = csrc[i+u]; }
      float e0a[4], e1a[4], e2a[4];
      float y0[4],y1[4],y2[4],y3[4],y4[4],y5[4],y6[4],y7[4],y8[4],y9[4];
      #pragma unroll
      for (int u=0;u<4;++u){
        const bf16* ep = eabuf + (size_t)(i+u)*384;
        e0a[u]=b2f(ep[h]); e1a[u]=b2f(ep[128+h]); e2a[u]=b2f(ep[256+h]);
        const bf16* yp = Y10 + (size_t)ss[u]*1280;
        y0[u]=b2f(yp[0*128+h]); y1[u]=b2f(yp[1*128+h]); y2[u]=b2f(yp[2*128+h]);
        y3[u]=b2f(yp[3*128+h]); y4[u]=b2f(yp[4*128+h]); y5[u]=b2f(yp[5*128+h]);
        y6[u]=b2f(yp[6*128+h]); y7[u]=b2f(yp[7*128+h]); y8[u]=b2f(yp[8*128+h]);
        y9[u]=b2f(yp[9*128+h]);
      }
      #pragma unroll
      for (int u=0;u<4;++u){
        am   += e0a[u]*y0[u];
        vm0  += e1a[u]*y1[u]; vm1 += e1a[u]*y2[u]; vm2 += e1a[u]*y3[u];
        smm0 += e2a[u]*y4[u]; smm1 += e2a[u]*y5[u]; smm2 += e2a[u]*y6[u];
        smm3 += e2a[u]*y7[u]; smm4 += e2a[u]*y8[u]; smm5 += e2a[u]*y9[u];
      }
    }
    for (; i<end; ++i){
      int s = csrc[i];
      const bf16* ep = eabuf + (size_t)i*384;
      float e0 = b2f(ep[h]), e1 = b2f(ep[128+h]), e2 = b2f(ep[256+h]);
      const bf16* yp = Y10 + (size_t)s*1280;
      am   += e0*b2f(yp[0*128+h]);
      vm0  += e1*b2f(yp[1*128+h]); vm1 += e1*b2f(yp[2*128+h]); vm2 += e1*b2f(yp[3*128+h]);
      smm0 += e2*b2f(yp[4*128+h]); smm1 += e2*b2f(yp[5*128+h]); smm2 += e2*b2f(yp[6*128+h]);
      smm3 += e2*b2f(yp[7*128+h]); smm4 += e2*b2f(yp[8*128+h]); smm5 += e2*b2f(yp[9*128+h]);
    }
    const bf16* yp = Y10 + (size_t)n*1280;
    float aY=b2f(yp[0*128+h]), u0=b2f(yp[1*128+h]), u1=b2f(yp[2*128+h]), u2=b2f(yp[3*128+h]);
    float q0=b2f(yp[4*128+h]), q1=b2f(yp[5*128+h]), q2=b2f(yp[6*128+h]);
    float q3=b2f(yp[7*128+h]), q4=b2f(yp[8*128+h]), q5=b2f(yp[9*128+h]);
    float m00=am+smm0,   m01=-vm2+smm1, m02= vm1+smm2;
    float m10= vm2+smm1, m11=am+smm3,  m12=-vm0+smm4;
    float m20=-vm1+smm2, m21= vm0+smm4, m22=am+smm5;
    float y00=aY+q0,  y01=-u2+q1, y02= u1+q2;
    float y10= u2+q1, y11=aY+q3,  y12=-u0+q4;
    float y20=-u1+q2, y21= u0+q4, y22=aY+q5;
    float ab00 = m00*y00+m01*y10+m02*y20 + y00*m00+y01*m10+y02*m20;
    float ab01 = m00*y01+m01*y11+m02*y21 + y00*m01+y01*m11+y02*m21;
    float ab02 = m00*y02+m01*y12+m02*y22 + y00*m02+y01*m12+y02*m22;
    float ab10 = m10*y00+m11*y10+m12*y20 + y10*m00+y11*m10+y12*m20;
    float ab11 = m10*y01+m11*y11+m12*y21 + y10*m01+y11*m11+y12*m21;
    float ab12 = m10*y02+m11*y12+m12*y22 + y10*m02+y11*m12+y12*m22;
    float ab20 = m20*y00+m21*y10+m22*y20 + y20*m00+y21*m10+y22*m20;
    float ab21 = m20*y01+m21*y11+m22*y21 + y20*m01+y21*m11+y22*m21;
    float ab22 = m20*y02+m21*y12+m22*y22 + y20*m02+y21*m12+y22*m22;
    float a2 = (ab00+ab11+ab22)*(1.0f/3.0f);
    float w0 = 0.5f*(ab21-ab12), w1 = 0.5f*(ab02-ab20), w2 = 0.5f*(ab10-ab01);
    float t0 = ab00-a2, t1 = 0.5f*(ab01+ab10), t2 = 0.5f*(ab02+ab20);
    float t3 = ab11-a2, t4 = 0.5f*(ab12+ab21), t5 = ab22-a2;
    float dnm = ab00*ab00+ab01*ab01+ab02*ab02+ab10*ab10+ab11*ab11+ab12*ab12
              + ab20*ab20+ab21*ab21+ab22*ab22 + 1.0f;
    float inv = 1.0f/dnm;
    sm[nn][0][h]=a2*inv; sm[nn][1][h]=w0*inv; sm[nn][2][h]=w1*inv; sm[nn][3][h]=w2*inv;
    sm[nn][4][h]=t0*inv; sm[nn][5][h]=t1*inv; sm[nn][6][h]=t2*inv;
    sm[nn][7][h]=t3*inv; sm[nn][8][h]=t4*inv; sm[nn][9][h]=t5*inv;
  }
  __syncthreads();
  float at[NB]={0};
  float vt0[NB]={0}, vt1[NB]={0}, vt2[NB]={0};
  float st0[NB]={0}, st1[NB]={0}, st2[NB]={0};
  float st3[NB]={0}, st4[NB]={0}, st5[NB]={0};
  for (int r=0;r<128;++r){
    float ww0 = ldf(lt,(size_t)r*128+h);
    float ww1 = ldf(lt,(size_t)16384+r*128+h);
    float ww2 = ldf(lt,(size_t)32768+r*128+h);
    #pragma unroll
    for (int nn=0;nn<NB;++nn){
      at[nn]  += sm[nn][0][r]*ww0;
      vt0[nn] += sm[nn][1][r]*ww1; vt1[nn] += sm[nn][2][r]*ww1; vt2[nn] += sm[nn][3][r]*ww1;
      st0[nn] += sm[nn][4][r]*ww2; st1[nn] += sm[nn][5][r]*ww2; st2[nn] += sm[nn][6][r]*ww2;
      st3[nn] += sm[nn][7][r]*ww2; st4[nn] += sm[nn][8][r]*ww2; st5[nn] += sm[nn][9][r]*ww2;
    }
  }
  #pragma unroll
  for (int nn=0;nn<NB;++nn){
    int n = n0+nn;
    float d00=at[nn]+st0[nn],   d01=-vt2[nn]+st1[nn], d02= vt1[nn]+st2[nn];
    float d10= vt2[nn]+st1[nn], d11=at[nn]+st3[nn],  d12=-vt0[nn]+st4[nn];
    float d20=-vt1[nn]+st2[nn], d21= vt0[nn]+st4[nn], d22=at[nn]+st5[nn];
    float g00 = d00 + d00*d00+d01*d10+d02*d20;
    float g01 = d01 + d00*d01+d01*d11+d02*d21;
    float g02 = d02 + d00*d02+d01*d12+d02*d22;
    float g10 = d10 + d10*d00+d11*d10+d12*d20;
    float g11 = d11 + d10*d01+d11*d11+d12*d21;
    float g12 = d12 + d10*d02+d11*d12+d12*d22;
    float g20 = d20 + d20*d00+d21*d10+d22*d20;
    float g21 = d21 + d20*d01+d21*d11+d22*d21;
    float g22 = d22 + d20*d02+d21*d12+d22*d22;
    float* xp = X9 + (size_t)n*1152;
    float x00=xp[0*128+h]+g00, x01=xp[1*128+h]+g01, x02=xp[2*128+h]+g02;
    float x10=xp[3*128+h]+g10, x11=xp[4*128+h]+g11, x12=xp[5*128+h]+g12;
    float x20=xp[6*128+h]+g20, x21=xp[7*128+h]+g21, x22=xp[8*128+h]+g22;
    if (write_out){
      if (sizeof(T)==4){
        float* of = (float*)out + ((size_t)n*128 + h)*9;
        of[0]=x00; of[1]=x01; of[2]=x02; of[3]=x10; of[4]=x11; of[5]=x12; of[6]=x20; of[7]=x21; of[8]=x22;
      } else {
        bf16* ob = (bf16*)out + ((size_t)n*128 + h)*9;
        ob[0]=__float2bfloat16(x00); ob[1]=__float2bfloat16(x01); ob[2]=__float2bfloat16(x02);
        ob[3]=__float2bfloat16(x10); ob[4]=__float2bfloat16(x11); ob[5]=__float2bfloat16(x12);
        ob[6]=__float2bfloat16(x20); ob[7]=__float2bfloat16(x21); ob[8]=__float2bfloat16(x22);
      }
    } else {
      xp[0*128+h]=x00; xp[1*128+h]=x01; xp[2*128+h]=x02;
      xp[3*128+h]=x10; xp[4*128+h]=x11; xp[5*128+h]=x12;
      xp[6*128+h]=x20; xp[7*128+h]=x21; xp[8*128+h]=x22;
    }
  }
}
__global__ void __launch_bounds__(128) k_msg_sf(
  const int* __restrict__ offsets, const int* __restrict__ csrc,
  const bf16* __restrict__ eabuf, const bf16* __restrict__ Y10,
  const void* lt, long ltoff, float* __restrict__ X9, void* __restrict__ out,
  const int* __restrict__ flag, int write_out)
{
  __shared__ float sm[NB][10][128];
  if (flag[0]) sf_impl<float>(offsets, csrc, eabuf, Y10, (const float*)lt + ltoff, X9, (float*)out, write_out, sm);
  else         sf_impl<bf16 >(offsets, csrc, eabuf, Y10, (const bf16* )lt + ltoff, X9, (bf16* )out, write_out, sm);
}

extern "C" void kernel_launch(void* const* d_in, const int* in_sizes, int n_in,
                              void* d_out, int out_size, void* d_ws, size_t ws_size,
                              hipStream_t stream)
{
  (void)in_sizes; (void)n_in; (void)out_size; (void)ws_size;
  const int* z    = (const int*)d_in[0];
  const int* eidx = (const int*)d_in[1];
  const int* src  = eidx;
  const int* dst  = eidx + NE;

  // Workspace: ~58.3 MiB (proven budget >= 74 MiB).
  char* w = (char*)d_ws;
  int* flag    = (int*)w;   w += 64;
  int* counts  = (int*)w;   w += (size_t)NN*4;
  int* offsets = (int*)w;   w += (size_t)(NN+1)*4 + 60;
  int* cursor  = (int*)w;   w += (size_t)NN*4;
  int* csr     = (int*)w;   w += (size_t)NE*4;
  int* pos     = (int*)w;   w += (size_t)NE*4;
  int* csrc    = (int*)w;   w += (size_t)NE*4;
  float* gC    = (float*)w; w += (size_t)NE*4;
  float* gVp   = (float*)w; w += (size_t)NE*12;
  float* P1z   = (float*)w; w += (size_t)MAXZ*HH*4;
  float* P2z   = (float*)w; w += (size_t)MAXZ*HH*4;
  bf16* eabuf  = (bf16*)w;  w += (size_t)NE*384*2;
  float* X9    = (float*)w; w += (size_t)NN*1152*4;
  bf16* Y10    = (bf16*)w;  w += (size_t)NN*1280*2;
  unsigned short* eattr_c = (unsigned short*)w; w += (size_t)NE*32*2;
  unsigned short* pw0[2]; unsigned short* pw1[2]; unsigned short* pw2[2];
  for (int l=0;l<2;++l){
    pw0[l] = (unsigned short*)w; w += 8*64*8*2;
    pw1[l] = (unsigned short*)w; w += 64*64*8*2;
    pw2[l] = (unsigned short*)w; w += 192*64*8*2;
  }

  k_detect<<<1, 256, 0, stream>>>((const unsigned int*)d_in[4], flag);
  hipMemsetAsync(counts, 0, (size_t)NN*4, stream);
  k_count<<<NE/256, 256, 0, stream>>>(dst, counts);
  k_scan<<<1, 1024, 0, stream>>>(counts, offsets, cursor);
  k_fill<<<NE/256, 256, 0, stream>>>(dst, src, cursor, csr, pos, csrc);
  k_geom<<<NE/256, 256, 0, stream>>>(d_in[2], d_in[3], src, dst, pos, gC, gVp, flag);
  k_zemb<<<MAXZ, 128, 0, stream>>>(d_in[5], d_in[12], P1z, P2z, flag);
  k_cvt_attr<<<NE*32/256, 256, 0, stream>>>(d_in[4], eattr_c, flag);

  PackDescs pd;
  for (int l=0;l<2;++l){
    pd.base[l*3+0] = d_in[21]; pd.eoff[l*3+0] = (long)l*32*128;
    pd.base[l*3+1] = d_in[23]; pd.eoff[l*3+1] = (long)l*128*256;
    pd.base[l*3+2] = d_in[25]; pd.eoff[l*3+2] = (long)l*256*384;
    pd.out[l*3+0] = pw0[l]; pd.K[l*3+0]=32;  pd.N[l*3+0]=128;
    pd.out[l*3+1] = pw1[l]; pd.K[l*3+1]=128; pd.N[l*3+1]=256;
    pd.out[l*3+2] = pw2[l]; pd.K[l*3+2]=256; pd.N[l*3+2]=384;
  }
  k_pack<<<dim3(48, 6), 256, 0, stream>>>(pd, flag);

  k_tne_edge<<<NE/TPB, 128, 0, stream>>>(d_in[4], src, dst, z, pos,
      d_in[6], d_in[7], d_in[8], d_in[9], d_in[10], d_in[11], d_in[13],
      P1z, P2z, gC, eabuf, flag);
  k_tne_node<<<NN/NB, 128, 0, stream>>>(offsets, gVp, eabuf,
      d_in[19], d_in[20], d_in[14], d_in[15], d_in[16], d_in[17], d_in[18], X9, flag);

  for (int l=0; l<2; ++l){
    k_msg_edge_mfma<<<NE/32, 128, 0, stream>>>(eattr_c, gC, pos, pw0[l], pw1[l], pw2[l],
        d_in[22], d_in[24], d_in[26], (long)l*128, (long)l*256, (long)l*384,
        (unsigned short*)eabuf, flag);
    k_msg_prep<<<NN/NB, 128, 0, stream>>>(X9, d_in[27], (long)l*3*128*128, Y10, flag);
    k_msg_sf<<<NN/NB, 128, 0, stream>>>(offsets, csrc, eabuf, Y10,
        d_in[28], (long)l*3*128*128, X9, d_out, flag, (l==1)?1:0);
  }
}

// Round 16
// 444.799 us; speedup vs baseline: 1.0677x; 1.0194x over previous
//
#include <hip/hip_runtime.h>
#include <hip/hip_bf16.h>

typedef __hip_bfloat16 bf16;
typedef __attribute__((ext_vector_type(8))) short short8v;   // 8 bf16 = 4 VGPRs (MFMA A/B frag)
typedef __attribute__((ext_vector_type(4))) float f32x4;     // MFMA C/D frag

#define NN 4096
#define NE 32768
#define HH 128
#define MAXZ 100
#define TPB 8    // edges per block, TNE edge kernel
#define NB 2     // nodes per block in node-side kernels

// ENVIRONMENT FACTS (r0-r15): float tensors are FLOAT32; runtime detector kept.
// MFMA msg-edge path hardware-validated r10. NB=2 best. eabuf CSR-ordered (r15).
// r15 lesson: tne_node is near its structural VALU cost; the bigger target is
// k_msg_edge_mfma (2 waves/SIMD, ~95us x2). r16: split N-dim across 4 waves,
// 16 edges/block, grid NE/16 -> 32 waves/CU. Same per-tile MFMA math =>
// absmax must stay 0.00206089.

__device__ __forceinline__ float b2f(bf16 v){ return __bfloat162float(v); }
__device__ __forceinline__ float ldf(const float* p, size_t i){ return p[i]; }
__device__ __forceinline__ float ldf(const bf16*  p, size_t i){ return __bfloat162float(p[i]); }
__device__ __forceinline__ float siluf(float x){ return x / (1.0f + __expf(-x)); }
__device__ __forceinline__ unsigned short f2bu(float x){
  bf16 h = __float2bfloat16(x);
  return *reinterpret_cast<unsigned short*>(&h);
}

// dtype detect: flag[0]=1 if float inputs are f32, 0 if bf16.
__global__ void __launch_bounds__(256) k_detect(const unsigned int* __restrict__ w, int* __restrict__ flag){
  __shared__ int cnt[256];
  int t = threadIdx.x;
  int c = 0;
  for (int i = t; i < 4096; i += 256){
    unsigned int lo = w[i] & 0xffffu;
    int e = (int)((lo >> 7) & 0xffu);
    c += (e >= 110 && e <= 132) ? 1 : 0;
  }
  cnt[t] = c; __syncthreads();
  for (int off=128; off>=1; off>>=1){ if (t<off) cnt[t]+=cnt[t+off]; __syncthreads(); }
  if (t==0) flag[0] = (cnt[0] < 2048) ? 1 : 0;
}

// ---------------- CSR build ----------------
__global__ void __launch_bounds__(256) k_count(const int* __restrict__ dst, int* __restrict__ counts){
  int e = blockIdx.x*256 + threadIdx.x;
  if (e < NE) atomicAdd(&counts[dst[e]], 1);
}

__global__ void __launch_bounds__(1024) k_scan(const int* __restrict__ counts, int* __restrict__ offsets, int* __restrict__ cursor){
  __shared__ int lds[1024];
  int t = threadIdx.x;
  int c0 = counts[4*t+0], c1 = counts[4*t+1], c2 = counts[4*t+2], c3 = counts[4*t+3];
  int s1 = c0+c1, s2 = s1+c2, s3 = s2+c3;
  lds[t] = s3;
  __syncthreads();
  for (int off=1; off<1024; off<<=1){
    int v = lds[t];
    int add = (t>=off)? lds[t-off] : 0;
    __syncthreads();
    lds[t] = v + add;
    __syncthreads();
  }
  int incl = lds[t];
  int base = incl - s3;
  offsets[4*t+0]=base;    offsets[4*t+1]=base+c0; offsets[4*t+2]=base+s1; offsets[4*t+3]=base+s2;
  cursor [4*t+0]=base;    cursor [4*t+1]=base+c0; cursor [4*t+2]=base+s1; cursor [4*t+3]=base+s2;
  if (t==1023) offsets[4096]=incl;
}

// fill: also record pos[e] (CSR slot of edge e) and csrc[p] (src node of CSR slot p)
__global__ void __launch_bounds__(256) k_fill(const int* __restrict__ dst, const int* __restrict__ src,
                                              int* __restrict__ cursor, int* __restrict__ csr,
                                              int* __restrict__ pos, int* __restrict__ csrc){
  int e = blockIdx.x*256 + threadIdx.x;
  if (e < NE){
    int p = atomicAdd(&cursor[dst[e]], 1);
    csr[p] = e;
    pos[e] = p;
    csrc[p] = src[e];
  }
}

// ---------------- edge geometry (gV written in CSR order) ----------------
template<typename T>
__device__ __forceinline__ void geom_impl(const T* ew, const T* evec,
    const int* src, const int* dst, const int* pos, float* gC, float* gVp){
  int e = blockIdx.x*256 + threadIdx.x;
  if (e >= NE) return;
  float d = ldf(ew, e);
  float c = 0.5f*(cosf(d*0.6283185307179586f)+1.0f);
  c = (d < 5.0f) ? c : 0.0f;
  gC[e] = c;
  float x = ldf(evec, (size_t)e*3+0), y = ldf(evec, (size_t)e*3+1), z = ldf(evec, (size_t)e*3+2);
  if (src[e] != dst[e]){
    float n = sqrtf(x*x+y*y+z*z);
    float inv = 1.0f/fmaxf(n, 1e-12f);
    x*=inv; y*=inv; z*=inv;
  }
  int p = pos[e];
  gVp[p*3+0]=x; gVp[p*3+1]=y; gVp[p*3+2]=z;
}
__global__ void __launch_bounds__(256) k_geom(const void* ew, const void* evec,
    const int* __restrict__ src, const int* __restrict__ dst, const int* __restrict__ pos,
    float* __restrict__ gC, float* __restrict__ gVp, const int* __restrict__ flag){
  if (flag[0]) geom_impl<float>((const float*)ew, (const float*)evec, src, dst, pos, gC, gVp);
  else         geom_impl<bf16 >((const bf16* )ew, (const bf16* )evec, src, dst, pos, gC, gVp);
}

// ---------------- per-z embedding products ----------------
template<typename T>
__device__ __forceinline__ void zemb_impl(const T* emb, const T* emb2_w,
    float* P1z, float* P2z, float* Zr){
  int zv = blockIdx.x, h = threadIdx.x;
  Zr[h] = ldf(emb, (size_t)zv*HH + h);
  __syncthreads();
  float p1=0.f, p2=0.f;
  for (int r=0;r<128;++r){
    float x = Zr[r];
    p1 += x*ldf(emb2_w, (size_t)r*HH+h);
    p2 += x*ldf(emb2_w, (size_t)(r+128)*HH+h);
  }
  P1z[zv*HH+h]=p1; P2z[zv*HH+h]=p2;
}
__global__ void __launch_bounds__(128) k_zemb(const void* emb, const void* emb2_w,
    float* __restrict__ P1z, float* __restrict__ P2z, const int* __restrict__ flag){
  __shared__ float Zr[128];
  if (flag[0]) zemb_impl<float>((const float*)emb, (const float*)emb2_w, P1z, P2z, Zr);
  else         zemb_impl<bf16 >((const bf16* )emb, (const bf16* )emb2_w, P1z, P2z, Zr);
}

// ---------------- convert edge_attr -> bf16 ----------------
__global__ void __launch_bounds__(256) k_cvt_attr(const void* in, unsigned short* __restrict__ out,
                                                  const int* __restrict__ flag){
  int i = blockIdx.x*256 + threadIdx.x;
  if (flag[0]) out[i] = f2bu(((const float*)in)[i]);
  else         out[i] = ((const unsigned short*)in)[i];
}

// ---------------- weight repack into MFMA B-fragment layout ----------------
struct PackDescs {
  const void*     base[6];
  long            eoff[6];
  unsigned short* out[6];
  int K[6]; int N[6];
};
template<typename T>
__device__ __forceinline__ void pack_impl(const PackDescs& d){
  int y = blockIdx.y;
  int K = d.K[y], N = d.N[y];
  int ktiles = K>>5, ntiles = N>>4;
  int total = ktiles*ntiles*64;
  int idx = blockIdx.x*256 + threadIdx.x;
  if (idx >= total) return;
  int lane = idx & 63, tile = idx >> 6;
  int kt = tile % ktiles, nt = tile / ktiles;
  const T* W = (const T*)d.base[y] + d.eoff[y];
  int n = nt*16 + (lane&15), k0 = kt*32 + (lane>>4)*8;
  unsigned int t[8];
  #pragma unroll
  for (int j=0;j<8;++j) t[j] = f2bu(ldf(W, (size_t)(k0+j)*N + n));
  uint4 v;
  v.x = t[0] | (t[1]<<16);
  v.y = t[2] | (t[3]<<16);
  v.z = t[4] | (t[5]<<16);
  v.w = t[6] | (t[7]<<16);
  *reinterpret_cast<uint4*>(d.out[y] + ((size_t)tile*64 + lane)*8) = v;
}
__global__ void __launch_bounds__(256) k_pack(PackDescs d, const int* __restrict__ flag){
  if (flag[0]) pack_impl<float>(d);
  else         pack_impl<bf16 >(d);
}

// ---------------- TNE edge coefficients -> eabuf bf16 (CSR-ordered rows) ----------------
template<typename T>
__device__ __forceinline__ void tne_edge_impl(
  const T* eattr, const int* src, const int* dst, const int* z, const int* pos,
  const T* dp1_w, const T* dp1_b, const T* dp2_w, const T* dp2_b,
  const T* dp3_w, const T* dp3_b, const T* emb2_b,
  const float* P1z, const float* P2z, const float* gC, bf16* eabuf,
  float (*attr)[32], int* zd, int* zs, int* ppos)
{
  int e0 = blockIdx.x*TPB;
  int h  = threadIdx.x;
  for (int i=h; i<TPB*32; i+=128) attr[i>>5][i&31] = ldf(eattr, (size_t)e0*32 + i);
  if (h < TPB){ int e=e0+h; zd[h]=z[dst[e]]; zs[h]=z[src[e]]; ppos[h]=pos[e]; }
  __syncthreads();
  float w1[TPB], w2[TPB], w3[TPB];
  float b1v=ldf(dp1_b,h), b2v=ldf(dp2_b,h), b3v=ldf(dp3_b,h);
  #pragma unroll
  for (int e=0;e<TPB;++e){ w1[e]=b1v; w2[e]=b2v; w3[e]=b3v; }
  for (int r=0;r<32;++r){
    float u1=ldf(dp1_w,(size_t)r*HH+h), u2=ldf(dp2_w,(size_t)r*HH+h), u3=ldf(dp3_w,(size_t)r*HH+h);
    #pragma unroll
    for (int e=0;e<TPB;++e){ float a=attr[e][r]; w1[e]+=a*u1; w2[e]+=a*u2; w3[e]+=a*u3; }
  }
  float eb = ldf(emb2_b,h);
  #pragma unroll
  for (int e=0;e<TPB;++e){
    float zij = P1z[zd[e]*HH+h] + P2z[zs[e]*HH+h] + eb;
    float c = gC[e0+e];
    bf16* p = eabuf + (size_t)ppos[e]*384;
    p[h]     = __float2bfloat16(zij*w1[e]*c);
    p[128+h] = __float2bfloat16(zij*w2[e]*c);
    p[256+h] = __float2bfloat16(zij*w3[e]*c);
  }
}
__global__ void __launch_bounds__(128) k_tne_edge(
  const void* eattr, const int* __restrict__ src, const int* __restrict__ dst,
  const int* __restrict__ z, const int* __restrict__ pos,
  const void* dp1_w, const void* dp1_b, const void* dp2_w, const void* dp2_b,
  const void* dp3_w, const void* dp3_b, const void* emb2_b,
  const float* __restrict__ P1z, const float* __restrict__ P2z,
  const float* __restrict__ gC, bf16* __restrict__ eabuf, const int* __restrict__ flag)
{
  __shared__ float attr[TPB][32];
  __shared__ int zd[TPB], zs[TPB], ppos[TPB];
  if (flag[0]) tne_edge_impl<float>((const float*)eattr, src, dst, z, pos,
      (const float*)dp1_w, (const float*)dp1_b, (const float*)dp2_w, (const float*)dp2_b,
      (const float*)dp3_w, (const float*)dp3_b, (const float*)emb2_b, P1z, P2z, gC, eabuf, attr, zd, zs, ppos);
  else tne_edge_impl<bf16>((const bf16*)eattr, src, dst, z, pos,
      (const bf16*)dp1_w, (const bf16*)dp1_b, (const bf16*)dp2_w, (const bf16*)dp2_b,
      (const bf16*)dp3_w, (const bf16*)dp3_b, (const bf16*)emb2_b, P1z, P2z, gC, eabuf, attr, zd, zs, ppos);
}

// ---------------- TNE node: NB nodes/block, SEQUENTIAL eabuf/gVp reads ----------------
template<typename T>
__device__ __forceinline__ void tne_node_impl(
  const int* offsets, const float* gVp, const bf16* eabuf,
  const T* ln_g, const T* ln_b, const T* tne_lt,
  const T* s0_w, const T* s0_b, const T* s1_w, const T* s1_b, float* X9,
  float (*sm)[10][128], float* red, float (*lnv)[128], float (*h1s)[256])
{
  int n0 = blockIdx.x*NB, h = threadIdx.x;
  float tnv[NB];
  #pragma unroll
  for (int nn=0;nn<NB;++nn){
    int n = n0+nn;
    float a=0, v0=0,v1=0,v2=0, s0=0,s1=0,s2=0,s3=0,s4=0,s5=0;
    int beg = offsets[n], end = offsets[n+1];
    int i = beg;
    for (; i+4 <= end; i += 4){
      float c1[4],c2[4],c3[4],vx[4],vy[4],vz[4];
      #pragma unroll
      for (int u=0;u<4;++u){
        const bf16* p = eabuf + (size_t)(i+u)*384;
        c1[u]=b2f(p[h]); c2[u]=b2f(p[128+h]); c3[u]=b2f(p[256+h]);
        vx[u]=gVp[(i+u)*3+0]; vy[u]=gVp[(i+u)*3+1]; vz[u]=gVp[(i+u)*3+2];
      }
      #pragma unroll
      for (int u=0;u<4;++u){
        float tr3 = (vx[u]*vx[u]+vy[u]*vy[u]+vz[u]*vz[u])*(1.0f/3.0f);
        a  += c1[u];
        v0 += c2[u]*vx[u]; v1 += c2[u]*vy[u]; v2 += c2[u]*vz[u];
        s0 += c3[u]*(vx[u]*vx[u] - tr3); s1 += c3[u]*vx[u]*vy[u]; s2 += c3[u]*vx[u]*vz[u];
        s3 += c3[u]*(vy[u]*vy[u] - tr3); s4 += c3[u]*vy[u]*vz[u]; s5 += c3[u]*(vz[u]*vz[u] - tr3);
      }
    }
    for (; i<end; ++i){
      const bf16* p = eabuf + (size_t)i*384;
      float c1 = b2f(p[h]), c2 = b2f(p[128+h]), c3 = b2f(p[256+h]);
      float vx = gVp[i*3+0], vy = gVp[i*3+1], vz = gVp[i*3+2];
      float tr3 = (vx*vx+vy*vy+vz*vz)*(1.0f/3.0f);
      a  += c1;
      v0 += c2*vx; v1 += c2*vy; v2 += c2*vz;
      s0 += c3*(vx*vx - tr3); s1 += c3*vx*vy;          s2 += c3*vx*vz;
      s3 += c3*(vy*vy - tr3); s4 += c3*vy*vz;          s5 += c3*(vz*vz - tr3);
    }
    sm[nn][0][h]=a; sm[nn][1][h]=v0; sm[nn][2][h]=v1; sm[nn][3][h]=v2;
    sm[nn][4][h]=s0; sm[nn][5][h]=s1; sm[nn][6][h]=s2; sm[nn][7][h]=s3; sm[nn][8][h]=s4; sm[nn][9][h]=s5;
    tnv[nn] = 3.0f*a*a + 2.0f*(v0*v0+v1*v1+v2*v2)
            + s0*s0 + s3*s3 + s5*s5 + 2.0f*(s1*s1 + s2*s2 + s4*s4);
  }
  float gg = ldf(ln_g,h), bb = ldf(ln_b,h);
  #pragma unroll
  for (int nn=0;nn<NB;++nn){
    __syncthreads();
    red[h] = tnv[nn]; __syncthreads();
    for (int off=64; off>=1; off>>=1){ if (h<off) red[h]+=red[h+off]; __syncthreads(); }
    float mean = red[0]*(1.0f/128.0f);
    __syncthreads();
    float dm = tnv[nn] - mean;
    red[h] = dm*dm; __syncthreads();
    for (int off=64; off>=1; off>>=1){ if (h<off) red[h]+=red[h+off]; __syncthreads(); }
    float var = red[0]*(1.0f/128.0f);
    lnv[nn][h] = dm*rsqrtf(var+1e-5f)*gg + bb;
  }
  __syncthreads();
  {
    float ba = ldf(s0_b,2*h), bc = ldf(s0_b,2*h+1);
    float a0[NB], a1[NB];
    #pragma unroll
    for (int nn=0;nn<NB;++nn){ a0[nn]=ba; a1[nn]=bc; }
    for (int r=0;r<128;++r){
      float u0 = ldf(s0_w,(size_t)r*256+2*h), u1 = ldf(s0_w,(size_t)r*256+2*h+1);
      #pragma unroll
      for (int nn=0;nn<NB;++nn){ float x = lnv[nn][r]; a0[nn]+=x*u0; a1[nn]+=x*u1; }
    }
    #pragma unroll
    for (int nn=0;nn<NB;++nn){ h1s[nn][2*h] = siluf(a0[nn]); h1s[nn][2*h+1] = siluf(a1[nn]); }
  }
  __syncthreads();
  float f0[NB], f1[NB], f2[NB];
  {
    float b0 = ldf(s1_b,3*h), b1 = ldf(s1_b,3*h+1), b2 = ldf(s1_b,3*h+2);
    #pragma unroll
    for (int nn=0;nn<NB;++nn){ f0[nn]=b0; f1[nn]=b1; f2[nn]=b2; }
    for (int r=0;r<256;++r){
      float u0 = ldf(s1_w,(size_t)r*384+3*h), u1 = ldf(s1_w,(size_t)r*384+3*h+1), u2 = ldf(s1_w,(size_t)r*384+3*h+2);
      #pragma unroll
      for (int nn=0;nn<NB;++nn){ float x = h1s[nn][r]; f0[nn]+=x*u0; f1[nn]+=x*u1; f2[nn]+=x*u2; }
    }
    #pragma unroll
    for (int nn=0;nn<NB;++nn){ f0[nn]=siluf(f0[nn]); f1[nn]=siluf(f1[nn]); f2[nn]=siluf(f2[nn]); }
  }
  float am[NB]={0};
  float wm0[NB]={0}, wm1[NB]={0}, wm2[NB]={0};
  float t0[NB]={0}, t1[NB]={0}, t2[NB]={0};
  float t3[NB]={0}, t4[NB]={0}, t5[NB]={0};
  for (int r=0;r<128;++r){
    float w0 = ldf(tne_lt,(size_t)r*128+h);
    float w1 = ldf(tne_lt,(size_t)16384+r*128+h);
    float w2 = ldf(tne_lt,(size_t)32768+r*128+h);
    #pragma unroll
    for (int nn=0;nn<NB;++nn){
      am[nn]  += sm[nn][0][r]*w0;
      wm0[nn] += sm[nn][1][r]*w1; wm1[nn] += sm[nn][2][r]*w1; wm2[nn] += sm[nn][3][r]*w1;
      t0[nn] += sm[nn][4][r]*w2; t1[nn] += sm[nn][5][r]*w2; t2[nn] += sm[nn][6][r]*w2;
      t3[nn] += sm[nn][7][r]*w2; t4[nn] += sm[nn][8][r]*w2; t5[nn] += sm[nn][9][r]*w2;
    }
  }
  #pragma unroll
  for (int nn=0;nn<NB;++nn){
    float x00 = f0[nn]*am[nn] + f2[nn]*t0[nn];
    float x01 = -f1[nn]*wm2[nn] + f2[nn]*t1[nn];
    float x02 =  f1[nn]*wm1[nn] + f2[nn]*t2[nn];
    float x10 =  f1[nn]*wm2[nn] + f2[nn]*t1[nn];
    float x11 = f0[nn]*am[nn] + f2[nn]*t3[nn];
    float x12 = -f1[nn]*wm0[nn] + f2[nn]*t4[nn];
    float x20 = -f1[nn]*wm1[nn] + f2[nn]*t2[nn];
    float x21 =  f1[nn]*wm0[nn] + f2[nn]*t4[nn];
    float x22 = f0[nn]*am[nn] + f2[nn]*t5[nn];
    float* xp = X9 + (size_t)(n0+nn)*1152;
    xp[0*128+h]=x00; xp[1*128+h]=x01; xp[2*128+h]=x02;
    xp[3*128+h]=x10; xp[4*128+h]=x11; xp[5*128+h]=x12;
    xp[6*128+h]=x20; xp[7*128+h]=x21; xp[8*128+h]=x22;
  }
}
__global__ void __launch_bounds__(128) k_tne_node(
  const int* __restrict__ offsets, const float* __restrict__ gVp, const bf16* __restrict__ eabuf,
  const void* ln_g, const void* ln_b, const void* tne_lt,
  const void* s0_w, const void* s0_b, const void* s1_w, const void* s1_b,
  float* __restrict__ X9, const int* __restrict__ flag)
{
  __shared__ float sm[NB][10][128];
  __shared__ float red[128];
  __shared__ float lnv[NB][128];
  __shared__ float h1s[NB][256];
  if (flag[0]) tne_node_impl<float>(offsets, gVp, eabuf,
      (const float*)ln_g, (const float*)ln_b, (const float*)tne_lt,
      (const float*)s0_w, (const float*)s0_b, (const float*)s1_w, (const float*)s1_b, X9, sm, red, lnv, h1s);
  else tne_node_impl<bf16>(offsets, gVp, eabuf,
      (const bf16*)ln_g, (const bf16*)ln_b, (const bf16*)tne_lt,
      (const bf16*)s0_w, (const bf16*)s0_b, (const bf16*)s1_w, (const bf16*)s1_b, X9, sm, red, lnv, h1s);
}

// ---------------- msg edge MLP via MFMA: 16 edges/block, 4 waves split the N dim ----------------
// wave w computes output tiles nt === w (mod 4) of each layer; h1/h2 shared in LDS.
// Per-tile math identical to r10-validated kernel => same values.
template<typename T>
__device__ __forceinline__ void mfma_impl(
  const unsigned short* eattr_c, const float* gC, const int* pos,
  const unsigned short* p0, const unsigned short* p1, const unsigned short* p2,
  const T* b0, const T* b1, const T* b2,
  unsigned short* eabuf, unsigned short* h1p, unsigned short* h2p, int* spos)
{
  int wid  = threadIdx.x >> 6;        // 0..3
  int lane = threadIdx.x & 63;
  int e0 = blockIdx.x*16;
  int m = lane & 15, g = lane >> 4;
  if (threadIdx.x < 16) spos[threadIdx.x] = pos[e0 + threadIdx.x];
  float cc[4];
  #pragma unroll
  for (int r=0;r<4;++r) cc[r] = gC[e0 + g*4 + r];
  short8v a1 = *reinterpret_cast<const short8v*>(eattr_c + (size_t)(e0+m)*32 + g*8);
  // l0: 8 nt tiles, 2 per wave
  for (int nt=wid; nt<8; nt+=4){
    float bias = ldf(b0, nt*16+m);
    f32x4 acc = {bias,bias,bias,bias};
    short8v b = *reinterpret_cast<const short8v*>(p0 + ((size_t)nt*64 + lane)*8);
    acc = __builtin_amdgcn_mfma_f32_16x16x32_bf16(a1, b, acc, 0,0,0);
    #pragma unroll
    for (int r=0;r<4;++r){
      int n = nt*16 + m, row = g*4 + r;
      h1p[(n>>5)*512 + (((n>>3)&3)*16+row)*8 + (n&7)] = f2bu(siluf(acc[r]));
    }
  }
  __syncthreads();
  short8v a2[4];
  #pragma unroll
  for (int ks=0; ks<4; ++ks) a2[ks] = *reinterpret_cast<const short8v*>(&h1p[ks*512 + lane*8]);
  // l1: 16 nt tiles, 4 per wave
  for (int nt=wid; nt<16; nt+=4){
    float bias = ldf(b1, nt*16+m);
    f32x4 acc = {bias,bias,bias,bias};
    #pragma unroll
    for (int ks=0; ks<4; ++ks){
      short8v b = *reinterpret_cast<const short8v*>(p1 + ((size_t)(nt*4+ks)*64 + lane)*8);
      acc = __builtin_amdgcn_mfma_f32_16x16x32_bf16(a2[ks], b, acc, 0,0,0);
    }
    #pragma unroll
    for (int r=0;r<4;++r){
      int n = nt*16 + m, row = g*4 + r;
      h2p[(n>>5)*512 + (((n>>3)&3)*16+row)*8 + (n&7)] = f2bu(siluf(acc[r]));
    }
  }
  __syncthreads();
  short8v a3[8];
  #pragma unroll
  for (int ks=0; ks<8; ++ks) a3[ks] = *reinterpret_cast<const short8v*>(&h2p[ks*512 + lane*8]);
  // l2: 24 nt tiles, 6 per wave
  for (int nt=wid; nt<24; nt+=4){
    float bias = ldf(b2, nt*16+m);
    f32x4 acc = {bias,bias,bias,bias};
    #pragma unroll
    for (int ks=0; ks<8; ++ks){
      short8v b = *reinterpret_cast<const short8v*>(p2 + ((size_t)(nt*8+ks)*64 + lane)*8);
      acc = __builtin_amdgcn_mfma_f32_16x16x32_bf16(a3[ks], b, acc, 0,0,0);
    }
    #pragma unroll
    for (int r=0;r<4;++r){
      int n = nt*16 + m, row = g*4 + r;
      float v = siluf(acc[r]) * cc[r];
      eabuf[(size_t)spos[row]*384 + (n%3)*128 + (n/3)] = f2bu(v);
    }
  }
}
__global__ void __launch_bounds__(256) k_msg_edge_mfma(
  const unsigned short* __restrict__ eattr_c, const float* __restrict__ gC,
  const int* __restrict__ pos,
  const unsigned short* __restrict__ p0, const unsigned short* __restrict__ p1,
  const unsigned short* __restrict__ p2,
  const void* b0, const void* b1, const void* b2, long boff0, long boff1, long boff2,
  unsigned short* __restrict__ eabuf, const int* __restrict__ flag)
{
  __shared__ __align__(16) unsigned short h1p[2048];
  __shared__ __align__(16) unsigned short h2p[4096];
  __shared__ int spos[16];
  if (flag[0]) mfma_impl<float>(eattr_c, gC, pos, p0, p1, p2,
      (const float*)b0 + boff0, (const float*)b1 + boff1, (const float*)b2 + boff2, eabuf, h1p, h2p, spos);
  else mfma_impl<bf16>(eattr_c, gC, pos, p0, p1, p2,
      (const bf16*)b0 + boff0, (const bf16*)b1 + boff1, (const bf16*)b2 + boff2, eabuf, h1p, h2p, spos);
}

// ---------------- msg node prep (NB nodes/block) ----------------
template<typename T>
__device__ __forceinline__ void prep_impl(
  float* X9, const T* lx, bf16* Y10, float (*sm)[10][128])
{
  int n0 = blockIdx.x*NB, h = threadIdx.x;
  #pragma unroll
  for (int nn=0;nn<NB;++nn){
    float* xp = X9 + (size_t)(n0+nn)*1152;
    float x00=xp[0*128+h], x01=xp[1*128+h], x02=xp[2*128+h];
    float x10=xp[3*128+h], x11=xp[4*128+h], x12=xp[5*128+h];
    float x20=xp[6*128+h], x21=xp[7*128+h], x22=xp[8*128+h];
    float tn = x00*x00+x01*x01+x02*x02+x10*x10+x11*x11+x12*x12+x20*x20+x21*x21+x22*x22;
    float inv = 1.0f/(tn+1.0f);
    x00*=inv; x01*=inv; x02*=inv; x10*=inv; x11*=inv; x12*=inv; x20*=inv; x21*=inv; x22*=inv;
    // Reference REBINDS X to normalized before the update (r3 fix).
    xp[0*128+h]=x00; xp[1*128+h]=x01; xp[2*128+h]=x02;
    xp[3*128+h]=x10; xp[4*128+h]=x11; xp[5*128+h]=x12;
    xp[6*128+h]=x20; xp[7*128+h]=x21; xp[8*128+h]=x22;
    float a = (x00+x11+x22)*(1.0f/3.0f);
    sm[nn][0][h]=a;
    sm[nn][1][h]=0.5f*(x21-x12);
    sm[nn][2][h]=0.5f*(x02-x20);
    sm[nn][3][h]=0.5f*(x10-x01);
    sm[nn][4][h]=x00-a;
    sm[nn][5][h]=0.5f*(x01+x10);
    sm[nn][6][h]=0.5f*(x02+x20);
    sm[nn][7][h]=x11-a;
    sm[nn][8][h]=0.5f*(x12+x21);
    sm[nn][9][h]=x22-a;
  }
  __syncthreads();
  float A[NB]={0};
  float V0[NB]={0}, V1[NB]={0}, V2[NB]={0};
  float S0[NB]={0}, S1[NB]={0}, S2[NB]={0};
  float S3[NB]={0}, S4[NB]={0}, S5[NB]={0};
  for (int r=0;r<128;++r){
    float w0 = ldf(lx,(size_t)r*128+h), w1 = ldf(lx,(size_t)16384+r*128+h), w2 = ldf(lx,(size_t)32768+r*128+h);
    #pragma unroll
    for (int nn=0;nn<NB;++nn){
      A[nn]  += sm[nn][0][r]*w0;
      V0[nn] += sm[nn][1][r]*w1; V1[nn] += sm[nn][2][r]*w1; V2[nn] += sm[nn][3][r]*w1;
      S0[nn] += sm[nn][4][r]*w2; S1[nn] += sm[nn][5][r]*w2; S2[nn] += sm[nn][6][r]*w2;
      S3[nn] += sm[nn][7][r]*w2; S4[nn] += sm[nn][8][r]*w2; S5[nn] += sm[nn][9][r]*w2;
    }
  }
  #pragma unroll
  for (int nn=0;nn<NB;++nn){
    bf16* yp = Y10 + (size_t)(n0+nn)*1280;
    yp[0*128+h]=__float2bfloat16(A[nn]);
    yp[1*128+h]=__float2bfloat16(V0[nn]); yp[2*128+h]=__float2bfloat16(V1[nn]); yp[3*128+h]=__float2bfloat16(V2[nn]);
    yp[4*128+h]=__float2bfloat16(S0[nn]); yp[5*128+h]=__float2bfloat16(S1[nn]); yp[6*128+h]=__float2bfloat16(S2[nn]);
    yp[7*128+h]=__float2bfloat16(S3[nn]); yp[8*128+h]=__float2bfloat16(S4[nn]); yp[9*128+h]=__float2bfloat16(S5[nn]);
  }
}
__global__ void __launch_bounds__(128) k_msg_prep(
  float* __restrict__ X9, const void* lx, long lxoff, bf16* __restrict__ Y10,
  const int* __restrict__ flag)
{
  __shared__ float sm[NB][10][128];
  if (flag[0]) prep_impl<float>(X9, (const float*)lx + lxoff, Y10, sm);
  else         prep_impl<bf16 >(X9, (const bf16* )lx + lxoff, Y10, sm);
}

// ---------------- msg scatter (sequential eabuf, Y10 gather via csrc) + AB + cmix + dX ----------------
template<typename T>
__device__ __forceinline__ void sf_impl(
  const int* offsets, const int* csrc,
  const bf16* eabuf, const bf16* Y10, const T* lt,
  float* X9, T* out, int write_out, float (*sm)[10][128])
{
  int n0 = blockIdx.x*NB, h = threadIdx.x;
  #pragma unroll
  for (int nn=0;nn<NB;++nn){
    int n = n0+nn;
    float am=0, vm0=0,vm1=0,vm2=0, smm0=0,smm1=0,smm2=0,smm3=0,smm4=0,smm5=0;
    int beg = offsets[n], end = offsets[n+1];
    int i = beg;
    for (; i+4 <= end; i += 4){
      int ss[4];
      #pragma unroll
      for (int u=0;u<4;++u){ ss[u] = csrc[i+u]; }
      float e0a[4], e1a[4], e2a[4];
      float y0[4],y1[4],y2[4],y3[4],y4[4],y5[4],y6[4],y7[4],y8[4],y9[4];
      #pragma unroll
      for (int u=0;u<4;++u){
        const bf16* ep = eabuf + (size_t)(i+u)*384;
        e0a[u]=b2f(ep[h]); e1a[u]=b2f(ep[128+h]); e2a[u]=b2f(ep[256+h]);
        const bf16* yp = Y10 + (size_t)ss[u]*1280;
        y0[u]=b2f(yp[0*128+h]); y1[u]=b2f(yp[1*128+h]); y2[u]=b2f(yp[2*128+h]);
        y3[u]=b2f(yp[3*128+h]); y4[u]=b2f(yp[4*128+h]); y5[u]=b2f(yp[5*128+h]);
        y6[u]=b2f(yp[6*128+h]); y7[u]=b2f(yp[7*128+h]); y8[u]=b2f(yp[8*128+h]);
        y9[u]=b2f(yp[9*128+h]);
      }
      #pragma unroll
      for (int u=0;u<4;++u){
        am   += e0a[u]*y0[u];
        vm0  += e1a[u]*y1[u]; vm1 += e1a[u]*y2[u]; vm2 += e1a[u]*y3[u];
        smm0 += e2a[u]*y4[u]; smm1 += e2a[u]*y5[u]; smm2 += e2a[u]*y6[u];
        smm3 += e2a[u]*y7[u]; smm4 += e2a[u]*y8[u]; smm5 += e2a[u]*y9[u];
      }
    }
    for (; i<end; ++i){
      int s = csrc[i];
      const bf16* ep = eabuf + (size_t)i*384;
      float e0 = b2f(ep[h]), e1 = b2f(ep[128+h]), e2 = b2f(ep[256+h]);
      const bf16* yp = Y10 + (size_t)s*1280;
      am   += e0*b2f(yp[0*128+h]);
      vm0  += e1*b2f(yp[1*128+h]); vm1 += e1*b2f(yp[2*128+h]); vm2 += e1*b2f(yp[3*128+h]);
      smm0 += e2*b2f(yp[4*128+h]); smm1 += e2*b2f(yp[5*128+h]); smm2 += e2*b2f(yp[6*128+h]);
      smm3 += e2*b2f(yp[7*128+h]); smm4 += e2*b2f(yp[8*128+h]); smm5 += e2*b2f(yp[9*128+h]);
    }
    const bf16* yp = Y10 + (size_t)n*1280;
    float aY=b2f(yp[0*128+h]), u0=b2f(yp[1*128+h]), u1=b2f(yp[2*128+h]), u2=b2f(yp[3*128+h]);
    float q0=b2f(yp[4*128+h]), q1=b2f(yp[5*128+h]), q2=b2f(yp[6*128+h]);
    float q3=b2f(yp[7*128+h]), q4=b2f(yp[8*128+h]), q5=b2f(yp[9*128+h]);
    float m00=am+smm0,   m01=-vm2+smm1, m02= vm1+smm2;
    float m10= vm2+smm1, m11=am+smm3,  m12=-vm0+smm4;
    float m20=-vm1+smm2, m21= vm0+smm4, m22=am+smm5;
    float y00=aY+q0,  y01=-u2+q1, y02= u1+q2;
    float y10= u2+q1, y11=aY+q3,  y12=-u0+q4;
    float y20=-u1+q2, y21= u0+q4, y22=aY+q5;
    float ab00 = m00*y00+m01*y10+m02*y20 + y00*m00+y01*m10+y02*m20;
    float ab01 = m00*y01+m01*y11+m02*y21 + y00*m01+y01*m11+y02*m21;
    float ab02 = m00*y02+m01*y12+m02*y22 + y00*m02+y01*m12+y02*m22;
    float ab10 = m10*y00+m11*y10+m12*y20 + y10*m00+y11*m10+y12*m20;
    float ab11 = m10*y01+m11*y11+m12*y21 + y10*m01+y11*m11+y12*m21;
    float ab12 = m10*y02+m11*y12+m12*y22 + y10*m02+y11*m12+y12*m22;
    float ab20 = m20*y00+m21*y10+m22*y20 + y20*m00+y21*m10+y22*m20;
    float ab21 = m20*y01+m21*y11+m22*y21 + y20*m01+y21*m11+y22*m21;
    float ab22 = m20*y02+m21*y12+m22*y22 + y20*m02+y21*m12+y22*m22;
    float a2 = (ab00+ab11+ab22)*(1.0f/3.0f);
    float w0 = 0.5f*(ab21-ab12), w1 = 0.5f*(ab02-ab20), w2 = 0.5f*(ab10-ab01);
    float t0 = ab00-a2, t1 = 0.5f*(ab01+ab10), t2 = 0.5f*(ab02+ab20);
    float t3 = ab11-a2, t4 = 0.5f*(ab12+ab21), t5 = ab22-a2;
    float dnm = ab00*ab00+ab01*ab01+ab02*ab02+ab10*ab10+ab11*ab11+ab12*ab12
              + ab20*ab20+ab21*ab21+ab22*ab22 + 1.0f;
    float inv = 1.0f/dnm;
    sm[nn][0][h]=a2*inv; sm[nn][1][h]=w0*inv; sm[nn][2][h]=w1*inv; sm[nn][3][h]=w2*inv;
    sm[nn][4][h]=t0*inv; sm[nn][5][h]=t1*inv; sm[nn][6][h]=t2*inv;
    sm[nn][7][h]=t3*inv; sm[nn][8][h]=t4*inv; sm[nn][9][h]=t5*inv;
  }
  __syncthreads();
  float at[NB]={0};
  float vt0[NB]={0}, vt1[NB]={0}, vt2[NB]={0};
  float st0[NB]={0}, st1[NB]={0}, st2[NB]={0};
  float st3[NB]={0}, st4[NB]={0}, st5[NB]={0};
  for (int r=0;r<128;++r){
    float ww0 = ldf(lt,(size_t)r*128+h);
    float ww1 = ldf(lt,(size_t)16384+r*128+h);
    float ww2 = ldf(lt,(size_t)32768+r*128+h);
    #pragma unroll
    for (int nn=0;nn<NB;++nn){
      at[nn]  += sm[nn][0][r]*ww0;
      vt0[nn] += sm[nn][1][r]*ww1; vt1[nn] += sm[nn][2][r]*ww1; vt2[nn] += sm[nn][3][r]*ww1;
      st0[nn] += sm[nn][4][r]*ww2; st1[nn] += sm[nn][5][r]*ww2; st2[nn] += sm[nn][6][r]*ww2;
      st3[nn] += sm[nn][7][r]*ww2; st4[nn] += sm[nn][8][r]*ww2; st5[nn] += sm[nn][9][r]*ww2;
    }
  }
  #pragma unroll
  for (int nn=0;nn<NB;++nn){
    int n = n0+nn;
    float d00=at[nn]+st0[nn],   d01=-vt2[nn]+st1[nn], d02= vt1[nn]+st2[nn];
    float d10= vt2[nn]+st1[nn], d11=at[nn]+st3[nn],  d12=-vt0[nn]+st4[nn];
    float d20=-vt1[nn]+st2[nn], d21= vt0[nn]+st4[nn], d22=at[nn]+st5[nn];
    float g00 = d00 + d00*d00+d01*d10+d02*d20;
    float g01 = d01 + d00*d01+d01*d11+d02*d21;
    float g02 = d02 + d00*d02+d01*d12+d02*d22;
    float g10 = d10 + d10*d00+d11*d10+d12*d20;
    float g11 = d11 + d10*d01+d11*d11+d12*d21;
    float g12 = d12 + d10*d02+d11*d12+d12*d22;
    float g20 = d20 + d20*d00+d21*d10+d22*d20;
    float g21 = d21 + d20*d01+d21*d11+d22*d21;
    float g22 = d22 + d20*d02+d21*d12+d22*d22;
    float* xp = X9 + (size_t)n*1152;
    float x00=xp[0*128+h]+g00, x01=xp[1*128+h]+g01, x02=xp[2*128+h]+g02;
    float x10=xp[3*128+h]+g10, x11=xp[4*128+h]+g11, x12=xp[5*128+h]+g12;
    float x20=xp[6*128+h]+g20, x21=xp[7*128+h]+g21, x22=xp[8*128+h]+g22;
    if (write_out){
      if (sizeof(T)==4){
        float* of = (float*)out + ((size_t)n*128 + h)*9;
        of[0]=x00; of[1]=x01; of[2]=x02; of[3]=x10; of[4]=x11; of[5]=x12; of[6]=x20; of[7]=x21; of[8]=x22;
      } else {
        bf16* ob = (bf16*)out + ((size_t)n*128 + h)*9;
        ob[0]=__float2bfloat16(x00); ob[1]=__float2bfloat16(x01); ob[2]=__float2bfloat16(x02);
        ob[3]=__float2bfloat16(x10); ob[4]=__float2bfloat16(x11); ob[5]=__float2bfloat16(x12);
        ob[6]=__float2bfloat16(x20); ob[7]=__float2bfloat16(x21); ob[8]=__float2bfloat16(x22);
      }
    } else {
      xp[0*128+h]=x00; xp[1*128+h]=x01; xp[2*128+h]=x02;
      xp[3*128+h]=x10; xp[4*128+h]=x11; xp[5*128+h]=x12;
      xp[6*128+h]=x20; xp[7*128+h]=x21; xp[8*128+h]=x22;
    }
  }
}
__global__ void __launch_bounds__(128) k_msg_sf(
  const int* __restrict__ offsets, const int* __restrict__ csrc,
  const bf16* __restrict__ eabuf, const bf16* __restrict__ Y10,
  const void* lt, long ltoff, float* __restrict__ X9, void* __restrict__ out,
  const int* __restrict__ flag, int write_out)
{
  __shared__ float sm[NB][10][128];
  if (flag[0]) sf_impl<float>(offsets, csrc, eabuf, Y10, (const float*)lt + ltoff, X9, (float*)out, write_out, sm);
  else         sf_impl<bf16 >(offsets, csrc, eabuf, Y10, (const bf16* )lt + ltoff, X9, (bf16* )out, write_out, sm);
}

extern "C" void kernel_launch(void* const* d_in, const int* in_sizes, int n_in,
                              void* d_out, int out_size, void* d_ws, size_t ws_size,
                              hipStream_t stream)
{
  (void)in_sizes; (void)n_in; (void)out_size; (void)ws_size;
  const int* z    = (const int*)d_in[0];
  const int* eidx = (const int*)d_in[1];
  const int* src  = eidx;
  const int* dst  = eidx + NE;

  // Workspace: ~58.3 MiB (proven budget >= 74 MiB).
  char* w = (char*)d_ws;
  int* flag    = (int*)w;   w += 64;
  int* counts  = (int*)w;   w += (size_t)NN*4;
  int* offsets = (int*)w;   w += (size_t)(NN+1)*4 + 60;
  int* cursor  = (int*)w;   w += (size_t)NN*4;
  int* csr     = (int*)w;   w += (size_t)NE*4;
  int* pos     = (int*)w;   w += (size_t)NE*4;
  int* csrc    = (int*)w;   w += (size_t)NE*4;
  float* gC    = (float*)w; w += (size_t)NE*4;
  float* gVp   = (float*)w; w += (size_t)NE*12;
  float* P1z   = (float*)w; w += (size_t)MAXZ*HH*4;
  float* P2z   = (float*)w; w += (size_t)MAXZ*HH*4;
  bf16* eabuf  = (bf16*)w;  w += (size_t)NE*384*2;
  float* X9    = (float*)w; w += (size_t)NN*1152*4;
  bf16* Y10    = (bf16*)w;  w += (size_t)NN*1280*2;
  unsigned short* eattr_c = (unsigned short*)w; w += (size_t)NE*32*2;
  unsigned short* pw0[2]; unsigned short* pw1[2]; unsigned short* pw2[2];
  for (int l=0;l<2;++l){
    pw0[l] = (unsigned short*)w; w += 8*64*8*2;
    pw1[l] = (unsigned short*)w; w += 64*64*8*2;
    pw2[l] = (unsigned short*)w; w += 192*64*8*2;
  }

  k_detect<<<1, 256, 0, stream>>>((const unsigned int*)d_in[4], flag);
  hipMemsetAsync(counts, 0, (size_t)NN*4, stream);
  k_count<<<NE/256, 256, 0, stream>>>(dst, counts);
  k_scan<<<1, 1024, 0, stream>>>(counts, offsets, cursor);
  k_fill<<<NE/256, 256, 0, stream>>>(dst, src, cursor, csr, pos, csrc);
  k_geom<<<NE/256, 256, 0, stream>>>(d_in[2], d_in[3], src, dst, pos, gC, gVp, flag);
  k_zemb<<<MAXZ, 128, 0, stream>>>(d_in[5], d_in[12], P1z, P2z, flag);
  k_cvt_attr<<<NE*32/256, 256, 0, stream>>>(d_in[4], eattr_c, flag);

  PackDescs pd;
  for (int l=0;l<2;++l){
    pd.base[l*3+0] = d_in[21]; pd.eoff[l*3+0] = (long)l*32*128;
    pd.base[l*3+1] = d_in[23]; pd.eoff[l*3+1] = (long)l*128*256;
    pd.base[l*3+2] = d_in[25]; pd.eoff[l*3+2] = (long)l*256*384;
    pd.out[l*3+0] = pw0[l]; pd.K[l*3+0]=32;  pd.N[l*3+0]=128;
    pd.out[l*3+1] = pw1[l]; pd.K[l*3+1]=128; pd.N[l*3+1]=256;
    pd.out[l*3+2] = pw2[l]; pd.K[l*3+2]=256; pd.N[l*3+2]=384;
  }
  k_pack<<<dim3(48, 6), 256, 0, stream>>>(pd, flag);

  k_tne_edge<<<NE/TPB, 128, 0, stream>>>(d_in[4], src, dst, z, pos,
      d_in[6], d_in[7], d_in[8], d_in[9], d_in[10], d_in[11], d_in[13],
      P1z, P2z, gC, eabuf, flag);
  k_tne_node<<<NN/NB, 128, 0, stream>>>(offsets, gVp, eabuf,
      d_in[19], d_in[20], d_in[14], d_in[15], d_in[16], d_in[17], d_in[18], X9, flag);

  for (int l=0; l<2; ++l){
    k_msg_edge_mfma<<<NE/16, 256, 0, stream>>>(eattr_c, gC, pos, pw0[l], pw1[l], pw2[l],
        d_in[22], d_in[24], d_in[26], (long)l*128, (long)l*256, (long)l*384,
        (unsigned short*)eabuf, flag);
    k_msg_prep<<<NN/NB, 128, 0, stream>>>(X9, d_in[27], (long)l*3*128*128, Y10, flag);
    k_msg_sf<<<NN/NB, 128, 0, stream>>>(offsets, csrc, eabuf, Y10,
        d_in[28], (long)l*3*128*128, X9, d_out, flag, (l==1)?1:0);
  }
}

// Round 17
// 387.629 us; speedup vs baseline: 1.2252x; 1.1475x over previous
//
#include <hip/hip_runtime.h>
#include <hip/hip_bf16.h>

typedef __hip_bfloat16 bf16;
typedef __attribute__((ext_vector_type(8))) short short8v;   // 8 bf16 = 4 VGPRs (MFMA A/B frag)
typedef __attribute__((ext_vector_type(4))) float f32x4;     // MFMA C/D frag

#define NN 4096
#define NE 32768
#define HH 128
#define MAXZ 100
#define TPB 8    // edges per block, TNE edge kernel
#define NB 2     // nodes per block in node-side kernels

// ENVIRONMENT FACTS (r0-r16): float tensors are FLOAT32; runtime detector kept.
// MFMA msg-edge path hardware-validated r10. eabuf CSR-ordered (r15).
// r16 diagnosis: tne_node was L2-BW-bound on redundant weight streams
// (~700KB/block x 2048 blocks = 1.4GB L2 = 41us floor). r17: node path split
// into scat + MFMA MLP + MFMA cmix (16-node tiles => weight traffic /8).
// absmax will shift (bf16+MFMA node path) — expect ~2-4e-3.

__device__ __forceinline__ float b2f(bf16 v){ return __bfloat162float(v); }
__device__ __forceinline__ float ldf(const float* p, size_t i){ return p[i]; }
__device__ __forceinline__ float ldf(const bf16*  p, size_t i){ return __bfloat162float(p[i]); }
__device__ __forceinline__ float siluf(float x){ return x / (1.0f + __expf(-x)); }
__device__ __forceinline__ unsigned short f2bu(float x){
  bf16 h = __float2bfloat16(x);
  return *reinterpret_cast<unsigned short*>(&h);
}

// dtype detect: flag[0]=1 if float inputs are f32, 0 if bf16.
__global__ void __launch_bounds__(256) k_detect(const unsigned int* __restrict__ w, int* __restrict__ flag){
  __shared__ int cnt[256];
  int t = threadIdx.x;
  int c = 0;
  for (int i = t; i < 4096; i += 256){
    unsigned int lo = w[i] & 0xffffu;
    int e = (int)((lo >> 7) & 0xffu);
    c += (e >= 110 && e <= 132) ? 1 : 0;
  }
  cnt[t] = c; __syncthreads();
  for (int off=128; off>=1; off>>=1){ if (t<off) cnt[t]+=cnt[t+off]; __syncthreads(); }
  if (t==0) flag[0] = (cnt[0] < 2048) ? 1 : 0;
}

// ---------------- CSR build ----------------
__global__ void __launch_bounds__(256) k_count(const int* __restrict__ dst, int* __restrict__ counts){
  int e = blockIdx.x*256 + threadIdx.x;
  if (e < NE) atomicAdd(&counts[dst[e]], 1);
}

__global__ void __launch_bounds__(1024) k_scan(const int* __restrict__ counts, int* __restrict__ offsets, int* __restrict__ cursor){
  __shared__ int lds[1024];
  int t = threadIdx.x;
  int c0 = counts[4*t+0], c1 = counts[4*t+1], c2 = counts[4*t+2], c3 = counts[4*t+3];
  int s1 = c0+c1, s2 = s1+c2, s3 = s2+c3;
  lds[t] = s3;
  __syncthreads();
  for (int off=1; off<1024; off<<=1){
    int v = lds[t];
    int add = (t>=off)? lds[t-off] : 0;
    __syncthreads();
    lds[t] = v + add;
    __syncthreads();
  }
  int incl = lds[t];
  int base = incl - s3;
  offsets[4*t+0]=base;    offsets[4*t+1]=base+c0; offsets[4*t+2]=base+s1; offsets[4*t+3]=base+s2;
  cursor [4*t+0]=base;    cursor [4*t+1]=base+c0; cursor [4*t+2]=base+s1; cursor [4*t+3]=base+s2;
  if (t==1023) offsets[4096]=incl;
}

__global__ void __launch_bounds__(256) k_fill(const int* __restrict__ dst, const int* __restrict__ src,
                                              int* __restrict__ cursor, int* __restrict__ csr,
                                              int* __restrict__ pos, int* __restrict__ csrc){
  int e = blockIdx.x*256 + threadIdx.x;
  if (e < NE){
    int p = atomicAdd(&cursor[dst[e]], 1);
    csr[p] = e;
    pos[e] = p;
    csrc[p] = src[e];
  }
}

// ---------------- edge geometry (gV written in CSR order) ----------------
template<typename T>
__device__ __forceinline__ void geom_impl(const T* ew, const T* evec,
    const int* src, const int* dst, const int* pos, float* gC, float* gVp){
  int e = blockIdx.x*256 + threadIdx.x;
  if (e >= NE) return;
  float d = ldf(ew, e);
  float c = 0.5f*(cosf(d*0.6283185307179586f)+1.0f);
  c = (d < 5.0f) ? c : 0.0f;
  gC[e] = c;
  float x = ldf(evec, (size_t)e*3+0), y = ldf(evec, (size_t)e*3+1), z = ldf(evec, (size_t)e*3+2);
  if (src[e] != dst[e]){
    float n = sqrtf(x*x+y*y+z*z);
    float inv = 1.0f/fmaxf(n, 1e-12f);
    x*=inv; y*=inv; z*=inv;
  }
  int p = pos[e];
  gVp[p*3+0]=x; gVp[p*3+1]=y; gVp[p*3+2]=z;
}
__global__ void __launch_bounds__(256) k_geom(const void* ew, const void* evec,
    const int* __restrict__ src, const int* __restrict__ dst, const int* __restrict__ pos,
    float* __restrict__ gC, float* __restrict__ gVp, const int* __restrict__ flag){
  if (flag[0]) geom_impl<float>((const float*)ew, (const float*)evec, src, dst, pos, gC, gVp);
  else         geom_impl<bf16 >((const bf16* )ew, (const bf16* )evec, src, dst, pos, gC, gVp);
}

// ---------------- per-z embedding products ----------------
template<typename T>
__device__ __forceinline__ void zemb_impl(const T* emb, const T* emb2_w,
    float* P1z, float* P2z, float* Zr){
  int zv = blockIdx.x, h = threadIdx.x;
  Zr[h] = ldf(emb, (size_t)zv*HH + h);
  __syncthreads();
  float p1=0.f, p2=0.f;
  for (int r=0;r<128;++r){
    float x = Zr[r];
    p1 += x*ldf(emb2_w, (size_t)r*HH+h);
    p2 += x*ldf(emb2_w, (size_t)(r+128)*HH+h);
  }
  P1z[zv*HH+h]=p1; P2z[zv*HH+h]=p2;
}
__global__ void __launch_bounds__(128) k_zemb(const void* emb, const void* emb2_w,
    float* __restrict__ P1z, float* __restrict__ P2z, const int* __restrict__ flag){
  __shared__ float Zr[128];
  if (flag[0]) zemb_impl<float>((const float*)emb, (const float*)emb2_w, P1z, P2z, Zr);
  else         zemb_impl<bf16 >((const bf16* )emb, (const bf16* )emb2_w, P1z, P2z, Zr);
}

// ---------------- convert edge_attr -> bf16 ----------------
__global__ void __launch_bounds__(256) k_cvt_attr(const void* in, unsigned short* __restrict__ out,
                                                  const int* __restrict__ flag){
  int i = blockIdx.x*256 + threadIdx.x;
  if (flag[0]) out[i] = f2bu(((const float*)in)[i]);
  else         out[i] = ((const unsigned short*)in)[i];
}

// ---------------- weight repack into MFMA B-fragment layout (11 matrices) ----------------
struct PackDescs {
  const void*     base[11];
  long            eoff[11];
  unsigned short* out[11];
  int K[11]; int N[11];
};
template<typename T>
__device__ __forceinline__ void pack_impl(const PackDescs& d){
  int y = blockIdx.y;
  int K = d.K[y], N = d.N[y];
  int ktiles = K>>5, ntiles = N>>4;
  int total = ktiles*ntiles*64;
  int idx = blockIdx.x*256 + threadIdx.x;
  if (idx >= total) return;
  int lane = idx & 63, tile = idx >> 6;
  int kt = tile % ktiles, nt = tile / ktiles;
  const T* W = (const T*)d.base[y] + d.eoff[y];
  int n = nt*16 + (lane&15), k0 = kt*32 + (lane>>4)*8;
  unsigned int t[8];
  #pragma unroll
  for (int j=0;j<8;++j) t[j] = f2bu(ldf(W, (size_t)(k0+j)*N + n));
  uint4 v;
  v.x = t[0] | (t[1]<<16);
  v.y = t[2] | (t[3]<<16);
  v.z = t[4] | (t[5]<<16);
  v.w = t[6] | (t[7]<<16);
  *reinterpret_cast<uint4*>(d.out[y] + ((size_t)tile*64 + lane)*8) = v;
}
__global__ void __launch_bounds__(256) k_pack(PackDescs d, const int* __restrict__ flag){
  if (flag[0]) pack_impl<float>(d);
  else         pack_impl<bf16 >(d);
}

// ---------------- TNE edge coefficients -> eabuf bf16 (CSR-ordered rows) ----------------
template<typename T>
__device__ __forceinline__ void tne_edge_impl(
  const T* eattr, const int* src, const int* dst, const int* z, const int* pos,
  const T* dp1_w, const T* dp1_b, const T* dp2_w, const T* dp2_b,
  const T* dp3_w, const T* dp3_b, const T* emb2_b,
  const float* P1z, const float* P2z, const float* gC, bf16* eabuf,
  float (*attr)[32], int* zd, int* zs, int* ppos)
{
  int e0 = blockIdx.x*TPB;
  int h  = threadIdx.x;
  for (int i=h; i<TPB*32; i+=128) attr[i>>5][i&31] = ldf(eattr, (size_t)e0*32 + i);
  if (h < TPB){ int e=e0+h; zd[h]=z[dst[e]]; zs[h]=z[src[e]]; ppos[h]=pos[e]; }
  __syncthreads();
  float w1[TPB], w2[TPB], w3[TPB];
  float b1v=ldf(dp1_b,h), b2v=ldf(dp2_b,h), b3v=ldf(dp3_b,h);
  #pragma unroll
  for (int e=0;e<TPB;++e){ w1[e]=b1v; w2[e]=b2v; w3[e]=b3v; }
  for (int r=0;r<32;++r){
    float u1=ldf(dp1_w,(size_t)r*HH+h), u2=ldf(dp2_w,(size_t)r*HH+h), u3=ldf(dp3_w,(size_t)r*HH+h);
    #pragma unroll
    for (int e=0;e<TPB;++e){ float a=attr[e][r]; w1[e]+=a*u1; w2[e]+=a*u2; w3[e]+=a*u3; }
  }
  float eb = ldf(emb2_b,h);
  #pragma unroll
  for (int e=0;e<TPB;++e){
    float zij = P1z[zd[e]*HH+h] + P2z[zs[e]*HH+h] + eb;
    float c = gC[e0+e];
    bf16* p = eabuf + (size_t)ppos[e]*384;
    p[h]     = __float2bfloat16(zij*w1[e]*c);
    p[128+h] = __float2bfloat16(zij*w2[e]*c);
    p[256+h] = __float2bfloat16(zij*w3[e]*c);
  }
}
__global__ void __launch_bounds__(128) k_tne_edge(
  const void* eattr, const int* __restrict__ src, const int* __restrict__ dst,
  const int* __restrict__ z, const int* __restrict__ pos,
  const void* dp1_w, const void* dp1_b, const void* dp2_w, const void* dp2_b,
  const void* dp3_w, const void* dp3_b, const void* emb2_b,
  const float* __restrict__ P1z, const float* __restrict__ P2z,
  const float* __restrict__ gC, bf16* __restrict__ eabuf, const int* __restrict__ flag)
{
  __shared__ float attr[TPB][32];
  __shared__ int zd[TPB], zs[TPB], ppos[TPB];
  if (flag[0]) tne_edge_impl<float>((const float*)eattr, src, dst, z, pos,
      (const float*)dp1_w, (const float*)dp1_b, (const float*)dp2_w, (const float*)dp2_b,
      (const float*)dp3_w, (const float*)dp3_b, (const float*)emb2_b, P1z, P2z, gC, eabuf, attr, zd, zs, ppos);
  else tne_edge_impl<bf16>((const bf16*)eattr, src, dst, z, pos,
      (const bf16*)dp1_w, (const bf16*)dp1_b, (const bf16*)dp2_w, (const bf16*)dp2_b,
      (const bf16*)dp3_w, (const bf16*)dp3_b, (const bf16*)emb2_b, P1z, P2z, gC, eabuf, attr, zd, zs, ppos);
}

// ---------------- TNE scatter + LN only: writes sm10 bf16 [NN][10][128] and ln bf16 [NN][128] ----------------
template<typename T>
__device__ __forceinline__ void tne_scat_impl(
  const int* offsets, const float* gVp, const bf16* eabuf,
  const T* ln_g, const T* ln_b, bf16* sm10, bf16* lnO, float* red)
{
  int n0 = blockIdx.x*NB, h = threadIdx.x;
  float tnv[NB];
  #pragma unroll
  for (int nn=0;nn<NB;++nn){
    int n = n0+nn;
    float a=0, v0=0,v1=0,v2=0, s0=0,s1=0,s2=0,s3=0,s4=0,s5=0;
    int beg = offsets[n], end = offsets[n+1];
    int i = beg;
    for (; i+4 <= end; i += 4){
      float c1[4],c2[4],c3[4],vx[4],vy[4],vz[4];
      #pragma unroll
      for (int u=0;u<4;++u){
        const bf16* p = eabuf + (size_t)(i+u)*384;
        c1[u]=b2f(p[h]); c2[u]=b2f(p[128+h]); c3[u]=b2f(p[256+h]);
        vx[u]=gVp[(i+u)*3+0]; vy[u]=gVp[(i+u)*3+1]; vz[u]=gVp[(i+u)*3+2];
      }
      #pragma unroll
      for (int u=0;u<4;++u){
        float tr3 = (vx[u]*vx[u]+vy[u]*vy[u]+vz[u]*vz[u])*(1.0f/3.0f);
        a  += c1[u];
        v0 += c2[u]*vx[u]; v1 += c2[u]*vy[u]; v2 += c2[u]*vz[u];
        s0 += c3[u]*(vx[u]*vx[u] - tr3); s1 += c3[u]*vx[u]*vy[u]; s2 += c3[u]*vx[u]*vz[u];
        s3 += c3[u]*(vy[u]*vy[u] - tr3); s4 += c3[u]*vy[u]*vz[u]; s5 += c3[u]*(vz[u]*vz[u] - tr3);
      }
    }
    for (; i<end; ++i){
      const bf16* p = eabuf + (size_t)i*384;
      float c1 = b2f(p[h]), c2 = b2f(p[128+h]), c3 = b2f(p[256+h]);
      float vx = gVp[i*3+0], vy = gVp[i*3+1], vz = gVp[i*3+2];
      float tr3 = (vx*vx+vy*vy+vz*vz)*(1.0f/3.0f);
      a  += c1;
      v0 += c2*vx; v1 += c2*vy; v2 += c2*vz;
      s0 += c3*(vx*vx - tr3); s1 += c3*vx*vy;          s2 += c3*vx*vz;
      s3 += c3*(vy*vy - tr3); s4 += c3*vy*vz;          s5 += c3*(vz*vz - tr3);
    }
    bf16* sp = sm10 + (size_t)n*1280;
    sp[0*128+h]=__float2bfloat16(a);
    sp[1*128+h]=__float2bfloat16(v0); sp[2*128+h]=__float2bfloat16(v1); sp[3*128+h]=__float2bfloat16(v2);
    sp[4*128+h]=__float2bfloat16(s0); sp[5*128+h]=__float2bfloat16(s1); sp[6*128+h]=__float2bfloat16(s2);
    sp[7*128+h]=__float2bfloat16(s3); sp[8*128+h]=__float2bfloat16(s4); sp[9*128+h]=__float2bfloat16(s5);
    tnv[nn] = 3.0f*a*a + 2.0f*(v0*v0+v1*v1+v2*v2)
            + s0*s0 + s3*s3 + s5*s5 + 2.0f*(s1*s1 + s2*s2 + s4*s4);
  }
  float gg = ldf(ln_g,h), bb = ldf(ln_b,h);
  #pragma unroll
  for (int nn=0;nn<NB;++nn){
    __syncthreads();
    red[h] = tnv[nn]; __syncthreads();
    for (int off=64; off>=1; off>>=1){ if (h<off) red[h]+=red[h+off]; __syncthreads(); }
    float mean = red[0]*(1.0f/128.0f);
    __syncthreads();
    float dm = tnv[nn] - mean;
    red[h] = dm*dm; __syncthreads();
    for (int off=64; off>=1; off>>=1){ if (h<off) red[h]+=red[h+off]; __syncthreads(); }
    float var = red[0]*(1.0f/128.0f);
    lnO[(size_t)(n0+nn)*128 + h] = __float2bfloat16(dm*rsqrtf(var+1e-5f)*gg + bb);
  }
}
__global__ void __launch_bounds__(128) k_tne_scat(
  const int* __restrict__ offsets, const float* __restrict__ gVp, const bf16* __restrict__ eabuf,
  const void* ln_g, const void* ln_b, bf16* __restrict__ sm10, bf16* __restrict__ lnO,
  const int* __restrict__ flag)
{
  __shared__ float red[128];
  if (flag[0]) tne_scat_impl<float>(offsets, gVp, eabuf, (const float*)ln_g, (const float*)ln_b, sm10, lnO, red);
  else         tne_scat_impl<bf16 >(offsets, gVp, eabuf, (const bf16* )ln_g, (const bf16* )ln_b, sm10, lnO, red);
}

// ---------------- node fsc MLP via MFMA: 16 nodes/block, 4 waves N-split ----------------
// Structure copied from r10-validated msg l1/l2 (same pack, repack, output map).
template<typename T>
__device__ __forceinline__ void node_mlp_impl(
  const bf16* lnO, const unsigned short* ps0, const unsigned short* ps1,
  const T* b0, const T* b1, bf16* fsc3, unsigned short* h2p)
{
  int wid  = threadIdx.x >> 6;
  int lane = threadIdx.x & 63;
  int n0 = blockIdx.x*16;
  int m = lane & 15, g = lane >> 4;
  // stage1: ln [16x128] @ s0_w [128x256] -> silu -> h2p
  short8v aln[4];
  #pragma unroll
  for (int ks=0; ks<4; ++ks)
    aln[ks] = *reinterpret_cast<const short8v*>((const unsigned short*)lnO + (size_t)(n0+m)*128 + ks*32 + g*8);
  for (int nt=wid; nt<16; nt+=4){
    float bias = ldf(b0, nt*16+m);
    f32x4 acc = {bias,bias,bias,bias};
    #pragma unroll
    for (int ks=0; ks<4; ++ks){
      short8v b = *reinterpret_cast<const short8v*>(ps0 + ((size_t)(nt*4+ks)*64 + lane)*8);
      acc = __builtin_amdgcn_mfma_f32_16x16x32_bf16(aln[ks], b, acc, 0,0,0);
    }
    #pragma unroll
    for (int r=0;r<4;++r){
      int n = nt*16 + m, row = g*4 + r;
      h2p[(n>>5)*512 + (((n>>3)&3)*16+row)*8 + (n&7)] = f2bu(siluf(acc[r]));
    }
  }
  __syncthreads();
  // stage2: h1 [16x256] @ s1_w [256x384] -> silu -> fsc3[node][j*128 + h]
  short8v a3[8];
  #pragma unroll
  for (int ks=0; ks<8; ++ks) a3[ks] = *reinterpret_cast<const short8v*>(&h2p[ks*512 + lane*8]);
  for (int nt=wid; nt<24; nt+=4){
    float bias = ldf(b1, nt*16+m);
    f32x4 acc = {bias,bias,bias,bias};
    #pragma unroll
    for (int ks=0; ks<8; ++ks){
      short8v b = *reinterpret_cast<const short8v*>(ps1 + ((size_t)(nt*8+ks)*64 + lane)*8);
      acc = __builtin_amdgcn_mfma_f32_16x16x32_bf16(a3[ks], b, acc, 0,0,0);
    }
    #pragma unroll
    for (int r=0;r<4;++r){
      int n = nt*16 + m, row = g*4 + r;
      ((unsigned short*)fsc3)[(size_t)(n0+row)*384 + (n%3)*128 + (n/3)] = f2bu(siluf(acc[r]));
    }
  }
}
__global__ void __launch_bounds__(256) k_node_mlp(
  const bf16* __restrict__ lnO, const unsigned short* __restrict__ ps0,
  const unsigned short* __restrict__ ps1,
  const void* b0, const void* b1, bf16* __restrict__ fsc3, const int* __restrict__ flag)
{
  __shared__ __align__(16) unsigned short h2p[4096];
  if (flag[0]) node_mlp_impl<float>(lnO, ps0, ps1, (const float*)b0, (const float*)b1, fsc3, h2p);
  else         node_mlp_impl<bf16 >(lnO, ps0, ps1, (const bf16* )b0, (const bf16* )b1, fsc3, h2p);
}

// ---------------- node cmix via MFMA + combine -> X9: 16 nodes/block, 4 waves ----------------
__global__ void __launch_bounds__(256) k_tne_cmix(
  const bf16* __restrict__ sm10, const unsigned short* __restrict__ pwlt,
  const bf16* __restrict__ fsc3, float* __restrict__ X9)
{
  int wid  = threadIdx.x >> 6;
  int lane = threadIdx.x & 63;
  int n0 = blockIdx.x*16;
  int m = lane & 15, g = lane >> 4;
  f32x4 acc[10][2];
  #pragma unroll
  for (int c=0;c<10;++c){ acc[c][0]=(f32x4){0,0,0,0}; acc[c][1]=(f32x4){0,0,0,0}; }
  #pragma unroll
  for (int c=0;c<10;++c){
    int mat = (c==0) ? 0 : (c<4) ? 1 : 2;
    const unsigned short* bw = pwlt + (size_t)mat*16384;
    short8v af[4];
    #pragma unroll
    for (int ks=0; ks<4; ++ks)
      af[ks] = *reinterpret_cast<const short8v*>((const unsigned short*)sm10 + (size_t)(n0+m)*1280 + c*128 + ks*32 + g*8);
    #pragma unroll
    for (int t=0;t<2;++t){
      int nt = wid + t*4;
      #pragma unroll
      for (int ks=0; ks<4; ++ks){
        short8v b = *reinterpret_cast<const short8v*>(bw + ((size_t)(nt*4+ks)*64 + lane)*8);
        acc[c][t] = __builtin_amdgcn_mfma_f32_16x16x32_bf16(af[ks], b, acc[c][t], 0,0,0);
      }
    }
  }
  #pragma unroll
  for (int t=0;t<2;++t){
    int nt = wid + t*4;
    int h = nt*16 + m;
    #pragma unroll
    for (int r=0;r<4;++r){
      int node = n0 + g*4 + r;
      float am  = acc[0][t][r];
      float wm0 = acc[1][t][r], wm1 = acc[2][t][r], wm2 = acc[3][t][r];
      float t0 = acc[4][t][r], t1 = acc[5][t][r], t2 = acc[6][t][r];
      float t3 = acc[7][t][r], t4 = acc[8][t][r], t5 = acc[9][t][r];
      float f0 = b2f(fsc3[(size_t)node*384 + h]);
      float f1 = b2f(fsc3[(size_t)node*384 + 128 + h]);
      float f2 = b2f(fsc3[(size_t)node*384 + 256 + h]);
      float* xp = X9 + (size_t)node*1152;
      xp[0*128+h] = f0*am + f2*t0;
      xp[1*128+h] = -f1*wm2 + f2*t1;
      xp[2*128+h] =  f1*wm1 + f2*t2;
      xp[3*128+h] =  f1*wm2 + f2*t1;
      xp[4*128+h] = f0*am + f2*t3;
      xp[5*128+h] = -f1*wm0 + f2*t4;
      xp[6*128+h] = -f1*wm1 + f2*t2;
      xp[7*128+h] =  f1*wm0 + f2*t4;
      xp[8*128+h] = f0*am + f2*t5;
    }
  }
}

// ---------------- msg edge MLP via MFMA: 16 edges/block, 4 waves split the N dim ----------------
template<typename T>
__device__ __forceinline__ void mfma_impl(
  const unsigned short* eattr_c, const float* gC, const int* pos,
  const unsigned short* p0, const unsigned short* p1, const unsigned short* p2,
  const T* b0, const T* b1, const T* b2,
  unsigned short* eabuf, unsigned short* h1p, unsigned short* h2p, int* spos)
{
  int wid  = threadIdx.x >> 6;
  int lane = threadIdx.x & 63;
  int e0 = blockIdx.x*16;
  int m = lane & 15, g = lane >> 4;
  if (threadIdx.x < 16) spos[threadIdx.x] = pos[e0 + threadIdx.x];
  float cc[4];
  #pragma unroll
  for (int r=0;r<4;++r) cc[r] = gC[e0 + g*4 + r];
  short8v a1 = *reinterpret_cast<const short8v*>(eattr_c + (size_t)(e0+m)*32 + g*8);
  for (int nt=wid; nt<8; nt+=4){
    float bias = ldf(b0, nt*16+m);
    f32x4 acc = {bias,bias,bias,bias};
    short8v b = *reinterpret_cast<const short8v*>(p0 + ((size_t)nt*64 + lane)*8);
    acc = __builtin_amdgcn_mfma_f32_16x16x32_bf16(a1, b, acc, 0,0,0);
    #pragma unroll
    for (int r=0;r<4;++r){
      int n = nt*16 + m, row = g*4 + r;
      h1p[(n>>5)*512 + (((n>>3)&3)*16+row)*8 + (n&7)] = f2bu(siluf(acc[r]));
    }
  }
  __syncthreads();
  short8v a2[4];
  #pragma unroll
  for (int ks=0; ks<4; ++ks) a2[ks] = *reinterpret_cast<const short8v*>(&h1p[ks*512 + lane*8]);
  for (int nt=wid; nt<16; nt+=4){
    float bias = ldf(b1, nt*16+m);
    f32x4 acc = {bias,bias,bias,bias};
    #pragma unroll
    for (int ks=0; ks<4; ++ks){
      short8v b = *reinterpret_cast<const short8v*>(p1 + ((size_t)(nt*4+ks)*64 + lane)*8);
      acc = __builtin_amdgcn_mfma_f32_16x16x32_bf16(a2[ks], b, acc, 0,0,0);
    }
    #pragma unroll
    for (int r=0;r<4;++r){
      int n = nt*16 + m, row = g*4 + r;
      h2p[(n>>5)*512 + (((n>>3)&3)*16+row)*8 + (n&7)] = f2bu(siluf(acc[r]));
    }
  }
  __syncthreads();
  short8v a3[8];
  #pragma unroll
  for (int ks=0; ks<8; ++ks) a3[ks] = *reinterpret_cast<const short8v*>(&h2p[ks*512 + lane*8]);
  for (int nt=wid; nt<24; nt+=4){
    float bias = ldf(b2, nt*16+m);
    f32x4 acc = {bias,bias,bias,bias};
    #pragma unroll
    for (int ks=0; ks<8; ++ks){
      short8v b = *reinterpret_cast<const short8v*>(p2 + ((size_t)(nt*8+ks)*64 + lane)*8);
      acc = __builtin_amdgcn_mfma_f32_16x16x32_bf16(a3[ks], b, acc, 0,0,0);
    }
    #pragma unroll
    for (int r=0;r<4;++r){
      int n = nt*16 + m, row = g*4 + r;
      float v = siluf(acc[r]) * cc[r];
      eabuf[(size_t)spos[row]*384 + (n%3)*128 + (n/3)] = f2bu(v);
    }
  }
}
__global__ void __launch_bounds__(256) k_msg_edge_mfma(
  const unsigned short* __restrict__ eattr_c, const float* __restrict__ gC,
  const int* __restrict__ pos,
  const unsigned short* __restrict__ p0, const unsigned short* __restrict__ p1,
  const unsigned short* __restrict__ p2,
  const void* b0, const void* b1, const void* b2, long boff0, long boff1, long boff2,
  unsigned short* __restrict__ eabuf, const int* __restrict__ flag)
{
  __shared__ __align__(16) unsigned short h1p[2048];
  __shared__ __align__(16) unsigned short h2p[4096];
  __shared__ int spos[16];
  if (flag[0]) mfma_impl<float>(eattr_c, gC, pos, p0, p1, p2,
      (const float*)b0 + boff0, (const float*)b1 + boff1, (const float*)b2 + boff2, eabuf, h1p, h2p, spos);
  else mfma_impl<bf16>(eattr_c, gC, pos, p0, p1, p2,
      (const bf16*)b0 + boff0, (const bf16*)b1 + boff1, (const bf16*)b2 + boff2, eabuf, h1p, h2p, spos);
}

// ---------------- msg node prep (NB nodes/block) ----------------
template<typename T>
__device__ __forceinline__ void prep_impl(
  float* X9, const T* lx, bf16* Y10, float (*sm)[10][128])
{
  int n0 = blockIdx.x*NB, h = threadIdx.x;
  #pragma unroll
  for (int nn=0;nn<NB;++nn){
    float* xp = X9 + (size_t)(n0+nn)*1152;
    float x00=xp[0*128+h], x01=xp[1*128+h], x02=xp[2*128+h];
    float x10=xp[3*128+h], x11=xp[4*128+h], x12=xp[5*128+h];
    float x20=xp[6*128+h], x21=xp[7*128+h], x22=xp[8*128+h];
    float tn = x00*x00+x01*x01+x02*x02+x10*x10+x11*x11+x12*x12+x20*x20+x21*x21+x22*x22;
    float inv = 1.0f/(tn+1.0f);
    x00*=inv; x01*=inv; x02*=inv; x10*=inv; x11*=inv; x12*=inv; x20*=inv; x21*=inv; x22*=inv;
    // Reference REBINDS X to normalized before the update (r3 fix).
    xp[0*128+h]=x00; xp[1*128+h]=x01; xp[2*128+h]=x02;
    xp[3*128+h]=x10; xp[4*128+h]=x11; xp[5*128+h]=x12;
    xp[6*128+h]=x20; xp[7*128+h]=x21; xp[8*128+h]=x22;
    float a = (x00+x11+x22)*(1.0f/3.0f);
    sm[nn][0][h]=a;
    sm[nn][1][h]=0.5f*(x21-x12);
    sm[nn][2][h]=0.5f*(x02-x20);
    sm[nn][3][h]=0.5f*(x10-x01);
    sm[nn][4][h]=x00-a;
    sm[nn][5][h]=0.5f*(x01+x10);
    sm[nn][6][h]=0.5f*(x02+x20);
    sm[nn][7][h]=x11-a;
    sm[nn][8][h]=0.5f*(x12+x21);
    sm[nn][9][h]=x22-a;
  }
  __syncthreads();
  float A[NB]={0};
  float V0[NB]={0}, V1[NB]={0}, V2[NB]={0};
  float S0[NB]={0}, S1[NB]={0}, S2[NB]={0};
  float S3[NB]={0}, S4[NB]={0}, S5[NB]={0};
  for (int r=0;r<128;++r){
    float w0 = ldf(lx,(size_t)r*128+h), w1 = ldf(lx,(size_t)16384+r*128+h), w2 = ldf(lx,(size_t)32768+r*128+h);
    #pragma unroll
    for (int nn=0;nn<NB;++nn){
      A[nn]  += sm[nn][0][r]*w0;
      V0[nn] += sm[nn][1][r]*w1; V1[nn] += sm[nn][2][r]*w1; V2[nn] += sm[nn][3][r]*w1;
      S0[nn] += sm[nn][4][r]*w2; S1[nn] += sm[nn][5][r]*w2; S2[nn] += sm[nn][6][r]*w2;
      S3[nn] += sm[nn][7][r]*w2; S4[nn] += sm[nn][8][r]*w2; S5[nn] += sm[nn][9][r]*w2;
    }
  }
  #pragma unroll
  for (int nn=0;nn<NB;++nn){
    bf16* yp = Y10 + (size_t)(n0+nn)*1280;
    yp[0*128+h]=__float2bfloat16(A[nn]);
    yp[1*128+h]=__float2bfloat16(V0[nn]); yp[2*128+h]=__float2bfloat16(V1[nn]); yp[3*128+h]=__float2bfloat16(V2[nn]);
    yp[4*128+h]=__float2bfloat16(S0[nn]); yp[5*128+h]=__float2bfloat16(S1[nn]); yp[6*128+h]=__float2bfloat16(S2[nn]);
    yp[7*128+h]=__float2bfloat16(S3[nn]); yp[8*128+h]=__float2bfloat16(S4[nn]); yp[9*128+h]=__float2bfloat16(S5[nn]);
  }
}
__global__ void __launch_bounds__(128) k_msg_prep(
  float* __restrict__ X9, const void* lx, long lxoff, bf16* __restrict__ Y10,
  const int* __restrict__ flag)
{
  __shared__ float sm[NB][10][128];
  if (flag[0]) prep_impl<float>(X9, (const float*)lx + lxoff, Y10, sm);
  else         prep_impl<bf16 >(X9, (const bf16* )lx + lxoff, Y10, sm);
}

// ---------------- msg scatter + AB + cmix + dX ----------------
template<typename T>
__device__ __forceinline__ void sf_impl(
  const int* offsets, const int* csrc,
  const bf16* eabuf, const bf16* Y10, const T* lt,
  float* X9, T* out, int write_out, float (*sm)[10][128])
{
  int n0 = blockIdx.x*NB, h = threadIdx.x;
  #pragma unroll
  for (int nn=0;nn<NB;++nn){
    int n = n0+nn;
    float am=0, vm0=0,vm1=0,vm2=0, smm0=0,smm1=0,smm2=0,smm3=0,smm4=0,smm5=0;
    int beg = offsets[n], end = offsets[n+1];
    int i = beg;
    for (; i+4 <= end; i += 4){
      int ss[4];
      #pragma unroll
      for (int u=0;u<4;++u){ ss[u] = csrc[i+u]; }
      float e0a[4], e1a[4], e2a[4];
      float y0[4],y1[4],y2[4],y3[4],y4[4],y5[4],y6[4],y7[4],y8[4],y9[4];
      #pragma unroll
      for (int u=0;u<4;++u){
        const bf16* ep = eabuf + (size_t)(i+u)*384;
        e0a[u]=b2f(ep[h]); e1a[u]=b2f(ep[128+h]); e2a[u]=b2f(ep[256+h]);
        const bf16* yp = Y10 + (size_t)ss[u]*1280;
        y0[u]=b2f(yp[0*128+h]); y1[u]=b2f(yp[1*128+h]); y2[u]=b2f(yp[2*128+h]);
        y3[u]=b2f(yp[3*128+h]); y4[u]=b2f(yp[4*128+h]); y5[u]=b2f(yp[5*128+h]);
        y6[u]=b2f(yp[6*128+h]); y7[u]=b2f(yp[7*128+h]); y8[u]=b2f(yp[8*128+h]);
        y9[u]=b2f(yp[9*128+h]);
      }
      #pragma unroll
      for (int u=0;u<4;++u){
        am   += e0a[u]*y0[u];
        vm0  += e1a[u]*y1[u]; vm1 += e1a[u]*y2[u]; vm2 += e1a[u]*y3[u];
        smm0 += e2a[u]*y4[u]; smm1 += e2a[u]*y5[u]; smm2 += e2a[u]*y6[u];
        smm3 += e2a[u]*y7[u]; smm4 += e2a[u]*y8[u]; smm5 += e2a[u]*y9[u];
      }
    }
    for (; i<end; ++i){
      int s = csrc[i];
      const bf16* ep = eabuf + (size_t)i*384;
      float e0 = b2f(ep[h]), e1 = b2f(ep[128+h]), e2 = b2f(ep[256+h]);
      const bf16* yp = Y10 + (size_t)s*1280;
      am   += e0*b2f(yp[0*128+h]);
      vm0  += e1*b2f(yp[1*128+h]); vm1 += e1*b2f(yp[2*128+h]); vm2 += e1*b2f(yp[3*128+h]);
      smm0 += e2*b2f(yp[4*128+h]); smm1 += e2*b2f(yp[5*128+h]); smm2 += e2*b2f(yp[6*128+h]);
      smm3 += e2*b2f(yp[7*128+h]); smm4 += e2*b2f(yp[8*128+h]); smm5 += e2*b2f(yp[9*128+h]);
    }
    const bf16* yp = Y10 + (size_t)n*1280;
    float aY=b2f(yp[0*128+h]), u0=b2f(yp[1*128+h]), u1=b2f(yp[2*128+h]), u2=b2f(yp[3*128+h]);
    float q0=b2f(yp[4*128+h]), q1=b2f(yp[5*128+h]), q2=b2f(yp[6*128+h]);
    float q3=b2f(yp[7*128+h]), q4=b2f(yp[8*128+h]), q5=b2f(yp[9*128+h]);
    float m00=am+smm0,   m01=-vm2+smm1, m02= vm1+smm2;
    float m10= vm2+smm1, m11=am+smm3,  m12=-vm0+smm4;
    float m20=-vm1+smm2, m21= vm0+smm4, m22=am+smm5;
    float y00=aY+q0,  y01=-u2+q1, y02= u1+q2;
    float y10= u2+q1, y11=aY+q3,  y12=-u0+q4;
    float y20=-u1+q2, y21= u0+q4, y22=aY+q5;
    float ab00 = m00*y00+m01*y10+m02*y20 + y00*m00+y01*m10+y02*m20;
    float ab01 = m00*y01+m01*y11+m02*y21 + y00*m01+y01*m11+y02*m21;
    float ab02 = m00*y02+m01*y12+m02*y22 + y00*m02+y01*m12+y02*m22;
    float ab10 = m10*y00+m11*y10+m12*y20 + y10*m00+y11*m10+y12*m20;
    float ab11 = m10*y01+m11*y11+m12*y21 + y10*m01+y11*m11+y12*m21;
    float ab12 = m10*y02+m11*y12+m12*y22 + y10*m02+y11*m12+y12*m22;
    float ab20 = m20*y00+m21*y10+m22*y20 + y20*m00+y21*m10+y22*m20;
    float ab21 = m20*y01+m21*y11+m22*y21 + y20*m01+y21*m11+y22*m21;
    float ab22 = m20*y02+m21*y12+m22*y22 + y20*m02+y21*m12+y22*m22;
    float a2 = (ab00+ab11+ab22)*(1.0f/3.0f);
    float w0 = 0.5f*(ab21-ab12), w1 = 0.5f*(ab02-ab20), w2 = 0.5f*(ab10-ab01);
    float t0 = ab00-a2, t1 = 0.5f*(ab01+ab10), t2 = 0.5f*(ab02+ab20);
    float t3 = ab11-a2, t4 = 0.5f*(ab12+ab21), t5 = ab22-a2;
    float dnm = ab00*ab00+ab01*ab01+ab02*ab02+ab10*ab10+ab11*ab11+ab12*ab12
              + ab20*ab20+ab21*ab21+ab22*ab22 + 1.0f;
    float inv = 1.0f/dnm;
    sm[nn][0][h]=a2*inv; sm[nn][1][h]=w0*inv; sm[nn][2][h]=w1*inv; sm[nn][3][h]=w2*inv;
    sm[nn][4][h]=t0*inv; sm[nn][5][h]=t1*inv; sm[nn][6][h]=t2*inv;
    sm[nn][7][h]=t3*inv; sm[nn][8][h]=t4*inv; sm[nn][9][h]=t5*inv;
  }
  __syncthreads();
  float at[NB]={0};
  float vt0[NB]={0}, vt1[NB]={0}, vt2[NB]={0};
  float st0[NB]={0}, st1[NB]={0}, st2[NB]={0};
  float st3[NB]={0}, st4[NB]={0}, st5[NB]={0};
  for (int r=0;r<128;++r){
    float ww0 = ldf(lt,(size_t)r*128+h);
    float ww1 = ldf(lt,(size_t)16384+r*128+h);
    float ww2 = ldf(lt,(size_t)32768+r*128+h);
    #pragma unroll
    for (int nn=0;nn<NB;++nn){
      at[nn]  += sm[nn][0][r]*ww0;
      vt0[nn] += sm[nn][1][r]*ww1; vt1[nn] += sm[nn][2][r]*ww1; vt2[nn] += sm[nn][3][r]*ww1;
      st0[nn] += sm[nn][4][r]*ww2; st1[nn] += sm[nn][5][r]*ww2; st2[nn] += sm[nn][6][r]*ww2;
      st3[nn] += sm[nn][7][r]*ww2; st4[nn] += sm[nn][8][r]*ww2; st5[nn] += sm[nn][9][r]*ww2;
    }
  }
  #pragma unroll
  for (int nn=0;nn<NB;++nn){
    int n = n0+nn;
    float d00=at[nn]+st0[nn],   d01=-vt2[nn]+st1[nn], d02= vt1[nn]+st2[nn];
    float d10= vt2[nn]+st1[nn], d11=at[nn]+st3[nn],  d12=-vt0[nn]+st4[nn];
    float d20=-vt1[nn]+st2[nn], d21= vt0[nn]+st4[nn], d22=at[nn]+st5[nn];
    float g00 = d00 + d00*d00+d01*d10+d02*d20;
    float g01 = d01 + d00*d01+d01*d11+d02*d21;
    float g02 = d02 + d00*d02+d01*d12+d02*d22;
    float g10 = d10 + d10*d00+d11*d10+d12*d20;
    float g11 = d11 + d10*d01+d11*d11+d12*d21;
    float g12 = d12 + d10*d02+d11*d12+d12*d22;
    float g20 = d20 + d20*d00+d21*d10+d22*d20;
    float g21 = d21 + d20*d01+d21*d11+d22*d21;
    float g22 = d22 + d20*d02+d21*d12+d22*d22;
    float* xp = X9 + (size_t)n*1152;
    float x00=xp[0*128+h]+g00, x01=xp[1*128+h]+g01, x02=xp[2*128+h]+g02;
    float x10=xp[3*128+h]+g10, x11=xp[4*128+h]+g11, x12=xp[5*128+h]+g12;
    float x20=xp[6*128+h]+g20, x21=xp[7*128+h]+g21, x22=xp[8*128+h]+g22;
    if (write_out){
      if (sizeof(T)==4){
        float* of = (float*)out + ((size_t)n*128 + h)*9;
        of[0]=x00; of[1]=x01; of[2]=x02; of[3]=x10; of[4]=x11; of[5]=x12; of[6]=x20; of[7]=x21; of[8]=x22;
      } else {
        bf16* ob = (bf16*)out + ((size_t)n*128 + h)*9;
        ob[0]=__float2bfloat16(x00); ob[1]=__float2bfloat16(x01); ob[2]=__float2bfloat16(x02);
        ob[3]=__float2bfloat16(x10); ob[4]=__float2bfloat16(x11); ob[5]=__float2bfloat16(x12);
        ob[6]=__float2bfloat16(x20); ob[7]=__float2bfloat16(x21); ob[8]=__float2bfloat16(x22);
      }
    } else {
      xp[0*128+h]=x00; xp[1*128+h]=x01; xp[2*128+h]=x02;
      xp[3*128+h]=x10; xp[4*128+h]=x11; xp[5*128+h]=x12;
      xp[6*128+h]=x20; xp[7*128+h]=x21; xp[8*128+h]=x22;
    }
  }
}
__global__ void __launch_bounds__(128) k_msg_sf(
  const int* __restrict__ offsets, const int* __restrict__ csrc,
  const bf16* __restrict__ eabuf, const bf16* __restrict__ Y10,
  const void* lt, long ltoff, float* __restrict__ X9, void* __restrict__ out,
  const int* __restrict__ flag, int write_out)
{
  __shared__ float sm[NB][10][128];
  if (flag[0]) sf_impl<float>(offsets, csrc, eabuf, Y10, (const float*)lt + ltoff, X9, (float*)out, write_out, sm);
  else         sf_impl<bf16 >(offsets, csrc, eabuf, Y10, (const bf16* )lt + ltoff, X9, (bf16* )out, write_out, sm);
}

extern "C" void kernel_launch(void* const* d_in, const int* in_sizes, int n_in,
                              void* d_out, int out_size, void* d_ws, size_t ws_size,
                              hipStream_t stream)
{
  (void)in_sizes; (void)n_in; (void)out_size; (void)ws_size;
  const int* z    = (const int*)d_in[0];
  const int* eidx = (const int*)d_in[1];
  const int* src  = eidx;
  const int* dst  = eidx + NE;

  // Workspace: ~63 MiB (proven budget >= 74 MiB). sm10 aliases Y10 (dead until msg prep).
  char* w = (char*)d_ws;
  int* flag    = (int*)w;   w += 64;
  int* counts  = (int*)w;   w += (size_t)NN*4;
  int* offsets = (int*)w;   w += (size_t)(NN+1)*4 + 60;
  int* cursor  = (int*)w;   w += (size_t)NN*4;
  int* csr     = (int*)w;   w += (size_t)NE*4;
  int* pos     = (int*)w;   w += (size_t)NE*4;
  int* csrc    = (int*)w;   w += (size_t)NE*4;
  float* gC    = (float*)w; w += (size_t)NE*4;
  float* gVp   = (float*)w; w += (size_t)NE*12;
  float* P1z   = (float*)w; w += (size_t)MAXZ*HH*4;
  float* P2z   = (float*)w; w += (size_t)MAXZ*HH*4;
  bf16* eabuf  = (bf16*)w;  w += (size_t)NE*384*2;
  float* X9    = (float*)w; w += (size_t)NN*1152*4;
  bf16* Y10    = (bf16*)w;  w += (size_t)NN*1280*2;
  unsigned short* eattr_c = (unsigned short*)w; w += (size_t)NE*32*2;
  unsigned short* pw0[2]; unsigned short* pw1[2]; unsigned short* pw2[2];
  for (int l=0;l<2;++l){
    pw0[l] = (unsigned short*)w; w += 8*64*8*2;
    pw1[l] = (unsigned short*)w; w += 64*64*8*2;
    pw2[l] = (unsigned short*)w; w += 192*64*8*2;
  }
  unsigned short* pw_s0 = (unsigned short*)w; w += 64*64*8*2;    //  64 KB
  unsigned short* pw_s1 = (unsigned short*)w; w += 192*64*8*2;   // 192 KB
  unsigned short* pwlt  = (unsigned short*)w; w += 3*32*64*8*2;  //  96 KB
  bf16* lnO    = (bf16*)w;  w += (size_t)NN*128*2;               // 1.05 MB
  bf16* fsc3   = (bf16*)w;  w += (size_t)NN*384*2;               // 3.15 MB
  bf16* sm10   = Y10;   // alias: dead until k_msg_prep overwrites Y10

  k_detect<<<1, 256, 0, stream>>>((const unsigned int*)d_in[4], flag);
  hipMemsetAsync(counts, 0, (size_t)NN*4, stream);
  k_count<<<NE/256, 256, 0, stream>>>(dst, counts);
  k_scan<<<1, 1024, 0, stream>>>(counts, offsets, cursor);
  k_fill<<<NE/256, 256, 0, stream>>>(dst, src, cursor, csr, pos, csrc);
  k_geom<<<NE/256, 256, 0, stream>>>(d_in[2], d_in[3], src, dst, pos, gC, gVp, flag);
  k_zemb<<<MAXZ, 128, 0, stream>>>(d_in[5], d_in[12], P1z, P2z, flag);
  k_cvt_attr<<<NE*32/256, 256, 0, stream>>>(d_in[4], eattr_c, flag);

  PackDescs pd;
  for (int l=0;l<2;++l){
    pd.base[l*3+0] = d_in[21]; pd.eoff[l*3+0] = (long)l*32*128;
    pd.base[l*3+1] = d_in[23]; pd.eoff[l*3+1] = (long)l*128*256;
    pd.base[l*3+2] = d_in[25]; pd.eoff[l*3+2] = (long)l*256*384;
    pd.out[l*3+0] = pw0[l]; pd.K[l*3+0]=32;  pd.N[l*3+0]=128;
    pd.out[l*3+1] = pw1[l]; pd.K[l*3+1]=128; pd.N[l*3+1]=256;
    pd.out[l*3+2] = pw2[l]; pd.K[l*3+2]=256; pd.N[l*3+2]=384;
  }
  pd.base[6] = d_in[15]; pd.eoff[6] = 0; pd.out[6] = pw_s0; pd.K[6]=128; pd.N[6]=256;
  pd.base[7] = d_in[17]; pd.eoff[7] = 0; pd.out[7] = pw_s1; pd.K[7]=256; pd.N[7]=384;
  for (int c=0;c<3;++c){
    pd.base[8+c] = d_in[14]; pd.eoff[8+c] = (long)c*16384;
    pd.out[8+c] = pwlt + (size_t)c*16384; pd.K[8+c]=128; pd.N[8+c]=128;
  }
  k_pack<<<dim3(48, 11), 256, 0, stream>>>(pd, flag);

  k_tne_edge<<<NE/TPB, 128, 0, stream>>>(d_in[4], src, dst, z, pos,
      d_in[6], d_in[7], d_in[8], d_in[9], d_in[10], d_in[11], d_in[13],
      P1z, P2z, gC, eabuf, flag);
  k_tne_scat<<<NN/NB, 128, 0, stream>>>(offsets, gVp, eabuf,
      d_in[19], d_in[20], sm10, lnO, flag);
  k_node_mlp<<<NN/16, 256, 0, stream>>>(lnO, pw_s0, pw_s1, d_in[16], d_in[18], fsc3, flag);
  k_tne_cmix<<<NN/16, 256, 0, stream>>>(sm10, pwlt, fsc3, X9);

  for (int l=0; l<2; ++l){
    k_msg_edge_mfma<<<NE/16, 256, 0, stream>>>(eattr_c, gC, pos, pw0[l], pw1[l], pw2[l],
        d_in[22], d_in[24], d_in[26], (long)l*128, (long)l*256, (long)l*384,
        (unsigned short*)eabuf, flag);
    k_msg_prep<<<NN/NB, 128, 0, stream>>>(X9, d_in[27], (long)l*3*128*128, Y10, flag);
    k_msg_sf<<<NN/NB, 128, 0, stream>>>(offsets, csrc, eabuf, Y10,
        d_in[28], (long)l*3*128*128, X9, d_out, flag, (l==1)?1:0);
  }
}

// Round 18
// 283.333 us; speedup vs baseline: 1.6762x; 1.3681x over previous
//
#include <hip/hip_runtime.h>
#include <hip/hip_bf16.h>

typedef __hip_bfloat16 bf16;
typedef __attribute__((ext_vector_type(8))) short short8v;
typedef __attribute__((ext_vector_type(4))) float f32x4;

#define NN 4096
#define NE 32768
#define HH 128
#define MAXZ 100
#define TPB 8
#define NB 2

// ENVIRONMENT FACTS (r0-r17): float tensors are FLOAT32; runtime detector kept.
// MFMA edge path validated r10; MFMA node cmix/MLP validated r17 (387us, 2.9e-3).
// r18: apply the r17 recipe to the msg path — prep/sf were streaming lx/lt
// weights redundantly (NB=2 => 400MB L2). Split into norm + MFMA cmix (Y10),
// scatter+AB (smb), in-place MFMA cmix (lt), finish. Workspace ~73.5MB
// (r1-proven ok at 74.2MB).

__device__ __forceinline__ float b2f(bf16 v){ return __bfloat162float(v); }
__device__ __forceinline__ float ldf(const float* p, size_t i){ return p[i]; }
__device__ __forceinline__ float ldf(const bf16*  p, size_t i){ return __bfloat162float(p[i]); }
__device__ __forceinline__ float siluf(float x){ return x / (1.0f + __expf(-x)); }
__device__ __forceinline__ unsigned short f2bu(float x){
  bf16 h = __float2bfloat16(x);
  return *reinterpret_cast<unsigned short*>(&h);
}

__global__ void __launch_bounds__(256) k_detect(const unsigned int* __restrict__ w, int* __restrict__ flag){
  __shared__ int cnt[256];
  int t = threadIdx.x;
  int c = 0;
  for (int i = t; i < 4096; i += 256){
    unsigned int lo = w[i] & 0xffffu;
    int e = (int)((lo >> 7) & 0xffu);
    c += (e >= 110 && e <= 132) ? 1 : 0;
  }
  cnt[t] = c; __syncthreads();
  for (int off=128; off>=1; off>>=1){ if (t<off) cnt[t]+=cnt[t+off]; __syncthreads(); }
  if (t==0) flag[0] = (cnt[0] < 2048) ? 1 : 0;
}

// ---------------- CSR build ----------------
__global__ void __launch_bounds__(256) k_count(const int* __restrict__ dst, int* __restrict__ counts){
  int e = blockIdx.x*256 + threadIdx.x;
  if (e < NE) atomicAdd(&counts[dst[e]], 1);
}

__global__ void __launch_bounds__(1024) k_scan(const int* __restrict__ counts, int* __restrict__ offsets, int* __restrict__ cursor){
  __shared__ int lds[1024];
  int t = threadIdx.x;
  int c0 = counts[4*t+0], c1 = counts[4*t+1], c2 = counts[4*t+2], c3 = counts[4*t+3];
  int s1 = c0+c1, s2 = s1+c2, s3 = s2+c3;
  lds[t] = s3;
  __syncthreads();
  for (int off=1; off<1024; off<<=1){
    int v = lds[t];
    int add = (t>=off)? lds[t-off] : 0;
    __syncthreads();
    lds[t] = v + add;
    __syncthreads();
  }
  int incl = lds[t];
  int base = incl - s3;
  offsets[4*t+0]=base;    offsets[4*t+1]=base+c0; offsets[4*t+2]=base+s1; offsets[4*t+3]=base+s2;
  cursor [4*t+0]=base;    cursor [4*t+1]=base+c0; cursor [4*t+2]=base+s1; cursor [4*t+3]=base+s2;
  if (t==1023) offsets[4096]=incl;
}

__global__ void __launch_bounds__(256) k_fill(const int* __restrict__ dst, const int* __restrict__ src,
                                              int* __restrict__ cursor,
                                              int* __restrict__ pos, int* __restrict__ csrc){
  int e = blockIdx.x*256 + threadIdx.x;
  if (e < NE){
    int p = atomicAdd(&cursor[dst[e]], 1);
    pos[e] = p;
    csrc[p] = src[e];
  }
}

// ---------------- edge geometry ----------------
template<typename T>
__device__ __forceinline__ void geom_impl(const T* ew, const T* evec,
    const int* src, const int* dst, const int* pos, float* gC, float* gVp){
  int e = blockIdx.x*256 + threadIdx.x;
  if (e >= NE) return;
  float d = ldf(ew, e);
  float c = 0.5f*(cosf(d*0.6283185307179586f)+1.0f);
  c = (d < 5.0f) ? c : 0.0f;
  gC[e] = c;
  float x = ldf(evec, (size_t)e*3+0), y = ldf(evec, (size_t)e*3+1), z = ldf(evec, (size_t)e*3+2);
  if (src[e] != dst[e]){
    float n = sqrtf(x*x+y*y+z*z);
    float inv = 1.0f/fmaxf(n, 1e-12f);
    x*=inv; y*=inv; z*=inv;
  }
  int p = pos[e];
  gVp[p*3+0]=x; gVp[p*3+1]=y; gVp[p*3+2]=z;
}
__global__ void __launch_bounds__(256) k_geom(const void* ew, const void* evec,
    const int* __restrict__ src, const int* __restrict__ dst, const int* __restrict__ pos,
    float* __restrict__ gC, float* __restrict__ gVp, const int* __restrict__ flag){
  if (flag[0]) geom_impl<float>((const float*)ew, (const float*)evec, src, dst, pos, gC, gVp);
  else         geom_impl<bf16 >((const bf16* )ew, (const bf16* )evec, src, dst, pos, gC, gVp);
}

// ---------------- per-z embedding products ----------------
template<typename T>
__device__ __forceinline__ void zemb_impl(const T* emb, const T* emb2_w,
    float* P1z, float* P2z, float* Zr){
  int zv = blockIdx.x, h = threadIdx.x;
  Zr[h] = ldf(emb, (size_t)zv*HH + h);
  __syncthreads();
  float p1=0.f, p2=0.f;
  for (int r=0;r<128;++r){
    float x = Zr[r];
    p1 += x*ldf(emb2_w, (size_t)r*HH+h);
    p2 += x*ldf(emb2_w, (size_t)(r+128)*HH+h);
  }
  P1z[zv*HH+h]=p1; P2z[zv*HH+h]=p2;
}
__global__ void __launch_bounds__(128) k_zemb(const void* emb, const void* emb2_w,
    float* __restrict__ P1z, float* __restrict__ P2z, const int* __restrict__ flag){
  __shared__ float Zr[128];
  if (flag[0]) zemb_impl<float>((const float*)emb, (const float*)emb2_w, P1z, P2z, Zr);
  else         zemb_impl<bf16 >((const bf16* )emb, (const bf16* )emb2_w, P1z, P2z, Zr);
}

// ---------------- convert edge_attr -> bf16 ----------------
__global__ void __launch_bounds__(256) k_cvt_attr(const void* in, unsigned short* __restrict__ out,
                                                  const int* __restrict__ flag){
  int i = blockIdx.x*256 + threadIdx.x;
  if (flag[0]) out[i] = f2bu(((const float*)in)[i]);
  else         out[i] = ((const unsigned short*)in)[i];
}

// ---------------- weight repack into MFMA B-fragment layout (23 matrices) ----------------
struct PackDescs {
  const void*     base[23];
  long            eoff[23];
  unsigned short* out[23];
  int K[23]; int N[23];
};
template<typename T>
__device__ __forceinline__ void pack_impl(const PackDescs& d){
  int y = blockIdx.y;
  int K = d.K[y], N = d.N[y];
  int ktiles = K>>5, ntiles = N>>4;
  int total = ktiles*ntiles*64;
  int idx = blockIdx.x*256 + threadIdx.x;
  if (idx >= total) return;
  int lane = idx & 63, tile = idx >> 6;
  int kt = tile % ktiles, nt = tile / ktiles;
  const T* W = (const T*)d.base[y] + d.eoff[y];
  int n = nt*16 + (lane&15), k0 = kt*32 + (lane>>4)*8;
  unsigned int t[8];
  #pragma unroll
  for (int j=0;j<8;++j) t[j] = f2bu(ldf(W, (size_t)(k0+j)*N + n));
  uint4 v;
  v.x = t[0] | (t[1]<<16);
  v.y = t[2] | (t[3]<<16);
  v.z = t[4] | (t[5]<<16);
  v.w = t[6] | (t[7]<<16);
  *reinterpret_cast<uint4*>(d.out[y] + ((size_t)tile*64 + lane)*8) = v;
}
__global__ void __launch_bounds__(256) k_pack(PackDescs d, const int* __restrict__ flag){
  if (flag[0]) pack_impl<float>(d);
  else         pack_impl<bf16 >(d);
}

// ---------------- TNE edge coefficients -> eabuf bf16 (CSR-ordered rows) ----------------
template<typename T>
__device__ __forceinline__ void tne_edge_impl(
  const T* eattr, const int* src, const int* dst, const int* z, const int* pos,
  const T* dp1_w, const T* dp1_b, const T* dp2_w, const T* dp2_b,
  const T* dp3_w, const T* dp3_b, const T* emb2_b,
  const float* P1z, const float* P2z, const float* gC, bf16* eabuf,
  float (*attr)[32], int* zd, int* zs, int* ppos)
{
  int e0 = blockIdx.x*TPB;
  int h  = threadIdx.x;
  for (int i=h; i<TPB*32; i+=128) attr[i>>5][i&31] = ldf(eattr, (size_t)e0*32 + i);
  if (h < TPB){ int e=e0+h; zd[h]=z[dst[e]]; zs[h]=z[src[e]]; ppos[h]=pos[e]; }
  __syncthreads();
  float w1[TPB], w2[TPB], w3[TPB];
  float b1v=ldf(dp1_b,h), b2v=ldf(dp2_b,h), b3v=ldf(dp3_b,h);
  #pragma unroll
  for (int e=0;e<TPB;++e){ w1[e]=b1v; w2[e]=b2v; w3[e]=b3v; }
  for (int r=0;r<32;++r){
    float u1=ldf(dp1_w,(size_t)r*HH+h), u2=ldf(dp2_w,(size_t)r*HH+h), u3=ldf(dp3_w,(size_t)r*HH+h);
    #pragma unroll
    for (int e=0;e<TPB;++e){ float a=attr[e][r]; w1[e]+=a*u1; w2[e]+=a*u2; w3[e]+=a*u3; }
  }
  float eb = ldf(emb2_b,h);
  #pragma unroll
  for (int e=0;e<TPB;++e){
    float zij = P1z[zd[e]*HH+h] + P2z[zs[e]*HH+h] + eb;
    float c = gC[e0+e];
    bf16* p = eabuf + (size_t)ppos[e]*384;
    p[h]     = __float2bfloat16(zij*w1[e]*c);
    p[128+h] = __float2bfloat16(zij*w2[e]*c);
    p[256+h] = __float2bfloat16(zij*w3[e]*c);
  }
}
__global__ void __launch_bounds__(128) k_tne_edge(
  const void* eattr, const int* __restrict__ src, const int* __restrict__ dst,
  const int* __restrict__ z, const int* __restrict__ pos,
  const void* dp1_w, const void* dp1_b, const void* dp2_w, const void* dp2_b,
  const void* dp3_w, const void* dp3_b, const void* emb2_b,
  const float* __restrict__ P1z, const float* __restrict__ P2z,
  const float* __restrict__ gC, bf16* __restrict__ eabuf, const int* __restrict__ flag)
{
  __shared__ float attr[TPB][32];
  __shared__ int zd[TPB], zs[TPB], ppos[TPB];
  if (flag[0]) tne_edge_impl<float>((const float*)eattr, src, dst, z, pos,
      (const float*)dp1_w, (const float*)dp1_b, (const float*)dp2_w, (const float*)dp2_b,
      (const float*)dp3_w, (const float*)dp3_b, (const float*)emb2_b, P1z, P2z, gC, eabuf, attr, zd, zs, ppos);
  else tne_edge_impl<bf16>((const bf16*)eattr, src, dst, z, pos,
      (const bf16*)dp1_w, (const bf16*)dp1_b, (const bf16*)dp2_w, (const bf16*)dp2_b,
      (const bf16*)dp3_w, (const bf16*)dp3_b, (const bf16*)emb2_b, P1z, P2z, gC, eabuf, attr, zd, zs, ppos);
}

// ---------------- TNE scatter + LN: writes sm10 bf16 and ln bf16 ----------------
template<typename T>
__device__ __forceinline__ void tne_scat_impl(
  const int* offsets, const float* gVp, const bf16* eabuf,
  const T* ln_g, const T* ln_b, bf16* sm10, bf16* lnO, float* red)
{
  int n0 = blockIdx.x*NB, h = threadIdx.x;
  float tnv[NB];
  #pragma unroll
  for (int nn=0;nn<NB;++nn){
    int n = n0+nn;
    float a=0, v0=0,v1=0,v2=0, s0=0,s1=0,s2=0,s3=0,s4=0,s5=0;
    int beg = offsets[n], end = offsets[n+1];
    int i = beg;
    for (; i+4 <= end; i += 4){
      float c1[4],c2[4],c3[4],vx[4],vy[4],vz[4];
      #pragma unroll
      for (int u=0;u<4;++u){
        const bf16* p = eabuf + (size_t)(i+u)*384;
        c1[u]=b2f(p[h]); c2[u]=b2f(p[128+h]); c3[u]=b2f(p[256+h]);
        vx[u]=gVp[(i+u)*3+0]; vy[u]=gVp[(i+u)*3+1]; vz[u]=gVp[(i+u)*3+2];
      }
      #pragma unroll
      for (int u=0;u<4;++u){
        float tr3 = (vx[u]*vx[u]+vy[u]*vy[u]+vz[u]*vz[u])*(1.0f/3.0f);
        a  += c1[u];
        v0 += c2[u]*vx[u]; v1 += c2[u]*vy[u]; v2 += c2[u]*vz[u];
        s0 += c3[u]*(vx[u]*vx[u] - tr3); s1 += c3[u]*vx[u]*vy[u]; s2 += c3[u]*vx[u]*vz[u];
        s3 += c3[u]*(vy[u]*vy[u] - tr3); s4 += c3[u]*vy[u]*vz[u]; s5 += c3[u]*(vz[u]*vz[u] - tr3);
      }
    }
    for (; i<end; ++i){
      const bf16* p = eabuf + (size_t)i*384;
      float c1 = b2f(p[h]), c2 = b2f(p[128+h]), c3 = b2f(p[256+h]);
      float vx = gVp[i*3+0], vy = gVp[i*3+1], vz = gVp[i*3+2];
      float tr3 = (vx*vx+vy*vy+vz*vz)*(1.0f/3.0f);
      a  += c1;
      v0 += c2*vx; v1 += c2*vy; v2 += c2*vz;
      s0 += c3*(vx*vx - tr3); s1 += c3*vx*vy;          s2 += c3*vx*vz;
      s3 += c3*(vy*vy - tr3); s4 += c3*vy*vz;          s5 += c3*(vz*vz - tr3);
    }
    bf16* sp = sm10 + (size_t)n*1280;
    sp[0*128+h]=__float2bfloat16(a);
    sp[1*128+h]=__float2bfloat16(v0); sp[2*128+h]=__float2bfloat16(v1); sp[3*128+h]=__float2bfloat16(v2);
    sp[4*128+h]=__float2bfloat16(s0); sp[5*128+h]=__float2bfloat16(s1); sp[6*128+h]=__float2bfloat16(s2);
    sp[7*128+h]=__float2bfloat16(s3); sp[8*128+h]=__float2bfloat16(s4); sp[9*128+h]=__float2bfloat16(s5);
    tnv[nn] = 3.0f*a*a + 2.0f*(v0*v0+v1*v1+v2*v2)
            + s0*s0 + s3*s3 + s5*s5 + 2.0f*(s1*s1 + s2*s2 + s4*s4);
  }
  float gg = ldf(ln_g,h), bb = ldf(ln_b,h);
  #pragma unroll
  for (int nn=0;nn<NB;++nn){
    __syncthreads();
    red[h] = tnv[nn]; __syncthreads();
    for (int off=64; off>=1; off>>=1){ if (h<off) red[h]+=red[h+off]; __syncthreads(); }
    float mean = red[0]*(1.0f/128.0f);
    __syncthreads();
    float dm = tnv[nn] - mean;
    red[h] = dm*dm; __syncthreads();
    for (int off=64; off>=1; off>>=1){ if (h<off) red[h]+=red[h+off]; __syncthreads(); }
    float var = red[0]*(1.0f/128.0f);
    lnO[(size_t)(n0+nn)*128 + h] = __float2bfloat16(dm*rsqrtf(var+1e-5f)*gg + bb);
  }
}
__global__ void __launch_bounds__(128) k_tne_scat(
  const int* __restrict__ offsets, const float* __restrict__ gVp, const bf16* __restrict__ eabuf,
  const void* ln_g, const void* ln_b, bf16* __restrict__ sm10, bf16* __restrict__ lnO,
  const int* __restrict__ flag)
{
  __shared__ float red[128];
  if (flag[0]) tne_scat_impl<float>(offsets, gVp, eabuf, (const float*)ln_g, (const float*)ln_b, sm10, lnO, red);
  else         tne_scat_impl<bf16 >(offsets, gVp, eabuf, (const bf16* )ln_g, (const bf16* )ln_b, sm10, lnO, red);
}

// ---------------- node fsc MLP via MFMA (r17-validated) ----------------
template<typename T>
__device__ __forceinline__ void node_mlp_impl(
  const bf16* lnO, const unsigned short* ps0, const unsigned short* ps1,
  const T* b0, const T* b1, bf16* fsc3, unsigned short* h2p)
{
  int wid  = threadIdx.x >> 6;
  int lane = threadIdx.x & 63;
  int n0 = blockIdx.x*16;
  int m = lane & 15, g = lane >> 4;
  short8v aln[4];
  #pragma unroll
  for (int ks=0; ks<4; ++ks)
    aln[ks] = *reinterpret_cast<const short8v*>((const unsigned short*)lnO + (size_t)(n0+m)*128 + ks*32 + g*8);
  for (int nt=wid; nt<16; nt+=4){
    float bias = ldf(b0, nt*16+m);
    f32x4 acc = {bias,bias,bias,bias};
    #pragma unroll
    for (int ks=0; ks<4; ++ks){
      short8v b = *reinterpret_cast<const short8v*>(ps0 + ((size_t)(nt*4+ks)*64 + lane)*8);
      acc = __builtin_amdgcn_mfma_f32_16x16x32_bf16(aln[ks], b, acc, 0,0,0);
    }
    #pragma unroll
    for (int r=0;r<4;++r){
      int n = nt*16 + m, row = g*4 + r;
      h2p[(n>>5)*512 + (((n>>3)&3)*16+row)*8 + (n&7)] = f2bu(siluf(acc[r]));
    }
  }
  __syncthreads();
  short8v a3[8];
  #pragma unroll
  for (int ks=0; ks<8; ++ks) a3[ks] = *reinterpret_cast<const short8v*>(&h2p[ks*512 + lane*8]);
  for (int nt=wid; nt<24; nt+=4){
    float bias = ldf(b1, nt*16+m);
    f32x4 acc = {bias,bias,bias,bias};
    #pragma unroll
    for (int ks=0; ks<8; ++ks){
      short8v b = *reinterpret_cast<const short8v*>(ps1 + ((size_t)(nt*8+ks)*64 + lane)*8);
      acc = __builtin_amdgcn_mfma_f32_16x16x32_bf16(a3[ks], b, acc, 0,0,0);
    }
    #pragma unroll
    for (int r=0;r<4;++r){
      int n = nt*16 + m, row = g*4 + r;
      ((unsigned short*)fsc3)[(size_t)(n0+row)*384 + (n%3)*128 + (n/3)] = f2bu(siluf(acc[r]));
    }
  }
}
__global__ void __launch_bounds__(256) k_node_mlp(
  const bf16* __restrict__ lnO, const unsigned short* __restrict__ ps0,
  const unsigned short* __restrict__ ps1,
  const void* b0, const void* b1, bf16* __restrict__ fsc3, const int* __restrict__ flag)
{
  __shared__ __align__(16) unsigned short h2p[4096];
  if (flag[0]) node_mlp_impl<float>(lnO, ps0, ps1, (const float*)b0, (const float*)b1, fsc3, h2p);
  else         node_mlp_impl<bf16 >(lnO, ps0, ps1, (const bf16* )b0, (const bf16* )b1, fsc3, h2p);
}

// ---------------- tne cmix via MFMA + fsc combine -> X9 (r17-validated) ----------------
__global__ void __launch_bounds__(256) k_tne_cmix(
  const bf16* __restrict__ sm10, const unsigned short* __restrict__ pwlt,
  const bf16* __restrict__ fsc3, float* __restrict__ X9)
{
  int wid  = threadIdx.x >> 6;
  int lane = threadIdx.x & 63;
  int n0 = blockIdx.x*16;
  int m = lane & 15, g = lane >> 4;
  f32x4 acc[10][2];
  #pragma unroll
  for (int c=0;c<10;++c){ acc[c][0]=(f32x4){0,0,0,0}; acc[c][1]=(f32x4){0,0,0,0}; }
  #pragma unroll
  for (int c=0;c<10;++c){
    int mat = (c==0) ? 0 : (c<4) ? 1 : 2;
    const unsigned short* bw = pwlt + (size_t)mat*16384;
    short8v af[4];
    #pragma unroll
    for (int ks=0; ks<4; ++ks)
      af[ks] = *reinterpret_cast<const short8v*>((const unsigned short*)sm10 + (size_t)(n0+m)*1280 + c*128 + ks*32 + g*8);
    #pragma unroll
    for (int t=0;t<2;++t){
      int nt = wid + t*4;
      #pragma unroll
      for (int ks=0; ks<4; ++ks){
        short8v b = *reinterpret_cast<const short8v*>(bw + ((size_t)(nt*4+ks)*64 + lane)*8);
        acc[c][t] = __builtin_amdgcn_mfma_f32_16x16x32_bf16(af[ks], b, acc[c][t], 0,0,0);
      }
    }
  }
  #pragma unroll
  for (int t=0;t<2;++t){
    int nt = wid + t*4;
    int h = nt*16 + m;
    #pragma unroll
    for (int r=0;r<4;++r){
      int node = n0 + g*4 + r;
      float am  = acc[0][t][r];
      float wm0 = acc[1][t][r], wm1 = acc[2][t][r], wm2 = acc[3][t][r];
      float t0 = acc[4][t][r], t1 = acc[5][t][r], t2 = acc[6][t][r];
      float t3 = acc[7][t][r], t4 = acc[8][t][r], t5 = acc[9][t][r];
      float f0 = b2f(fsc3[(size_t)node*384 + h]);
      float f1 = b2f(fsc3[(size_t)node*384 + 128 + h]);
      float f2 = b2f(fsc3[(size_t)node*384 + 256 + h]);
      float* xp = X9 + (size_t)node*1152;
      xp[0*128+h] = f0*am + f2*t0;
      xp[1*128+h] = -f1*wm2 + f2*t1;
      xp[2*128+h] =  f1*wm1 + f2*t2;
      xp[3*128+h] =  f1*wm2 + f2*t1;
      xp[4*128+h] = f0*am + f2*t3;
      xp[5*128+h] = -f1*wm0 + f2*t4;
      xp[6*128+h] = -f1*wm1 + f2*t2;
      xp[7*128+h] =  f1*wm0 + f2*t4;
      xp[8*128+h] = f0*am + f2*t5;
    }
  }
}

// ---------------- generic 10-channel cmix via MFMA: in10 @ pw(3 mats) -> out10 bf16 ----------------
// Same layout machinery as k_tne_cmix. Safe in-place (out10==in10): block only
// touches its own 16 rows; __syncthreads separates all reads from all writes.
__global__ void __launch_bounds__(256) k_cmix10(
  const bf16* __restrict__ in10, const unsigned short* __restrict__ pw,
  bf16* __restrict__ out10)
{
  int wid  = threadIdx.x >> 6;
  int lane = threadIdx.x & 63;
  int n0 = blockIdx.x*16;
  int m = lane & 15, g = lane >> 4;
  f32x4 acc[10][2];
  #pragma unroll
  for (int c=0;c<10;++c){ acc[c][0]=(f32x4){0,0,0,0}; acc[c][1]=(f32x4){0,0,0,0}; }
  #pragma unroll
  for (int c=0;c<10;++c){
    int mat = (c==0) ? 0 : (c<4) ? 1 : 2;
    const unsigned short* bw = pw + (size_t)mat*16384;
    short8v af[4];
    #pragma unroll
    for (int ks=0; ks<4; ++ks)
      af[ks] = *reinterpret_cast<const short8v*>((const unsigned short*)in10 + (size_t)(n0+m)*1280 + c*128 + ks*32 + g*8);
    #pragma unroll
    for (int t=0;t<2;++t){
      int nt = wid + t*4;
      #pragma unroll
      for (int ks=0; ks<4; ++ks){
        short8v b = *reinterpret_cast<const short8v*>(bw + ((size_t)(nt*4+ks)*64 + lane)*8);
        acc[c][t] = __builtin_amdgcn_mfma_f32_16x16x32_bf16(af[ks], b, acc[c][t], 0,0,0);
      }
    }
  }
  __syncthreads();   // all reads done before any write (enables in-place)
  #pragma unroll
  for (int t=0;t<2;++t){
    int nt = wid + t*4;
    int h = nt*16 + m;
    #pragma unroll
    for (int r=0;r<4;++r){
      int node = n0 + g*4 + r;
      unsigned short* op = (unsigned short*)out10 + (size_t)node*1280;
      #pragma unroll
      for (int c=0;c<10;++c) op[c*128 + h] = f2bu(acc[c][t][r]);
    }
  }
}

// ---------------- msg edge MLP via MFMA (r10/r16-validated) ----------------
template<typename T>
__device__ __forceinline__ void mfma_impl(
  const unsigned short* eattr_c, const float* gC, const int* pos,
  const unsigned short* p0, const unsigned short* p1, const unsigned short* p2,
  const T* b0, const T* b1, const T* b2,
  unsigned short* eabuf, unsigned short* h1p, unsigned short* h2p, int* spos)
{
  int wid  = threadIdx.x >> 6;
  int lane = threadIdx.x & 63;
  int e0 = blockIdx.x*16;
  int m = lane & 15, g = lane >> 4;
  if (threadIdx.x < 16) spos[threadIdx.x] = pos[e0 + threadIdx.x];
  float cc[4];
  #pragma unroll
  for (int r=0;r<4;++r) cc[r] = gC[e0 + g*4 + r];
  short8v a1 = *reinterpret_cast<const short8v*>(eattr_c + (size_t)(e0+m)*32 + g*8);
  for (int nt=wid; nt<8; nt+=4){
    float bias = ldf(b0, nt*16+m);
    f32x4 acc = {bias,bias,bias,bias};
    short8v b = *reinterpret_cast<const short8v*>(p0 + ((size_t)nt*64 + lane)*8);
    acc = __builtin_amdgcn_mfma_f32_16x16x32_bf16(a1, b, acc, 0,0,0);
    #pragma unroll
    for (int r=0;r<4;++r){
      int n = nt*16 + m, row = g*4 + r;
      h1p[(n>>5)*512 + (((n>>3)&3)*16+row)*8 + (n&7)] = f2bu(siluf(acc[r]));
    }
  }
  __syncthreads();
  short8v a2[4];
  #pragma unroll
  for (int ks=0; ks<4; ++ks) a2[ks] = *reinterpret_cast<const short8v*>(&h1p[ks*512 + lane*8]);
  for (int nt=wid; nt<16; nt+=4){
    float bias = ldf(b1, nt*16+m);
    f32x4 acc = {bias,bias,bias,bias};
    #pragma unroll
    for (int ks=0; ks<4; ++ks){
      short8v b = *reinterpret_cast<const short8v*>(p1 + ((size_t)(nt*4+ks)*64 + lane)*8);
      acc = __builtin_amdgcn_mfma_f32_16x16x32_bf16(a2[ks], b, acc, 0,0,0);
    }
    #pragma unroll
    for (int r=0;r<4;++r){
      int n = nt*16 + m, row = g*4 + r;
      h2p[(n>>5)*512 + (((n>>3)&3)*16+row)*8 + (n&7)] = f2bu(siluf(acc[r]));
    }
  }
  __syncthreads();
  short8v a3[8];
  #pragma unroll
  for (int ks=0; ks<8; ++ks) a3[ks] = *reinterpret_cast<const short8v*>(&h2p[ks*512 + lane*8]);
  for (int nt=wid; nt<24; nt+=4){
    float bias = ldf(b2, nt*16+m);
    f32x4 acc = {bias,bias,bias,bias};
    #pragma unroll
    for (int ks=0; ks<8; ++ks){
      short8v b = *reinterpret_cast<const short8v*>(p2 + ((size_t)(nt*8+ks)*64 + lane)*8);
      acc = __builtin_amdgcn_mfma_f32_16x16x32_bf16(a3[ks], b, acc, 0,0,0);
    }
    #pragma unroll
    for (int r=0;r<4;++r){
      int n = nt*16 + m, row = g*4 + r;
      float v = siluf(acc[r]) * cc[r];
      eabuf[(size_t)spos[row]*384 + (n%3)*128 + (n/3)] = f2bu(v);
    }
  }
}
__global__ void __launch_bounds__(256) k_msg_edge_mfma(
  const unsigned short* __restrict__ eattr_c, const float* __restrict__ gC,
  const int* __restrict__ pos,
  const unsigned short* __restrict__ p0, const unsigned short* __restrict__ p1,
  const unsigned short* __restrict__ p2,
  const void* b0, const void* b1, const void* b2, long boff0, long boff1, long boff2,
  unsigned short* __restrict__ eabuf, const int* __restrict__ flag)
{
  __shared__ __align__(16) unsigned short h1p[2048];
  __shared__ __align__(16) unsigned short h2p[4096];
  __shared__ int spos[16];
  if (flag[0]) mfma_impl<float>(eattr_c, gC, pos, p0, p1, p2,
      (const float*)b0 + boff0, (const float*)b1 + boff1, (const float*)b2 + boff2, eabuf, h1p, h2p, spos);
  else mfma_impl<bf16>(eattr_c, gC, pos, p0, p1, p2,
      (const bf16*)b0 + boff0, (const bf16*)b1 + boff1, (const bf16*)b2 + boff2, eabuf, h1p, h2p, spos);
}

// ---------------- msg norm: normalize X (write back), decompose -> smb bf16 ----------------
__global__ void __launch_bounds__(128) k_msg_norm(
  float* __restrict__ X9, bf16* __restrict__ smb)
{
  int n0 = blockIdx.x*NB, h = threadIdx.x;
  #pragma unroll
  for (int nn=0;nn<NB;++nn){
    int n = n0+nn;
    float* xp = X9 + (size_t)n*1152;
    float x00=xp[0*128+h], x01=xp[1*128+h], x02=xp[2*128+h];
    float x10=xp[3*128+h], x11=xp[4*128+h], x12=xp[5*128+h];
    float x20=xp[6*128+h], x21=xp[7*128+h], x22=xp[8*128+h];
    float tn = x00*x00+x01*x01+x02*x02+x10*x10+x11*x11+x12*x12+x20*x20+x21*x21+x22*x22;
    float inv = 1.0f/(tn+1.0f);
    x00*=inv; x01*=inv; x02*=inv; x10*=inv; x11*=inv; x12*=inv; x20*=inv; x21*=inv; x22*=inv;
    // Reference REBINDS X to normalized before the update (r3 fix).
    xp[0*128+h]=x00; xp[1*128+h]=x01; xp[2*128+h]=x02;
    xp[3*128+h]=x10; xp[4*128+h]=x11; xp[5*128+h]=x12;
    xp[6*128+h]=x20; xp[7*128+h]=x21; xp[8*128+h]=x22;
    float a = (x00+x11+x22)*(1.0f/3.0f);
    bf16* sp = smb + (size_t)n*1280;
    sp[0*128+h]=__float2bfloat16(a);
    sp[1*128+h]=__float2bfloat16(0.5f*(x21-x12));
    sp[2*128+h]=__float2bfloat16(0.5f*(x02-x20));
    sp[3*128+h]=__float2bfloat16(0.5f*(x10-x01));
    sp[4*128+h]=__float2bfloat16(x00-a);
    sp[5*128+h]=__float2bfloat16(0.5f*(x01+x10));
    sp[6*128+h]=__float2bfloat16(0.5f*(x02+x20));
    sp[7*128+h]=__float2bfloat16(x11-a);
    sp[8*128+h]=__float2bfloat16(0.5f*(x12+x21));
    sp[9*128+h]=__float2bfloat16(x22-a);
  }
}

// ---------------- msg scatter + AB + decompose -> smb bf16 ----------------
__global__ void __launch_bounds__(128) k_msg_sab(
  const int* __restrict__ offsets, const int* __restrict__ csrc,
  const bf16* __restrict__ eabuf, const bf16* __restrict__ Y10, bf16* __restrict__ smb)
{
  int n0 = blockIdx.x*NB, h = threadIdx.x;
  #pragma unroll
  for (int nn=0;nn<NB;++nn){
    int n = n0+nn;
    float am=0, vm0=0,vm1=0,vm2=0, smm0=0,smm1=0,smm2=0,smm3=0,smm4=0,smm5=0;
    int beg = offsets[n], end = offsets[n+1];
    int i = beg;
    for (; i+4 <= end; i += 4){
      int ss[4];
      #pragma unroll
      for (int u=0;u<4;++u){ ss[u] = csrc[i+u]; }
      float e0a[4], e1a[4], e2a[4];
      float y0[4],y1[4],y2[4],y3[4],y4[4],y5[4],y6[4],y7[4],y8[4],y9[4];
      #pragma unroll
      for (int u=0;u<4;++u){
        const bf16* ep = eabuf + (size_t)(i+u)*384;
        e0a[u]=b2f(ep[h]); e1a[u]=b2f(ep[128+h]); e2a[u]=b2f(ep[256+h]);
        const bf16* yp = Y10 + (size_t)ss[u]*1280;
        y0[u]=b2f(yp[0*128+h]); y1[u]=b2f(yp[1*128+h]); y2[u]=b2f(yp[2*128+h]);
        y3[u]=b2f(yp[3*128+h]); y4[u]=b2f(yp[4*128+h]); y5[u]=b2f(yp[5*128+h]);
        y6[u]=b2f(yp[6*128+h]); y7[u]=b2f(yp[7*128+h]); y8[u]=b2f(yp[8*128+h]);
        y9[u]=b2f(yp[9*128+h]);
      }
      #pragma unroll
      for (int u=0;u<4;++u){
        am   += e0a[u]*y0[u];
        vm0  += e1a[u]*y1[u]; vm1 += e1a[u]*y2[u]; vm2 += e1a[u]*y3[u];
        smm0 += e2a[u]*y4[u]; smm1 += e2a[u]*y5[u]; smm2 += e2a[u]*y6[u];
        smm3 += e2a[u]*y7[u]; smm4 += e2a[u]*y8[u]; smm5 += e2a[u]*y9[u];
      }
    }
    for (; i<end; ++i){
      int s = csrc[i];
      const bf16* ep = eabuf + (size_t)i*384;
      float e0 = b2f(ep[h]), e1 = b2f(ep[128+h]), e2 = b2f(ep[256+h]);
      const bf16* yp = Y10 + (size_t)s*1280;
      am   += e0*b2f(yp[0*128+h]);
      vm0  += e1*b2f(yp[1*128+h]); vm1 += e1*b2f(yp[2*128+h]); vm2 += e1*b2f(yp[3*128+h]);
      smm0 += e2*b2f(yp[4*128+h]); smm1 += e2*b2f(yp[5*128+h]); smm2 += e2*b2f(yp[6*128+h]);
      smm3 += e2*b2f(yp[7*128+h]); smm4 += e2*b2f(yp[8*128+h]); smm5 += e2*b2f(yp[9*128+h]);
    }
    const bf16* yp = Y10 + (size_t)n*1280;
    float aY=b2f(yp[0*128+h]), u0=b2f(yp[1*128+h]), u1=b2f(yp[2*128+h]), u2=b2f(yp[3*128+h]);
    float q0=b2f(yp[4*128+h]), q1=b2f(yp[5*128+h]), q2=b2f(yp[6*128+h]);
    float q3=b2f(yp[7*128+h]), q4=b2f(yp[8*128+h]), q5=b2f(yp[9*128+h]);
    float m00=am+smm0,   m01=-vm2+smm1, m02= vm1+smm2;
    float m10= vm2+smm1, m11=am+smm3,  m12=-vm0+smm4;
    float m20=-vm1+smm2, m21= vm0+smm4, m22=am+smm5;
    float y00=aY+q0,  y01=-u2+q1, y02= u1+q2;
    float y10= u2+q1, y11=aY+q3,  y12=-u0+q4;
    float y20=-u1+q2, y21= u0+q4, y22=aY+q5;
    float ab00 = m00*y00+m01*y10+m02*y20 + y00*m00+y01*m10+y02*m20;
    float ab01 = m00*y01+m01*y11+m02*y21 + y00*m01+y01*m11+y02*m21;
    float ab02 = m00*y02+m01*y12+m02*y22 + y00*m02+y01*m12+y02*m22;
    float ab10 = m10*y00+m11*y10+m12*y20 + y10*m00+y11*m10+y12*m20;
    float ab11 = m10*y01+m11*y11+m12*y21 + y10*m01+y11*m11+y12*m21;
    float ab12 = m10*y02+m11*y12+m12*y22 + y10*m02+y11*m12+y12*m22;
    float ab20 = m20*y00+m21*y10+m22*y20 + y20*m00+y21*m10+y22*m20;
    float ab21 = m20*y01+m21*y11+m22*y21 + y20*m01+y21*m11+y22*m21;
    float ab22 = m20*y02+m21*y12+m22*y22 + y20*m02+y21*m12+y22*m22;
    float a2 = (ab00+ab11+ab22)*(1.0f/3.0f);
    float w0 = 0.5f*(ab21-ab12), w1 = 0.5f*(ab02-ab20), w2 = 0.5f*(ab10-ab01);
    float t0 = ab00-a2, t1 = 0.5f*(ab01+ab10), t2 = 0.5f*(ab02+ab20);
    float t3 = ab11-a2, t4 = 0.5f*(ab12+ab21), t5 = ab22-a2;
    float dnm = ab00*ab00+ab01*ab01+ab02*ab02+ab10*ab10+ab11*ab11+ab12*ab12
              + ab20*ab20+ab21*ab21+ab22*ab22 + 1.0f;
    float inv = 1.0f/dnm;
    bf16* sp = smb + (size_t)n*1280;
    sp[0*128+h]=__float2bfloat16(a2*inv);
    sp[1*128+h]=__float2bfloat16(w0*inv); sp[2*128+h]=__float2bfloat16(w1*inv); sp[3*128+h]=__float2bfloat16(w2*inv);
    sp[4*128+h]=__float2bfloat16(t0*inv); sp[5*128+h]=__float2bfloat16(t1*inv); sp[6*128+h]=__float2bfloat16(t2*inv);
    sp[7*128+h]=__float2bfloat16(t3*inv); sp[8*128+h]=__float2bfloat16(t4*inv); sp[9*128+h]=__float2bfloat16(t5*inv);
  }
}

// ---------------- msg finish: dt (smb) -> dX + dX^2, X update, optional out ----------------
template<typename T>
__device__ __forceinline__ void fin_impl(
  const bf16* smb, float* X9, T* out, int write_out)
{
  int n0 = blockIdx.x*NB, h = threadIdx.x;
  #pragma unroll
  for (int nn=0;nn<NB;++nn){
    int n = n0+nn;
    const bf16* sp = smb + (size_t)n*1280;
    float at  = b2f(sp[0*128+h]);
    float vt0 = b2f(sp[1*128+h]), vt1 = b2f(sp[2*128+h]), vt2 = b2f(sp[3*128+h]);
    float st0 = b2f(sp[4*128+h]), st1 = b2f(sp[5*128+h]), st2 = b2f(sp[6*128+h]);
    float st3 = b2f(sp[7*128+h]), st4 = b2f(sp[8*128+h]), st5 = b2f(sp[9*128+h]);
    float d00=at+st0,   d01=-vt2+st1, d02= vt1+st2;
    float d10= vt2+st1, d11=at+st3,  d12=-vt0+st4;
    float d20=-vt1+st2, d21= vt0+st4, d22=at+st5;
    float g00 = d00 + d00*d00+d01*d10+d02*d20;
    float g01 = d01 + d00*d01+d01*d11+d02*d21;
    float g02 = d02 + d00*d02+d01*d12+d02*d22;
    float g10 = d10 + d10*d00+d11*d10+d12*d20;
    float g11 = d11 + d10*d01+d11*d11+d12*d21;
    float g12 = d12 + d10*d02+d11*d12+d12*d22;
    float g20 = d20 + d20*d00+d21*d10+d22*d20;
    float g21 = d21 + d20*d01+d21*d11+d22*d21;
    float g22 = d22 + d20*d02+d21*d12+d22*d22;
    float* xp = X9 + (size_t)n*1152;
    float x00=xp[0*128+h]+g00, x01=xp[1*128+h]+g01, x02=xp[2*128+h]+g02;
    float x10=xp[3*128+h]+g10, x11=xp[4*128+h]+g11, x12=xp[5*128+h]+g12;
    float x20=xp[6*128+h]+g20, x21=xp[7*128+h]+g21, x22=xp[8*128+h]+g22;
    if (write_out){
      if (sizeof(T)==4){
        float* of = (float*)out + ((size_t)n*128 + h)*9;
        of[0]=x00; of[1]=x01; of[2]=x02; of[3]=x10; of[4]=x11; of[5]=x12; of[6]=x20; of[7]=x21; of[8]=x22;
      } else {
        bf16* ob = (bf16*)out + ((size_t)n*128 + h)*9;
        ob[0]=__float2bfloat16(x00); ob[1]=__float2bfloat16(x01); ob[2]=__float2bfloat16(x02);
        ob[3]=__float2bfloat16(x10); ob[4]=__float2bfloat16(x11); ob[5]=__float2bfloat16(x12);
        ob[6]=__float2bfloat16(x20); ob[7]=__float2bfloat16(x21); ob[8]=__float2bfloat16(x22);
      }
    } else {
      xp[0*128+h]=x00; xp[1*128+h]=x01; xp[2*128+h]=x02;
      xp[3*128+h]=x10; xp[4*128+h]=x11; xp[5*128+h]=x12;
      xp[6*128+h]=x20; xp[7*128+h]=x21; xp[8*128+h]=x22;
    }
  }
}
__global__ void __launch_bounds__(128) k_msg_fin(
  const bf16* __restrict__ smb, float* __restrict__ X9, void* __restrict__ out,
  const int* __restrict__ flag, int write_out)
{
  if (flag[0]) fin_impl<float>(smb, X9, (float*)out, write_out);
  else         fin_impl<bf16 >(smb, X9, (bf16* )out, write_out);
}

extern "C" void kernel_launch(void* const* d_in, const int* in_sizes, int n_in,
                              void* d_out, int out_size, void* d_ws, size_t ws_size,
                              hipStream_t stream)
{
  (void)in_sizes; (void)n_in; (void)out_size; (void)ws_size;
  const int* z    = (const int*)d_in[0];
  const int* eidx = (const int*)d_in[1];
  const int* src  = eidx;
  const int* dst  = eidx + NE;

  // Workspace ~73.5 MB (r1-proven budget 74.2 MB).
  char* w = (char*)d_ws;
  int* flag    = (int*)w;   w += 64;
  int* counts  = (int*)w;   w += (size_t)NN*4;
  int* offsets = (int*)w;   w += (size_t)(NN+1)*4 + 60;
  int* cursor  = (int*)w;   w += (size_t)NN*4;
  int* pos     = (int*)w;   w += (size_t)NE*4;
  int* csrc    = (int*)w;   w += (size_t)NE*4;
  float* gC    = (float*)w; w += (size_t)NE*4;
  float* gVp   = (float*)w; w += (size_t)NE*12;
  float* P1z   = (float*)w; w += (size_t)MAXZ*HH*4;
  float* P2z   = (float*)w; w += (size_t)MAXZ*HH*4;
  bf16* eabuf  = (bf16*)w;  w += (size_t)NE*384*2;       // 25.17 MB
  float* X9    = (float*)w; w += (size_t)NN*1152*4;      // 18.87 MB
  bf16* Y10    = (bf16*)w;  w += (size_t)NN*1280*2;      // 10.49 MB
  bf16* smb    = (bf16*)w;  w += (size_t)NN*1280*2;      // 10.49 MB
  unsigned short* eattr_c = (unsigned short*)w; w += (size_t)NE*32*2;  // 2.10 MB
  unsigned short* pw0[2]; unsigned short* pw1[2]; unsigned short* pw2[2];
  for (int l=0;l<2;++l){
    pw0[l] = (unsigned short*)w; w += 8*64*8*2;
    pw1[l] = (unsigned short*)w; w += 64*64*8*2;
    pw2[l] = (unsigned short*)w; w += 192*64*8*2;
  }
  unsigned short* pw_s0 = (unsigned short*)w; w += 64*64*8*2;
  unsigned short* pw_s1 = (unsigned short*)w; w += 192*64*8*2;
  unsigned short* pwlt  = (unsigned short*)w; w += 3*32*64*8*2;
  unsigned short* pwlx2 = (unsigned short*)w; w += 2*3*32*64*8*2;  // lx both layers
  unsigned short* pwlt2 = (unsigned short*)w; w += 2*3*32*64*8*2;  // lt both layers
  bf16* lnO    = (bf16*)w;  w += (size_t)NN*128*2;
  bf16* fsc3   = (bf16*)w;  w += (size_t)NN*384*2;
  bf16* sm10   = Y10;   // tne alias: dead until msg norm/cmix overwrites Y10

  k_detect<<<1, 256, 0, stream>>>((const unsigned int*)d_in[4], flag);
  hipMemsetAsync(counts, 0, (size_t)NN*4, stream);
  k_count<<<NE/256, 256, 0, stream>>>(dst, counts);
  k_scan<<<1, 1024, 0, stream>>>(counts, offsets, cursor);
  k_fill<<<NE/256, 256, 0, stream>>>(dst, src, cursor, pos, csrc);
  k_geom<<<NE/256, 256, 0, stream>>>(d_in[2], d_in[3], src, dst, pos, gC, gVp, flag);
  k_zemb<<<MAXZ, 128, 0, stream>>>(d_in[5], d_in[12], P1z, P2z, flag);
  k_cvt_attr<<<NE*32/256, 256, 0, stream>>>(d_in[4], eattr_c, flag);

  PackDescs pd;
  for (int l=0;l<2;++l){
    pd.base[l*3+0] = d_in[21]; pd.eoff[l*3+0] = (long)l*32*128;
    pd.base[l*3+1] = d_in[23]; pd.eoff[l*3+1] = (long)l*128*256;
    pd.base[l*3+2] = d_in[25]; pd.eoff[l*3+2] = (long)l*256*384;
    pd.out[l*3+0] = pw0[l]; pd.K[l*3+0]=32;  pd.N[l*3+0]=128;
    pd.out[l*3+1] = pw1[l]; pd.K[l*3+1]=128; pd.N[l*3+1]=256;
    pd.out[l*3+2] = pw2[l]; pd.K[l*3+2]=256; pd.N[l*3+2]=384;
  }
  pd.base[6] = d_in[15]; pd.eoff[6] = 0; pd.out[6] = pw_s0; pd.K[6]=128; pd.N[6]=256;
  pd.base[7] = d_in[17]; pd.eoff[7] = 0; pd.out[7] = pw_s1; pd.K[7]=256; pd.N[7]=384;
  for (int c=0;c<3;++c){
    pd.base[8+c] = d_in[14]; pd.eoff[8+c] = (long)c*16384;
    pd.out[8+c] = pwlt + (size_t)c*16384; pd.K[8+c]=128; pd.N[8+c]=128;
  }
  for (int l=0;l<2;++l)
    for (int c=0;c<3;++c){
      pd.base[11+l*3+c] = d_in[27]; pd.eoff[11+l*3+c] = (long)(l*3+c)*16384;
      pd.out[11+l*3+c] = pwlx2 + (size_t)(l*3+c)*16384; pd.K[11+l*3+c]=128; pd.N[11+l*3+c]=128;
      pd.base[17+l*3+c] = d_in[28]; pd.eoff[17+l*3+c] = (long)(l*3+c)*16384;
      pd.out[17+l*3+c] = pwlt2 + (size_t)(l*3+c)*16384; pd.K[17+l*3+c]=128; pd.N[17+l*3+c]=128;
    }
  k_pack<<<dim3(48, 23), 256, 0, stream>>>(pd, flag);

  k_tne_edge<<<NE/TPB, 128, 0, stream>>>(d_in[4], src, dst, z, pos,
      d_in[6], d_in[7], d_in[8], d_in[9], d_in[10], d_in[11], d_in[13],
      P1z, P2z, gC, eabuf, flag);
  k_tne_scat<<<NN/NB, 128, 0, stream>>>(offsets, gVp, eabuf,
      d_in[19], d_in[20], sm10, lnO, flag);
  k_node_mlp<<<NN/16, 256, 0, stream>>>(lnO, pw_s0, pw_s1, d_in[16], d_in[18], fsc3, flag);
  k_tne_cmix<<<NN/16, 256, 0, stream>>>(sm10, pwlt, fsc3, X9);

  for (int l=0; l<2; ++l){
    k_msg_edge_mfma<<<NE/16, 256, 0, stream>>>(eattr_c, gC, pos, pw0[l], pw1[l], pw2[l],
        d_in[22], d_in[24], d_in[26], (long)l*128, (long)l*256, (long)l*384,
        (unsigned short*)eabuf, flag);
    k_msg_norm<<<NN/NB, 128, 0, stream>>>(X9, smb);
    k_cmix10<<<NN/16, 256, 0, stream>>>(smb, pwlx2 + (size_t)l*3*16384, Y10);
    k_msg_sab<<<NN/NB, 128, 0, stream>>>(offsets, csrc, eabuf, Y10, smb);
    k_cmix10<<<NN/16, 256, 0, stream>>>(smb, pwlt2 + (size_t)l*3*16384, smb);
    k_msg_fin<<<NN/NB, 128, 0, stream>>>(smb, X9, d_out, flag, (l==1)?1:0);
  }
}

// Round 19
// 279.872 us; speedup vs baseline: 1.6969x; 1.0124x over previous
//
#include <hip/hip_runtime.h>
#include <hip/hip_bf16.h>

typedef __hip_bfloat16 bf16;
typedef __attribute__((ext_vector_type(8))) short short8v;
typedef __attribute__((ext_vector_type(4))) float f32x4;

#define NN 4096
#define NE 32768
#define HH 128
#define MAXZ 100
#define TPB 8
#define NB 2

// ENVIRONMENT FACTS (r0-r18): float tensors are FLOAT32; runtime detector kept.
// MFMA edge path validated r10/r16; MFMA node+msg cmix validated r17/r18
// (283us, absmax 2.9e-3). r18 counters: k_msg_edge_mfma is L2-BW-bound on
// cross-block weight streams (528KB x 2048 blocks = 1.08GB L2 ~ 24TB/s).
// r19: 32 edges/block, 2 m-tiles per wave, B-fragments register-reused 2x
// => B traffic halved. Per-tile MFMA math identical => absmax must stay
// 0.002929688.

__device__ __forceinline__ float b2f(bf16 v){ return __bfloat162float(v); }
__device__ __forceinline__ float ldf(const float* p, size_t i){ return p[i]; }
__device__ __forceinline__ float ldf(const bf16*  p, size_t i){ return __bfloat162float(p[i]); }
__device__ __forceinline__ float siluf(float x){ return x / (1.0f + __expf(-x)); }
__device__ __forceinline__ unsigned short f2bu(float x){
  bf16 h = __float2bfloat16(x);
  return *reinterpret_cast<unsigned short*>(&h);
}

__global__ void __launch_bounds__(256) k_detect(const unsigned int* __restrict__ w, int* __restrict__ flag){
  __shared__ int cnt[256];
  int t = threadIdx.x;
  int c = 0;
  for (int i = t; i < 4096; i += 256){
    unsigned int lo = w[i] & 0xffffu;
    int e = (int)((lo >> 7) & 0xffu);
    c += (e >= 110 && e <= 132) ? 1 : 0;
  }
  cnt[t] = c; __syncthreads();
  for (int off=128; off>=1; off>>=1){ if (t<off) cnt[t]+=cnt[t+off]; __syncthreads(); }
  if (t==0) flag[0] = (cnt[0] < 2048) ? 1 : 0;
}

// ---------------- CSR build ----------------
__global__ void __launch_bounds__(256) k_count(const int* __restrict__ dst, int* __restrict__ counts){
  int e = blockIdx.x*256 + threadIdx.x;
  if (e < NE) atomicAdd(&counts[dst[e]], 1);
}

__global__ void __launch_bounds__(1024) k_scan(const int* __restrict__ counts, int* __restrict__ offsets, int* __restrict__ cursor){
  __shared__ int lds[1024];
  int t = threadIdx.x;
  int c0 = counts[4*t+0], c1 = counts[4*t+1], c2 = counts[4*t+2], c3 = counts[4*t+3];
  int s1 = c0+c1, s2 = s1+c2, s3 = s2+c3;
  lds[t] = s3;
  __syncthreads();
  for (int off=1; off<1024; off<<=1){
    int v = lds[t];
    int add = (t>=off)? lds[t-off] : 0;
    __syncthreads();
    lds[t] = v + add;
    __syncthreads();
  }
  int incl = lds[t];
  int base = incl - s3;
  offsets[4*t+0]=base;    offsets[4*t+1]=base+c0; offsets[4*t+2]=base+s1; offsets[4*t+3]=base+s2;
  cursor [4*t+0]=base;    cursor [4*t+1]=base+c0; cursor [4*t+2]=base+s1; cursor [4*t+3]=base+s2;
  if (t==1023) offsets[4096]=incl;
}

__global__ void __launch_bounds__(256) k_fill(const int* __restrict__ dst, const int* __restrict__ src,
                                              int* __restrict__ cursor,
                                              int* __restrict__ pos, int* __restrict__ csrc){
  int e = blockIdx.x*256 + threadIdx.x;
  if (e < NE){
    int p = atomicAdd(&cursor[dst[e]], 1);
    pos[e] = p;
    csrc[p] = src[e];
  }
}

// ---------------- edge geometry ----------------
template<typename T>
__device__ __forceinline__ void geom_impl(const T* ew, const T* evec,
    const int* src, const int* dst, const int* pos, float* gC, float* gVp){
  int e = blockIdx.x*256 + threadIdx.x;
  if (e >= NE) return;
  float d = ldf(ew, e);
  float c = 0.5f*(cosf(d*0.6283185307179586f)+1.0f);
  c = (d < 5.0f) ? c : 0.0f;
  gC[e] = c;
  float x = ldf(evec, (size_t)e*3+0), y = ldf(evec, (size_t)e*3+1), z = ldf(evec, (size_t)e*3+2);
  if (src[e] != dst[e]){
    float n = sqrtf(x*x+y*y+z*z);
    float inv = 1.0f/fmaxf(n, 1e-12f);
    x*=inv; y*=inv; z*=inv;
  }
  int p = pos[e];
  gVp[p*3+0]=x; gVp[p*3+1]=y; gVp[p*3+2]=z;
}
__global__ void __launch_bounds__(256) k_geom(const void* ew, const void* evec,
    const int* __restrict__ src, const int* __restrict__ dst, const int* __restrict__ pos,
    float* __restrict__ gC, float* __restrict__ gVp, const int* __restrict__ flag){
  if (flag[0]) geom_impl<float>((const float*)ew, (const float*)evec, src, dst, pos, gC, gVp);
  else         geom_impl<bf16 >((const bf16* )ew, (const bf16* )evec, src, dst, pos, gC, gVp);
}

// ---------------- per-z embedding products ----------------
template<typename T>
__device__ __forceinline__ void zemb_impl(const T* emb, const T* emb2_w,
    float* P1z, float* P2z, float* Zr){
  int zv = blockIdx.x, h = threadIdx.x;
  Zr[h] = ldf(emb, (size_t)zv*HH + h);
  __syncthreads();
  float p1=0.f, p2=0.f;
  for (int r=0;r<128;++r){
    float x = Zr[r];
    p1 += x*ldf(emb2_w, (size_t)r*HH+h);
    p2 += x*ldf(emb2_w, (size_t)(r+128)*HH+h);
  }
  P1z[zv*HH+h]=p1; P2z[zv*HH+h]=p2;
}
__global__ void __launch_bounds__(128) k_zemb(const void* emb, const void* emb2_w,
    float* __restrict__ P1z, float* __restrict__ P2z, const int* __restrict__ flag){
  __shared__ float Zr[128];
  if (flag[0]) zemb_impl<float>((const float*)emb, (const float*)emb2_w, P1z, P2z, Zr);
  else         zemb_impl<bf16 >((const bf16* )emb, (const bf16* )emb2_w, P1z, P2z, Zr);
}

// ---------------- convert edge_attr -> bf16 ----------------
__global__ void __launch_bounds__(256) k_cvt_attr(const void* in, unsigned short* __restrict__ out,
                                                  const int* __restrict__ flag){
  int i = blockIdx.x*256 + threadIdx.x;
  if (flag[0]) out[i] = f2bu(((const float*)in)[i]);
  else         out[i] = ((const unsigned short*)in)[i];
}

// ---------------- weight repack into MFMA B-fragment layout (23 matrices) ----------------
struct PackDescs {
  const void*     base[23];
  long            eoff[23];
  unsigned short* out[23];
  int K[23]; int N[23];
};
template<typename T>
__device__ __forceinline__ void pack_impl(const PackDescs& d){
  int y = blockIdx.y;
  int K = d.K[y], N = d.N[y];
  int ktiles = K>>5, ntiles = N>>4;
  int total = ktiles*ntiles*64;
  int idx = blockIdx.x*256 + threadIdx.x;
  if (idx >= total) return;
  int lane = idx & 63, tile = idx >> 6;
  int kt = tile % ktiles, nt = tile / ktiles;
  const T* W = (const T*)d.base[y] + d.eoff[y];
  int n = nt*16 + (lane&15), k0 = kt*32 + (lane>>4)*8;
  unsigned int t[8];
  #pragma unroll
  for (int j=0;j<8;++j) t[j] = f2bu(ldf(W, (size_t)(k0+j)*N + n));
  uint4 v;
  v.x = t[0] | (t[1]<<16);
  v.y = t[2] | (t[3]<<16);
  v.z = t[4] | (t[5]<<16);
  v.w = t[6] | (t[7]<<16);
  *reinterpret_cast<uint4*>(d.out[y] + ((size_t)tile*64 + lane)*8) = v;
}
__global__ void __launch_bounds__(256) k_pack(PackDescs d, const int* __restrict__ flag){
  if (flag[0]) pack_impl<float>(d);
  else         pack_impl<bf16 >(d);
}

// ---------------- TNE edge coefficients -> eabuf bf16 (CSR-ordered rows) ----------------
template<typename T>
__device__ __forceinline__ void tne_edge_impl(
  const T* eattr, const int* src, const int* dst, const int* z, const int* pos,
  const T* dp1_w, const T* dp1_b, const T* dp2_w, const T* dp2_b,
  const T* dp3_w, const T* dp3_b, const T* emb2_b,
  const float* P1z, const float* P2z, const float* gC, bf16* eabuf,
  float (*attr)[32], int* zd, int* zs, int* ppos)
{
  int e0 = blockIdx.x*TPB;
  int h  = threadIdx.x;
  for (int i=h; i<TPB*32; i+=128) attr[i>>5][i&31] = ldf(eattr, (size_t)e0*32 + i);
  if (h < TPB){ int e=e0+h; zd[h]=z[dst[e]]; zs[h]=z[src[e]]; ppos[h]=pos[e]; }
  __syncthreads();
  float w1[TPB], w2[TPB], w3[TPB];
  float b1v=ldf(dp1_b,h), b2v=ldf(dp2_b,h), b3v=ldf(dp3_b,h);
  #pragma unroll
  for (int e=0;e<TPB;++e){ w1[e]=b1v; w2[e]=b2v; w3[e]=b3v; }
  for (int r=0;r<32;++r){
    float u1=ldf(dp1_w,(size_t)r*HH+h), u2=ldf(dp2_w,(size_t)r*HH+h), u3=ldf(dp3_w,(size_t)r*HH+h);
    #pragma unroll
    for (int e=0;e<TPB;++e){ float a=attr[e][r]; w1[e]+=a*u1; w2[e]+=a*u2; w3[e]+=a*u3; }
  }
  float eb = ldf(emb2_b,h);
  #pragma unroll
  for (int e=0;e<TPB;++e){
    float zij = P1z[zd[e]*HH+h] + P2z[zs[e]*HH+h] + eb;
    float c = gC[e0+e];
    bf16* p = eabuf + (size_t)ppos[e]*384;
    p[h]     = __float2bfloat16(zij*w1[e]*c);
    p[128+h] = __float2bfloat16(zij*w2[e]*c);
    p[256+h] = __float2bfloat16(zij*w3[e]*c);
  }
}
__global__ void __launch_bounds__(128) k_tne_edge(
  const void* eattr, const int* __restrict__ src, const int* __restrict__ dst,
  const int* __restrict__ z, const int* __restrict__ pos,
  const void* dp1_w, const void* dp1_b, const void* dp2_w, const void* dp2_b,
  const void* dp3_w, const void* dp3_b, const void* emb2_b,
  const float* __restrict__ P1z, const float* __restrict__ P2z,
  const float* __restrict__ gC, bf16* __restrict__ eabuf, const int* __restrict__ flag)
{
  __shared__ float attr[TPB][32];
  __shared__ int zd[TPB], zs[TPB], ppos[TPB];
  if (flag[0]) tne_edge_impl<float>((const float*)eattr, src, dst, z, pos,
      (const float*)dp1_w, (const float*)dp1_b, (const float*)dp2_w, (const float*)dp2_b,
      (const float*)dp3_w, (const float*)dp3_b, (const float*)emb2_b, P1z, P2z, gC, eabuf, attr, zd, zs, ppos);
  else tne_edge_impl<bf16>((const bf16*)eattr, src, dst, z, pos,
      (const bf16*)dp1_w, (const bf16*)dp1_b, (const bf16*)dp2_w, (const bf16*)dp2_b,
      (const bf16*)dp3_w, (const bf16*)dp3_b, (const bf16*)emb2_b, P1z, P2z, gC, eabuf, attr, zd, zs, ppos);
}

// ---------------- TNE scatter + LN: writes sm10 bf16 and ln bf16 ----------------
template<typename T>
__device__ __forceinline__ void tne_scat_impl(
  const int* offsets, const float* gVp, const bf16* eabuf,
  const T* ln_g, const T* ln_b, bf16* sm10, bf16* lnO, float* red)
{
  int n0 = blockIdx.x*NB, h = threadIdx.x;
  float tnv[NB];
  #pragma unroll
  for (int nn=0;nn<NB;++nn){
    int n = n0+nn;
    float a=0, v0=0,v1=0,v2=0, s0=0,s1=0,s2=0,s3=0,s4=0,s5=0;
    int beg = offsets[n], end = offsets[n+1];
    int i = beg;
    for (; i+4 <= end; i += 4){
      float c1[4],c2[4],c3[4],vx[4],vy[4],vz[4];
      #pragma unroll
      for (int u=0;u<4;++u){
        const bf16* p = eabuf + (size_t)(i+u)*384;
        c1[u]=b2f(p[h]); c2[u]=b2f(p[128+h]); c3[u]=b2f(p[256+h]);
        vx[u]=gVp[(i+u)*3+0]; vy[u]=gVp[(i+u)*3+1]; vz[u]=gVp[(i+u)*3+2];
      }
      #pragma unroll
      for (int u=0;u<4;++u){
        float tr3 = (vx[u]*vx[u]+vy[u]*vy[u]+vz[u]*vz[u])*(1.0f/3.0f);
        a  += c1[u];
        v0 += c2[u]*vx[u]; v1 += c2[u]*vy[u]; v2 += c2[u]*vz[u];
        s0 += c3[u]*(vx[u]*vx[u] - tr3); s1 += c3[u]*vx[u]*vy[u]; s2 += c3[u]*vx[u]*vz[u];
        s3 += c3[u]*(vy[u]*vy[u] - tr3); s4 += c3[u]*vy[u]*vz[u]; s5 += c3[u]*(vz[u]*vz[u] - tr3);
      }
    }
    for (; i<end; ++i){
      const bf16* p = eabuf + (size_t)i*384;
      float c1 = b2f(p[h]), c2 = b2f(p[128+h]), c3 = b2f(p[256+h]);
      float vx = gVp[i*3+0], vy = gVp[i*3+1], vz = gVp[i*3+2];
      float tr3 = (vx*vx+vy*vy+vz*vz)*(1.0f/3.0f);
      a  += c1;
      v0 += c2*vx; v1 += c2*vy; v2 += c2*vz;
      s0 += c3*(vx*vx - tr3); s1 += c3*vx*vy;          s2 += c3*vx*vz;
      s3 += c3*(vy*vy - tr3); s4 += c3*vy*vz;          s5 += c3*(vz*vz - tr3);
    }
    bf16* sp = sm10 + (size_t)n*1280;
    sp[0*128+h]=__float2bfloat16(a);
    sp[1*128+h]=__float2bfloat16(v0); sp[2*128+h]=__float2bfloat16(v1); sp[3*128+h]=__float2bfloat16(v2);
    sp[4*128+h]=__float2bfloat16(s0); sp[5*128+h]=__float2bfloat16(s1); sp[6*128+h]=__float2bfloat16(s2);
    sp[7*128+h]=__float2bfloat16(s3); sp[8*128+h]=__float2bfloat16(s4); sp[9*128+h]=__float2bfloat16(s5);
    tnv[nn] = 3.0f*a*a + 2.0f*(v0*v0+v1*v1+v2*v2)
            + s0*s0 + s3*s3 + s5*s5 + 2.0f*(s1*s1 + s2*s2 + s4*s4);
  }
  float gg = ldf(ln_g,h), bb = ldf(ln_b,h);
  #pragma unroll
  for (int nn=0;nn<NB;++nn){
    __syncthreads();
    red[h] = tnv[nn]; __syncthreads();
    for (int off=64; off>=1; off>>=1){ if (h<off) red[h]+=red[h+off]; __syncthreads(); }
    float mean = red[0]*(1.0f/128.0f);
    __syncthreads();
    float dm = tnv[nn] - mean;
    red[h] = dm*dm; __syncthreads();
    for (int off=64; off>=1; off>>=1){ if (h<off) red[h]+=red[h+off]; __syncthreads(); }
    float var = red[0]*(1.0f/128.0f);
    lnO[(size_t)(n0+nn)*128 + h] = __float2bfloat16(dm*rsqrtf(var+1e-5f)*gg + bb);
  }
}
__global__ void __launch_bounds__(128) k_tne_scat(
  const int* __restrict__ offsets, const float* __restrict__ gVp, const bf16* __restrict__ eabuf,
  const void* ln_g, const void* ln_b, bf16* __restrict__ sm10, bf16* __restrict__ lnO,
  const int* __restrict__ flag)
{
  __shared__ float red[128];
  if (flag[0]) tne_scat_impl<float>(offsets, gVp, eabuf, (const float*)ln_g, (const float*)ln_b, sm10, lnO, red);
  else         tne_scat_impl<bf16 >(offsets, gVp, eabuf, (const bf16* )ln_g, (const bf16* )ln_b, sm10, lnO, red);
}

// ---------------- node fsc MLP via MFMA (r17-validated) ----------------
template<typename T>
__device__ __forceinline__ void node_mlp_impl(
  const bf16* lnO, const unsigned short* ps0, const unsigned short* ps1,
  const T* b0, const T* b1, bf16* fsc3, unsigned short* h2p)
{
  int wid  = threadIdx.x >> 6;
  int lane = threadIdx.x & 63;
  int n0 = blockIdx.x*16;
  int m = lane & 15, g = lane >> 4;
  short8v aln[4];
  #pragma unroll
  for (int ks=0; ks<4; ++ks)
    aln[ks] = *reinterpret_cast<const short8v*>((const unsigned short*)lnO + (size_t)(n0+m)*128 + ks*32 + g*8);
  for (int nt=wid; nt<16; nt+=4){
    float bias = ldf(b0, nt*16+m);
    f32x4 acc = {bias,bias,bias,bias};
    #pragma unroll
    for (int ks=0; ks<4; ++ks){
      short8v b = *reinterpret_cast<const short8v*>(ps0 + ((size_t)(nt*4+ks)*64 + lane)*8);
      acc = __builtin_amdgcn_mfma_f32_16x16x32_bf16(aln[ks], b, acc, 0,0,0);
    }
    #pragma unroll
    for (int r=0;r<4;++r){
      int n = nt*16 + m, row = g*4 + r;
      h2p[(n>>5)*512 + (((n>>3)&3)*16+row)*8 + (n&7)] = f2bu(siluf(acc[r]));
    }
  }
  __syncthreads();
  short8v a3[8];
  #pragma unroll
  for (int ks=0; ks<8; ++ks) a3[ks] = *reinterpret_cast<const short8v*>(&h2p[ks*512 + lane*8]);
  for (int nt=wid; nt<24; nt+=4){
    float bias = ldf(b1, nt*16+m);
    f32x4 acc = {bias,bias,bias,bias};
    #pragma unroll
    for (int ks=0; ks<8; ++ks){
      short8v b = *reinterpret_cast<const short8v*>(ps1 + ((size_t)(nt*8+ks)*64 + lane)*8);
      acc = __builtin_amdgcn_mfma_f32_16x16x32_bf16(a3[ks], b, acc, 0,0,0);
    }
    #pragma unroll
    for (int r=0;r<4;++r){
      int n = nt*16 + m, row = g*4 + r;
      ((unsigned short*)fsc3)[(size_t)(n0+row)*384 + (n%3)*128 + (n/3)] = f2bu(siluf(acc[r]));
    }
  }
}
__global__ void __launch_bounds__(256) k_node_mlp(
  const bf16* __restrict__ lnO, const unsigned short* __restrict__ ps0,
  const unsigned short* __restrict__ ps1,
  const void* b0, const void* b1, bf16* __restrict__ fsc3, const int* __restrict__ flag)
{
  __shared__ __align__(16) unsigned short h2p[4096];
  if (flag[0]) node_mlp_impl<float>(lnO, ps0, ps1, (const float*)b0, (const float*)b1, fsc3, h2p);
  else         node_mlp_impl<bf16 >(lnO, ps0, ps1, (const bf16* )b0, (const bf16* )b1, fsc3, h2p);
}

// ---------------- tne cmix via MFMA + fsc combine -> X9 (r17-validated) ----------------
__global__ void __launch_bounds__(256) k_tne_cmix(
  const bf16* __restrict__ sm10, const unsigned short* __restrict__ pwlt,
  const bf16* __restrict__ fsc3, float* __restrict__ X9)
{
  int wid  = threadIdx.x >> 6;
  int lane = threadIdx.x & 63;
  int n0 = blockIdx.x*16;
  int m = lane & 15, g = lane >> 4;
  f32x4 acc[10][2];
  #pragma unroll
  for (int c=0;c<10;++c){ acc[c][0]=(f32x4){0,0,0,0}; acc[c][1]=(f32x4){0,0,0,0}; }
  #pragma unroll
  for (int c=0;c<10;++c){
    int mat = (c==0) ? 0 : (c<4) ? 1 : 2;
    const unsigned short* bw = pwlt + (size_t)mat*16384;
    short8v af[4];
    #pragma unroll
    for (int ks=0; ks<4; ++ks)
      af[ks] = *reinterpret_cast<const short8v*>((const unsigned short*)sm10 + (size_t)(n0+m)*1280 + c*128 + ks*32 + g*8);
    #pragma unroll
    for (int t=0;t<2;++t){
      int nt = wid + t*4;
      #pragma unroll
      for (int ks=0; ks<4; ++ks){
        short8v b = *reinterpret_cast<const short8v*>(bw + ((size_t)(nt*4+ks)*64 + lane)*8);
        acc[c][t] = __builtin_amdgcn_mfma_f32_16x16x32_bf16(af[ks], b, acc[c][t], 0,0,0);
      }
    }
  }
  #pragma unroll
  for (int t=0;t<2;++t){
    int nt = wid + t*4;
    int h = nt*16 + m;
    #pragma unroll
    for (int r=0;r<4;++r){
      int node = n0 + g*4 + r;
      float am  = acc[0][t][r];
      float wm0 = acc[1][t][r], wm1 = acc[2][t][r], wm2 = acc[3][t][r];
      float t0 = acc[4][t][r], t1 = acc[5][t][r], t2 = acc[6][t][r];
      float t3 = acc[7][t][r], t4 = acc[8][t][r], t5 = acc[9][t][r];
      float f0 = b2f(fsc3[(size_t)node*384 + h]);
      float f1 = b2f(fsc3[(size_t)node*384 + 128 + h]);
      float f2 = b2f(fsc3[(size_t)node*384 + 256 + h]);
      float* xp = X9 + (size_t)node*1152;
      xp[0*128+h] = f0*am + f2*t0;
      xp[1*128+h] = -f1*wm2 + f2*t1;
      xp[2*128+h] =  f1*wm1 + f2*t2;
      xp[3*128+h] =  f1*wm2 + f2*t1;
      xp[4*128+h] = f0*am + f2*t3;
      xp[5*128+h] = -f1*wm0 + f2*t4;
      xp[6*128+h] = -f1*wm1 + f2*t2;
      xp[7*128+h] =  f1*wm0 + f2*t4;
      xp[8*128+h] = f0*am + f2*t5;
    }
  }
}

// ---------------- generic 10-channel cmix via MFMA (r18-validated; in-place safe) ----------------
__global__ void __launch_bounds__(256) k_cmix10(
  const bf16* __restrict__ in10, const unsigned short* __restrict__ pw,
  bf16* __restrict__ out10)
{
  int wid  = threadIdx.x >> 6;
  int lane = threadIdx.x & 63;
  int n0 = blockIdx.x*16;
  int m = lane & 15, g = lane >> 4;
  f32x4 acc[10][2];
  #pragma unroll
  for (int c=0;c<10;++c){ acc[c][0]=(f32x4){0,0,0,0}; acc[c][1]=(f32x4){0,0,0,0}; }
  #pragma unroll
  for (int c=0;c<10;++c){
    int mat = (c==0) ? 0 : (c<4) ? 1 : 2;
    const unsigned short* bw = pw + (size_t)mat*16384;
    short8v af[4];
    #pragma unroll
    for (int ks=0; ks<4; ++ks)
      af[ks] = *reinterpret_cast<const short8v*>((const unsigned short*)in10 + (size_t)(n0+m)*1280 + c*128 + ks*32 + g*8);
    #pragma unroll
    for (int t=0;t<2;++t){
      int nt = wid + t*4;
      #pragma unroll
      for (int ks=0; ks<4; ++ks){
        short8v b = *reinterpret_cast<const short8v*>(bw + ((size_t)(nt*4+ks)*64 + lane)*8);
        acc[c][t] = __builtin_amdgcn_mfma_f32_16x16x32_bf16(af[ks], b, acc[c][t], 0,0,0);
      }
    }
  }
  __syncthreads();
  #pragma unroll
  for (int t=0;t<2;++t){
    int nt = wid + t*4;
    int h = nt*16 + m;
    #pragma unroll
    for (int r=0;r<4;++r){
      int node = n0 + g*4 + r;
      unsigned short* op = (unsigned short*)out10 + (size_t)node*1280;
      #pragma unroll
      for (int c=0;c<10;++c) op[c*128 + h] = f2bu(acc[c][t][r]);
    }
  }
}

// ---------------- msg edge MLP via MFMA: 32 edges/block, 2 m-tiles/wave, 4-wave N-split ----------------
// B fragments loaded once, register-reused across both m-tiles (r19: halves L2 B traffic).
// Per-tile MFMA math identical to r16/r18 => same values.
template<typename T>
__device__ __forceinline__ void mfma_impl(
  const unsigned short* eattr_c, const float* gC, const int* pos,
  const unsigned short* p0, const unsigned short* p1, const unsigned short* p2,
  const T* b0, const T* b1, const T* b2,
  unsigned short* eabuf, unsigned short (*h1p)[2048], unsigned short (*h2p)[4096], int* spos)
{
  int wid  = threadIdx.x >> 6;
  int lane = threadIdx.x & 63;
  int e0 = blockIdx.x*32;
  int m = lane & 15, g = lane >> 4;
  if (threadIdx.x < 32) spos[threadIdx.x] = pos[e0 + threadIdx.x];
  float cc[2][4];
  #pragma unroll
  for (int mt=0;mt<2;++mt)
    #pragma unroll
    for (int r=0;r<4;++r) cc[mt][r] = gC[e0 + mt*16 + g*4 + r];
  short8v a1[2];
  #pragma unroll
  for (int mt=0;mt<2;++mt)
    a1[mt] = *reinterpret_cast<const short8v*>(eattr_c + (size_t)(e0+mt*16+m)*32 + g*8);
  // l0: 8 nt tiles, 2 per wave
  for (int nt=wid; nt<8; nt+=4){
    float bias = ldf(b0, nt*16+m);
    short8v b = *reinterpret_cast<const short8v*>(p0 + ((size_t)nt*64 + lane)*8);
    #pragma unroll
    for (int mt=0;mt<2;++mt){
      f32x4 acc = {bias,bias,bias,bias};
      acc = __builtin_amdgcn_mfma_f32_16x16x32_bf16(a1[mt], b, acc, 0,0,0);
      #pragma unroll
      for (int r=0;r<4;++r){
        int n = nt*16 + m, row = g*4 + r;
        h1p[mt][(n>>5)*512 + (((n>>3)&3)*16+row)*8 + (n&7)] = f2bu(siluf(acc[r]));
      }
    }
  }
  __syncthreads();
  short8v a2[2][4];
  #pragma unroll
  for (int mt=0;mt<2;++mt)
    #pragma unroll
    for (int ks=0; ks<4; ++ks)
      a2[mt][ks] = *reinterpret_cast<const short8v*>(&h1p[mt][ks*512 + lane*8]);
  // l1: 16 nt tiles, 4 per wave
  for (int nt=wid; nt<16; nt+=4){
    float bias = ldf(b1, nt*16+m);
    short8v bfr[4];
    #pragma unroll
    for (int ks=0; ks<4; ++ks)
      bfr[ks] = *reinterpret_cast<const short8v*>(p1 + ((size_t)(nt*4+ks)*64 + lane)*8);
    #pragma unroll
    for (int mt=0;mt<2;++mt){
      f32x4 acc = {bias,bias,bias,bias};
      #pragma unroll
      for (int ks=0; ks<4; ++ks)
        acc = __builtin_amdgcn_mfma_f32_16x16x32_bf16(a2[mt][ks], bfr[ks], acc, 0,0,0);
      #pragma unroll
      for (int r=0;r<4;++r){
        int n = nt*16 + m, row = g*4 + r;
        h2p[mt][(n>>5)*512 + (((n>>3)&3)*16+row)*8 + (n&7)] = f2bu(siluf(acc[r]));
      }
    }
  }
  __syncthreads();
  short8v a3[2][8];
  #pragma unroll
  for (int mt=0;mt<2;++mt)
    #pragma unroll
    for (int ks=0; ks<8; ++ks)
      a3[mt][ks] = *reinterpret_cast<const short8v*>(&h2p[mt][ks*512 + lane*8]);
  // l2: 24 nt tiles, 6 per wave
  for (int nt=wid; nt<24; nt+=4){
    float bias = ldf(b2, nt*16+m);
    short8v bfr[8];
    #pragma unroll
    for (int ks=0; ks<8; ++ks)
      bfr[ks] = *reinterpret_cast<const short8v*>(p2 + ((size_t)(nt*8+ks)*64 + lane)*8);
    #pragma unroll
    for (int mt=0;mt<2;++mt){
      f32x4 acc = {bias,bias,bias,bias};
      #pragma unroll
      for (int ks=0; ks<8; ++ks)
        acc = __builtin_amdgcn_mfma_f32_16x16x32_bf16(a3[mt][ks], bfr[ks], acc, 0,0,0);
      #pragma unroll
      for (int r=0;r<4;++r){
        int n = nt*16 + m, row = g*4 + r;
        float v = siluf(acc[r]) * cc[mt][r];
        eabuf[(size_t)spos[mt*16+row]*384 + (n%3)*128 + (n/3)] = f2bu(v);
      }
    }
  }
}
__global__ void __launch_bounds__(256) k_msg_edge_mfma(
  const unsigned short* __restrict__ eattr_c, const float* __restrict__ gC,
  const int* __restrict__ pos,
  const unsigned short* __restrict__ p0, const unsigned short* __restrict__ p1,
  const unsigned short* __restrict__ p2,
  const void* b0, const void* b1, const void* b2, long boff0, long boff1, long boff2,
  unsigned short* __restrict__ eabuf, const int* __restrict__ flag)
{
  __shared__ __align__(16) unsigned short h1p[2][2048];
  __shared__ __align__(16) unsigned short h2p[2][4096];
  __shared__ int spos[32];
  if (flag[0]) mfma_impl<float>(eattr_c, gC, pos, p0, p1, p2,
      (const float*)b0 + boff0, (const float*)b1 + boff1, (const float*)b2 + boff2, eabuf, h1p, h2p, spos);
  else mfma_impl<bf16>(eattr_c, gC, pos, p0, p1, p2,
      (const bf16*)b0 + boff0, (const bf16*)b1 + boff1, (const bf16*)b2 + boff2, eabuf, h1p, h2p, spos);
}

// ---------------- msg norm: normalize X (write back), decompose -> smb bf16 ----------------
__global__ void __launch_bounds__(128) k_msg_norm(
  float* __restrict__ X9, bf16* __restrict__ smb)
{
  int n0 = blockIdx.x*NB, h = threadIdx.x;
  #pragma unroll
  for (int nn=0;nn<NB;++nn){
    int n = n0+nn;
    float* xp = X9 + (size_t)n*1152;
    float x00=xp[0*128+h], x01=xp[1*128+h], x02=xp[2*128+h];
    float x10=xp[3*128+h], x11=xp[4*128+h], x12=xp[5*128+h];
    float x20=xp[6*128+h], x21=xp[7*128+h], x22=xp[8*128+h];
    float tn = x00*x00+x01*x01+x02*x02+x10*x10+x11*x11+x12*x12+x20*x20+x21*x21+x22*x22;
    float inv = 1.0f/(tn+1.0f);
    x00*=inv; x01*=inv; x02*=inv; x10*=inv; x11*=inv; x12*=inv; x20*=inv; x21*=inv; x22*=inv;
    // Reference REBINDS X to normalized before the update (r3 fix).
    xp[0*128+h]=x00; xp[1*128+h]=x01; xp[2*128+h]=x02;
    xp[3*128+h]=x10; xp[4*128+h]=x11; xp[5*128+h]=x12;
    xp[6*128+h]=x20; xp[7*128+h]=x21; xp[8*128+h]=x22;
    float a = (x00+x11+x22)*(1.0f/3.0f);
    bf16* sp = smb + (size_t)n*1280;
    sp[0*128+h]=__float2bfloat16(a);
    sp[1*128+h]=__float2bfloat16(0.5f*(x21-x12));
    sp[2*128+h]=__float2bfloat16(0.5f*(x02-x20));
    sp[3*128+h]=__float2bfloat16(0.5f*(x10-x01));
    sp[4*128+h]=__float2bfloat16(x00-a);
    sp[5*128+h]=__float2bfloat16(0.5f*(x01+x10));
    sp[6*128+h]=__float2bfloat16(0.5f*(x02+x20));
    sp[7*128+h]=__float2bfloat16(x11-a);
    sp[8*128+h]=__float2bfloat16(0.5f*(x12+x21));
    sp[9*128+h]=__float2bfloat16(x22-a);
  }
}

// ---------------- msg scatter + AB + decompose -> smb bf16 ----------------
__global__ void __launch_bounds__(128) k_msg_sab(
  const int* __restrict__ offsets, const int* __restrict__ csrc,
  const bf16* __restrict__ eabuf, const bf16* __restrict__ Y10, bf16* __restrict__ smb)
{
  int n0 = blockIdx.x*NB, h = threadIdx.x;
  #pragma unroll
  for (int nn=0;nn<NB;++nn){
    int n = n0+nn;
    float am=0, vm0=0,vm1=0,vm2=0, smm0=0,smm1=0,smm2=0,smm3=0,smm4=0,smm5=0;
    int beg = offsets[n], end = offsets[n+1];
    int i = beg;
    for (; i+4 <= end; i += 4){
      int ss[4];
      #pragma unroll
      for (int u=0;u<4;++u){ ss[u] = csrc[i+u]; }
      float e0a[4], e1a[4], e2a[4];
      float y0[4],y1[4],y2[4],y3[4],y4[4],y5[4],y6[4],y7[4],y8[4],y9[4];
      #pragma unroll
      for (int u=0;u<4;++u){
        const bf16* ep = eabuf + (size_t)(i+u)*384;
        e0a[u]=b2f(ep[h]); e1a[u]=b2f(ep[128+h]); e2a[u]=b2f(ep[256+h]);
        const bf16* yp = Y10 + (size_t)ss[u]*1280;
        y0[u]=b2f(yp[0*128+h]); y1[u]=b2f(yp[1*128+h]); y2[u]=b2f(yp[2*128+h]);
        y3[u]=b2f(yp[3*128+h]); y4[u]=b2f(yp[4*128+h]); y5[u]=b2f(yp[5*128+h]);
        y6[u]=b2f(yp[6*128+h]); y7[u]=b2f(yp[7*128+h]); y8[u]=b2f(yp[8*128+h]);
        y9[u]=b2f(yp[9*128+h]);
      }
      #pragma unroll
      for (int u=0;u<4;++u){
        am   += e0a[u]*y0[u];
        vm0  += e1a[u]*y1[u]; vm1 += e1a[u]*y2[u]; vm2 += e1a[u]*y3[u];
        smm0 += e2a[u]*y4[u]; smm1 += e2a[u]*y5[u]; smm2 += e2a[u]*y6[u];
        smm3 += e2a[u]*y7[u]; smm4 += e2a[u]*y8[u]; smm5 += e2a[u]*y9[u];
      }
    }
    for (; i<end; ++i){
      int s = csrc[i];
      const bf16* ep = eabuf + (size_t)i*384;
      float e0 = b2f(ep[h]), e1 = b2f(ep[128+h]), e2 = b2f(ep[256+h]);
      const bf16* yp = Y10 + (size_t)s*1280;
      am   += e0*b2f(yp[0*128+h]);
      vm0  += e1*b2f(yp[1*128+h]); vm1 += e1*b2f(yp[2*128+h]); vm2 += e1*b2f(yp[3*128+h]);
      smm0 += e2*b2f(yp[4*128+h]); smm1 += e2*b2f(yp[5*128+h]); smm2 += e2*b2f(yp[6*128+h]);
      smm3 += e2*b2f(yp[7*128+h]); smm4 += e2*b2f(yp[8*128+h]); smm5 += e2*b2f(yp[9*128+h]);
    }
    const bf16* yp = Y10 + (size_t)n*1280;
    float aY=b2f(yp[0*128+h]), u0=b2f(yp[1*128+h]), u1=b2f(yp[2*128+h]), u2=b2f(yp[3*128+h]);
    float q0=b2f(yp[4*128+h]), q1=b2f(yp[5*128+h]), q2=b2f(yp[6*128+h]);
    float q3=b2f(yp[7*128+h]), q4=b2f(yp[8*128+h]), q5=b2f(yp[9*128+h]);
    float m00=am+smm0,   m01=-vm2+smm1, m02= vm1+smm2;
    float m10= vm2+smm1, m11=am+smm3,  m12=-vm0+smm4;
    float m20=-vm1+smm2, m21= vm0+smm4, m22=am+smm5;
    float y00=aY+q0,  y01=-u2+q1, y02= u1+q2;
    float y10= u2+q1, y11=aY+q3,  y12=-u0+q4;
    float y20=-u1+q2, y21= u0+q4, y22=aY+q5;
    float ab00 = m00*y00+m01*y10+m02*y20 + y00*m00+y01*m10+y02*m20;
    float ab01 = m00*y01+m01*y11+m02*y21 + y00*m01+y01*m11+y02*m21;
    float ab02 = m00*y02+m01*y12+m02*y22 + y00*m02+y01*m12+y02*m22;
    float ab10 = m10*y00+m11*y10+m12*y20 + y10*m00+y11*m10+y12*m20;
    float ab11 = m10*y01+m11*y11+m12*y21 + y10*m01+y11*m11+y12*m21;
    float ab12 = m10*y02+m11*y12+m12*y22 + y10*m02+y11*m12+y12*m22;
    float ab20 = m20*y00+m21*y10+m22*y20 + y20*m00+y21*m10+y22*m20;
    float ab21 = m20*y01+m21*y11+m22*y21 + y20*m01+y21*m11+y22*m21;
    float ab22 = m20*y02+m21*y12+m22*y22 + y20*m02+y21*m12+y22*m22;
    float a2 = (ab00+ab11+ab22)*(1.0f/3.0f);
    float w0 = 0.5f*(ab21-ab12), w1 = 0.5f*(ab02-ab20), w2 = 0.5f*(ab10-ab01);
    float t0 = ab00-a2, t1 = 0.5f*(ab01+ab10), t2 = 0.5f*(ab02+ab20);
    float t3 = ab11-a2, t4 = 0.5f*(ab12+ab21), t5 = ab22-a2;
    float dnm = ab00*ab00+ab01*ab01+ab02*ab02+ab10*ab10+ab11*ab11+ab12*ab12
              + ab20*ab20+ab21*ab21+ab22*ab22 + 1.0f;
    float inv = 1.0f/dnm;
    bf16* sp = smb + (size_t)n*1280;
    sp[0*128+h]=__float2bfloat16(a2*inv);
    sp[1*128+h]=__float2bfloat16(w0*inv); sp[2*128+h]=__float2bfloat16(w1*inv); sp[3*128+h]=__float2bfloat16(w2*inv);
    sp[4*128+h]=__float2bfloat16(t0*inv); sp[5*128+h]=__float2bfloat16(t1*inv); sp[6*128+h]=__float2bfloat16(t2*inv);
    sp[7*128+h]=__float2bfloat16(t3*inv); sp[8*128+h]=__float2bfloat16(t4*inv); sp[9*128+h]=__float2bfloat16(t5*inv);
  }
}

// ---------------- msg finish: dt (smb) -> dX + dX^2, X update, optional out ----------------
template<typename T>
__device__ __forceinline__ void fin_impl(
  const bf16* smb, float* X9, T* out, int write_out)
{
  int n0 = blockIdx.x*NB, h = threadIdx.x;
  #pragma unroll
  for (int nn=0;nn<NB;++nn){
    int n = n0+nn;
    const bf16* sp = smb + (size_t)n*1280;
    float at  = b2f(sp[0*128+h]);
    float vt0 = b2f(sp[1*128+h]), vt1 = b2f(sp[2*128+h]), vt2 = b2f(sp[3*128+h]);
    float st0 = b2f(sp[4*128+h]), st1 = b2f(sp[5*128+h]), st2 = b2f(sp[6*128+h]);
    float st3 = b2f(sp[7*128+h]), st4 = b2f(sp[8*128+h]), st5 = b2f(sp[9*128+h]);
    float d00=at+st0,   d01=-vt2+st1, d02= vt1+st2;
    float d10= vt2+st1, d11=at+st3,  d12=-vt0+st4;
    float d20=-vt1+st2, d21= vt0+st4, d22=at+st5;
    float g00 = d00 + d00*d00+d01*d10+d02*d20;
    float g01 = d01 + d00*d01+d01*d11+d02*d21;
    float g02 = d02 + d00*d02+d01*d12+d02*d22;
    float g10 = d10 + d10*d00+d11*d10+d12*d20;
    float g11 = d11 + d10*d01+d11*d11+d12*d21;
    float g12 = d12 + d10*d02+d11*d12+d12*d22;
    float g20 = d20 + d20*d00+d21*d10+d22*d20;
    float g21 = d21 + d20*d01+d21*d11+d22*d21;
    float g22 = d22 + d20*d02+d21*d12+d22*d22;
    float* xp = X9 + (size_t)n*1152;
    float x00=xp[0*128+h]+g00, x01=xp[1*128+h]+g01, x02=xp[2*128+h]+g02;
    float x10=xp[3*128+h]+g10, x11=xp[4*128+h]+g11, x12=xp[5*128+h]+g12;
    float x20=xp[6*128+h]+g20, x21=xp[7*128+h]+g21, x22=xp[8*128+h]+g22;
    if (write_out){
      if (sizeof(T)==4){
        float* of = (float*)out + ((size_t)n*128 + h)*9;
        of[0]=x00; of[1]=x01; of[2]=x02; of[3]=x10; of[4]=x11; of[5]=x12; of[6]=x20; of[7]=x21; of[8]=x22;
      } else {
        bf16* ob = (bf16*)out + ((size_t)n*128 + h)*9;
        ob[0]=__float2bfloat16(x00); ob[1]=__float2bfloat16(x01); ob[2]=__float2bfloat16(x02);
        ob[3]=__float2bfloat16(x10); ob[4]=__float2bfloat16(x11); ob[5]=__float2bfloat16(x12);
        ob[6]=__float2bfloat16(x20); ob[7]=__float2bfloat16(x21); ob[8]=__float2bfloat16(x22);
      }
    } else {
      xp[0*128+h]=x00; xp[1*128+h]=x01; xp[2*128+h]=x02;
      xp[3*128+h]=x10; xp[4*128+h]=x11; xp[5*128+h]=x12;
      xp[6*128+h]=x20; xp[7*128+h]=x21; xp[8*128+h]=x22;
    }
  }
}
__global__ void __launch_bounds__(128) k_msg_fin(
  const bf16* __restrict__ smb, float* __restrict__ X9, void* __restrict__ out,
  const int* __restrict__ flag, int write_out)
{
  if (flag[0]) fin_impl<float>(smb, X9, (float*)out, write_out);
  else         fin_impl<bf16 >(smb, X9, (bf16* )out, write_out);
}

extern "C" void kernel_launch(void* const* d_in, const int* in_sizes, int n_in,
                              void* d_out, int out_size, void* d_ws, size_t ws_size,
                              hipStream_t stream)
{
  (void)in_sizes; (void)n_in; (void)out_size; (void)ws_size;
  const int* z    = (const int*)d_in[0];
  const int* eidx = (const int*)d_in[1];
  const int* src  = eidx;
  const int* dst  = eidx + NE;

  // Workspace ~73.5 MB (r1-proven budget 74.2 MB).
  char* w = (char*)d_ws;
  int* flag    = (int*)w;   w += 64;
  int* counts  = (int*)w;   w += (size_t)NN*4;
  int* offsets = (int*)w;   w += (size_t)(NN+1)*4 + 60;
  int* cursor  = (int*)w;   w += (size_t)NN*4;
  int* pos     = (int*)w;   w += (size_t)NE*4;
  int* csrc    = (int*)w;   w += (size_t)NE*4;
  float* gC    = (float*)w; w += (size_t)NE*4;
  float* gVp   = (float*)w; w += (size_t)NE*12;
  float* P1z   = (float*)w; w += (size_t)MAXZ*HH*4;
  float* P2z   = (float*)w; w += (size_t)MAXZ*HH*4;
  bf16* eabuf  = (bf16*)w;  w += (size_t)NE*384*2;
  float* X9    = (float*)w; w += (size_t)NN*1152*4;
  bf16* Y10    = (bf16*)w;  w += (size_t)NN*1280*2;
  bf16* smb    = (bf16*)w;  w += (size_t)NN*1280*2;
  unsigned short* eattr_c = (unsigned short*)w; w += (size_t)NE*32*2;
  unsigned short* pw0[2]; unsigned short* pw1[2]; unsigned short* pw2[2];
  for (int l=0;l<2;++l){
    pw0[l] = (unsigned short*)w; w += 8*64*8*2;
    pw1[l] = (unsigned short*)w; w += 64*64*8*2;
    pw2[l] = (unsigned short*)w; w += 192*64*8*2;
  }
  unsigned short* pw_s0 = (unsigned short*)w; w += 64*64*8*2;
  unsigned short* pw_s1 = (unsigned short*)w; w += 192*64*8*2;
  unsigned short* pwlt  = (unsigned short*)w; w += 3*32*64*8*2;
  unsigned short* pwlx2 = (unsigned short*)w; w += 2*3*32*64*8*2;
  unsigned short* pwlt2 = (unsigned short*)w; w += 2*3*32*64*8*2;
  bf16* lnO    = (bf16*)w;  w += (size_t)NN*128*2;
  bf16* fsc3   = (bf16*)w;  w += (size_t)NN*384*2;
  bf16* sm10   = Y10;   // tne alias: dead until msg norm/cmix overwrites Y10

  k_detect<<<1, 256, 0, stream>>>((const unsigned int*)d_in[4], flag);
  hipMemsetAsync(counts, 0, (size_t)NN*4, stream);
  k_count<<<NE/256, 256, 0, stream>>>(dst, counts);
  k_scan<<<1, 1024, 0, stream>>>(counts, offsets, cursor);
  k_fill<<<NE/256, 256, 0, stream>>>(dst, src, cursor, pos, csrc);
  k_geom<<<NE/256, 256, 0, stream>>>(d_in[2], d_in[3], src, dst, pos, gC, gVp, flag);
  k_zemb<<<MAXZ, 128, 0, stream>>>(d_in[5], d_in[12], P1z, P2z, flag);
  k_cvt_attr<<<NE*32/256, 256, 0, stream>>>(d_in[4], eattr_c, flag);

  PackDescs pd;
  for (int l=0;l<2;++l){
    pd.base[l*3+0] = d_in[21]; pd.eoff[l*3+0] = (long)l*32*128;
    pd.base[l*3+1] = d_in[23]; pd.eoff[l*3+1] = (long)l*128*256;
    pd.base[l*3+2] = d_in[25]; pd.eoff[l*3+2] = (long)l*256*384;
    pd.out[l*3+0] = pw0[l]; pd.K[l*3+0]=32;  pd.N[l*3+0]=128;
    pd.out[l*3+1] = pw1[l]; pd.K[l*3+1]=128; pd.N[l*3+1]=256;
    pd.out[l*3+2] = pw2[l]; pd.K[l*3+2]=256; pd.N[l*3+2]=384;
  }
  pd.base[6] = d_in[15]; pd.eoff[6] = 0; pd.out[6] = pw_s0; pd.K[6]=128; pd.N[6]=256;
  pd.base[7] = d_in[17]; pd.eoff[7] = 0; pd.out[7] = pw_s1; pd.K[7]=256; pd.N[7]=384;
  for (int c=0;c<3;++c){
    pd.base[8+c] = d_in[14]; pd.eoff[8+c] = (long)c*16384;
    pd.out[8+c] = pwlt + (size_t)c*16384; pd.K[8+c]=128; pd.N[8+c]=128;
  }
  for (int l=0;l<2;++l)
    for (int c=0;c<3;++c){
      pd.base[11+l*3+c] = d_in[27]; pd.eoff[11+l*3+c] = (long)(l*3+c)*16384;
      pd.out[11+l*3+c] = pwlx2 + (size_t)(l*3+c)*16384; pd.K[11+l*3+c]=128; pd.N[11+l*3+c]=128;
      pd.base[17+l*3+c] = d_in[28]; pd.eoff[17+l*3+c] = (long)(l*3+c)*16384;
      pd.out[17+l*3+c] = pwlt2 + (size_t)(l*3+c)*16384; pd.K[17+l*3+c]=128; pd.N[17+l*3+c]=128;
    }
  k_pack<<<dim3(48, 23), 256, 0, stream>>>(pd, flag);

  k_tne_edge<<<NE/TPB, 128, 0, stream>>>(d_in[4], src, dst, z, pos,
      d_in[6], d_in[7], d_in[8], d_in[9], d_in[10], d_in[11], d_in[13],
      P1z, P2z, gC, eabuf, flag);
  k_tne_scat<<<NN/NB, 128, 0, stream>>>(offsets, gVp, eabuf,
      d_in[19], d_in[20], sm10, lnO, flag);
  k_node_mlp<<<NN/16, 256, 0, stream>>>(lnO, pw_s0, pw_s1, d_in[16], d_in[18], fsc3, flag);
  k_tne_cmix<<<NN/16, 256, 0, stream>>>(sm10, pwlt, fsc3, X9);

  for (int l=0; l<2; ++l){
    k_msg_edge_mfma<<<NE/32, 256, 0, stream>>>(eattr_c, gC, pos, pw0[l], pw1[l], pw2[l],
        d_in[22], d_in[24], d_in[26], (long)l*128, (long)l*256, (long)l*384,
        (unsigned short*)eabuf, flag);
    k_msg_norm<<<NN/NB, 128, 0, stream>>>(X9, smb);
    k_cmix10<<<NN/16, 256, 0, stream>>>(smb, pwlx2 + (size_t)l*3*16384, Y10);
    k_msg_sab<<<NN/NB, 128, 0, stream>>>(offsets, csrc, eabuf, Y10, smb);
    k_cmix10<<<NN/16, 256, 0, stream>>>(smb, pwlt2 + (size_t)l*3*16384, smb);
    k_msg_fin<<<NN/NB, 128, 0, stream>>>(smb, X9, d_out, flag, (l==1)?1:0);
  }
}

// Round 20
// 261.543 us; speedup vs baseline: 1.8158x; 1.0701x over previous
//
#include <hip/hip_runtime.h>
#include <hip/hip_bf16.h>

typedef __hip_bfloat16 bf16;
typedef __attribute__((ext_vector_type(8))) short short8v;
typedef __attribute__((ext_vector_type(4))) float f32x4;

#define NN 4096
#define NE 32768
#define HH 128
#define MAXZ 100
#define TPB 8
#define NB 2

// ENVIRONMENT FACTS (r0-r19): float tensors are FLOAT32; runtime detector kept.
// MFMA edge path validated r10/r16/r19; MFMA cmix validated r17/r18 (absmax
// 0.002929688). ws_size ~256MB (fillBuffer evidence r19). r20: fuse msg_norm
// into cmix(lx) (LDS-staged A) and msg_fin into cmix(lt) epilogue (with bf16
// re-rounding of accs to preserve exact values). absmax must stay 0.002929688.

__device__ __forceinline__ float b2f(bf16 v){ return __bfloat162float(v); }
__device__ __forceinline__ float ldf(const float* p, size_t i){ return p[i]; }
__device__ __forceinline__ float ldf(const bf16*  p, size_t i){ return __bfloat162float(p[i]); }
__device__ __forceinline__ float siluf(float x){ return x / (1.0f + __expf(-x)); }
__device__ __forceinline__ unsigned short f2bu(float x){
  bf16 h = __float2bfloat16(x);
  return *reinterpret_cast<unsigned short*>(&h);
}
__device__ __forceinline__ float bround(float x){   // round through bf16 (matches old smb round-trip)
  bf16 h = __float2bfloat16(x);
  return __bfloat162float(h);
}

__global__ void __launch_bounds__(256) k_detect(const unsigned int* __restrict__ w, int* __restrict__ flag){
  __shared__ int cnt[256];
  int t = threadIdx.x;
  int c = 0;
  for (int i = t; i < 4096; i += 256){
    unsigned int lo = w[i] & 0xffffu;
    int e = (int)((lo >> 7) & 0xffu);
    c += (e >= 110 && e <= 132) ? 1 : 0;
  }
  cnt[t] = c; __syncthreads();
  for (int off=128; off>=1; off>>=1){ if (t<off) cnt[t]+=cnt[t+off]; __syncthreads(); }
  if (t==0) flag[0] = (cnt[0] < 2048) ? 1 : 0;
}

// ---------------- CSR build ----------------
__global__ void __launch_bounds__(256) k_count(const int* __restrict__ dst, int* __restrict__ counts){
  int e = blockIdx.x*256 + threadIdx.x;
  if (e < NE) atomicAdd(&counts[dst[e]], 1);
}

__global__ void __launch_bounds__(1024) k_scan(const int* __restrict__ counts, int* __restrict__ offsets, int* __restrict__ cursor){
  __shared__ int lds[1024];
  int t = threadIdx.x;
  int c0 = counts[4*t+0], c1 = counts[4*t+1], c2 = counts[4*t+2], c3 = counts[4*t+3];
  int s1 = c0+c1, s2 = s1+c2, s3 = s2+c3;
  lds[t] = s3;
  __syncthreads();
  for (int off=1; off<1024; off<<=1){
    int v = lds[t];
    int add = (t>=off)? lds[t-off] : 0;
    __syncthreads();
    lds[t] = v + add;
    __syncthreads();
  }
  int incl = lds[t];
  int base = incl - s3;
  offsets[4*t+0]=base;    offsets[4*t+1]=base+c0; offsets[4*t+2]=base+s1; offsets[4*t+3]=base+s2;
  cursor [4*t+0]=base;    cursor [4*t+1]=base+c0; cursor [4*t+2]=base+s1; cursor [4*t+3]=base+s2;
  if (t==1023) offsets[4096]=incl;
}

__global__ void __launch_bounds__(256) k_fill(const int* __restrict__ dst, const int* __restrict__ src,
                                              int* __restrict__ cursor,
                                              int* __restrict__ pos, int* __restrict__ csrc){
  int e = blockIdx.x*256 + threadIdx.x;
  if (e < NE){
    int p = atomicAdd(&cursor[dst[e]], 1);
    pos[e] = p;
    csrc[p] = src[e];
  }
}

// ---------------- edge geometry ----------------
template<typename T>
__device__ __forceinline__ void geom_impl(const T* ew, const T* evec,
    const int* src, const int* dst, const int* pos, float* gC, float* gVp){
  int e = blockIdx.x*256 + threadIdx.x;
  if (e >= NE) return;
  float d = ldf(ew, e);
  float c = 0.5f*(cosf(d*0.6283185307179586f)+1.0f);
  c = (d < 5.0f) ? c : 0.0f;
  gC[e] = c;
  float x = ldf(evec, (size_t)e*3+0), y = ldf(evec, (size_t)e*3+1), z = ldf(evec, (size_t)e*3+2);
  if (src[e] != dst[e]){
    float n = sqrtf(x*x+y*y+z*z);
    float inv = 1.0f/fmaxf(n, 1e-12f);
    x*=inv; y*=inv; z*=inv;
  }
  int p = pos[e];
  gVp[p*3+0]=x; gVp[p*3+1]=y; gVp[p*3+2]=z;
}
__global__ void __launch_bounds__(256) k_geom(const void* ew, const void* evec,
    const int* __restrict__ src, const int* __restrict__ dst, const int* __restrict__ pos,
    float* __restrict__ gC, float* __restrict__ gVp, const int* __restrict__ flag){
  if (flag[0]) geom_impl<float>((const float*)ew, (const float*)evec, src, dst, pos, gC, gVp);
  else         geom_impl<bf16 >((const bf16* )ew, (const bf16* )evec, src, dst, pos, gC, gVp);
}

// ---------------- per-z embedding products ----------------
template<typename T>
__device__ __forceinline__ void zemb_impl(const T* emb, const T* emb2_w,
    float* P1z, float* P2z, float* Zr){
  int zv = blockIdx.x, h = threadIdx.x;
  Zr[h] = ldf(emb, (size_t)zv*HH + h);
  __syncthreads();
  float p1=0.f, p2=0.f;
  for (int r=0;r<128;++r){
    float x = Zr[r];
    p1 += x*ldf(emb2_w, (size_t)r*HH+h);
    p2 += x*ldf(emb2_w, (size_t)(r+128)*HH+h);
  }
  P1z[zv*HH+h]=p1; P2z[zv*HH+h]=p2;
}
__global__ void __launch_bounds__(128) k_zemb(const void* emb, const void* emb2_w,
    float* __restrict__ P1z, float* __restrict__ P2z, const int* __restrict__ flag){
  __shared__ float Zr[128];
  if (flag[0]) zemb_impl<float>((const float*)emb, (const float*)emb2_w, P1z, P2z, Zr);
  else         zemb_impl<bf16 >((const bf16* )emb, (const bf16* )emb2_w, P1z, P2z, Zr);
}

// ---------------- convert edge_attr -> bf16 ----------------
__global__ void __launch_bounds__(256) k_cvt_attr(const void* in, unsigned short* __restrict__ out,
                                                  const int* __restrict__ flag){
  int i = blockIdx.x*256 + threadIdx.x;
  if (flag[0]) out[i] = f2bu(((const float*)in)[i]);
  else         out[i] = ((const unsigned short*)in)[i];
}

// ---------------- weight repack into MFMA B-fragment layout (23 matrices) ----------------
struct PackDescs {
  const void*     base[23];
  long            eoff[23];
  unsigned short* out[23];
  int K[23]; int N[23];
};
template<typename T>
__device__ __forceinline__ void pack_impl(const PackDescs& d){
  int y = blockIdx.y;
  int K = d.K[y], N = d.N[y];
  int ktiles = K>>5, ntiles = N>>4;
  int total = ktiles*ntiles*64;
  int idx = blockIdx.x*256 + threadIdx.x;
  if (idx >= total) return;
  int lane = idx & 63, tile = idx >> 6;
  int kt = tile % ktiles, nt = tile / ktiles;
  const T* W = (const T*)d.base[y] + d.eoff[y];
  int n = nt*16 + (lane&15), k0 = kt*32 + (lane>>4)*8;
  unsigned int t[8];
  #pragma unroll
  for (int j=0;j<8;++j) t[j] = f2bu(ldf(W, (size_t)(k0+j)*N + n));
  uint4 v;
  v.x = t[0] | (t[1]<<16);
  v.y = t[2] | (t[3]<<16);
  v.z = t[4] | (t[5]<<16);
  v.w = t[6] | (t[7]<<16);
  *reinterpret_cast<uint4*>(d.out[y] + ((size_t)tile*64 + lane)*8) = v;
}
__global__ void __launch_bounds__(256) k_pack(PackDescs d, const int* __restrict__ flag){
  if (flag[0]) pack_impl<float>(d);
  else         pack_impl<bf16 >(d);
}

// ---------------- TNE edge coefficients -> eabuf bf16 (CSR-ordered rows) ----------------
template<typename T>
__device__ __forceinline__ void tne_edge_impl(
  const T* eattr, const int* src, const int* dst, const int* z, const int* pos,
  const T* dp1_w, const T* dp1_b, const T* dp2_w, const T* dp2_b,
  const T* dp3_w, const T* dp3_b, const T* emb2_b,
  const float* P1z, const float* P2z, const float* gC, bf16* eabuf,
  float (*attr)[32], int* zd, int* zs, int* ppos)
{
  int e0 = blockIdx.x*TPB;
  int h  = threadIdx.x;
  for (int i=h; i<TPB*32; i+=128) attr[i>>5][i&31] = ldf(eattr, (size_t)e0*32 + i);
  if (h < TPB){ int e=e0+h; zd[h]=z[dst[e]]; zs[h]=z[src[e]]; ppos[h]=pos[e]; }
  __syncthreads();
  float w1[TPB], w2[TPB], w3[TPB];
  float b1v=ldf(dp1_b,h), b2v=ldf(dp2_b,h), b3v=ldf(dp3_b,h);
  #pragma unroll
  for (int e=0;e<TPB;++e){ w1[e]=b1v; w2[e]=b2v; w3[e]=b3v; }
  for (int r=0;r<32;++r){
    float u1=ldf(dp1_w,(size_t)r*HH+h), u2=ldf(dp2_w,(size_t)r*HH+h), u3=ldf(dp3_w,(size_t)r*HH+h);
    #pragma unroll
    for (int e=0;e<TPB;++e){ float a=attr[e][r]; w1[e]+=a*u1; w2[e]+=a*u2; w3[e]+=a*u3; }
  }
  float eb = ldf(emb2_b,h);
  #pragma unroll
  for (int e=0;e<TPB;++e){
    float zij = P1z[zd[e]*HH+h] + P2z[zs[e]*HH+h] + eb;
    float c = gC[e0+e];
    bf16* p = eabuf + (size_t)ppos[e]*384;
    p[h]     = __float2bfloat16(zij*w1[e]*c);
    p[128+h] = __float2bfloat16(zij*w2[e]*c);
    p[256+h] = __float2bfloat16(zij*w3[e]*c);
  }
}
__global__ void __launch_bounds__(128) k_tne_edge(
  const void* eattr, const int* __restrict__ src, const int* __restrict__ dst,
  const int* __restrict__ z, const int* __restrict__ pos,
  const void* dp1_w, const void* dp1_b, const void* dp2_w, const void* dp2_b,
  const void* dp3_w, const void* dp3_b, const void* emb2_b,
  const float* __restrict__ P1z, const float* __restrict__ P2z,
  const float* __restrict__ gC, bf16* __restrict__ eabuf, const int* __restrict__ flag)
{
  __shared__ float attr[TPB][32];
  __shared__ int zd[TPB], zs[TPB], ppos[TPB];
  if (flag[0]) tne_edge_impl<float>((const float*)eattr, src, dst, z, pos,
      (const float*)dp1_w, (const float*)dp1_b, (const float*)dp2_w, (const float*)dp2_b,
      (const float*)dp3_w, (const float*)dp3_b, (const float*)emb2_b, P1z, P2z, gC, eabuf, attr, zd, zs, ppos);
  else tne_edge_impl<bf16>((const bf16*)eattr, src, dst, z, pos,
      (const bf16*)dp1_w, (const bf16*)dp1_b, (const bf16*)dp2_w, (const bf16*)dp2_b,
      (const bf16*)dp3_w, (const bf16*)dp3_b, (const bf16*)emb2_b, P1z, P2z, gC, eabuf, attr, zd, zs, ppos);
}

// ---------------- TNE scatter + LN: writes sm10 bf16 and ln bf16 ----------------
template<typename T>
__device__ __forceinline__ void tne_scat_impl(
  const int* offsets, const float* gVp, const bf16* eabuf,
  const T* ln_g, const T* ln_b, bf16* sm10, bf16* lnO, float* red)
{
  int n0 = blockIdx.x*NB, h = threadIdx.x;
  float tnv[NB];
  #pragma unroll
  for (int nn=0;nn<NB;++nn){
    int n = n0+nn;
    float a=0, v0=0,v1=0,v2=0, s0=0,s1=0,s2=0,s3=0,s4=0,s5=0;
    int beg = offsets[n], end = offsets[n+1];
    int i = beg;
    for (; i+4 <= end; i += 4){
      float c1[4],c2[4],c3[4],vx[4],vy[4],vz[4];
      #pragma unroll
      for (int u=0;u<4;++u){
        const bf16* p = eabuf + (size_t)(i+u)*384;
        c1[u]=b2f(p[h]); c2[u]=b2f(p[128+h]); c3[u]=b2f(p[256+h]);
        vx[u]=gVp[(i+u)*3+0]; vy[u]=gVp[(i+u)*3+1]; vz[u]=gVp[(i+u)*3+2];
      }
      #pragma unroll
      for (int u=0;u<4;++u){
        float tr3 = (vx[u]*vx[u]+vy[u]*vy[u]+vz[u]*vz[u])*(1.0f/3.0f);
        a  += c1[u];
        v0 += c2[u]*vx[u]; v1 += c2[u]*vy[u]; v2 += c2[u]*vz[u];
        s0 += c3[u]*(vx[u]*vx[u] - tr3); s1 += c3[u]*vx[u]*vy[u]; s2 += c3[u]*vx[u]*vz[u];
        s3 += c3[u]*(vy[u]*vy[u] - tr3); s4 += c3[u]*vy[u]*vz[u]; s5 += c3[u]*(vz[u]*vz[u] - tr3);
      }
    }
    for (; i<end; ++i){
      const bf16* p = eabuf + (size_t)i*384;
      float c1 = b2f(p[h]), c2 = b2f(p[128+h]), c3 = b2f(p[256+h]);
      float vx = gVp[i*3+0], vy = gVp[i*3+1], vz = gVp[i*3+2];
      float tr3 = (vx*vx+vy*vy+vz*vz)*(1.0f/3.0f);
      a  += c1;
      v0 += c2*vx; v1 += c2*vy; v2 += c2*vz;
      s0 += c3*(vx*vx - tr3); s1 += c3*vx*vy;          s2 += c3*vx*vz;
      s3 += c3*(vy*vy - tr3); s4 += c3*vy*vz;          s5 += c3*(vz*vz - tr3);
    }
    bf16* sp = sm10 + (size_t)n*1280;
    sp[0*128+h]=__float2bfloat16(a);
    sp[1*128+h]=__float2bfloat16(v0); sp[2*128+h]=__float2bfloat16(v1); sp[3*128+h]=__float2bfloat16(v2);
    sp[4*128+h]=__float2bfloat16(s0); sp[5*128+h]=__float2bfloat16(s1); sp[6*128+h]=__float2bfloat16(s2);
    sp[7*128+h]=__float2bfloat16(s3); sp[8*128+h]=__float2bfloat16(s4); sp[9*128+h]=__float2bfloat16(s5);
    tnv[nn] = 3.0f*a*a + 2.0f*(v0*v0+v1*v1+v2*v2)
            + s0*s0 + s3*s3 + s5*s5 + 2.0f*(s1*s1 + s2*s2 + s4*s4);
  }
  float gg = ldf(ln_g,h), bb = ldf(ln_b,h);
  #pragma unroll
  for (int nn=0;nn<NB;++nn){
    __syncthreads();
    red[h] = tnv[nn]; __syncthreads();
    for (int off=64; off>=1; off>>=1){ if (h<off) red[h]+=red[h+off]; __syncthreads(); }
    float mean = red[0]*(1.0f/128.0f);
    __syncthreads();
    float dm = tnv[nn] - mean;
    red[h] = dm*dm; __syncthreads();
    for (int off=64; off>=1; off>>=1){ if (h<off) red[h]+=red[h+off]; __syncthreads(); }
    float var = red[0]*(1.0f/128.0f);
    lnO[(size_t)(n0+nn)*128 + h] = __float2bfloat16(dm*rsqrtf(var+1e-5f)*gg + bb);
  }
}
__global__ void __launch_bounds__(128) k_tne_scat(
  const int* __restrict__ offsets, const float* __restrict__ gVp, const bf16* __restrict__ eabuf,
  const void* ln_g, const void* ln_b, bf16* __restrict__ sm10, bf16* __restrict__ lnO,
  const int* __restrict__ flag)
{
  __shared__ float red[128];
  if (flag[0]) tne_scat_impl<float>(offsets, gVp, eabuf, (const float*)ln_g, (const float*)ln_b, sm10, lnO, red);
  else         tne_scat_impl<bf16 >(offsets, gVp, eabuf, (const bf16* )ln_g, (const bf16* )ln_b, sm10, lnO, red);
}

// ---------------- node fsc MLP via MFMA (r17-validated) ----------------
template<typename T>
__device__ __forceinline__ void node_mlp_impl(
  const bf16* lnO, const unsigned short* ps0, const unsigned short* ps1,
  const T* b0, const T* b1, bf16* fsc3, unsigned short* h2p)
{
  int wid  = threadIdx.x >> 6;
  int lane = threadIdx.x & 63;
  int n0 = blockIdx.x*16;
  int m = lane & 15, g = lane >> 4;
  short8v aln[4];
  #pragma unroll
  for (int ks=0; ks<4; ++ks)
    aln[ks] = *reinterpret_cast<const short8v*>((const unsigned short*)lnO + (size_t)(n0+m)*128 + ks*32 + g*8);
  for (int nt=wid; nt<16; nt+=4){
    float bias = ldf(b0, nt*16+m);
    f32x4 acc = {bias,bias,bias,bias};
    #pragma unroll
    for (int ks=0; ks<4; ++ks){
      short8v b = *reinterpret_cast<const short8v*>(ps0 + ((size_t)(nt*4+ks)*64 + lane)*8);
      acc = __builtin_amdgcn_mfma_f32_16x16x32_bf16(aln[ks], b, acc, 0,0,0);
    }
    #pragma unroll
    for (int r=0;r<4;++r){
      int n = nt*16 + m, row = g*4 + r;
      h2p[(n>>5)*512 + (((n>>3)&3)*16+row)*8 + (n&7)] = f2bu(siluf(acc[r]));
    }
  }
  __syncthreads();
  short8v a3[8];
  #pragma unroll
  for (int ks=0; ks<8; ++ks) a3[ks] = *reinterpret_cast<const short8v*>(&h2p[ks*512 + lane*8]);
  for (int nt=wid; nt<24; nt+=4){
    float bias = ldf(b1, nt*16+m);
    f32x4 acc = {bias,bias,bias,bias};
    #pragma unroll
    for (int ks=0; ks<8; ++ks){
      short8v b = *reinterpret_cast<const short8v*>(ps1 + ((size_t)(nt*8+ks)*64 + lane)*8);
      acc = __builtin_amdgcn_mfma_f32_16x16x32_bf16(a3[ks], b, acc, 0,0,0);
    }
    #pragma unroll
    for (int r=0;r<4;++r){
      int n = nt*16 + m, row = g*4 + r;
      ((unsigned short*)fsc3)[(size_t)(n0+row)*384 + (n%3)*128 + (n/3)] = f2bu(siluf(acc[r]));
    }
  }
}
__global__ void __launch_bounds__(256) k_node_mlp(
  const bf16* __restrict__ lnO, const unsigned short* __restrict__ ps0,
  const unsigned short* __restrict__ ps1,
  const void* b0, const void* b1, bf16* __restrict__ fsc3, const int* __restrict__ flag)
{
  __shared__ __align__(16) unsigned short h2p[4096];
  if (flag[0]) node_mlp_impl<float>(lnO, ps0, ps1, (const float*)b0, (const float*)b1, fsc3, h2p);
  else         node_mlp_impl<bf16 >(lnO, ps0, ps1, (const bf16* )b0, (const bf16* )b1, fsc3, h2p);
}

// ---------------- tne cmix via MFMA + fsc combine -> X9 (r17-validated) ----------------
__global__ void __launch_bounds__(256) k_tne_cmix(
  const bf16* __restrict__ sm10, const unsigned short* __restrict__ pwlt,
  const bf16* __restrict__ fsc3, float* __restrict__ X9)
{
  int wid  = threadIdx.x >> 6;
  int lane = threadIdx.x & 63;
  int n0 = blockIdx.x*16;
  int m = lane & 15, g = lane >> 4;
  f32x4 acc[10][2];
  #pragma unroll
  for (int c=0;c<10;++c){ acc[c][0]=(f32x4){0,0,0,0}; acc[c][1]=(f32x4){0,0,0,0}; }
  #pragma unroll
  for (int c=0;c<10;++c){
    int mat = (c==0) ? 0 : (c<4) ? 1 : 2;
    const unsigned short* bw = pwlt + (size_t)mat*16384;
    short8v af[4];
    #pragma unroll
    for (int ks=0; ks<4; ++ks)
      af[ks] = *reinterpret_cast<const short8v*>((const unsigned short*)sm10 + (size_t)(n0+m)*1280 + c*128 + ks*32 + g*8);
    #pragma unroll
    for (int t=0;t<2;++t){
      int nt = wid + t*4;
      #pragma unroll
      for (int ks=0; ks<4; ++ks){
        short8v b = *reinterpret_cast<const short8v*>(bw + ((size_t)(nt*4+ks)*64 + lane)*8);
        acc[c][t] = __builtin_amdgcn_mfma_f32_16x16x32_bf16(af[ks], b, acc[c][t], 0,0,0);
      }
    }
  }
  #pragma unroll
  for (int t=0;t<2;++t){
    int nt = wid + t*4;
    int h = nt*16 + m;
    #pragma unroll
    for (int r=0;r<4;++r){
      int node = n0 + g*4 + r;
      float am  = acc[0][t][r];
      float wm0 = acc[1][t][r], wm1 = acc[2][t][r], wm2 = acc[3][t][r];
      float t0 = acc[4][t][r], t1 = acc[5][t][r], t2 = acc[6][t][r];
      float t3 = acc[7][t][r], t4 = acc[8][t][r], t5 = acc[9][t][r];
      float f0 = b2f(fsc3[(size_t)node*384 + h]);
      float f1 = b2f(fsc3[(size_t)node*384 + 128 + h]);
      float f2 = b2f(fsc3[(size_t)node*384 + 256 + h]);
      float* xp = X9 + (size_t)node*1152;
      xp[0*128+h] = f0*am + f2*t0;
      xp[1*128+h] = -f1*wm2 + f2*t1;
      xp[2*128+h] =  f1*wm1 + f2*t2;
      xp[3*128+h] =  f1*wm2 + f2*t1;
      xp[4*128+h] = f0*am + f2*t3;
      xp[5*128+h] = -f1*wm0 + f2*t4;
      xp[6*128+h] = -f1*wm1 + f2*t2;
      xp[7*128+h] =  f1*wm0 + f2*t4;
      xp[8*128+h] = f0*am + f2*t5;
    }
  }
}

// ---------------- FUSED: normalize X (16 nodes) + cmix(lx) via MFMA -> Y10 ----------------
// Prologue reproduces k_msg_norm exactly (same FP ops, bf16 staging); MFMA core
// is the r18-validated k_cmix10 with A-fragments from LDS.
__global__ void __launch_bounds__(256) k_cmix_norm(
  float* __restrict__ X9, const unsigned short* __restrict__ pw, bf16* __restrict__ Y10)
{
  __shared__ __align__(16) unsigned short sst[16*1280];   // 40 KB
  int n0 = blockIdx.x*16;
  int tid = threadIdx.x;
  #pragma unroll
  for (int it=0; it<8; ++it){
    int idx = it*256 + tid;          // 0..2047
    int nn = idx >> 7, h = idx & 127;
    float* xp = X9 + (size_t)(n0+nn)*1152;
    float x00=xp[0*128+h], x01=xp[1*128+h], x02=xp[2*128+h];
    float x10=xp[3*128+h], x11=xp[4*128+h], x12=xp[5*128+h];
    float x20=xp[6*128+h], x21=xp[7*128+h], x22=xp[8*128+h];
    float tn = x00*x00+x01*x01+x02*x02+x10*x10+x11*x11+x12*x12+x20*x20+x21*x21+x22*x22;
    float inv = 1.0f/(tn+1.0f);
    x00*=inv; x01*=inv; x02*=inv; x10*=inv; x11*=inv; x12*=inv; x20*=inv; x21*=inv; x22*=inv;
    xp[0*128+h]=x00; xp[1*128+h]=x01; xp[2*128+h]=x02;
    xp[3*128+h]=x10; xp[4*128+h]=x11; xp[5*128+h]=x12;
    xp[6*128+h]=x20; xp[7*128+h]=x21; xp[8*128+h]=x22;
    float a = (x00+x11+x22)*(1.0f/3.0f);
    unsigned short* sp = sst + (size_t)nn*1280;
    sp[0*128+h]=f2bu(a);
    sp[1*128+h]=f2bu(0.5f*(x21-x12));
    sp[2*128+h]=f2bu(0.5f*(x02-x20));
    sp[3*128+h]=f2bu(0.5f*(x10-x01));
    sp[4*128+h]=f2bu(x00-a);
    sp[5*128+h]=f2bu(0.5f*(x01+x10));
    sp[6*128+h]=f2bu(0.5f*(x02+x20));
    sp[7*128+h]=f2bu(x11-a);
    sp[8*128+h]=f2bu(0.5f*(x12+x21));
    sp[9*128+h]=f2bu(x22-a);
  }
  __syncthreads();
  int wid  = tid >> 6;
  int lane = tid & 63;
  int m = lane & 15, g = lane >> 4;
  f32x4 acc[10][2];
  #pragma unroll
  for (int c=0;c<10;++c){ acc[c][0]=(f32x4){0,0,0,0}; acc[c][1]=(f32x4){0,0,0,0}; }
  #pragma unroll
  for (int c=0;c<10;++c){
    int mat = (c==0) ? 0 : (c<4) ? 1 : 2;
    const unsigned short* bw = pw + (size_t)mat*16384;
    short8v af[4];
    #pragma unroll
    for (int ks=0; ks<4; ++ks)
      af[ks] = *reinterpret_cast<const short8v*>(&sst[(size_t)m*1280 + c*128 + ks*32 + g*8]);
    #pragma unroll
    for (int t=0;t<2;++t){
      int nt = wid + t*4;
      #pragma unroll
      for (int ks=0; ks<4; ++ks){
        short8v b = *reinterpret_cast<const short8v*>(bw + ((size_t)(nt*4+ks)*64 + lane)*8);
        acc[c][t] = __builtin_amdgcn_mfma_f32_16x16x32_bf16(af[ks], b, acc[c][t], 0,0,0);
      }
    }
  }
  #pragma unroll
  for (int t=0;t<2;++t){
    int nt = wid + t*4;
    int h = nt*16 + m;
    #pragma unroll
    for (int r=0;r<4;++r){
      int node = n0 + g*4 + r;
      unsigned short* op = (unsigned short*)Y10 + (size_t)node*1280;
      #pragma unroll
      for (int c=0;c<10;++c) op[c*128 + h] = f2bu(acc[c][t][r]);
    }
  }
}

// ---------------- msg edge MLP via MFMA (r19 version, unchanged) ----------------
template<typename T>
__device__ __forceinline__ void mfma_impl(
  const unsigned short* eattr_c, const float* gC, const int* pos,
  const unsigned short* p0, const unsigned short* p1, const unsigned short* p2,
  const T* b0, const T* b1, const T* b2,
  unsigned short* eabuf, unsigned short (*h1p)[2048], unsigned short (*h2p)[4096], int* spos)
{
  int wid  = threadIdx.x >> 6;
  int lane = threadIdx.x & 63;
  int e0 = blockIdx.x*32;
  int m = lane & 15, g = lane >> 4;
  if (threadIdx.x < 32) spos[threadIdx.x] = pos[e0 + threadIdx.x];
  float cc[2][4];
  #pragma unroll
  for (int mt=0;mt<2;++mt)
    #pragma unroll
    for (int r=0;r<4;++r) cc[mt][r] = gC[e0 + mt*16 + g*4 + r];
  short8v a1[2];
  #pragma unroll
  for (int mt=0;mt<2;++mt)
    a1[mt] = *reinterpret_cast<const short8v*>(eattr_c + (size_t)(e0+mt*16+m)*32 + g*8);
  for (int nt=wid; nt<8; nt+=4){
    float bias = ldf(b0, nt*16+m);
    short8v b = *reinterpret_cast<const short8v*>(p0 + ((size_t)nt*64 + lane)*8);
    #pragma unroll
    for (int mt=0;mt<2;++mt){
      f32x4 acc = {bias,bias,bias,bias};
      acc = __builtin_amdgcn_mfma_f32_16x16x32_bf16(a1[mt], b, acc, 0,0,0);
      #pragma unroll
      for (int r=0;r<4;++r){
        int n = nt*16 + m, row = g*4 + r;
        h1p[mt][(n>>5)*512 + (((n>>3)&3)*16+row)*8 + (n&7)] = f2bu(siluf(acc[r]));
      }
    }
  }
  __syncthreads();
  short8v a2[2][4];
  #pragma unroll
  for (int mt=0;mt<2;++mt)
    #pragma unroll
    for (int ks=0; ks<4; ++ks)
      a2[mt][ks] = *reinterpret_cast<const short8v*>(&h1p[mt][ks*512 + lane*8]);
  for (int nt=wid; nt<16; nt+=4){
    float bias = ldf(b1, nt*16+m);
    short8v bfr[4];
    #pragma unroll
    for (int ks=0; ks<4; ++ks)
      bfr[ks] = *reinterpret_cast<const short8v*>(p1 + ((size_t)(nt*4+ks)*64 + lane)*8);
    #pragma unroll
    for (int mt=0;mt<2;++mt){
      f32x4 acc = {bias,bias,bias,bias};
      #pragma unroll
      for (int ks=0; ks<4; ++ks)
        acc = __builtin_amdgcn_mfma_f32_16x16x32_bf16(a2[mt][ks], bfr[ks], acc, 0,0,0);
      #pragma unroll
      for (int r=0;r<4;++r){
        int n = nt*16 + m, row = g*4 + r;
        h2p[mt][(n>>5)*512 + (((n>>3)&3)*16+row)*8 + (n&7)] = f2bu(siluf(acc[r]));
      }
    }
  }
  __syncthreads();
  short8v a3[2][8];
  #pragma unroll
  for (int mt=0;mt<2;++mt)
    #pragma unroll
    for (int ks=0; ks<8; ++ks)
      a3[mt][ks] = *reinterpret_cast<const short8v*>(&h2p[mt][ks*512 + lane*8]);
  for (int nt=wid; nt<24; nt+=4){
    float bias = ldf(b2, nt*16+m);
    short8v bfr[8];
    #pragma unroll
    for (int ks=0; ks<8; ++ks)
      bfr[ks] = *reinterpret_cast<const short8v*>(p2 + ((size_t)(nt*8+ks)*64 + lane)*8);
    #pragma unroll
    for (int mt=0;mt<2;++mt){
      f32x4 acc = {bias,bias,bias,bias};
      #pragma unroll
      for (int ks=0; ks<8; ++ks)
        acc = __builtin_amdgcn_mfma_f32_16x16x32_bf16(a3[mt][ks], bfr[ks], acc, 0,0,0);
      #pragma unroll
      for (int r=0;r<4;++r){
        int n = nt*16 + m, row = g*4 + r;
        float v = siluf(acc[r]) * cc[mt][r];
        eabuf[(size_t)spos[mt*16+row]*384 + (n%3)*128 + (n/3)] = f2bu(v);
      }
    }
  }
}
__global__ void __launch_bounds__(256) k_msg_edge_mfma(
  const unsigned short* __restrict__ eattr_c, const float* __restrict__ gC,
  const int* __restrict__ pos,
  const unsigned short* __restrict__ p0, const unsigned short* __restrict__ p1,
  const unsigned short* __restrict__ p2,
  const void* b0, const void* b1, const void* b2, long boff0, long boff1, long boff2,
  unsigned short* __restrict__ eabuf, const int* __restrict__ flag)
{
  __shared__ __align__(16) unsigned short h1p[2][2048];
  __shared__ __align__(16) unsigned short h2p[2][4096];
  __shared__ int spos[32];
  if (flag[0]) mfma_impl<float>(eattr_c, gC, pos, p0, p1, p2,
      (const float*)b0 + boff0, (const float*)b1 + boff1, (const float*)b2 + boff2, eabuf, h1p, h2p, spos);
  else mfma_impl<bf16>(eattr_c, gC, pos, p0, p1, p2,
      (const bf16*)b0 + boff0, (const bf16*)b1 + boff1, (const bf16*)b2 + boff2, eabuf, h1p, h2p, spos);
}

// ---------------- msg scatter + AB + decompose -> smb bf16 ----------------
__global__ void __launch_bounds__(128) k_msg_sab(
  const int* __restrict__ offsets, const int* __restrict__ csrc,
  const bf16* __restrict__ eabuf, const bf16* __restrict__ Y10, bf16* __restrict__ smb)
{
  int n0 = blockIdx.x*NB, h = threadIdx.x;
  #pragma unroll
  for (int nn=0;nn<NB;++nn){
    int n = n0+nn;
    float am=0, vm0=0,vm1=0,vm2=0, smm0=0,smm1=0,smm2=0,smm3=0,smm4=0,smm5=0;
    int beg = offsets[n], end = offsets[n+1];
    int i = beg;
    for (; i+4 <= end; i += 4){
      int ss[4];
      #pragma unroll
      for (int u=0;u<4;++u){ ss[u] = csrc[i+u]; }
      float e0a[4], e1a[4], e2a[4];
      float y0[4],y1[4],y2[4],y3[4],y4[4],y5[4],y6[4],y7[4],y8[4],y9[4];
      #pragma unroll
      for (int u=0;u<4;++u){
        const bf16* ep = eabuf + (size_t)(i+u)*384;
        e0a[u]=b2f(ep[h]); e1a[u]=b2f(ep[128+h]); e2a[u]=b2f(ep[256+h]);
        const bf16* yp = Y10 + (size_t)ss[u]*1280;
        y0[u]=b2f(yp[0*128+h]); y1[u]=b2f(yp[1*128+h]); y2[u]=b2f(yp[2*128+h]);
        y3[u]=b2f(yp[3*128+h]); y4[u]=b2f(yp[4*128+h]); y5[u]=b2f(yp[5*128+h]);
        y6[u]=b2f(yp[6*128+h]); y7[u]=b2f(yp[7*128+h]); y8[u]=b2f(yp[8*128+h]);
        y9[u]=b2f(yp[9*128+h]);
      }
      #pragma unroll
      for (int u=0;u<4;++u){
        am   += e0a[u]*y0[u];
        vm0  += e1a[u]*y1[u]; vm1 += e1a[u]*y2[u]; vm2 += e1a[u]*y3[u];
        smm0 += e2a[u]*y4[u]; smm1 += e2a[u]*y5[u]; smm2 += e2a[u]*y6[u];
        smm3 += e2a[u]*y7[u]; smm4 += e2a[u]*y8[u]; smm5 += e2a[u]*y9[u];
      }
    }
    for (; i<end; ++i){
      int s = csrc[i];
      const bf16* ep = eabuf + (size_t)i*384;
      float e0 = b2f(ep[h]), e1 = b2f(ep[128+h]), e2 = b2f(ep[256+h]);
      const bf16* yp = Y10 + (size_t)s*1280;
      am   += e0*b2f(yp[0*128+h]);
      vm0  += e1*b2f(yp[1*128+h]); vm1 += e1*b2f(yp[2*128+h]); vm2 += e1*b2f(yp[3*128+h]);
      smm0 += e2*b2f(yp[4*128+h]); smm1 += e2*b2f(yp[5*128+h]); smm2 += e2*b2f(yp[6*128+h]);
      smm3 += e2*b2f(yp[7*128+h]); smm4 += e2*b2f(yp[8*128+h]); smm5 += e2*b2f(yp[9*128+h]);
    }
    const bf16* yp = Y10 + (size_t)n*1280;
    float aY=b2f(yp[0*128+h]), u0=b2f(yp[1*128+h]), u1=b2f(yp[2*128+h]), u2=b2f(yp[3*128+h]);
    float q0=b2f(yp[4*128+h]), q1=b2f(yp[5*128+h]), q2=b2f(yp[6*128+h]);
    float q3=b2f(yp[7*128+h]), q4=b2f(yp[8*128+h]), q5=b2f(yp[9*128+h]);
    float m00=am+smm0,   m01=-vm2+smm1, m02= vm1+smm2;
    float m10= vm2+smm1, m11=am+smm3,  m12=-vm0+smm4;
    float m20=-vm1+smm2, m21= vm0+smm4, m22=am+smm5;
    float y00=aY+q0,  y01=-u2+q1, y02= u1+q2;
    float y10= u2+q1, y11=aY+q3,  y12=-u0+q4;
    float y20=-u1+q2, y21= u0+q4, y22=aY+q5;
    float ab00 = m00*y00+m01*y10+m02*y20 + y00*m00+y01*m10+y02*m20;
    float ab01 = m00*y01+m01*y11+m02*y21 + y00*m01+y01*m11+y02*m21;
    float ab02 = m00*y02+m01*y12+m02*y22 + y00*m02+y01*m12+y02*m22;
    float ab10 = m10*y00+m11*y10+m12*y20 + y10*m00+y11*m10+y12*m20;
    float ab11 = m10*y01+m11*y11+m12*y21 + y10*m01+y11*m11+y12*m21;
    float ab12 = m10*y02+m11*y12+m12*y22 + y10*m02+y11*m12+y12*m22;
    float ab20 = m20*y00+m21*y10+m22*y20 + y20*m00+y21*m10+y22*m20;
    float ab21 = m20*y01+m21*y11+m22*y21 + y20*m01+y21*m11+y22*m21;
    float ab22 = m20*y02+m21*y12+m22*y22 + y20*m02+y21*m12+y22*m22;
    float a2 = (ab00+ab11+ab22)*(1.0f/3.0f);
    float w0 = 0.5f*(ab21-ab12), w1 = 0.5f*(ab02-ab20), w2 = 0.5f*(ab10-ab01);
    float t0 = ab00-a2, t1 = 0.5f*(ab01+ab10), t2 = 0.5f*(ab02+ab20);
    float t3 = ab11-a2, t4 = 0.5f*(ab12+ab21), t5 = ab22-a2;
    float dnm = ab00*ab00+ab01*ab01+ab02*ab02+ab10*ab10+ab11*ab11+ab12*ab12
              + ab20*ab20+ab21*ab21+ab22*ab22 + 1.0f;
    float inv = 1.0f/dnm;
    bf16* sp = smb + (size_t)n*1280;
    sp[0*128+h]=__float2bfloat16(a2*inv);
    sp[1*128+h]=__float2bfloat16(w0*inv); sp[2*128+h]=__float2bfloat16(w1*inv); sp[3*128+h]=__float2bfloat16(w2*inv);
    sp[4*128+h]=__float2bfloat16(t0*inv); sp[5*128+h]=__float2bfloat16(t1*inv); sp[6*128+h]=__float2bfloat16(t2*inv);
    sp[7*128+h]=__float2bfloat16(t3*inv); sp[8*128+h]=__float2bfloat16(t4*inv); sp[9*128+h]=__float2bfloat16(t5*inv);
  }
}

// ---------------- FUSED: cmix(lt) via MFMA + dX+dX^2 + X update / output ----------------
// MFMA core = r18-validated k_cmix10; epilogue bf16-rounds accs (bround) to
// reproduce the old smb round-trip exactly, then applies k_msg_fin math.
template<typename T>
__device__ __forceinline__ void cmix_fin_impl(
  const bf16* smb, const unsigned short* pw, float* X9, T* out, int write_out)
{
  int wid  = threadIdx.x >> 6;
  int lane = threadIdx.x & 63;
  int n0 = blockIdx.x*16;
  int m = lane & 15, g = lane >> 4;
  f32x4 acc[10][2];
  #pragma unroll
  for (int c=0;c<10;++c){ acc[c][0]=(f32x4){0,0,0,0}; acc[c][1]=(f32x4){0,0,0,0}; }
  #pragma unroll
  for (int c=0;c<10;++c){
    int mat = (c==0) ? 0 : (c<4) ? 1 : 2;
    const unsigned short* bw = pw + (size_t)mat*16384;
    short8v af[4];
    #pragma unroll
    for (int ks=0; ks<4; ++ks)
      af[ks] = *reinterpret_cast<const short8v*>((const unsigned short*)smb + (size_t)(n0+m)*1280 + c*128 + ks*32 + g*8);
    #pragma unroll
    for (int t=0;t<2;++t){
      int nt = wid + t*4;
      #pragma unroll
      for (int ks=0; ks<4; ++ks){
        short8v b = *reinterpret_cast<const short8v*>(bw + ((size_t)(nt*4+ks)*64 + lane)*8);
        acc[c][t] = __builtin_amdgcn_mfma_f32_16x16x32_bf16(af[ks], b, acc[c][t], 0,0,0);
      }
    }
  }
  #pragma unroll
  for (int t=0;t<2;++t){
    int nt = wid + t*4;
    int h = nt*16 + m;
    #pragma unroll
    for (int r=0;r<4;++r){
      int node = n0 + g*4 + r;
      float at  = bround(acc[0][t][r]);
      float vt0 = bround(acc[1][t][r]), vt1 = bround(acc[2][t][r]), vt2 = bround(acc[3][t][r]);
      float st0 = bround(acc[4][t][r]), st1 = bround(acc[5][t][r]), st2 = bround(acc[6][t][r]);
      float st3 = bround(acc[7][t][r]), st4 = bround(acc[8][t][r]), st5 = bround(acc[9][t][r]);
      float d00=at+st0,   d01=-vt2+st1, d02= vt1+st2;
      float d10= vt2+st1, d11=at+st3,  d12=-vt0+st4;
      float d20=-vt1+st2, d21= vt0+st4, d22=at+st5;
      float g00 = d00 + d00*d00+d01*d10+d02*d20;
      float g01 = d01 + d00*d01+d01*d11+d02*d21;
      float g02 = d02 + d00*d02+d01*d12+d02*d22;
      float g10 = d10 + d10*d00+d11*d10+d12*d20;
      float g11 = d11 + d10*d01+d11*d11+d12*d21;
      float g12 = d12 + d10*d02+d11*d12+d12*d22;
      float g20 = d20 + d20*d00+d21*d10+d22*d20;
      float g21 = d21 + d20*d01+d21*d11+d22*d21;
      float g22 = d22 + d20*d02+d21*d12+d22*d22;
      float* xp = X9 + (size_t)node*1152;
      float x00=xp[0*128+h]+g00, x01=xp[1*128+h]+g01, x02=xp[2*128+h]+g02;
      float x10=xp[3*128+h]+g10, x11=xp[4*128+h]+g11, x12=xp[5*128+h]+g12;
      float x20=xp[6*128+h]+g20, x21=xp[7*128+h]+g21, x22=xp[8*128+h]+g22;
      if (write_out){
        if (sizeof(T)==4){
          float* of = (float*)out + ((size_t)node*128 + h)*9;
          of[0]=x00; of[1]=x01; of[2]=x02; of[3]=x10; of[4]=x11; of[5]=x12; of[6]=x20; of[7]=x21; of[8]=x22;
        } else {
          bf16* ob = (bf16*)out + ((size_t)node*128 + h)*9;
          ob[0]=__float2bfloat16(x00); ob[1]=__float2bfloat16(x01); ob[2]=__float2bfloat16(x02);
          ob[3]=__float2bfloat16(x10); ob[4]=__float2bfloat16(x11); ob[5]=__float2bfloat16(x12);
          ob[6]=__float2bfloat16(x20); ob[7]=__float2bfloat16(x21); ob[8]=__float2bfloat16(x22);
        }
      } else {
        xp[0*128+h]=x00; xp[1*128+h]=x01; xp[2*128+h]=x02;
        xp[3*128+h]=x10; xp[4*128+h]=x11; xp[5*128+h]=x12;
        xp[6*128+h]=x20; xp[7*128+h]=x21; xp[8*128+h]=x22;
      }
    }
  }
}
__global__ void __launch_bounds__(256) k_cmix_fin(
  const bf16* __restrict__ smb, const unsigned short* __restrict__ pw,
  float* __restrict__ X9, void* __restrict__ out,
  const int* __restrict__ flag, int write_out)
{
  if (flag[0]) cmix_fin_impl<float>(smb, pw, X9, (float*)out, write_out);
  else         cmix_fin_impl<bf16 >(smb, pw, X9, (bf16* )out, write_out);
}

extern "C" void kernel_launch(void* const* d_in, const int* in_sizes, int n_in,
                              void* d_out, int out_size, void* d_ws, size_t ws_size,
                              hipStream_t stream)
{
  (void)in_sizes; (void)n_in; (void)out_size; (void)ws_size;
  const int* z    = (const int*)d_in[0];
  const int* eidx = (const int*)d_in[1];
  const int* src  = eidx;
  const int* dst  = eidx + NE;

  char* w = (char*)d_ws;
  int* flag    = (int*)w;   w += 64;
  int* counts  = (int*)w;   w += (size_t)NN*4;
  int* offsets = (int*)w;   w += (size_t)(NN+1)*4 + 60;
  int* cursor  = (int*)w;   w += (size_t)NN*4;
  int* pos     = (int*)w;   w += (size_t)NE*4;
  int* csrc    = (int*)w;   w += (size_t)NE*4;
  float* gC    = (float*)w; w += (size_t)NE*4;
  float* gVp   = (float*)w; w += (size_t)NE*12;
  float* P1z   = (float*)w; w += (size_t)MAXZ*HH*4;
  float* P2z   = (float*)w; w += (size_t)MAXZ*HH*4;
  bf16* eabuf  = (bf16*)w;  w += (size_t)NE*384*2;
  float* X9    = (float*)w; w += (size_t)NN*1152*4;
  bf16* Y10    = (bf16*)w;  w += (size_t)NN*1280*2;
  bf16* smb    = (bf16*)w;  w += (size_t)NN*1280*2;
  unsigned short* eattr_c = (unsigned short*)w; w += (size_t)NE*32*2;
  unsigned short* pw0[2]; unsigned short* pw1[2]; unsigned short* pw2[2];
  for (int l=0;l<2;++l){
    pw0[l] = (unsigned short*)w; w += 8*64*8*2;
    pw1[l] = (unsigned short*)w; w += 64*64*8*2;
    pw2[l] = (unsigned short*)w; w += 192*64*8*2;
  }
  unsigned short* pw_s0 = (unsigned short*)w; w += 64*64*8*2;
  unsigned short* pw_s1 = (unsigned short*)w; w += 192*64*8*2;
  unsigned short* pwlt  = (unsigned short*)w; w += 3*32*64*8*2;
  unsigned short* pwlx2 = (unsigned short*)w; w += 2*3*32*64*8*2;
  unsigned short* pwlt2 = (unsigned short*)w; w += 2*3*32*64*8*2;
  bf16* lnO    = (bf16*)w;  w += (size_t)NN*128*2;
  bf16* fsc3   = (bf16*)w;  w += (size_t)NN*384*2;
  bf16* sm10   = Y10;   // tne alias: dead until msg cmix_norm overwrites Y10

  k_detect<<<1, 256, 0, stream>>>((const unsigned int*)d_in[4], flag);
  hipMemsetAsync(counts, 0, (size_t)NN*4, stream);
  k_count<<<NE/256, 256, 0, stream>>>(dst, counts);
  k_scan<<<1, 1024, 0, stream>>>(counts, offsets, cursor);
  k_fill<<<NE/256, 256, 0, stream>>>(dst, src, cursor, pos, csrc);
  k_geom<<<NE/256, 256, 0, stream>>>(d_in[2], d_in[3], src, dst, pos, gC, gVp, flag);
  k_zemb<<<MAXZ, 128, 0, stream>>>(d_in[5], d_in[12], P1z, P2z, flag);
  k_cvt_attr<<<NE*32/256, 256, 0, stream>>>(d_in[4], eattr_c, flag);

  PackDescs pd;
  for (int l=0;l<2;++l){
    pd.base[l*3+0] = d_in[21]; pd.eoff[l*3+0] = (long)l*32*128;
    pd.base[l*3+1] = d_in[23]; pd.eoff[l*3+1] = (long)l*128*256;
    pd.base[l*3+2] = d_in[25]; pd.eoff[l*3+2] = (long)l*256*384;
    pd.out[l*3+0] = pw0[l]; pd.K[l*3+0]=32;  pd.N[l*3+0]=128;
    pd.out[l*3+1] = pw1[l]; pd.K[l*3+1]=128; pd.N[l*3+1]=256;
    pd.out[l*3+2] = pw2[l]; pd.K[l*3+2]=256; pd.N[l*3+2]=384;
  }
  pd.base[6] = d_in[15]; pd.eoff[6] = 0; pd.out[6] = pw_s0; pd.K[6]=128; pd.N[6]=256;
  pd.base[7] = d_in[17]; pd.eoff[7] = 0; pd.out[7] = pw_s1; pd.K[7]=256; pd.N[7]=384;
  for (int c=0;c<3;++c){
    pd.base[8+c] = d_in[14]; pd.eoff[8+c] = (long)c*16384;
    pd.out[8+c] = pwlt + (size_t)c*16384; pd.K[8+c]=128; pd.N[8+c]=128;
  }
  for (int l=0;l<2;++l)
    for (int c=0;c<3;++c){
      pd.base[11+l*3+c] = d_in[27]; pd.eoff[11+l*3+c] = (long)(l*3+c)*16384;
      pd.out[11+l*3+c] = pwlx2 + (size_t)(l*3+c)*16384; pd.K[11+l*3+c]=128; pd.N[11+l*3+c]=128;
      pd.base[17+l*3+c] = d_in[28]; pd.eoff[17+l*3+c] = (long)(l*3+c)*16384;
      pd.out[17+l*3+c] = pwlt2 + (size_t)(l*3+c)*16384; pd.K[17+l*3+c]=128; pd.N[17+l*3+c]=128;
    }
  k_pack<<<dim3(48, 23), 256, 0, stream>>>(pd, flag);

  k_tne_edge<<<NE/TPB, 128, 0, stream>>>(d_in[4], src, dst, z, pos,
      d_in[6], d_in[7], d_in[8], d_in[9], d_in[10], d_in[11], d_in[13],
      P1z, P2z, gC, eabuf, flag);
  k_tne_scat<<<NN/NB, 128, 0, stream>>>(offsets, gVp, eabuf,
      d_in[19], d_in[20], sm10, lnO, flag);
  k_node_mlp<<<NN/16, 256, 0, stream>>>(lnO, pw_s0, pw_s1, d_in[16], d_in[18], fsc3, flag);
  k_tne_cmix<<<NN/16, 256, 0, stream>>>(sm10, pwlt, fsc3, X9);

  for (int l=0; l<2; ++l){
    k_msg_edge_mfma<<<NE/32, 256, 0, stream>>>(eattr_c, gC, pos, pw0[l], pw1[l], pw2[l],
        d_in[22], d_in[24], d_in[26], (long)l*128, (long)l*256, (long)l*384,
        (unsigned short*)eabuf, flag);
    k_cmix_norm<<<NN/16, 256, 0, stream>>>(X9, pwlx2 + (size_t)l*3*16384, Y10);
    k_msg_sab<<<NN/NB, 128, 0, stream>>>(offsets, csrc, eabuf, Y10, smb);
    k_cmix_fin<<<NN/16, 256, 0, stream>>>(smb, pwlt2 + (size_t)l*3*16384, X9, d_out,
        flag, (l==1)?1:0);
  }
}

// Round 21
// 250.329 us; speedup vs baseline: 1.8972x; 1.0448x over previous
//
#include <hip/hip_runtime.h>
#include <hip/hip_bf16.h>

typedef __hip_bfloat16 bf16;
typedef __attribute__((ext_vector_type(8))) short short8v;
typedef __attribute__((ext_vector_type(4))) float f32x4;

#define NN 4096
#define NE 32768
#define HH 128
#define MAXZ 100
#define TPB 8
#define NB 2

// ENVIRONMENT FACTS (r0-r20): float tensors are FLOAT32; runtime detector kept.
// MFMA edge path validated r10/r16/r19; MFMA cmix validated r17/r18; fusions
// r20 (261.5us, absmax 0.002929688 bit-stable). ws_size ~256MB. r21: edge MLP
// depends only on edge_attr => compute BOTH layers' eabuf in ONE dispatch
// (dim3(NE/32,2)) into eabuf_msg[2] — doubles wave supply for the
// latency-bound edge kernel. Math identical => absmax must stay 0.002929688.

__device__ __forceinline__ float b2f(bf16 v){ return __bfloat162float(v); }
__device__ __forceinline__ float ldf(const float* p, size_t i){ return p[i]; }
__device__ __forceinline__ float ldf(const bf16*  p, size_t i){ return __bfloat162float(p[i]); }
__device__ __forceinline__ float siluf(float x){ return x / (1.0f + __expf(-x)); }
__device__ __forceinline__ unsigned short f2bu(float x){
  bf16 h = __float2bfloat16(x);
  return *reinterpret_cast<unsigned short*>(&h);
}
__device__ __forceinline__ float bround(float x){   // round through bf16 (matches old smb round-trip)
  bf16 h = __float2bfloat16(x);
  return __bfloat162float(h);
}

__global__ void __launch_bounds__(256) k_detect(const unsigned int* __restrict__ w, int* __restrict__ flag){
  __shared__ int cnt[256];
  int t = threadIdx.x;
  int c = 0;
  for (int i = t; i < 4096; i += 256){
    unsigned int lo = w[i] & 0xffffu;
    int e = (int)((lo >> 7) & 0xffu);
    c += (e >= 110 && e <= 132) ? 1 : 0;
  }
  cnt[t] = c; __syncthreads();
  for (int off=128; off>=1; off>>=1){ if (t<off) cnt[t]+=cnt[t+off]; __syncthreads(); }
  if (t==0) flag[0] = (cnt[0] < 2048) ? 1 : 0;
}

// ---------------- CSR build ----------------
__global__ void __launch_bounds__(256) k_count(const int* __restrict__ dst, int* __restrict__ counts){
  int e = blockIdx.x*256 + threadIdx.x;
  if (e < NE) atomicAdd(&counts[dst[e]], 1);
}

__global__ void __launch_bounds__(1024) k_scan(const int* __restrict__ counts, int* __restrict__ offsets, int* __restrict__ cursor){
  __shared__ int lds[1024];
  int t = threadIdx.x;
  int c0 = counts[4*t+0], c1 = counts[4*t+1], c2 = counts[4*t+2], c3 = counts[4*t+3];
  int s1 = c0+c1, s2 = s1+c2, s3 = s2+c3;
  lds[t] = s3;
  __syncthreads();
  for (int off=1; off<1024; off<<=1){
    int v = lds[t];
    int add = (t>=off)? lds[t-off] : 0;
    __syncthreads();
    lds[t] = v + add;
    __syncthreads();
  }
  int incl = lds[t];
  int base = incl - s3;
  offsets[4*t+0]=base;    offsets[4*t+1]=base+c0; offsets[4*t+2]=base+s1; offsets[4*t+3]=base+s2;
  cursor [4*t+0]=base;    cursor [4*t+1]=base+c0; cursor [4*t+2]=base+s1; cursor [4*t+3]=base+s2;
  if (t==1023) offsets[4096]=incl;
}

__global__ void __launch_bounds__(256) k_fill(const int* __restrict__ dst, const int* __restrict__ src,
                                              int* __restrict__ cursor,
                                              int* __restrict__ pos, int* __restrict__ csrc){
  int e = blockIdx.x*256 + threadIdx.x;
  if (e < NE){
    int p = atomicAdd(&cursor[dst[e]], 1);
    pos[e] = p;
    csrc[p] = src[e];
  }
}

// ---------------- edge geometry ----------------
template<typename T>
__device__ __forceinline__ void geom_impl(const T* ew, const T* evec,
    const int* src, const int* dst, const int* pos, float* gC, float* gVp){
  int e = blockIdx.x*256 + threadIdx.x;
  if (e >= NE) return;
  float d = ldf(ew, e);
  float c = 0.5f*(cosf(d*0.6283185307179586f)+1.0f);
  c = (d < 5.0f) ? c : 0.0f;
  gC[e] = c;
  float x = ldf(evec, (size_t)e*3+0), y = ldf(evec, (size_t)e*3+1), z = ldf(evec, (size_t)e*3+2);
  if (src[e] != dst[e]){
    float n = sqrtf(x*x+y*y+z*z);
    float inv = 1.0f/fmaxf(n, 1e-12f);
    x*=inv; y*=inv; z*=inv;
  }
  int p = pos[e];
  gVp[p*3+0]=x; gVp[p*3+1]=y; gVp[p*3+2]=z;
}
__global__ void __launch_bounds__(256) k_geom(const void* ew, const void* evec,
    const int* __restrict__ src, const int* __restrict__ dst, const int* __restrict__ pos,
    float* __restrict__ gC, float* __restrict__ gVp, const int* __restrict__ flag){
  if (flag[0]) geom_impl<float>((const float*)ew, (const float*)evec, src, dst, pos, gC, gVp);
  else         geom_impl<bf16 >((const bf16* )ew, (const bf16* )evec, src, dst, pos, gC, gVp);
}

// ---------------- per-z embedding products ----------------
template<typename T>
__device__ __forceinline__ void zemb_impl(const T* emb, const T* emb2_w,
    float* P1z, float* P2z, float* Zr){
  int zv = blockIdx.x, h = threadIdx.x;
  Zr[h] = ldf(emb, (size_t)zv*HH + h);
  __syncthreads();
  float p1=0.f, p2=0.f;
  for (int r=0;r<128;++r){
    float x = Zr[r];
    p1 += x*ldf(emb2_w, (size_t)r*HH+h);
    p2 += x*ldf(emb2_w, (size_t)(r+128)*HH+h);
  }
  P1z[zv*HH+h]=p1; P2z[zv*HH+h]=p2;
}
__global__ void __launch_bounds__(128) k_zemb(const void* emb, const void* emb2_w,
    float* __restrict__ P1z, float* __restrict__ P2z, const int* __restrict__ flag){
  __shared__ float Zr[128];
  if (flag[0]) zemb_impl<float>((const float*)emb, (const float*)emb2_w, P1z, P2z, Zr);
  else         zemb_impl<bf16 >((const bf16* )emb, (const bf16* )emb2_w, P1z, P2z, Zr);
}

// ---------------- convert edge_attr -> bf16 ----------------
__global__ void __launch_bounds__(256) k_cvt_attr(const void* in, unsigned short* __restrict__ out,
                                                  const int* __restrict__ flag){
  int i = blockIdx.x*256 + threadIdx.x;
  if (flag[0]) out[i] = f2bu(((const float*)in)[i]);
  else         out[i] = ((const unsigned short*)in)[i];
}

// ---------------- weight repack into MFMA B-fragment layout (23 matrices) ----------------
struct PackDescs {
  const void*     base[23];
  long            eoff[23];
  unsigned short* out[23];
  int K[23]; int N[23];
};
template<typename T>
__device__ __forceinline__ void pack_impl(const PackDescs& d){
  int y = blockIdx.y;
  int K = d.K[y], N = d.N[y];
  int ktiles = K>>5, ntiles = N>>4;
  int total = ktiles*ntiles*64;
  int idx = blockIdx.x*256 + threadIdx.x;
  if (idx >= total) return;
  int lane = idx & 63, tile = idx >> 6;
  int kt = tile % ktiles, nt = tile / ktiles;
  const T* W = (const T*)d.base[y] + d.eoff[y];
  int n = nt*16 + (lane&15), k0 = kt*32 + (lane>>4)*8;
  unsigned int t[8];
  #pragma unroll
  for (int j=0;j<8;++j) t[j] = f2bu(ldf(W, (size_t)(k0+j)*N + n));
  uint4 v;
  v.x = t[0] | (t[1]<<16);
  v.y = t[2] | (t[3]<<16);
  v.z = t[4] | (t[5]<<16);
  v.w = t[6] | (t[7]<<16);
  *reinterpret_cast<uint4*>(d.out[y] + ((size_t)tile*64 + lane)*8) = v;
}
__global__ void __launch_bounds__(256) k_pack(PackDescs d, const int* __restrict__ flag){
  if (flag[0]) pack_impl<float>(d);
  else         pack_impl<bf16 >(d);
}

// ---------------- TNE edge coefficients -> eabuf bf16 (CSR-ordered rows) ----------------
template<typename T>
__device__ __forceinline__ void tne_edge_impl(
  const T* eattr, const int* src, const int* dst, const int* z, const int* pos,
  const T* dp1_w, const T* dp1_b, const T* dp2_w, const T* dp2_b,
  const T* dp3_w, const T* dp3_b, const T* emb2_b,
  const float* P1z, const float* P2z, const float* gC, bf16* eabuf,
  float (*attr)[32], int* zd, int* zs, int* ppos)
{
  int e0 = blockIdx.x*TPB;
  int h  = threadIdx.x;
  for (int i=h; i<TPB*32; i+=128) attr[i>>5][i&31] = ldf(eattr, (size_t)e0*32 + i);
  if (h < TPB){ int e=e0+h; zd[h]=z[dst[e]]; zs[h]=z[src[e]]; ppos[h]=pos[e]; }
  __syncthreads();
  float w1[TPB], w2[TPB], w3[TPB];
  float b1v=ldf(dp1_b,h), b2v=ldf(dp2_b,h), b3v=ldf(dp3_b,h);
  #pragma unroll
  for (int e=0;e<TPB;++e){ w1[e]=b1v; w2[e]=b2v; w3[e]=b3v; }
  for (int r=0;r<32;++r){
    float u1=ldf(dp1_w,(size_t)r*HH+h), u2=ldf(dp2_w,(size_t)r*HH+h), u3=ldf(dp3_w,(size_t)r*HH+h);
    #pragma unroll
    for (int e=0;e<TPB;++e){ float a=attr[e][r]; w1[e]+=a*u1; w2[e]+=a*u2; w3[e]+=a*u3; }
  }
  float eb = ldf(emb2_b,h);
  #pragma unroll
  for (int e=0;e<TPB;++e){
    float zij = P1z[zd[e]*HH+h] + P2z[zs[e]*HH+h] + eb;
    float c = gC[e0+e];
    bf16* p = eabuf + (size_t)ppos[e]*384;
    p[h]     = __float2bfloat16(zij*w1[e]*c);
    p[128+h] = __float2bfloat16(zij*w2[e]*c);
    p[256+h] = __float2bfloat16(zij*w3[e]*c);
  }
}
__global__ void __launch_bounds__(128) k_tne_edge(
  const void* eattr, const int* __restrict__ src, const int* __restrict__ dst,
  const int* __restrict__ z, const int* __restrict__ pos,
  const void* dp1_w, const void* dp1_b, const void* dp2_w, const void* dp2_b,
  const void* dp3_w, const void* dp3_b, const void* emb2_b,
  const float* __restrict__ P1z, const float* __restrict__ P2z,
  const float* __restrict__ gC, bf16* __restrict__ eabuf, const int* __restrict__ flag)
{
  __shared__ float attr[TPB][32];
  __shared__ int zd[TPB], zs[TPB], ppos[TPB];
  if (flag[0]) tne_edge_impl<float>((const float*)eattr, src, dst, z, pos,
      (const float*)dp1_w, (const float*)dp1_b, (const float*)dp2_w, (const float*)dp2_b,
      (const float*)dp3_w, (const float*)dp3_b, (const float*)emb2_b, P1z, P2z, gC, eabuf, attr, zd, zs, ppos);
  else tne_edge_impl<bf16>((const bf16*)eattr, src, dst, z, pos,
      (const bf16*)dp1_w, (const bf16*)dp1_b, (const bf16*)dp2_w, (const bf16*)dp2_b,
      (const bf16*)dp3_w, (const bf16*)dp3_b, (const bf16*)emb2_b, P1z, P2z, gC, eabuf, attr, zd, zs, ppos);
}

// ---------------- TNE scatter + LN: writes sm10 bf16 and ln bf16 ----------------
template<typename T>
__device__ __forceinline__ void tne_scat_impl(
  const int* offsets, const float* gVp, const bf16* eabuf,
  const T* ln_g, const T* ln_b, bf16* sm10, bf16* lnO, float* red)
{
  int n0 = blockIdx.x*NB, h = threadIdx.x;
  float tnv[NB];
  #pragma unroll
  for (int nn=0;nn<NB;++nn){
    int n = n0+nn;
    float a=0, v0=0,v1=0,v2=0, s0=0,s1=0,s2=0,s3=0,s4=0,s5=0;
    int beg = offsets[n], end = offsets[n+1];
    int i = beg;
    for (; i+4 <= end; i += 4){
      float c1[4],c2[4],c3[4],vx[4],vy[4],vz[4];
      #pragma unroll
      for (int u=0;u<4;++u){
        const bf16* p = eabuf + (size_t)(i+u)*384;
        c1[u]=b2f(p[h]); c2[u]=b2f(p[128+h]); c3[u]=b2f(p[256+h]);
        vx[u]=gVp[(i+u)*3+0]; vy[u]=gVp[(i+u)*3+1]; vz[u]=gVp[(i+u)*3+2];
      }
      #pragma unroll
      for (int u=0;u<4;++u){
        float tr3 = (vx[u]*vx[u]+vy[u]*vy[u]+vz[u]*vz[u])*(1.0f/3.0f);
        a  += c1[u];
        v0 += c2[u]*vx[u]; v1 += c2[u]*vy[u]; v2 += c2[u]*vz[u];
        s0 += c3[u]*(vx[u]*vx[u] - tr3); s1 += c3[u]*vx[u]*vy[u]; s2 += c3[u]*vx[u]*vz[u];
        s3 += c3[u]*(vy[u]*vy[u] - tr3); s4 += c3[u]*vy[u]*vz[u]; s5 += c3[u]*(vz[u]*vz[u] - tr3);
      }
    }
    for (; i<end; ++i){
      const bf16* p = eabuf + (size_t)i*384;
      float c1 = b2f(p[h]), c2 = b2f(p[128+h]), c3 = b2f(p[256+h]);
      float vx = gVp[i*3+0], vy = gVp[i*3+1], vz = gVp[i*3+2];
      float tr3 = (vx*vx+vy*vy+vz*vz)*(1.0f/3.0f);
      a  += c1;
      v0 += c2*vx; v1 += c2*vy; v2 += c2*vz;
      s0 += c3*(vx*vx - tr3); s1 += c3*vx*vy;          s2 += c3*vx*vz;
      s3 += c3*(vy*vy - tr3); s4 += c3*vy*vz;          s5 += c3*(vz*vz - tr3);
    }
    bf16* sp = sm10 + (size_t)n*1280;
    sp[0*128+h]=__float2bfloat16(a);
    sp[1*128+h]=__float2bfloat16(v0); sp[2*128+h]=__float2bfloat16(v1); sp[3*128+h]=__float2bfloat16(v2);
    sp[4*128+h]=__float2bfloat16(s0); sp[5*128+h]=__float2bfloat16(s1); sp[6*128+h]=__float2bfloat16(s2);
    sp[7*128+h]=__float2bfloat16(s3); sp[8*128+h]=__float2bfloat16(s4); sp[9*128+h]=__float2bfloat16(s5);
    tnv[nn] = 3.0f*a*a + 2.0f*(v0*v0+v1*v1+v2*v2)
            + s0*s0 + s3*s3 + s5*s5 + 2.0f*(s1*s1 + s2*s2 + s4*s4);
  }
  float gg = ldf(ln_g,h), bb = ldf(ln_b,h);
  #pragma unroll
  for (int nn=0;nn<NB;++nn){
    __syncthreads();
    red[h] = tnv[nn]; __syncthreads();
    for (int off=64; off>=1; off>>=1){ if (h<off) red[h]+=red[h+off]; __syncthreads(); }
    float mean = red[0]*(1.0f/128.0f);
    __syncthreads();
    float dm = tnv[nn] - mean;
    red[h] = dm*dm; __syncthreads();
    for (int off=64; off>=1; off>>=1){ if (h<off) red[h]+=red[h+off]; __syncthreads(); }
    float var = red[0]*(1.0f/128.0f);
    lnO[(size_t)(n0+nn)*128 + h] = __float2bfloat16(dm*rsqrtf(var+1e-5f)*gg + bb);
  }
}
__global__ void __launch_bounds__(128) k_tne_scat(
  const int* __restrict__ offsets, const float* __restrict__ gVp, const bf16* __restrict__ eabuf,
  const void* ln_g, const void* ln_b, bf16* __restrict__ sm10, bf16* __restrict__ lnO,
  const int* __restrict__ flag)
{
  __shared__ float red[128];
  if (flag[0]) tne_scat_impl<float>(offsets, gVp, eabuf, (const float*)ln_g, (const float*)ln_b, sm10, lnO, red);
  else         tne_scat_impl<bf16 >(offsets, gVp, eabuf, (const bf16* )ln_g, (const bf16* )ln_b, sm10, lnO, red);
}

// ---------------- node fsc MLP via MFMA (r17-validated) ----------------
template<typename T>
__device__ __forceinline__ void node_mlp_impl(
  const bf16* lnO, const unsigned short* ps0, const unsigned short* ps1,
  const T* b0, const T* b1, bf16* fsc3, unsigned short* h2p)
{
  int wid  = threadIdx.x >> 6;
  int lane = threadIdx.x & 63;
  int n0 = blockIdx.x*16;
  int m = lane & 15, g = lane >> 4;
  short8v aln[4];
  #pragma unroll
  for (int ks=0; ks<4; ++ks)
    aln[ks] = *reinterpret_cast<const short8v*>((const unsigned short*)lnO + (size_t)(n0+m)*128 + ks*32 + g*8);
  for (int nt=wid; nt<16; nt+=4){
    float bias = ldf(b0, nt*16+m);
    f32x4 acc = {bias,bias,bias,bias};
    #pragma unroll
    for (int ks=0; ks<4; ++ks){
      short8v b = *reinterpret_cast<const short8v*>(ps0 + ((size_t)(nt*4+ks)*64 + lane)*8);
      acc = __builtin_amdgcn_mfma_f32_16x16x32_bf16(aln[ks], b, acc, 0,0,0);
    }
    #pragma unroll
    for (int r=0;r<4;++r){
      int n = nt*16 + m, row = g*4 + r;
      h2p[(n>>5)*512 + (((n>>3)&3)*16+row)*8 + (n&7)] = f2bu(siluf(acc[r]));
    }
  }
  __syncthreads();
  short8v a3[8];
  #pragma unroll
  for (int ks=0; ks<8; ++ks) a3[ks] = *reinterpret_cast<const short8v*>(&h2p[ks*512 + lane*8]);
  for (int nt=wid; nt<24; nt+=4){
    float bias = ldf(b1, nt*16+m);
    f32x4 acc = {bias,bias,bias,bias};
    #pragma unroll
    for (int ks=0; ks<8; ++ks){
      short8v b = *reinterpret_cast<const short8v*>(ps1 + ((size_t)(nt*8+ks)*64 + lane)*8);
      acc = __builtin_amdgcn_mfma_f32_16x16x32_bf16(a3[ks], b, acc, 0,0,0);
    }
    #pragma unroll
    for (int r=0;r<4;++r){
      int n = nt*16 + m, row = g*4 + r;
      ((unsigned short*)fsc3)[(size_t)(n0+row)*384 + (n%3)*128 + (n/3)] = f2bu(siluf(acc[r]));
    }
  }
}
__global__ void __launch_bounds__(256) k_node_mlp(
  const bf16* __restrict__ lnO, const unsigned short* __restrict__ ps0,
  const unsigned short* __restrict__ ps1,
  const void* b0, const void* b1, bf16* __restrict__ fsc3, const int* __restrict__ flag)
{
  __shared__ __align__(16) unsigned short h2p[4096];
  if (flag[0]) node_mlp_impl<float>(lnO, ps0, ps1, (const float*)b0, (const float*)b1, fsc3, h2p);
  else         node_mlp_impl<bf16 >(lnO, ps0, ps1, (const bf16* )b0, (const bf16* )b1, fsc3, h2p);
}

// ---------------- tne cmix via MFMA + fsc combine -> X9 (r17-validated) ----------------
__global__ void __launch_bounds__(256) k_tne_cmix(
  const bf16* __restrict__ sm10, const unsigned short* __restrict__ pwlt,
  const bf16* __restrict__ fsc3, float* __restrict__ X9)
{
  int wid  = threadIdx.x >> 6;
  int lane = threadIdx.x & 63;
  int n0 = blockIdx.x*16;
  int m = lane & 15, g = lane >> 4;
  f32x4 acc[10][2];
  #pragma unroll
  for (int c=0;c<10;++c){ acc[c][0]=(f32x4){0,0,0,0}; acc[c][1]=(f32x4){0,0,0,0}; }
  #pragma unroll
  for (int c=0;c<10;++c){
    int mat = (c==0) ? 0 : (c<4) ? 1 : 2;
    const unsigned short* bw = pwlt + (size_t)mat*16384;
    short8v af[4];
    #pragma unroll
    for (int ks=0; ks<4; ++ks)
      af[ks] = *reinterpret_cast<const short8v*>((const unsigned short*)sm10 + (size_t)(n0+m)*1280 + c*128 + ks*32 + g*8);
    #pragma unroll
    for (int t=0;t<2;++t){
      int nt = wid + t*4;
      #pragma unroll
      for (int ks=0; ks<4; ++ks){
        short8v b = *reinterpret_cast<const short8v*>(bw + ((size_t)(nt*4+ks)*64 + lane)*8);
        acc[c][t] = __builtin_amdgcn_mfma_f32_16x16x32_bf16(af[ks], b, acc[c][t], 0,0,0);
      }
    }
  }
  #pragma unroll
  for (int t=0;t<2;++t){
    int nt = wid + t*4;
    int h = nt*16 + m;
    #pragma unroll
    for (int r=0;r<4;++r){
      int node = n0 + g*4 + r;
      float am  = acc[0][t][r];
      float wm0 = acc[1][t][r], wm1 = acc[2][t][r], wm2 = acc[3][t][r];
      float t0 = acc[4][t][r], t1 = acc[5][t][r], t2 = acc[6][t][r];
      float t3 = acc[7][t][r], t4 = acc[8][t][r], t5 = acc[9][t][r];
      float f0 = b2f(fsc3[(size_t)node*384 + h]);
      float f1 = b2f(fsc3[(size_t)node*384 + 128 + h]);
      float f2 = b2f(fsc3[(size_t)node*384 + 256 + h]);
      float* xp = X9 + (size_t)node*1152;
      xp[0*128+h] = f0*am + f2*t0;
      xp[1*128+h] = -f1*wm2 + f2*t1;
      xp[2*128+h] =  f1*wm1 + f2*t2;
      xp[3*128+h] =  f1*wm2 + f2*t1;
      xp[4*128+h] = f0*am + f2*t3;
      xp[5*128+h] = -f1*wm0 + f2*t4;
      xp[6*128+h] = -f1*wm1 + f2*t2;
      xp[7*128+h] =  f1*wm0 + f2*t4;
      xp[8*128+h] = f0*am + f2*t5;
    }
  }
}

// ---------------- FUSED: normalize X (16 nodes) + cmix(lx) via MFMA -> Y10 ----------------
__global__ void __launch_bounds__(256) k_cmix_norm(
  float* __restrict__ X9, const unsigned short* __restrict__ pw, bf16* __restrict__ Y10)
{
  __shared__ __align__(16) unsigned short sst[16*1280];   // 40 KB
  int n0 = blockIdx.x*16;
  int tid = threadIdx.x;
  #pragma unroll
  for (int it=0; it<8; ++it){
    int idx = it*256 + tid;          // 0..2047
    int nn = idx >> 7, h = idx & 127;
    float* xp = X9 + (size_t)(n0+nn)*1152;
    float x00=xp[0*128+h], x01=xp[1*128+h], x02=xp[2*128+h];
    float x10=xp[3*128+h], x11=xp[4*128+h], x12=xp[5*128+h];
    float x20=xp[6*128+h], x21=xp[7*128+h], x22=xp[8*128+h];
    float tn = x00*x00+x01*x01+x02*x02+x10*x10+x11*x11+x12*x12+x20*x20+x21*x21+x22*x22;
    float inv = 1.0f/(tn+1.0f);
    x00*=inv; x01*=inv; x02*=inv; x10*=inv; x11*=inv; x12*=inv; x20*=inv; x21*=inv; x22*=inv;
    xp[0*128+h]=x00; xp[1*128+h]=x01; xp[2*128+h]=x02;
    xp[3*128+h]=x10; xp[4*128+h]=x11; xp[5*128+h]=x12;
    xp[6*128+h]=x20; xp[7*128+h]=x21; xp[8*128+h]=x22;
    float a = (x00+x11+x22)*(1.0f/3.0f);
    unsigned short* sp = sst + (size_t)nn*1280;
    sp[0*128+h]=f2bu(a);
    sp[1*128+h]=f2bu(0.5f*(x21-x12));
    sp[2*128+h]=f2bu(0.5f*(x02-x20));
    sp[3*128+h]=f2bu(0.5f*(x10-x01));
    sp[4*128+h]=f2bu(x00-a);
    sp[5*128+h]=f2bu(0.5f*(x01+x10));
    sp[6*128+h]=f2bu(0.5f*(x02+x20));
    sp[7*128+h]=f2bu(x11-a);
    sp[8*128+h]=f2bu(0.5f*(x12+x21));
    sp[9*128+h]=f2bu(x22-a);
  }
  __syncthreads();
  int wid  = tid >> 6;
  int lane = tid & 63;
  int m = lane & 15, g = lane >> 4;
  f32x4 acc[10][2];
  #pragma unroll
  for (int c=0;c<10;++c){ acc[c][0]=(f32x4){0,0,0,0}; acc[c][1]=(f32x4){0,0,0,0}; }
  #pragma unroll
  for (int c=0;c<10;++c){
    int mat = (c==0) ? 0 : (c<4) ? 1 : 2;
    const unsigned short* bw = pw + (size_t)mat*16384;
    short8v af[4];
    #pragma unroll
    for (int ks=0; ks<4; ++ks)
      af[ks] = *reinterpret_cast<const short8v*>(&sst[(size_t)m*1280 + c*128 + ks*32 + g*8]);
    #pragma unroll
    for (int t=0;t<2;++t){
      int nt = wid + t*4;
      #pragma unroll
      for (int ks=0; ks<4; ++ks){
        short8v b = *reinterpret_cast<const short8v*>(bw + ((size_t)(nt*4+ks)*64 + lane)*8);
        acc[c][t] = __builtin_amdgcn_mfma_f32_16x16x32_bf16(af[ks], b, acc[c][t], 0,0,0);
      }
    }
  }
  #pragma unroll
  for (int t=0;t<2;++t){
    int nt = wid + t*4;
    int h = nt*16 + m;
    #pragma unroll
    for (int r=0;r<4;++r){
      int node = n0 + g*4 + r;
      unsigned short* op = (unsigned short*)Y10 + (size_t)node*1280;
      #pragma unroll
      for (int c=0;c<10;++c) op[c*128 + h] = f2bu(acc[c][t][r]);
    }
  }
}

// ---------------- msg edge MLP via MFMA: BOTH layers in one dispatch (blockIdx.y = layer) ----------------
// Per-tile math identical to r19; only launch geometry + output buffer differ.
template<typename T>
__device__ __forceinline__ void mfma_impl(
  const unsigned short* eattr_c, const float* gC, const int* pos,
  const unsigned short* p0, const unsigned short* p1, const unsigned short* p2,
  const T* b0, const T* b1, const T* b2,
  unsigned short* eabuf, unsigned short (*h1p)[2048], unsigned short (*h2p)[4096], int* spos)
{
  int wid  = threadIdx.x >> 6;
  int lane = threadIdx.x & 63;
  int e0 = blockIdx.x*32;
  int m = lane & 15, g = lane >> 4;
  if (threadIdx.x < 32) spos[threadIdx.x] = pos[e0 + threadIdx.x];
  float cc[2][4];
  #pragma unroll
  for (int mt=0;mt<2;++mt)
    #pragma unroll
    for (int r=0;r<4;++r) cc[mt][r] = gC[e0 + mt*16 + g*4 + r];
  short8v a1[2];
  #pragma unroll
  for (int mt=0;mt<2;++mt)
    a1[mt] = *reinterpret_cast<const short8v*>(eattr_c + (size_t)(e0+mt*16+m)*32 + g*8);
  for (int nt=wid; nt<8; nt+=4){
    float bias = ldf(b0, nt*16+m);
    short8v b = *reinterpret_cast<const short8v*>(p0 + ((size_t)nt*64 + lane)*8);
    #pragma unroll
    for (int mt=0;mt<2;++mt){
      f32x4 acc = {bias,bias,bias,bias};
      acc = __builtin_amdgcn_mfma_f32_16x16x32_bf16(a1[mt], b, acc, 0,0,0);
      #pragma unroll
      for (int r=0;r<4;++r){
        int n = nt*16 + m, row = g*4 + r;
        h1p[mt][(n>>5)*512 + (((n>>3)&3)*16+row)*8 + (n&7)] = f2bu(siluf(acc[r]));
      }
    }
  }
  __syncthreads();
  short8v a2[2][4];
  #pragma unroll
  for (int mt=0;mt<2;++mt)
    #pragma unroll
    for (int ks=0; ks<4; ++ks)
      a2[mt][ks] = *reinterpret_cast<const short8v*>(&h1p[mt][ks*512 + lane*8]);
  for (int nt=wid; nt<16; nt+=4){
    float bias = ldf(b1, nt*16+m);
    short8v bfr[4];
    #pragma unroll
    for (int ks=0; ks<4; ++ks)
      bfr[ks] = *reinterpret_cast<const short8v*>(p1 + ((size_t)(nt*4+ks)*64 + lane)*8);
    #pragma unroll
    for (int mt=0;mt<2;++mt){
      f32x4 acc = {bias,bias,bias,bias};
      #pragma unroll
      for (int ks=0; ks<4; ++ks)
        acc = __builtin_amdgcn_mfma_f32_16x16x32_bf16(a2[mt][ks], bfr[ks], acc, 0,0,0);
      #pragma unroll
      for (int r=0;r<4;++r){
        int n = nt*16 + m, row = g*4 + r;
        h2p[mt][(n>>5)*512 + (((n>>3)&3)*16+row)*8 + (n&7)] = f2bu(siluf(acc[r]));
      }
    }
  }
  __syncthreads();
  short8v a3[2][8];
  #pragma unroll
  for (int mt=0;mt<2;++mt)
    #pragma unroll
    for (int ks=0; ks<8; ++ks)
      a3[mt][ks] = *reinterpret_cast<const short8v*>(&h2p[mt][ks*512 + lane*8]);
  for (int nt=wid; nt<24; nt+=4){
    float bias = ldf(b2, nt*16+m);
    short8v bfr[8];
    #pragma unroll
    for (int ks=0; ks<8; ++ks)
      bfr[ks] = *reinterpret_cast<const short8v*>(p2 + ((size_t)(nt*8+ks)*64 + lane)*8);
    #pragma unroll
    for (int mt=0;mt<2;++mt){
      f32x4 acc = {bias,bias,bias,bias};
      #pragma unroll
      for (int ks=0; ks<8; ++ks)
        acc = __builtin_amdgcn_mfma_f32_16x16x32_bf16(a3[mt][ks], bfr[ks], acc, 0,0,0);
      #pragma unroll
      for (int r=0;r<4;++r){
        int n = nt*16 + m, row = g*4 + r;
        float v = siluf(acc[r]) * cc[mt][r];
        eabuf[(size_t)spos[mt*16+row]*384 + (n%3)*128 + (n/3)] = f2bu(v);
      }
    }
  }
}
__global__ void __launch_bounds__(256) k_msg_edge_mfma(
  const unsigned short* __restrict__ eattr_c, const float* __restrict__ gC,
  const int* __restrict__ pos,
  const unsigned short* __restrict__ p0a, const unsigned short* __restrict__ p0b,
  const unsigned short* __restrict__ p1a, const unsigned short* __restrict__ p1b,
  const unsigned short* __restrict__ p2a, const unsigned short* __restrict__ p2b,
  const void* b0, const void* b1, const void* b2,
  unsigned short* __restrict__ eabuf_msg, const int* __restrict__ flag)
{
  __shared__ __align__(16) unsigned short h1p[2][2048];
  __shared__ __align__(16) unsigned short h2p[2][4096];
  __shared__ int spos[32];
  int l = blockIdx.y;
  const unsigned short* p0 = l ? p0b : p0a;
  const unsigned short* p1 = l ? p1b : p1a;
  const unsigned short* p2 = l ? p2b : p2a;
  unsigned short* eabuf = eabuf_msg + (size_t)l*NE*384;
  if (flag[0]) mfma_impl<float>(eattr_c, gC, pos, p0, p1, p2,
      (const float*)b0 + (long)l*128, (const float*)b1 + (long)l*256, (const float*)b2 + (long)l*384,
      eabuf, h1p, h2p, spos);
  else mfma_impl<bf16>(eattr_c, gC, pos, p0, p1, p2,
      (const bf16*)b0 + (long)l*128, (const bf16*)b1 + (long)l*256, (const bf16*)b2 + (long)l*384,
      eabuf, h1p, h2p, spos);
}

// ---------------- msg scatter + AB + decompose -> smb bf16 ----------------
__global__ void __launch_bounds__(128) k_msg_sab(
  const int* __restrict__ offsets, const int* __restrict__ csrc,
  const bf16* __restrict__ eabuf, const bf16* __restrict__ Y10, bf16* __restrict__ smb)
{
  int n0 = blockIdx.x*NB, h = threadIdx.x;
  #pragma unroll
  for (int nn=0;nn<NB;++nn){
    int n = n0+nn;
    float am=0, vm0=0,vm1=0,vm2=0, smm0=0,smm1=0,smm2=0,smm3=0,smm4=0,smm5=0;
    int beg = offsets[n], end = offsets[n+1];
    int i = beg;
    for (; i+4 <= end; i += 4){
      int ss[4];
      #pragma unroll
      for (int u=0;u<4;++u){ ss[u] = csrc[i+u]; }
      float e0a[4], e1a[4], e2a[4];
      float y0[4],y1[4],y2[4],y3[4],y4[4],y5[4],y6[4],y7[4],y8[4],y9[4];
      #pragma unroll
      for (int u=0;u<4;++u){
        const bf16* ep = eabuf + (size_t)(i+u)*384;
        e0a[u]=b2f(ep[h]); e1a[u]=b2f(ep[128+h]); e2a[u]=b2f(ep[256+h]);
        const bf16* yp = Y10 + (size_t)ss[u]*1280;
        y0[u]=b2f(yp[0*128+h]); y1[u]=b2f(yp[1*128+h]); y2[u]=b2f(yp[2*128+h]);
        y3[u]=b2f(yp[3*128+h]); y4[u]=b2f(yp[4*128+h]); y5[u]=b2f(yp[5*128+h]);
        y6[u]=b2f(yp[6*128+h]); y7[u]=b2f(yp[7*128+h]); y8[u]=b2f(yp[8*128+h]);
        y9[u]=b2f(yp[9*128+h]);
      }
      #pragma unroll
      for (int u=0;u<4;++u){
        am   += e0a[u]*y0[u];
        vm0  += e1a[u]*y1[u]; vm1 += e1a[u]*y2[u]; vm2 += e1a[u]*y3[u];
        smm0 += e2a[u]*y4[u]; smm1 += e2a[u]*y5[u]; smm2 += e2a[u]*y6[u];
        smm3 += e2a[u]*y7[u]; smm4 += e2a[u]*y8[u]; smm5 += e2a[u]*y9[u];
      }
    }
    for (; i<end; ++i){
      int s = csrc[i];
      const bf16* ep = eabuf + (size_t)i*384;
      float e0 = b2f(ep[h]), e1 = b2f(ep[128+h]), e2 = b2f(ep[256+h]);
      const bf16* yp = Y10 + (size_t)s*1280;
      am   += e0*b2f(yp[0*128+h]);
      vm0  += e1*b2f(yp[1*128+h]); vm1 += e1*b2f(yp[2*128+h]); vm2 += e1*b2f(yp[3*128+h]);
      smm0 += e2*b2f(yp[4*128+h]); smm1 += e2*b2f(yp[5*128+h]); smm2 += e2*b2f(yp[6*128+h]);
      smm3 += e2*b2f(yp[7*128+h]); smm4 += e2*b2f(yp[8*128+h]); smm5 += e2*b2f(yp[9*128+h]);
    }
    const bf16* yp = Y10 + (size_t)n*1280;
    float aY=b2f(yp[0*128+h]), u0=b2f(yp[1*128+h]), u1=b2f(yp[2*128+h]), u2=b2f(yp[3*128+h]);
    float q0=b2f(yp[4*128+h]), q1=b2f(yp[5*128+h]), q2=b2f(yp[6*128+h]);
    float q3=b2f(yp[7*128+h]), q4=b2f(yp[8*128+h]), q5=b2f(yp[9*128+h]);
    float m00=am+smm0,   m01=-vm2+smm1, m02= vm1+smm2;
    float m10= vm2+smm1, m11=am+smm3,  m12=-vm0+smm4;
    float m20=-vm1+smm2, m21= vm0+smm4, m22=am+smm5;
    float y00=aY+q0,  y01=-u2+q1, y02= u1+q2;
    float y10= u2+q1, y11=aY+q3,  y12=-u0+q4;
    float y20=-u1+q2, y21= u0+q4, y22=aY+q5;
    float ab00 = m00*y00+m01*y10+m02*y20 + y00*m00+y01*m10+y02*m20;
    float ab01 = m00*y01+m01*y11+m02*y21 + y00*m01+y01*m11+y02*m21;
    float ab02 = m00*y02+m01*y12+m02*y22 + y00*m02+y01*m12+y02*m22;
    float ab10 = m10*y00+m11*y10+m12*y20 + y10*m00+y11*m10+y12*m20;
    float ab11 = m10*y01+m11*y11+m12*y21 + y10*m01+y11*m11+y12*m21;
    float ab12 = m10*y02+m11*y12+m12*y22 + y10*m02+y11*m12+y12*m22;
    float ab20 = m20*y00+m21*y10+m22*y20 + y20*m00+y21*m10+y22*m20;
    float ab21 = m20*y01+m21*y11+m22*y21 + y20*m01+y21*m11+y22*m21;
    float ab22 = m20*y02+m21*y12+m22*y22 + y20*m02+y21*m12+y22*m22;
    float a2 = (ab00+ab11+ab22)*(1.0f/3.0f);
    float w0 = 0.5f*(ab21-ab12), w1 = 0.5f*(ab02-ab20), w2 = 0.5f*(ab10-ab01);
    float t0 = ab00-a2, t1 = 0.5f*(ab01+ab10), t2 = 0.5f*(ab02+ab20);
    float t3 = ab11-a2, t4 = 0.5f*(ab12+ab21), t5 = ab22-a2;
    float dnm = ab00*ab00+ab01*ab01+ab02*ab02+ab10*ab10+ab11*ab11+ab12*ab12
              + ab20*ab20+ab21*ab21+ab22*ab22 + 1.0f;
    float inv = 1.0f/dnm;
    bf16* sp = smb + (size_t)n*1280;
    sp[0*128+h]=__float2bfloat16(a2*inv);
    sp[1*128+h]=__float2bfloat16(w0*inv); sp[2*128+h]=__float2bfloat16(w1*inv); sp[3*128+h]=__float2bfloat16(w2*inv);
    sp[4*128+h]=__float2bfloat16(t0*inv); sp[5*128+h]=__float2bfloat16(t1*inv); sp[6*128+h]=__float2bfloat16(t2*inv);
    sp[7*128+h]=__float2bfloat16(t3*inv); sp[8*128+h]=__float2bfloat16(t4*inv); sp[9*128+h]=__float2bfloat16(t5*inv);
  }
}

// ---------------- FUSED: cmix(lt) via MFMA + dX+dX^2 + X update / output ----------------
template<typename T>
__device__ __forceinline__ void cmix_fin_impl(
  const bf16* smb, const unsigned short* pw, float* X9, T* out, int write_out)
{
  int wid  = threadIdx.x >> 6;
  int lane = threadIdx.x & 63;
  int n0 = blockIdx.x*16;
  int m = lane & 15, g = lane >> 4;
  f32x4 acc[10][2];
  #pragma unroll
  for (int c=0;c<10;++c){ acc[c][0]=(f32x4){0,0,0,0}; acc[c][1]=(f32x4){0,0,0,0}; }
  #pragma unroll
  for (int c=0;c<10;++c){
    int mat = (c==0) ? 0 : (c<4) ? 1 : 2;
    const unsigned short* bw = pw + (size_t)mat*16384;
    short8v af[4];
    #pragma unroll
    for (int ks=0; ks<4; ++ks)
      af[ks] = *reinterpret_cast<const short8v*>((const unsigned short*)smb + (size_t)(n0+m)*1280 + c*128 + ks*32 + g*8);
    #pragma unroll
    for (int t=0;t<2;++t){
      int nt = wid + t*4;
      #pragma unroll
      for (int ks=0; ks<4; ++ks){
        short8v b = *reinterpret_cast<const short8v*>(bw + ((size_t)(nt*4+ks)*64 + lane)*8);
        acc[c][t] = __builtin_amdgcn_mfma_f32_16x16x32_bf16(af[ks], b, acc[c][t], 0,0,0);
      }
    }
  }
  #pragma unroll
  for (int t=0;t<2;++t){
    int nt = wid + t*4;
    int h = nt*16 + m;
    #pragma unroll
    for (int r=0;r<4;++r){
      int node = n0 + g*4 + r;
      float at  = bround(acc[0][t][r]);
      float vt0 = bround(acc[1][t][r]), vt1 = bround(acc[2][t][r]), vt2 = bround(acc[3][t][r]);
      float st0 = bround(acc[4][t][r]), st1 = bround(acc[5][t][r]), st2 = bround(acc[6][t][r]);
      float st3 = bround(acc[7][t][r]), st4 = bround(acc[8][t][r]), st5 = bround(acc[9][t][r]);
      float d00=at+st0,   d01=-vt2+st1, d02= vt1+st2;
      float d10= vt2+st1, d11=at+st3,  d12=-vt0+st4;
      float d20=-vt1+st2, d21= vt0+st4, d22=at+st5;
      float g00 = d00 + d00*d00+d01*d10+d02*d20;
      float g01 = d01 + d00*d01+d01*d11+d02*d21;
      float g02 = d02 + d00*d02+d01*d12+d02*d22;
      float g10 = d10 + d10*d00+d11*d10+d12*d20;
      float g11 = d11 + d10*d01+d11*d11+d12*d21;
      float g12 = d12 + d10*d02+d11*d12+d12*d22;
      float g20 = d20 + d20*d00+d21*d10+d22*d20;
      float g21 = d21 + d20*d01+d21*d11+d22*d21;
      float g22 = d22 + d20*d02+d21*d12+d22*d22;
      float* xp = X9 + (size_t)node*1152;
      float x00=xp[0*128+h]+g00, x01=xp[1*128+h]+g01, x02=xp[2*128+h]+g02;
      float x10=xp[3*128+h]+g10, x11=xp[4*128+h]+g11, x12=xp[5*128+h]+g12;
      float x20=xp[6*128+h]+g20, x21=xp[7*128+h]+g21, x22=xp[8*128+h]+g22;
      if (write_out){
        if (sizeof(T)==4){
          float* of = (float*)out + ((size_t)node*128 + h)*9;
          of[0]=x00; of[1]=x01; of[2]=x02; of[3]=x10; of[4]=x11; of[5]=x12; of[6]=x20; of[7]=x21; of[8]=x22;
        } else {
          bf16* ob = (bf16*)out + ((size_t)node*128 + h)*9;
          ob[0]=__float2bfloat16(x00); ob[1]=__float2bfloat16(x01); ob[2]=__float2bfloat16(x02);
          ob[3]=__float2bfloat16(x10); ob[4]=__float2bfloat16(x11); ob[5]=__float2bfloat16(x12);
          ob[6]=__float2bfloat16(x20); ob[7]=__float2bfloat16(x21); ob[8]=__float2bfloat16(x22);
        }
      } else {
        xp[0*128+h]=x00; xp[1*128+h]=x01; xp[2*128+h]=x02;
        xp[3*128+h]=x10; xp[4*128+h]=x11; xp[5*128+h]=x12;
        xp[6*128+h]=x20; xp[7*128+h]=x21; xp[8*128+h]=x22;
      }
    }
  }
}
__global__ void __launch_bounds__(256) k_cmix_fin(
  const bf16* __restrict__ smb, const unsigned short* __restrict__ pw,
  float* __restrict__ X9, void* __restrict__ out,
  const int* __restrict__ flag, int write_out)
{
  if (flag[0]) cmix_fin_impl<float>(smb, pw, X9, (float*)out, write_out);
  else         cmix_fin_impl<bf16 >(smb, pw, X9, (bf16* )out, write_out);
}

extern "C" void kernel_launch(void* const* d_in, const int* in_sizes, int n_in,
                              void* d_out, int out_size, void* d_ws, size_t ws_size,
                              hipStream_t stream)
{
  (void)in_sizes; (void)n_in; (void)out_size; (void)ws_size;
  const int* z    = (const int*)d_in[0];
  const int* eidx = (const int*)d_in[1];
  const int* src  = eidx;
  const int* dst  = eidx + NE;

  // Workspace ~160 MB (ws_size ~256 MB per r19 fillBuffer evidence).
  char* w = (char*)d_ws;
  int* flag    = (int*)w;   w += 64;
  int* counts  = (int*)w;   w += (size_t)NN*4;
  int* offsets = (int*)w;   w += (size_t)(NN+1)*4 + 60;
  int* cursor  = (int*)w;   w += (size_t)NN*4;
  int* pos     = (int*)w;   w += (size_t)NE*4;
  int* csrc    = (int*)w;   w += (size_t)NE*4;
  float* gC    = (float*)w; w += (size_t)NE*4;
  float* gVp   = (float*)w; w += (size_t)NE*12;
  float* P1z   = (float*)w; w += (size_t)MAXZ*HH*4;
  float* P2z   = (float*)w; w += (size_t)MAXZ*HH*4;
  bf16* eabuf  = (bf16*)w;  w += (size_t)NE*384*2;          // tne coefficients
  bf16* eabuf_msg = (bf16*)w; w += (size_t)2*NE*384*2;      // msg edge MLP, both layers
  float* X9    = (float*)w; w += (size_t)NN*1152*4;
  bf16* Y10    = (bf16*)w;  w += (size_t)NN*1280*2;
  bf16* smb    = (bf16*)w;  w += (size_t)NN*1280*2;
  unsigned short* eattr_c = (unsigned short*)w; w += (size_t)NE*32*2;
  unsigned short* pw0[2]; unsigned short* pw1[2]; unsigned short* pw2[2];
  for (int l=0;l<2;++l){
    pw0[l] = (unsigned short*)w; w += 8*64*8*2;
    pw1[l] = (unsigned short*)w; w += 64*64*8*2;
    pw2[l] = (unsigned short*)w; w += 192*64*8*2;
  }
  unsigned short* pw_s0 = (unsigned short*)w; w += 64*64*8*2;
  unsigned short* pw_s1 = (unsigned short*)w; w += 192*64*8*2;
  unsigned short* pwlt  = (unsigned short*)w; w += 3*32*64*8*2;
  unsigned short* pwlx2 = (unsigned short*)w; w += 2*3*32*64*8*2;
  unsigned short* pwlt2 = (unsigned short*)w; w += 2*3*32*64*8*2;
  bf16* lnO    = (bf16*)w;  w += (size_t)NN*128*2;
  bf16* fsc3   = (bf16*)w;  w += (size_t)NN*384*2;
  bf16* sm10   = Y10;   // tne alias: dead until msg cmix_norm overwrites Y10

  k_detect<<<1, 256, 0, stream>>>((const unsigned int*)d_in[4], flag);
  hipMemsetAsync(counts, 0, (size_t)NN*4, stream);
  k_count<<<NE/256, 256, 0, stream>>>(dst, counts);
  k_scan<<<1, 1024, 0, stream>>>(counts, offsets, cursor);
  k_fill<<<NE/256, 256, 0, stream>>>(dst, src, cursor, pos, csrc);
  k_geom<<<NE/256, 256, 0, stream>>>(d_in[2], d_in[3], src, dst, pos, gC, gVp, flag);
  k_zemb<<<MAXZ, 128, 0, stream>>>(d_in[5], d_in[12], P1z, P2z, flag);
  k_cvt_attr<<<NE*32/256, 256, 0, stream>>>(d_in[4], eattr_c, flag);

  PackDescs pd;
  for (int l=0;l<2;++l){
    pd.base[l*3+0] = d_in[21]; pd.eoff[l*3+0] = (long)l*32*128;
    pd.base[l*3+1] = d_in[23]; pd.eoff[l*3+1] = (long)l*128*256;
    pd.base[l*3+2] = d_in[25]; pd.eoff[l*3+2] = (long)l*256*384;
    pd.out[l*3+0] = pw0[l]; pd.K[l*3+0]=32;  pd.N[l*3+0]=128;
    pd.out[l*3+1] = pw1[l]; pd.K[l*3+1]=128; pd.N[l*3+1]=256;
    pd.out[l*3+2] = pw2[l]; pd.K[l*3+2]=256; pd.N[l*3+2]=384;
  }
  pd.base[6] = d_in[15]; pd.eoff[6] = 0; pd.out[6] = pw_s0; pd.K[6]=128; pd.N[6]=256;
  pd.base[7] = d_in[17]; pd.eoff[7] = 0; pd.out[7] = pw_s1; pd.K[7]=256; pd.N[7]=384;
  for (int c=0;c<3;++c){
    pd.base[8+c] = d_in[14]; pd.eoff[8+c] = (long)c*16384;
    pd.out[8+c] = pwlt + (size_t)c*16384; pd.K[8+c]=128; pd.N[8+c]=128;
  }
  for (int l=0;l<2;++l)
    for (int c=0;c<3;++c){
      pd.base[11+l*3+c] = d_in[27]; pd.eoff[11+l*3+c] = (long)(l*3+c)*16384;
      pd.out[11+l*3+c] = pwlx2 + (size_t)(l*3+c)*16384; pd.K[11+l*3+c]=128; pd.N[11+l*3+c]=128;
      pd.base[17+l*3+c] = d_in[28]; pd.eoff[17+l*3+c] = (long)(l*3+c)*16384;
      pd.out[17+l*3+c] = pwlt2 + (size_t)(l*3+c)*16384; pd.K[17+l*3+c]=128; pd.N[17+l*3+c]=128;
    }
  k_pack<<<dim3(48, 23), 256, 0, stream>>>(pd, flag);

  // Both layers' edge MLPs in one dispatch (edge MLP is X-independent).
  k_msg_edge_mfma<<<dim3(NE/32, 2), 256, 0, stream>>>(eattr_c, gC, pos,
      pw0[0], pw0[1], pw1[0], pw1[1], pw2[0], pw2[1],
      d_in[22], d_in[24], d_in[26],
      (unsigned short*)eabuf_msg, flag);

  k_tne_edge<<<NE/TPB, 128, 0, stream>>>(d_in[4], src, dst, z, pos,
      d_in[6], d_in[7], d_in[8], d_in[9], d_in[10], d_in[11], d_in[13],
      P1z, P2z, gC, eabuf, flag);
  k_tne_scat<<<NN/NB, 128, 0, stream>>>(offsets, gVp, eabuf,
      d_in[19], d_in[20], sm10, lnO, flag);
  k_node_mlp<<<NN/16, 256, 0, stream>>>(lnO, pw_s0, pw_s1, d_in[16], d_in[18], fsc3, flag);
  k_tne_cmix<<<NN/16, 256, 0, stream>>>(sm10, pwlt, fsc3, X9);

  for (int l=0; l<2; ++l){
    k_cmix_norm<<<NN/16, 256, 0, stream>>>(X9, pwlx2 + (size_t)l*3*16384, Y10);
    k_msg_sab<<<NN/NB, 128, 0, stream>>>(offsets, csrc,
        eabuf_msg + (size_t)l*NE*384, Y10, smb);
    k_cmix_fin<<<NN/16, 256, 0, stream>>>(smb, pwlt2 + (size_t)l*3*16384, X9, d_out,
        flag, (l==1)?1:0);
  }
}

// Round 22
// 233.970 us; speedup vs baseline: 2.0298x; 1.0699x over previous
//
#include <hip/hip_runtime.h>
#include <hip/hip_bf16.h>

typedef __hip_bfloat16 bf16;
typedef __attribute__((ext_vector_type(8))) short short8v;
typedef __attribute__((ext_vector_type(4))) float f32x4;

#define NN 4096
#define NE 32768
#define HH 128
#define MAXZ 100
#define TPB 8
#define NB 2

// ENVIRONMENT FACTS (r0-r21): float tensors are FLOAT32; runtime detector kept.
// MFMA edge path validated r10/r16/r19/r21; MFMA cmix validated r17/r18;
// fusions r20; merged-layer edge dispatch r21 (250.3us, absmax 0.002929688
// bit-stable). ws_size ~256MB. r22: edge kernel epilogue was 24 scattered
// 2B stores/lane + 25KB LDS capping residency. Back to 16-edge tile (r16 math)
// + LDS output staging (reuses h1p/h2p space after a3 is in regs) + coalesced
// uint4 write-out. Math bit-identical => absmax must stay 0.002929688.

__device__ __forceinline__ float b2f(bf16 v){ return __bfloat162float(v); }
__device__ __forceinline__ float ldf(const float* p, size_t i){ return p[i]; }
__device__ __forceinline__ float ldf(const bf16*  p, size_t i){ return __bfloat162float(p[i]); }
__device__ __forceinline__ float siluf(float x){ return x / (1.0f + __expf(-x)); }
__device__ __forceinline__ unsigned short f2bu(float x){
  bf16 h = __float2bfloat16(x);
  return *reinterpret_cast<unsigned short*>(&h);
}
__device__ __forceinline__ float bround(float x){   // round through bf16 (matches old smb round-trip)
  bf16 h = __float2bfloat16(x);
  return __bfloat162float(h);
}

__global__ void __launch_bounds__(256) k_detect(const unsigned int* __restrict__ w, int* __restrict__ flag){
  __shared__ int cnt[256];
  int t = threadIdx.x;
  int c = 0;
  for (int i = t; i < 4096; i += 256){
    unsigned int lo = w[i] & 0xffffu;
    int e = (int)((lo >> 7) & 0xffu);
    c += (e >= 110 && e <= 132) ? 1 : 0;
  }
  cnt[t] = c; __syncthreads();
  for (int off=128; off>=1; off>>=1){ if (t<off) cnt[t]+=cnt[t+off]; __syncthreads(); }
  if (t==0) flag[0] = (cnt[0] < 2048) ? 1 : 0;
}

// ---------------- CSR build ----------------
__global__ void __launch_bounds__(256) k_count(const int* __restrict__ dst, int* __restrict__ counts){
  int e = blockIdx.x*256 + threadIdx.x;
  if (e < NE) atomicAdd(&counts[dst[e]], 1);
}

__global__ void __launch_bounds__(1024) k_scan(const int* __restrict__ counts, int* __restrict__ offsets, int* __restrict__ cursor){
  __shared__ int lds[1024];
  int t = threadIdx.x;
  int c0 = counts[4*t+0], c1 = counts[4*t+1], c2 = counts[4*t+2], c3 = counts[4*t+3];
  int s1 = c0+c1, s2 = s1+c2, s3 = s2+c3;
  lds[t] = s3;
  __syncthreads();
  for (int off=1; off<1024; off<<=1){
    int v = lds[t];
    int add = (t>=off)? lds[t-off] : 0;
    __syncthreads();
    lds[t] = v + add;
    __syncthreads();
  }
  int incl = lds[t];
  int base = incl - s3;
  offsets[4*t+0]=base;    offsets[4*t+1]=base+c0; offsets[4*t+2]=base+s1; offsets[4*t+3]=base+s2;
  cursor [4*t+0]=base;    cursor [4*t+1]=base+c0; cursor [4*t+2]=base+s1; cursor [4*t+3]=base+s2;
  if (t==1023) offsets[4096]=incl;
}

__global__ void __launch_bounds__(256) k_fill(const int* __restrict__ dst, const int* __restrict__ src,
                                              int* __restrict__ cursor,
                                              int* __restrict__ pos, int* __restrict__ csrc){
  int e = blockIdx.x*256 + threadIdx.x;
  if (e < NE){
    int p = atomicAdd(&cursor[dst[e]], 1);
    pos[e] = p;
    csrc[p] = src[e];
  }
}

// ---------------- edge geometry ----------------
template<typename T>
__device__ __forceinline__ void geom_impl(const T* ew, const T* evec,
    const int* src, const int* dst, const int* pos, float* gC, float* gVp){
  int e = blockIdx.x*256 + threadIdx.x;
  if (e >= NE) return;
  float d = ldf(ew, e);
  float c = 0.5f*(cosf(d*0.6283185307179586f)+1.0f);
  c = (d < 5.0f) ? c : 0.0f;
  gC[e] = c;
  float x = ldf(evec, (size_t)e*3+0), y = ldf(evec, (size_t)e*3+1), z = ldf(evec, (size_t)e*3+2);
  if (src[e] != dst[e]){
    float n = sqrtf(x*x+y*y+z*z);
    float inv = 1.0f/fmaxf(n, 1e-12f);
    x*=inv; y*=inv; z*=inv;
  }
  int p = pos[e];
  gVp[p*3+0]=x; gVp[p*3+1]=y; gVp[p*3+2]=z;
}
__global__ void __launch_bounds__(256) k_geom(const void* ew, const void* evec,
    const int* __restrict__ src, const int* __restrict__ dst, const int* __restrict__ pos,
    float* __restrict__ gC, float* __restrict__ gVp, const int* __restrict__ flag){
  if (flag[0]) geom_impl<float>((const float*)ew, (const float*)evec, src, dst, pos, gC, gVp);
  else         geom_impl<bf16 >((const bf16* )ew, (const bf16* )evec, src, dst, pos, gC, gVp);
}

// ---------------- per-z embedding products ----------------
template<typename T>
__device__ __forceinline__ void zemb_impl(const T* emb, const T* emb2_w,
    float* P1z, float* P2z, float* Zr){
  int zv = blockIdx.x, h = threadIdx.x;
  Zr[h] = ldf(emb, (size_t)zv*HH + h);
  __syncthreads();
  float p1=0.f, p2=0.f;
  for (int r=0;r<128;++r){
    float x = Zr[r];
    p1 += x*ldf(emb2_w, (size_t)r*HH+h);
    p2 += x*ldf(emb2_w, (size_t)(r+128)*HH+h);
  }
  P1z[zv*HH+h]=p1; P2z[zv*HH+h]=p2;
}
__global__ void __launch_bounds__(128) k_zemb(const void* emb, const void* emb2_w,
    float* __restrict__ P1z, float* __restrict__ P2z, const int* __restrict__ flag){
  __shared__ float Zr[128];
  if (flag[0]) zemb_impl<float>((const float*)emb, (const float*)emb2_w, P1z, P2z, Zr);
  else         zemb_impl<bf16 >((const bf16* )emb, (const bf16* )emb2_w, P1z, P2z, Zr);
}

// ---------------- convert edge_attr -> bf16 ----------------
__global__ void __launch_bounds__(256) k_cvt_attr(const void* in, unsigned short* __restrict__ out,
                                                  const int* __restrict__ flag){
  int i = blockIdx.x*256 + threadIdx.x;
  if (flag[0]) out[i] = f2bu(((const float*)in)[i]);
  else         out[i] = ((const unsigned short*)in)[i];
}

// ---------------- weight repack into MFMA B-fragment layout (23 matrices) ----------------
struct PackDescs {
  const void*     base[23];
  long            eoff[23];
  unsigned short* out[23];
  int K[23]; int N[23];
};
template<typename T>
__device__ __forceinline__ void pack_impl(const PackDescs& d){
  int y = blockIdx.y;
  int K = d.K[y], N = d.N[y];
  int ktiles = K>>5, ntiles = N>>4;
  int total = ktiles*ntiles*64;
  int idx = blockIdx.x*256 + threadIdx.x;
  if (idx >= total) return;
  int lane = idx & 63, tile = idx >> 6;
  int kt = tile % ktiles, nt = tile / ktiles;
  const T* W = (const T*)d.base[y] + d.eoff[y];
  int n = nt*16 + (lane&15), k0 = kt*32 + (lane>>4)*8;
  unsigned int t[8];
  #pragma unroll
  for (int j=0;j<8;++j) t[j] = f2bu(ldf(W, (size_t)(k0+j)*N + n));
  uint4 v;
  v.x = t[0] | (t[1]<<16);
  v.y = t[2] | (t[3]<<16);
  v.z = t[4] | (t[5]<<16);
  v.w = t[6] | (t[7]<<16);
  *reinterpret_cast<uint4*>(d.out[y] + ((size_t)tile*64 + lane)*8) = v;
}
__global__ void __launch_bounds__(256) k_pack(PackDescs d, const int* __restrict__ flag){
  if (flag[0]) pack_impl<float>(d);
  else         pack_impl<bf16 >(d);
}

// ---------------- TNE edge coefficients -> eabuf bf16 (CSR-ordered rows) ----------------
template<typename T>
__device__ __forceinline__ void tne_edge_impl(
  const T* eattr, const int* src, const int* dst, const int* z, const int* pos,
  const T* dp1_w, const T* dp1_b, const T* dp2_w, const T* dp2_b,
  const T* dp3_w, const T* dp3_b, const T* emb2_b,
  const float* P1z, const float* P2z, const float* gC, bf16* eabuf,
  float (*attr)[32], int* zd, int* zs, int* ppos)
{
  int e0 = blockIdx.x*TPB;
  int h  = threadIdx.x;
  for (int i=h; i<TPB*32; i+=128) attr[i>>5][i&31] = ldf(eattr, (size_t)e0*32 + i);
  if (h < TPB){ int e=e0+h; zd[h]=z[dst[e]]; zs[h]=z[src[e]]; ppos[h]=pos[e]; }
  __syncthreads();
  float w1[TPB], w2[TPB], w3[TPB];
  float b1v=ldf(dp1_b,h), b2v=ldf(dp2_b,h), b3v=ldf(dp3_b,h);
  #pragma unroll
  for (int e=0;e<TPB;++e){ w1[e]=b1v; w2[e]=b2v; w3[e]=b3v; }
  for (int r=0;r<32;++r){
    float u1=ldf(dp1_w,(size_t)r*HH+h), u2=ldf(dp2_w,(size_t)r*HH+h), u3=ldf(dp3_w,(size_t)r*HH+h);
    #pragma unroll
    for (int e=0;e<TPB;++e){ float a=attr[e][r]; w1[e]+=a*u1; w2[e]+=a*u2; w3[e]+=a*u3; }
  }
  float eb = ldf(emb2_b,h);
  #pragma unroll
  for (int e=0;e<TPB;++e){
    float zij = P1z[zd[e]*HH+h] + P2z[zs[e]*HH+h] + eb;
    float c = gC[e0+e];
    bf16* p = eabuf + (size_t)ppos[e]*384;
    p[h]     = __float2bfloat16(zij*w1[e]*c);
    p[128+h] = __float2bfloat16(zij*w2[e]*c);
    p[256+h] = __float2bfloat16(zij*w3[e]*c);
  }
}
__global__ void __launch_bounds__(128) k_tne_edge(
  const void* eattr, const int* __restrict__ src, const int* __restrict__ dst,
  const int* __restrict__ z, const int* __restrict__ pos,
  const void* dp1_w, const void* dp1_b, const void* dp2_w, const void* dp2_b,
  const void* dp3_w, const void* dp3_b, const void* emb2_b,
  const float* __restrict__ P1z, const float* __restrict__ P2z,
  const float* __restrict__ gC, bf16* __restrict__ eabuf, const int* __restrict__ flag)
{
  __shared__ float attr[TPB][32];
  __shared__ int zd[TPB], zs[TPB], ppos[TPB];
  if (flag[0]) tne_edge_impl<float>((const float*)eattr, src, dst, z, pos,
      (const float*)dp1_w, (const float*)dp1_b, (const float*)dp2_w, (const float*)dp2_b,
      (const float*)dp3_w, (const float*)dp3_b, (const float*)emb2_b, P1z, P2z, gC, eabuf, attr, zd, zs, ppos);
  else tne_edge_impl<bf16>((const bf16*)eattr, src, dst, z, pos,
      (const bf16*)dp1_w, (const bf16*)dp1_b, (const bf16*)dp2_w, (const bf16*)dp2_b,
      (const bf16*)dp3_w, (const bf16*)dp3_b, (const bf16*)emb2_b, P1z, P2z, gC, eabuf, attr, zd, zs, ppos);
}

// ---------------- TNE scatter + LN: writes sm10 bf16 and ln bf16 ----------------
template<typename T>
__device__ __forceinline__ void tne_scat_impl(
  const int* offsets, const float* gVp, const bf16* eabuf,
  const T* ln_g, const T* ln_b, bf16* sm10, bf16* lnO, float* red)
{
  int n0 = blockIdx.x*NB, h = threadIdx.x;
  float tnv[NB];
  #pragma unroll
  for (int nn=0;nn<NB;++nn){
    int n = n0+nn;
    float a=0, v0=0,v1=0,v2=0, s0=0,s1=0,s2=0,s3=0,s4=0,s5=0;
    int beg = offsets[n], end = offsets[n+1];
    int i = beg;
    for (; i+4 <= end; i += 4){
      float c1[4],c2[4],c3[4],vx[4],vy[4],vz[4];
      #pragma unroll
      for (int u=0;u<4;++u){
        const bf16* p = eabuf + (size_t)(i+u)*384;
        c1[u]=b2f(p[h]); c2[u]=b2f(p[128+h]); c3[u]=b2f(p[256+h]);
        vx[u]=gVp[(i+u)*3+0]; vy[u]=gVp[(i+u)*3+1]; vz[u]=gVp[(i+u)*3+2];
      }
      #pragma unroll
      for (int u=0;u<4;++u){
        float tr3 = (vx[u]*vx[u]+vy[u]*vy[u]+vz[u]*vz[u])*(1.0f/3.0f);
        a  += c1[u];
        v0 += c2[u]*vx[u]; v1 += c2[u]*vy[u]; v2 += c2[u]*vz[u];
        s0 += c3[u]*(vx[u]*vx[u] - tr3); s1 += c3[u]*vx[u]*vy[u]; s2 += c3[u]*vx[u]*vz[u];
        s3 += c3[u]*(vy[u]*vy[u] - tr3); s4 += c3[u]*vy[u]*vz[u]; s5 += c3[u]*(vz[u]*vz[u] - tr3);
      }
    }
    for (; i<end; ++i){
      const bf16* p = eabuf + (size_t)i*384;
      float c1 = b2f(p[h]), c2 = b2f(p[128+h]), c3 = b2f(p[256+h]);
      float vx = gVp[i*3+0], vy = gVp[i*3+1], vz = gVp[i*3+2];
      float tr3 = (vx*vx+vy*vy+vz*vz)*(1.0f/3.0f);
      a  += c1;
      v0 += c2*vx; v1 += c2*vy; v2 += c2*vz;
      s0 += c3*(vx*vx - tr3); s1 += c3*vx*vy;          s2 += c3*vx*vz;
      s3 += c3*(vy*vy - tr3); s4 += c3*vy*vz;          s5 += c3*(vz*vz - tr3);
    }
    bf16* sp = sm10 + (size_t)n*1280;
    sp[0*128+h]=__float2bfloat16(a);
    sp[1*128+h]=__float2bfloat16(v0); sp[2*128+h]=__float2bfloat16(v1); sp[3*128+h]=__float2bfloat16(v2);
    sp[4*128+h]=__float2bfloat16(s0); sp[5*128+h]=__float2bfloat16(s1); sp[6*128+h]=__float2bfloat16(s2);
    sp[7*128+h]=__float2bfloat16(s3); sp[8*128+h]=__float2bfloat16(s4); sp[9*128+h]=__float2bfloat16(s5);
    tnv[nn] = 3.0f*a*a + 2.0f*(v0*v0+v1*v1+v2*v2)
            + s0*s0 + s3*s3 + s5*s5 + 2.0f*(s1*s1 + s2*s2 + s4*s4);
  }
  float gg = ldf(ln_g,h), bb = ldf(ln_b,h);
  #pragma unroll
  for (int nn=0;nn<NB;++nn){
    __syncthreads();
    red[h] = tnv[nn]; __syncthreads();
    for (int off=64; off>=1; off>>=1){ if (h<off) red[h]+=red[h+off]; __syncthreads(); }
    float mean = red[0]*(1.0f/128.0f);
    __syncthreads();
    float dm = tnv[nn] - mean;
    red[h] = dm*dm; __syncthreads();
    for (int off=64; off>=1; off>>=1){ if (h<off) red[h]+=red[h+off]; __syncthreads(); }
    float var = red[0]*(1.0f/128.0f);
    lnO[(size_t)(n0+nn)*128 + h] = __float2bfloat16(dm*rsqrtf(var+1e-5f)*gg + bb);
  }
}
__global__ void __launch_bounds__(128) k_tne_scat(
  const int* __restrict__ offsets, const float* __restrict__ gVp, const bf16* __restrict__ eabuf,
  const void* ln_g, const void* ln_b, bf16* __restrict__ sm10, bf16* __restrict__ lnO,
  const int* __restrict__ flag)
{
  __shared__ float red[128];
  if (flag[0]) tne_scat_impl<float>(offsets, gVp, eabuf, (const float*)ln_g, (const float*)ln_b, sm10, lnO, red);
  else         tne_scat_impl<bf16 >(offsets, gVp, eabuf, (const bf16* )ln_g, (const bf16* )ln_b, sm10, lnO, red);
}

// ---------------- node fsc MLP via MFMA (r17-validated) ----------------
template<typename T>
__device__ __forceinline__ void node_mlp_impl(
  const bf16* lnO, const unsigned short* ps0, const unsigned short* ps1,
  const T* b0, const T* b1, bf16* fsc3, unsigned short* h2p)
{
  int wid  = threadIdx.x >> 6;
  int lane = threadIdx.x & 63;
  int n0 = blockIdx.x*16;
  int m = lane & 15, g = lane >> 4;
  short8v aln[4];
  #pragma unroll
  for (int ks=0; ks<4; ++ks)
    aln[ks] = *reinterpret_cast<const short8v*>((const unsigned short*)lnO + (size_t)(n0+m)*128 + ks*32 + g*8);
  for (int nt=wid; nt<16; nt+=4){
    float bias = ldf(b0, nt*16+m);
    f32x4 acc = {bias,bias,bias,bias};
    #pragma unroll
    for (int ks=0; ks<4; ++ks){
      short8v b = *reinterpret_cast<const short8v*>(ps0 + ((size_t)(nt*4+ks)*64 + lane)*8);
      acc = __builtin_amdgcn_mfma_f32_16x16x32_bf16(aln[ks], b, acc, 0,0,0);
    }
    #pragma unroll
    for (int r=0;r<4;++r){
      int n = nt*16 + m, row = g*4 + r;
      h2p[(n>>5)*512 + (((n>>3)&3)*16+row)*8 + (n&7)] = f2bu(siluf(acc[r]));
    }
  }
  __syncthreads();
  short8v a3[8];
  #pragma unroll
  for (int ks=0; ks<8; ++ks) a3[ks] = *reinterpret_cast<const short8v*>(&h2p[ks*512 + lane*8]);
  for (int nt=wid; nt<24; nt+=4){
    float bias = ldf(b1, nt*16+m);
    f32x4 acc = {bias,bias,bias,bias};
    #pragma unroll
    for (int ks=0; ks<8; ++ks){
      short8v b = *reinterpret_cast<const short8v*>(ps1 + ((size_t)(nt*8+ks)*64 + lane)*8);
      acc = __builtin_amdgcn_mfma_f32_16x16x32_bf16(a3[ks], b, acc, 0,0,0);
    }
    #pragma unroll
    for (int r=0;r<4;++r){
      int n = nt*16 + m, row = g*4 + r;
      ((unsigned short*)fsc3)[(size_t)(n0+row)*384 + (n%3)*128 + (n/3)] = f2bu(siluf(acc[r]));
    }
  }
}
__global__ void __launch_bounds__(256) k_node_mlp(
  const bf16* __restrict__ lnO, const unsigned short* __restrict__ ps0,
  const unsigned short* __restrict__ ps1,
  const void* b0, const void* b1, bf16* __restrict__ fsc3, const int* __restrict__ flag)
{
  __shared__ __align__(16) unsigned short h2p[4096];
  if (flag[0]) node_mlp_impl<float>(lnO, ps0, ps1, (const float*)b0, (const float*)b1, fsc3, h2p);
  else         node_mlp_impl<bf16 >(lnO, ps0, ps1, (const bf16* )b0, (const bf16* )b1, fsc3, h2p);
}

// ---------------- tne cmix via MFMA + fsc combine -> X9 (r17-validated) ----------------
__global__ void __launch_bounds__(256) k_tne_cmix(
  const bf16* __restrict__ sm10, const unsigned short* __restrict__ pwlt,
  const bf16* __restrict__ fsc3, float* __restrict__ X9)
{
  int wid  = threadIdx.x >> 6;
  int lane = threadIdx.x & 63;
  int n0 = blockIdx.x*16;
  int m = lane & 15, g = lane >> 4;
  f32x4 acc[10][2];
  #pragma unroll
  for (int c=0;c<10;++c){ acc[c][0]=(f32x4){0,0,0,0}; acc[c][1]=(f32x4){0,0,0,0}; }
  #pragma unroll
  for (int c=0;c<10;++c){
    int mat = (c==0) ? 0 : (c<4) ? 1 : 2;
    const unsigned short* bw = pwlt + (size_t)mat*16384;
    short8v af[4];
    #pragma unroll
    for (int ks=0; ks<4; ++ks)
      af[ks] = *reinterpret_cast<const short8v*>((const unsigned short*)sm10 + (size_t)(n0+m)*1280 + c*128 + ks*32 + g*8);
    #pragma unroll
    for (int t=0;t<2;++t){
      int nt = wid + t*4;
      #pragma unroll
      for (int ks=0; ks<4; ++ks){
        short8v b = *reinterpret_cast<const short8v*>(bw + ((size_t)(nt*4+ks)*64 + lane)*8);
        acc[c][t] = __builtin_amdgcn_mfma_f32_16x16x32_bf16(af[ks], b, acc[c][t], 0,0,0);
      }
    }
  }
  #pragma unroll
  for (int t=0;t<2;++t){
    int nt = wid + t*4;
    int h = nt*16 + m;
    #pragma unroll
    for (int r=0;r<4;++r){
      int node = n0 + g*4 + r;
      float am  = acc[0][t][r];
      float wm0 = acc[1][t][r], wm1 = acc[2][t][r], wm2 = acc[3][t][r];
      float t0 = acc[4][t][r], t1 = acc[5][t][r], t2 = acc[6][t][r];
      float t3 = acc[7][t][r], t4 = acc[8][t][r], t5 = acc[9][t][r];
      float f0 = b2f(fsc3[(size_t)node*384 + h]);
      float f1 = b2f(fsc3[(size_t)node*384 + 128 + h]);
      float f2 = b2f(fsc3[(size_t)node*384 + 256 + h]);
      float* xp = X9 + (size_t)node*1152;
      xp[0*128+h] = f0*am + f2*t0;
      xp[1*128+h] = -f1*wm2 + f2*t1;
      xp[2*128+h] =  f1*wm1 + f2*t2;
      xp[3*128+h] =  f1*wm2 + f2*t1;
      xp[4*128+h] = f0*am + f2*t3;
      xp[5*128+h] = -f1*wm0 + f2*t4;
      xp[6*128+h] = -f1*wm1 + f2*t2;
      xp[7*128+h] =  f1*wm0 + f2*t4;
      xp[8*128+h] = f0*am + f2*t5;
    }
  }
}

// ---------------- FUSED: normalize X (16 nodes) + cmix(lx) via MFMA -> Y10 ----------------
__global__ void __launch_bounds__(256) k_cmix_norm(
  float* __restrict__ X9, const unsigned short* __restrict__ pw, bf16* __restrict__ Y10)
{
  __shared__ __align__(16) unsigned short sst[16*1280];   // 40 KB
  int n0 = blockIdx.x*16;
  int tid = threadIdx.x;
  #pragma unroll
  for (int it=0; it<8; ++it){
    int idx = it*256 + tid;          // 0..2047
    int nn = idx >> 7, h = idx & 127;
    float* xp = X9 + (size_t)(n0+nn)*1152;
    float x00=xp[0*128+h], x01=xp[1*128+h], x02=xp[2*128+h];
    float x10=xp[3*128+h], x11=xp[4*128+h], x12=xp[5*128+h];
    float x20=xp[6*128+h], x21=xp[7*128+h], x22=xp[8*128+h];
    float tn = x00*x00+x01*x01+x02*x02+x10*x10+x11*x11+x12*x12+x20*x20+x21*x21+x22*x22;
    float inv = 1.0f/(tn+1.0f);
    x00*=inv; x01*=inv; x02*=inv; x10*=inv; x11*=inv; x12*=inv; x20*=inv; x21*=inv; x22*=inv;
    xp[0*128+h]=x00; xp[1*128+h]=x01; xp[2*128+h]=x02;
    xp[3*128+h]=x10; xp[4*128+h]=x11; xp[5*128+h]=x12;
    xp[6*128+h]=x20; xp[7*128+h]=x21; xp[8*128+h]=x22;
    float a = (x00+x11+x22)*(1.0f/3.0f);
    unsigned short* sp = sst + (size_t)nn*1280;
    sp[0*128+h]=f2bu(a);
    sp[1*128+h]=f2bu(0.5f*(x21-x12));
    sp[2*128+h]=f2bu(0.5f*(x02-x20));
    sp[3*128+h]=f2bu(0.5f*(x10-x01));
    sp[4*128+h]=f2bu(x00-a);
    sp[5*128+h]=f2bu(0.5f*(x01+x10));
    sp[6*128+h]=f2bu(0.5f*(x02+x20));
    sp[7*128+h]=f2bu(x11-a);
    sp[8*128+h]=f2bu(0.5f*(x12+x21));
    sp[9*128+h]=f2bu(x22-a);
  }
  __syncthreads();
  int wid  = tid >> 6;
  int lane = tid & 63;
  int m = lane & 15, g = lane >> 4;
  f32x4 acc[10][2];
  #pragma unroll
  for (int c=0;c<10;++c){ acc[c][0]=(f32x4){0,0,0,0}; acc[c][1]=(f32x4){0,0,0,0}; }
  #pragma unroll
  for (int c=0;c<10;++c){
    int mat = (c==0) ? 0 : (c<4) ? 1 : 2;
    const unsigned short* bw = pw + (size_t)mat*16384;
    short8v af[4];
    #pragma unroll
    for (int ks=0; ks<4; ++ks)
      af[ks] = *reinterpret_cast<const short8v*>(&sst[(size_t)m*1280 + c*128 + ks*32 + g*8]);
    #pragma unroll
    for (int t=0;t<2;++t){
      int nt = wid + t*4;
      #pragma unroll
      for (int ks=0; ks<4; ++ks){
        short8v b = *reinterpret_cast<const short8v*>(bw + ((size_t)(nt*4+ks)*64 + lane)*8);
        acc[c][t] = __builtin_amdgcn_mfma_f32_16x16x32_bf16(af[ks], b, acc[c][t], 0,0,0);
      }
    }
  }
  #pragma unroll
  for (int t=0;t<2;++t){
    int nt = wid + t*4;
    int h = nt*16 + m;
    #pragma unroll
    for (int r=0;r<4;++r){
      int node = n0 + g*4 + r;
      unsigned short* op = (unsigned short*)Y10 + (size_t)node*1280;
      #pragma unroll
      for (int c=0;c<10;++c) op[c*128 + h] = f2bu(acc[c][t][r]);
    }
  }
}

// ---------------- msg edge MLP via MFMA: 16 edges/block, both layers (blockIdx.y),
// LDS output staging + coalesced uint4 write-out (r22) ----------------
// Per-tile MFMA math identical to r16/r21 => same values bit-for-bit.
// buf: phase A = h1p(2048 shorts) + h2p(4096 shorts); phase B = ostage
// (16 rows x stride 392 shorts) reusing the same space after a3 is in regs.
template<typename T>
__device__ __forceinline__ void mfma_impl(
  const unsigned short* eattr_c, const float* gC, const int* pos,
  const unsigned short* p0, const unsigned short* p1, const unsigned short* p2,
  const T* b0, const T* b1, const T* b2,
  unsigned short* eabuf, unsigned short* buf, int* spos)
{
  int wid  = threadIdx.x >> 6;
  int lane = threadIdx.x & 63;
  int e0 = blockIdx.x*16;
  int m = lane & 15, g = lane >> 4;
  if (threadIdx.x < 16) spos[threadIdx.x] = pos[e0 + threadIdx.x];
  float cc[4];
  #pragma unroll
  for (int r=0;r<4;++r) cc[r] = gC[e0 + g*4 + r];
  unsigned short* h1p = buf;
  unsigned short* h2p = buf + 2048;
  short8v a1 = *reinterpret_cast<const short8v*>(eattr_c + (size_t)(e0+m)*32 + g*8);
  // l0: 8 nt tiles, 2 per wave
  for (int nt=wid; nt<8; nt+=4){
    float bias = ldf(b0, nt*16+m);
    f32x4 acc = {bias,bias,bias,bias};
    short8v b = *reinterpret_cast<const short8v*>(p0 + ((size_t)nt*64 + lane)*8);
    acc = __builtin_amdgcn_mfma_f32_16x16x32_bf16(a1, b, acc, 0,0,0);
    #pragma unroll
    for (int r=0;r<4;++r){
      int n = nt*16 + m, row = g*4 + r;
      h1p[(n>>5)*512 + (((n>>3)&3)*16+row)*8 + (n&7)] = f2bu(siluf(acc[r]));
    }
  }
  __syncthreads();
  short8v a2[4];
  #pragma unroll
  for (int ks=0; ks<4; ++ks) a2[ks] = *reinterpret_cast<const short8v*>(&h1p[ks*512 + lane*8]);
  // l1: 16 nt tiles, 4 per wave
  for (int nt=wid; nt<16; nt+=4){
    float bias = ldf(b1, nt*16+m);
    f32x4 acc = {bias,bias,bias,bias};
    #pragma unroll
    for (int ks=0; ks<4; ++ks){
      short8v b = *reinterpret_cast<const short8v*>(p1 + ((size_t)(nt*4+ks)*64 + lane)*8);
      acc = __builtin_amdgcn_mfma_f32_16x16x32_bf16(a2[ks], b, acc, 0,0,0);
    }
    #pragma unroll
    for (int r=0;r<4;++r){
      int n = nt*16 + m, row = g*4 + r;
      h2p[(n>>5)*512 + (((n>>3)&3)*16+row)*8 + (n&7)] = f2bu(siluf(acc[r]));
    }
  }
  __syncthreads();
  short8v a3[8];
  #pragma unroll
  for (int ks=0; ks<8; ++ks) a3[ks] = *reinterpret_cast<const short8v*>(&h2p[ks*512 + lane*8]);
  __syncthreads();   // all waves hold a3 in regs; buf is now free for ostage
  // l2: 24 nt tiles, 6 per wave -> ostage (row stride 392 shorts)
  for (int nt=wid; nt<24; nt+=4){
    float bias = ldf(b2, nt*16+m);
    f32x4 acc = {bias,bias,bias,bias};
    #pragma unroll
    for (int ks=0; ks<8; ++ks){
      short8v b = *reinterpret_cast<const short8v*>(p2 + ((size_t)(nt*8+ks)*64 + lane)*8);
      acc = __builtin_amdgcn_mfma_f32_16x16x32_bf16(a3[ks], b, acc, 0,0,0);
    }
    #pragma unroll
    for (int r=0;r<4;++r){
      int n = nt*16 + m, row = g*4 + r;
      float v = siluf(acc[r]) * cc[r];
      buf[row*392 + (n%3)*128 + (n/3)] = f2bu(v);
    }
  }
  __syncthreads();
  // coalesced write-out: 16 threads per row, 3 x uint4 each (768B/row)
  int r  = threadIdx.x >> 4;
  int ch = threadIdx.x & 15;
  size_t base = (size_t)spos[r]*384;
  #pragma unroll
  for (int it=0; it<3; ++it){
    uint4 v = *reinterpret_cast<const uint4*>(&buf[r*392 + (ch + it*16)*8]);
    *reinterpret_cast<uint4*>(eabuf + base + (size_t)(ch + it*16)*8) = v;
  }
}
__global__ void __launch_bounds__(256) k_msg_edge_mfma(
  const unsigned short* __restrict__ eattr_c, const float* __restrict__ gC,
  const int* __restrict__ pos,
  const unsigned short* __restrict__ p0a, const unsigned short* __restrict__ p0b,
  const unsigned short* __restrict__ p1a, const unsigned short* __restrict__ p1b,
  const unsigned short* __restrict__ p2a, const unsigned short* __restrict__ p2b,
  const void* b0, const void* b1, const void* b2,
  unsigned short* __restrict__ eabuf_msg, const int* __restrict__ flag)
{
  __shared__ __align__(16) unsigned short buf[6272];   // max(h1p+h2p=6144, ostage 16*392=6272)
  __shared__ int spos[16];
  int l = blockIdx.y;
  const unsigned short* p0 = l ? p0b : p0a;
  const unsigned short* p1 = l ? p1b : p1a;
  const unsigned short* p2 = l ? p2b : p2a;
  unsigned short* eabuf = eabuf_msg + (size_t)l*NE*384;
  if (flag[0]) mfma_impl<float>(eattr_c, gC, pos, p0, p1, p2,
      (const float*)b0 + (long)l*128, (const float*)b1 + (long)l*256, (const float*)b2 + (long)l*384,
      eabuf, buf, spos);
  else mfma_impl<bf16>(eattr_c, gC, pos, p0, p1, p2,
      (const bf16*)b0 + (long)l*128, (const bf16*)b1 + (long)l*256, (const bf16*)b2 + (long)l*384,
      eabuf, buf, spos);
}

// ---------------- msg scatter + AB + decompose -> smb bf16 ----------------
__global__ void __launch_bounds__(128) k_msg_sab(
  const int* __restrict__ offsets, const int* __restrict__ csrc,
  const bf16* __restrict__ eabuf, const bf16* __restrict__ Y10, bf16* __restrict__ smb)
{
  int n0 = blockIdx.x*NB, h = threadIdx.x;
  #pragma unroll
  for (int nn=0;nn<NB;++nn){
    int n = n0+nn;
    float am=0, vm0=0,vm1=0,vm2=0, smm0=0,smm1=0,smm2=0,smm3=0,smm4=0,smm5=0;
    int beg = offsets[n], end = offsets[n+1];
    int i = beg;
    for (; i+4 <= end; i += 4){
      int ss[4];
      #pragma unroll
      for (int u=0;u<4;++u){ ss[u] = csrc[i+u]; }
      float e0a[4], e1a[4], e2a[4];
      float y0[4],y1[4],y2[4],y3[4],y4[4],y5[4],y6[4],y7[4],y8[4],y9[4];
      #pragma unroll
      for (int u=0;u<4;++u){
        const bf16* ep = eabuf + (size_t)(i+u)*384;
        e0a[u]=b2f(ep[h]); e1a[u]=b2f(ep[128+h]); e2a[u]=b2f(ep[256+h]);
        const bf16* yp = Y10 + (size_t)ss[u]*1280;
        y0[u]=b2f(yp[0*128+h]); y1[u]=b2f(yp[1*128+h]); y2[u]=b2f(yp[2*128+h]);
        y3[u]=b2f(yp[3*128+h]); y4[u]=b2f(yp[4*128+h]); y5[u]=b2f(yp[5*128+h]);
        y6[u]=b2f(yp[6*128+h]); y7[u]=b2f(yp[7*128+h]); y8[u]=b2f(yp[8*128+h]);
        y9[u]=b2f(yp[9*128+h]);
      }
      #pragma unroll
      for (int u=0;u<4;++u){
        am   += e0a[u]*y0[u];
        vm0  += e1a[u]*y1[u]; vm1 += e1a[u]*y2[u]; vm2 += e1a[u]*y3[u];
        smm0 += e2a[u]*y4[u]; smm1 += e2a[u]*y5[u]; smm2 += e2a[u]*y6[u];
        smm3 += e2a[u]*y7[u]; smm4 += e2a[u]*y8[u]; smm5 += e2a[u]*y9[u];
      }
    }
    for (; i<end; ++i){
      int s = csrc[i];
      const bf16* ep = eabuf + (size_t)i*384;
      float e0 = b2f(ep[h]), e1 = b2f(ep[128+h]), e2 = b2f(ep[256+h]);
      const bf16* yp = Y10 + (size_t)s*1280;
      am   += e0*b2f(yp[0*128+h]);
      vm0  += e1*b2f(yp[1*128+h]); vm1 += e1*b2f(yp[2*128+h]); vm2 += e1*b2f(yp[3*128+h]);
      smm0 += e2*b2f(yp[4*128+h]); smm1 += e2*b2f(yp[5*128+h]); smm2 += e2*b2f(yp[6*128+h]);
      smm3 += e2*b2f(yp[7*128+h]); smm4 += e2*b2f(yp[8*128+h]); smm5 += e2*b2f(yp[9*128+h]);
    }
    const bf16* yp = Y10 + (size_t)n*1280;
    float aY=b2f(yp[0*128+h]), u0=b2f(yp[1*128+h]), u1=b2f(yp[2*128+h]), u2=b2f(yp[3*128+h]);
    float q0=b2f(yp[4*128+h]), q1=b2f(yp[5*128+h]), q2=b2f(yp[6*128+h]);
    float q3=b2f(yp[7*128+h]), q4=b2f(yp[8*128+h]), q5=b2f(yp[9*128+h]);
    float m00=am+smm0,   m01=-vm2+smm1, m02= vm1+smm2;
    float m10= vm2+smm1, m11=am+smm3,  m12=-vm0+smm4;
    float m20=-vm1+smm2, m21= vm0+smm4, m22=am+smm5;
    float y00=aY+q0,  y01=-u2+q1, y02= u1+q2;
    float y10= u2+q1, y11=aY+q3,  y12=-u0+q4;
    float y20=-u1+q2, y21= u0+q4, y22=aY+q5;
    float ab00 = m00*y00+m01*y10+m02*y20 + y00*m00+y01*m10+y02*m20;
    float ab01 = m00*y01+m01*y11+m02*y21 + y00*m01+y01*m11+y02*m21;
    float ab02 = m00*y02+m01*y12+m02*y22 + y00*m02+y01*m12+y02*m22;
    float ab10 = m10*y00+m11*y10+m12*y20 + y10*m00+y11*m10+y12*m20;
    float ab11 = m10*y01+m11*y11+m12*y21 + y10*m01+y11*m11+y12*m21;
    float ab12 = m10*y02+m11*y12+m12*y22 + y10*m02+y11*m12+y12*m22;
    float ab20 = m20*y00+m21*y10+m22*y20 + y20*m00+y21*m10+y22*m20;
    float ab21 = m20*y01+m21*y11+m22*y21 + y20*m01+y21*m11+y22*m21;
    float ab22 = m20*y02+m21*y12+m22*y22 + y20*m02+y21*m12+y22*m22;
    float a2 = (ab00+ab11+ab22)*(1.0f/3.0f);
    float w0 = 0.5f*(ab21-ab12), w1 = 0.5f*(ab02-ab20), w2 = 0.5f*(ab10-ab01);
    float t0 = ab00-a2, t1 = 0.5f*(ab01+ab10), t2 = 0.5f*(ab02+ab20);
    float t3 = ab11-a2, t4 = 0.5f*(ab12+ab21), t5 = ab22-a2;
    float dnm = ab00*ab00+ab01*ab01+ab02*ab02+ab10*ab10+ab11*ab11+ab12*ab12
              + ab20*ab20+ab21*ab21+ab22*ab22 + 1.0f;
    float inv = 1.0f/dnm;
    bf16* sp = smb + (size_t)n*1280;
    sp[0*128+h]=__float2bfloat16(a2*inv);
    sp[1*128+h]=__float2bfloat16(w0*inv); sp[2*128+h]=__float2bfloat16(w1*inv); sp[3*128+h]=__float2bfloat16(w2*inv);
    sp[4*128+h]=__float2bfloat16(t0*inv); sp[5*128+h]=__float2bfloat16(t1*inv); sp[6*128+h]=__float2bfloat16(t2*inv);
    sp[7*128+h]=__float2bfloat16(t3*inv); sp[8*128+h]=__float2bfloat16(t4*inv); sp[9*128+h]=__float2bfloat16(t5*inv);
  }
}

// ---------------- FUSED: cmix(lt) via MFMA + dX+dX^2 + X update / output ----------------
template<typename T>
__device__ __forceinline__ void cmix_fin_impl(
  const bf16* smb, const unsigned short* pw, float* X9, T* out, int write_out)
{
  int wid  = threadIdx.x >> 6;
  int lane = threadIdx.x & 63;
  int n0 = blockIdx.x*16;
  int m = lane & 15, g = lane >> 4;
  f32x4 acc[10][2];
  #pragma unroll
  for (int c=0;c<10;++c){ acc[c][0]=(f32x4){0,0,0,0}; acc[c][1]=(f32x4){0,0,0,0}; }
  #pragma unroll
  for (int c=0;c<10;++c){
    int mat = (c==0) ? 0 : (c<4) ? 1 : 2;
    const unsigned short* bw = pw + (size_t)mat*16384;
    short8v af[4];
    #pragma unroll
    for (int ks=0; ks<4; ++ks)
      af[ks] = *reinterpret_cast<const short8v*>((const unsigned short*)smb + (size_t)(n0+m)*1280 + c*128 + ks*32 + g*8);
    #pragma unroll
    for (int t=0;t<2;++t){
      int nt = wid + t*4;
      #pragma unroll
      for (int ks=0; ks<4; ++ks){
        short8v b = *reinterpret_cast<const short8v*>(bw + ((size_t)(nt*4+ks)*64 + lane)*8);
        acc[c][t] = __builtin_amdgcn_mfma_f32_16x16x32_bf16(af[ks], b, acc[c][t], 0,0,0);
      }
    }
  }
  #pragma unroll
  for (int t=0;t<2;++t){
    int nt = wid + t*4;
    int h = nt*16 + m;
    #pragma unroll
    for (int r=0;r<4;++r){
      int node = n0 + g*4 + r;
      float at  = bround(acc[0][t][r]);
      float vt0 = bround(acc[1][t][r]), vt1 = bround(acc[2][t][r]), vt2 = bround(acc[3][t][r]);
      float st0 = bround(acc[4][t][r]), st1 = bround(acc[5][t][r]), st2 = bround(acc[6][t][r]);
      float st3 = bround(acc[7][t][r]), st4 = bround(acc[8][t][r]), st5 = bround(acc[9][t][r]);
      float d00=at+st0,   d01=-vt2+st1, d02= vt1+st2;
      float d10= vt2+st1, d11=at+st3,  d12=-vt0+st4;
      float d20=-vt1+st2, d21= vt0+st4, d22=at+st5;
      float g00 = d00 + d00*d00+d01*d10+d02*d20;
      float g01 = d01 + d00*d01+d01*d11+d02*d21;
      float g02 = d02 + d00*d02+d01*d12+d02*d22;
      float g10 = d10 + d10*d00+d11*d10+d12*d20;
      float g11 = d11 + d10*d01+d11*d11+d12*d21;
      float g12 = d12 + d10*d02+d11*d12+d12*d22;
      float g20 = d20 + d20*d00+d21*d10+d22*d20;
      float g21 = d21 + d20*d01+d21*d11+d22*d21;
      float g22 = d22 + d20*d02+d21*d12+d22*d22;
      float* xp = X9 + (size_t)node*1152;
      float x00=xp[0*128+h]+g00, x01=xp[1*128+h]+g01, x02=xp[2*128+h]+g02;
      float x10=xp[3*128+h]+g10, x11=xp[4*128+h]+g11, x12=xp[5*128+h]+g12;
      float x20=xp[6*128+h]+g20, x21=xp[7*128+h]+g21, x22=xp[8*128+h]+g22;
      if (write_out){
        if (sizeof(T)==4){
          float* of = (float*)out + ((size_t)node*128 + h)*9;
          of[0]=x00; of[1]=x01; of[2]=x02; of[3]=x10; of[4]=x11; of[5]=x12; of[6]=x20; of[7]=x21; of[8]=x22;
        } else {
          bf16* ob = (bf16*)out + ((size_t)node*128 + h)*9;
          ob[0]=__float2bfloat16(x00); ob[1]=__float2bfloat16(x01); ob[2]=__float2bfloat16(x02);
          ob[3]=__float2bfloat16(x10); ob[4]=__float2bfloat16(x11); ob[5]=__float2bfloat16(x12);
          ob[6]=__float2bfloat16(x20); ob[7]=__float2bfloat16(x21); ob[8]=__float2bfloat16(x22);
        }
      } else {
        xp[0*128+h]=x00; xp[1*128+h]=x01; xp[2*128+h]=x02;
        xp[3*128+h]=x10; xp[4*128+h]=x11; xp[5*128+h]=x12;
        xp[6*128+h]=x20; xp[7*128+h]=x21; xp[8*128+h]=x22;
      }
    }
  }
}
__global__ void __launch_bounds__(256) k_cmix_fin(
  const bf16* __restrict__ smb, const unsigned short* __restrict__ pw,
  float* __restrict__ X9, void* __restrict__ out,
  const int* __restrict__ flag, int write_out)
{
  if (flag[0]) cmix_fin_impl<float>(smb, pw, X9, (float*)out, write_out);
  else         cmix_fin_impl<bf16 >(smb, pw, X9, (bf16* )out, write_out);
}

extern "C" void kernel_launch(void* const* d_in, const int* in_sizes, int n_in,
                              void* d_out, int out_size, void* d_ws, size_t ws_size,
                              hipStream_t stream)
{
  (void)in_sizes; (void)n_in; (void)out_size; (void)ws_size;
  const int* z    = (const int*)d_in[0];
  const int* eidx = (const int*)d_in[1];
  const int* src  = eidx;
  const int* dst  = eidx + NE;

  // Workspace ~160 MB (ws_size ~256 MB per r19 fillBuffer evidence).
  char* w = (char*)d_ws;
  int* flag    = (int*)w;   w += 64;
  int* counts  = (int*)w;   w += (size_t)NN*4;
  int* offsets = (int*)w;   w += (size_t)(NN+1)*4 + 60;
  int* cursor  = (int*)w;   w += (size_t)NN*4;
  int* pos     = (int*)w;   w += (size_t)NE*4;
  int* csrc    = (int*)w;   w += (size_t)NE*4;
  float* gC    = (float*)w; w += (size_t)NE*4;
  float* gVp   = (float*)w; w += (size_t)NE*12;
  float* P1z   = (float*)w; w += (size_t)MAXZ*HH*4;
  float* P2z   = (float*)w; w += (size_t)MAXZ*HH*4;
  bf16* eabuf  = (bf16*)w;  w += (size_t)NE*384*2;          // tne coefficients
  bf16* eabuf_msg = (bf16*)w; w += (size_t)2*NE*384*2;      // msg edge MLP, both layers
  float* X9    = (float*)w; w += (size_t)NN*1152*4;
  bf16* Y10    = (bf16*)w;  w += (size_t)NN*1280*2;
  bf16* smb    = (bf16*)w;  w += (size_t)NN*1280*2;
  unsigned short* eattr_c = (unsigned short*)w; w += (size_t)NE*32*2;
  unsigned short* pw0[2]; unsigned short* pw1[2]; unsigned short* pw2[2];
  for (int l=0;l<2;++l){
    pw0[l] = (unsigned short*)w; w += 8*64*8*2;
    pw1[l] = (unsigned short*)w; w += 64*64*8*2;
    pw2[l] = (unsigned short*)w; w += 192*64*8*2;
  }
  unsigned short* pw_s0 = (unsigned short*)w; w += 64*64*8*2;
  unsigned short* pw_s1 = (unsigned short*)w; w += 192*64*8*2;
  unsigned short* pwlt  = (unsigned short*)w; w += 3*32*64*8*2;
  unsigned short* pwlx2 = (unsigned short*)w; w += 2*3*32*64*8*2;
  unsigned short* pwlt2 = (unsigned short*)w; w += 2*3*32*64*8*2;
  bf16* lnO    = (bf16*)w;  w += (size_t)NN*128*2;
  bf16* fsc3   = (bf16*)w;  w += (size_t)NN*384*2;
  bf16* sm10   = Y10;   // tne alias: dead until msg cmix_norm overwrites Y10

  k_detect<<<1, 256, 0, stream>>>((const unsigned int*)d_in[4], flag);
  hipMemsetAsync(counts, 0, (size_t)NN*4, stream);
  k_count<<<NE/256, 256, 0, stream>>>(dst, counts);
  k_scan<<<1, 1024, 0, stream>>>(counts, offsets, cursor);
  k_fill<<<NE/256, 256, 0, stream>>>(dst, src, cursor, pos, csrc);
  k_geom<<<NE/256, 256, 0, stream>>>(d_in[2], d_in[3], src, dst, pos, gC, gVp, flag);
  k_zemb<<<MAXZ, 128, 0, stream>>>(d_in[5], d_in[12], P1z, P2z, flag);
  k_cvt_attr<<<NE*32/256, 256, 0, stream>>>(d_in[4], eattr_c, flag);

  PackDescs pd;
  for (int l=0;l<2;++l){
    pd.base[l*3+0] = d_in[21]; pd.eoff[l*3+0] = (long)l*32*128;
    pd.base[l*3+1] = d_in[23]; pd.eoff[l*3+1] = (long)l*128*256;
    pd.base[l*3+2] = d_in[25]; pd.eoff[l*3+2] = (long)l*256*384;
    pd.out[l*3+0] = pw0[l]; pd.K[l*3+0]=32;  pd.N[l*3+0]=128;
    pd.out[l*3+1] = pw1[l]; pd.K[l*3+1]=128; pd.N[l*3+1]=256;
    pd.out[l*3+2] = pw2[l]; pd.K[l*3+2]=256; pd.N[l*3+2]=384;
  }
  pd.base[6] = d_in[15]; pd.eoff[6] = 0; pd.out[6] = pw_s0; pd.K[6]=128; pd.N[6]=256;
  pd.base[7] = d_in[17]; pd.eoff[7] = 0; pd.out[7] = pw_s1; pd.K[7]=256; pd.N[7]=384;
  for (int c=0;c<3;++c){
    pd.base[8+c] = d_in[14]; pd.eoff[8+c] = (long)c*16384;
    pd.out[8+c] = pwlt + (size_t)c*16384; pd.K[8+c]=128; pd.N[8+c]=128;
  }
  for (int l=0;l<2;++l)
    for (int c=0;c<3;++c){
      pd.base[11+l*3+c] = d_in[27]; pd.eoff[11+l*3+c] = (long)(l*3+c)*16384;
      pd.out[11+l*3+c] = pwlx2 + (size_t)(l*3+c)*16384; pd.K[11+l*3+c]=128; pd.N[11+l*3+c]=128;
      pd.base[17+l*3+c] = d_in[28]; pd.eoff[17+l*3+c] = (long)(l*3+c)*16384;
      pd.out[17+l*3+c] = pwlt2 + (size_t)(l*3+c)*16384; pd.K[17+l*3+c]=128; pd.N[17+l*3+c]=128;
    }
  k_pack<<<dim3(48, 23), 256, 0, stream>>>(pd, flag);

  // Both layers' edge MLPs in one dispatch (edge MLP is X-independent).
  k_msg_edge_mfma<<<dim3(NE/16, 2), 256, 0, stream>>>(eattr_c, gC, pos,
      pw0[0], pw0[1], pw1[0], pw1[1], pw2[0], pw2[1],
      d_in[22], d_in[24], d_in[26],
      (unsigned short*)eabuf_msg, flag);

  k_tne_edge<<<NE/TPB, 128, 0, stream>>>(d_in[4], src, dst, z, pos,
      d_in[6], d_in[7], d_in[8], d_in[9], d_in[10], d_in[11], d_in[13],
      P1z, P2z, gC, eabuf, flag);
  k_tne_scat<<<NN/NB, 128, 0, stream>>>(offsets, gVp, eabuf,
      d_in[19], d_in[20], sm10, lnO, flag);
  k_node_mlp<<<NN/16, 256, 0, stream>>>(lnO, pw_s0, pw_s1, d_in[16], d_in[18], fsc3, flag);
  k_tne_cmix<<<NN/16, 256, 0, stream>>>(sm10, pwlt, fsc3, X9);

  for (int l=0; l<2; ++l){
    k_cmix_norm<<<NN/16, 256, 0, stream>>>(X9, pwlx2 + (size_t)l*3*16384, Y10);
    k_msg_sab<<<NN/NB, 128, 0, stream>>>(offsets, csrc,
        eabuf_msg + (size_t)l*NE*384, Y10, smb);
    k_cmix_fin<<<NN/16, 256, 0, stream>>>(smb, pwlt2 + (size_t)l*3*16384, X9, d_out,
        flag, (l==1)?1:0);
  }
}

// Round 23
// 231.984 us; speedup vs baseline: 2.0472x; 1.0086x over previous
//
#include <hip/hip_runtime.h>
#include <hip/hip_bf16.h>

typedef __hip_bfloat16 bf16;
typedef __attribute__((ext_vector_type(8))) short short8v;
typedef __attribute__((ext_vector_type(4))) float f32x4;

#define NN 4096
#define NE 32768
#define HH 128
#define MAXZ 100
#define TPB 8
#define NB 1

// ENVIRONMENT FACTS (r0-r22): float tensors are FLOAT32; runtime detector kept.
// MFMA edge path validated r10/r16/r19/r21/r22; MFMA cmix validated r17/r18;
// fusions r20; merged-layer+LDS-staged edge r22 (234.0us, absmax 0.002929688
// bit-stable). ws_size ~256MB. r23: (1) NB=2->1 for sab/scat (latency-bound
// gathers; double wave supply, per-node FP order unchanged); (2) ostage
// segment stride 128->136 shorts + row stride 408 (de-alias bank 0; the
// three 128-short segments all hit bank 0 at stride 128). Global layout and
// all math bit-identical => absmax must stay 0.002929688.

__device__ __forceinline__ float b2f(bf16 v){ return __bfloat162float(v); }
__device__ __forceinline__ float ldf(const float* p, size_t i){ return p[i]; }
__device__ __forceinline__ float ldf(const bf16*  p, size_t i){ return __bfloat162float(p[i]); }
__device__ __forceinline__ float siluf(float x){ return x / (1.0f + __expf(-x)); }
__device__ __forceinline__ unsigned short f2bu(float x){
  bf16 h = __float2bfloat16(x);
  return *reinterpret_cast<unsigned short*>(&h);
}
__device__ __forceinline__ float bround(float x){   // round through bf16 (matches old smb round-trip)
  bf16 h = __float2bfloat16(x);
  return __bfloat162float(h);
}

__global__ void __launch_bounds__(256) k_detect(const unsigned int* __restrict__ w, int* __restrict__ flag){
  __shared__ int cnt[256];
  int t = threadIdx.x;
  int c = 0;
  for (int i = t; i < 4096; i += 256){
    unsigned int lo = w[i] & 0xffffu;
    int e = (int)((lo >> 7) & 0xffu);
    c += (e >= 110 && e <= 132) ? 1 : 0;
  }
  cnt[t] = c; __syncthreads();
  for (int off=128; off>=1; off>>=1){ if (t<off) cnt[t]+=cnt[t+off]; __syncthreads(); }
  if (t==0) flag[0] = (cnt[0] < 2048) ? 1 : 0;
}

// ---------------- CSR build ----------------
__global__ void __launch_bounds__(256) k_count(const int* __restrict__ dst, int* __restrict__ counts){
  int e = blockIdx.x*256 + threadIdx.x;
  if (e < NE) atomicAdd(&counts[dst[e]], 1);
}

__global__ void __launch_bounds__(1024) k_scan(const int* __restrict__ counts, int* __restrict__ offsets, int* __restrict__ cursor){
  __shared__ int lds[1024];
  int t = threadIdx.x;
  int c0 = counts[4*t+0], c1 = counts[4*t+1], c2 = counts[4*t+2], c3 = counts[4*t+3];
  int s1 = c0+c1, s2 = s1+c2, s3 = s2+c3;
  lds[t] = s3;
  __syncthreads();
  for (int off=1; off<1024; off<<=1){
    int v = lds[t];
    int add = (t>=off)? lds[t-off] : 0;
    __syncthreads();
    lds[t] = v + add;
    __syncthreads();
  }
  int incl = lds[t];
  int base = incl - s3;
  offsets[4*t+0]=base;    offsets[4*t+1]=base+c0; offsets[4*t+2]=base+s1; offsets[4*t+3]=base+s2;
  cursor [4*t+0]=base;    cursor [4*t+1]=base+c0; cursor [4*t+2]=base+s1; cursor [4*t+3]=base+s2;
  if (t==1023) offsets[4096]=incl;
}

__global__ void __launch_bounds__(256) k_fill(const int* __restrict__ dst, const int* __restrict__ src,
                                              int* __restrict__ cursor,
                                              int* __restrict__ pos, int* __restrict__ csrc){
  int e = blockIdx.x*256 + threadIdx.x;
  if (e < NE){
    int p = atomicAdd(&cursor[dst[e]], 1);
    pos[e] = p;
    csrc[p] = src[e];
  }
}

// ---------------- edge geometry ----------------
template<typename T>
__device__ __forceinline__ void geom_impl(const T* ew, const T* evec,
    const int* src, const int* dst, const int* pos, float* gC, float* gVp){
  int e = blockIdx.x*256 + threadIdx.x;
  if (e >= NE) return;
  float d = ldf(ew, e);
  float c = 0.5f*(cosf(d*0.6283185307179586f)+1.0f);
  c = (d < 5.0f) ? c : 0.0f;
  gC[e] = c;
  float x = ldf(evec, (size_t)e*3+0), y = ldf(evec, (size_t)e*3+1), z = ldf(evec, (size_t)e*3+2);
  if (src[e] != dst[e]){
    float n = sqrtf(x*x+y*y+z*z);
    float inv = 1.0f/fmaxf(n, 1e-12f);
    x*=inv; y*=inv; z*=inv;
  }
  int p = pos[e];
  gVp[p*3+0]=x; gVp[p*3+1]=y; gVp[p*3+2]=z;
}
__global__ void __launch_bounds__(256) k_geom(const void* ew, const void* evec,
    const int* __restrict__ src, const int* __restrict__ dst, const int* __restrict__ pos,
    float* __restrict__ gC, float* __restrict__ gVp, const int* __restrict__ flag){
  if (flag[0]) geom_impl<float>((const float*)ew, (const float*)evec, src, dst, pos, gC, gVp);
  else         geom_impl<bf16 >((const bf16* )ew, (const bf16* )evec, src, dst, pos, gC, gVp);
}

// ---------------- per-z embedding products ----------------
template<typename T>
__device__ __forceinline__ void zemb_impl(const T* emb, const T* emb2_w,
    float* P1z, float* P2z, float* Zr){
  int zv = blockIdx.x, h = threadIdx.x;
  Zr[h] = ldf(emb, (size_t)zv*HH + h);
  __syncthreads();
  float p1=0.f, p2=0.f;
  for (int r=0;r<128;++r){
    float x = Zr[r];
    p1 += x*ldf(emb2_w, (size_t)r*HH+h);
    p2 += x*ldf(emb2_w, (size_t)(r+128)*HH+h);
  }
  P1z[zv*HH+h]=p1; P2z[zv*HH+h]=p2;
}
__global__ void __launch_bounds__(128) k_zemb(const void* emb, const void* emb2_w,
    float* __restrict__ P1z, float* __restrict__ P2z, const int* __restrict__ flag){
  __shared__ float Zr[128];
  if (flag[0]) zemb_impl<float>((const float*)emb, (const float*)emb2_w, P1z, P2z, Zr);
  else         zemb_impl<bf16 >((const bf16* )emb, (const bf16* )emb2_w, P1z, P2z, Zr);
}

// ---------------- convert edge_attr -> bf16 ----------------
__global__ void __launch_bounds__(256) k_cvt_attr(const void* in, unsigned short* __restrict__ out,
                                                  const int* __restrict__ flag){
  int i = blockIdx.x*256 + threadIdx.x;
  if (flag[0]) out[i] = f2bu(((const float*)in)[i]);
  else         out[i] = ((const unsigned short*)in)[i];
}

// ---------------- weight repack into MFMA B-fragment layout (23 matrices) ----------------
struct PackDescs {
  const void*     base[23];
  long            eoff[23];
  unsigned short* out[23];
  int K[23]; int N[23];
};
template<typename T>
__device__ __forceinline__ void pack_impl(const PackDescs& d){
  int y = blockIdx.y;
  int K = d.K[y], N = d.N[y];
  int ktiles = K>>5, ntiles = N>>4;
  int total = ktiles*ntiles*64;
  int idx = blockIdx.x*256 + threadIdx.x;
  if (idx >= total) return;
  int lane = idx & 63, tile = idx >> 6;
  int kt = tile % ktiles, nt = tile / ktiles;
  const T* W = (const T*)d.base[y] + d.eoff[y];
  int n = nt*16 + (lane&15), k0 = kt*32 + (lane>>4)*8;
  unsigned int t[8];
  #pragma unroll
  for (int j=0;j<8;++j) t[j] = f2bu(ldf(W, (size_t)(k0+j)*N + n));
  uint4 v;
  v.x = t[0] | (t[1]<<16);
  v.y = t[2] | (t[3]<<16);
  v.z = t[4] | (t[5]<<16);
  v.w = t[6] | (t[7]<<16);
  *reinterpret_cast<uint4*>(d.out[y] + ((size_t)tile*64 + lane)*8) = v;
}
__global__ void __launch_bounds__(256) k_pack(PackDescs d, const int* __restrict__ flag){
  if (flag[0]) pack_impl<float>(d);
  else         pack_impl<bf16 >(d);
}

// ---------------- TNE edge coefficients -> eabuf bf16 (CSR-ordered rows) ----------------
template<typename T>
__device__ __forceinline__ void tne_edge_impl(
  const T* eattr, const int* src, const int* dst, const int* z, const int* pos,
  const T* dp1_w, const T* dp1_b, const T* dp2_w, const T* dp2_b,
  const T* dp3_w, const T* dp3_b, const T* emb2_b,
  const float* P1z, const float* P2z, const float* gC, bf16* eabuf,
  float (*attr)[32], int* zd, int* zs, int* ppos)
{
  int e0 = blockIdx.x*TPB;
  int h  = threadIdx.x;
  for (int i=h; i<TPB*32; i+=128) attr[i>>5][i&31] = ldf(eattr, (size_t)e0*32 + i);
  if (h < TPB){ int e=e0+h; zd[h]=z[dst[e]]; zs[h]=z[src[e]]; ppos[h]=pos[e]; }
  __syncthreads();
  float w1[TPB], w2[TPB], w3[TPB];
  float b1v=ldf(dp1_b,h), b2v=ldf(dp2_b,h), b3v=ldf(dp3_b,h);
  #pragma unroll
  for (int e=0;e<TPB;++e){ w1[e]=b1v; w2[e]=b2v; w3[e]=b3v; }
  for (int r=0;r<32;++r){
    float u1=ldf(dp1_w,(size_t)r*HH+h), u2=ldf(dp2_w,(size_t)r*HH+h), u3=ldf(dp3_w,(size_t)r*HH+h);
    #pragma unroll
    for (int e=0;e<TPB;++e){ float a=attr[e][r]; w1[e]+=a*u1; w2[e]+=a*u2; w3[e]+=a*u3; }
  }
  float eb = ldf(emb2_b,h);
  #pragma unroll
  for (int e=0;e<TPB;++e){
    float zij = P1z[zd[e]*HH+h] + P2z[zs[e]*HH+h] + eb;
    float c = gC[e0+e];
    bf16* p = eabuf + (size_t)ppos[e]*384;
    p[h]     = __float2bfloat16(zij*w1[e]*c);
    p[128+h] = __float2bfloat16(zij*w2[e]*c);
    p[256+h] = __float2bfloat16(zij*w3[e]*c);
  }
}
__global__ void __launch_bounds__(128) k_tne_edge(
  const void* eattr, const int* __restrict__ src, const int* __restrict__ dst,
  const int* __restrict__ z, const int* __restrict__ pos,
  const void* dp1_w, const void* dp1_b, const void* dp2_w, const void* dp2_b,
  const void* dp3_w, const void* dp3_b, const void* emb2_b,
  const float* __restrict__ P1z, const float* __restrict__ P2z,
  const float* __restrict__ gC, bf16* __restrict__ eabuf, const int* __restrict__ flag)
{
  __shared__ float attr[TPB][32];
  __shared__ int zd[TPB], zs[TPB], ppos[TPB];
  if (flag[0]) tne_edge_impl<float>((const float*)eattr, src, dst, z, pos,
      (const float*)dp1_w, (const float*)dp1_b, (const float*)dp2_w, (const float*)dp2_b,
      (const float*)dp3_w, (const float*)dp3_b, (const float*)emb2_b, P1z, P2z, gC, eabuf, attr, zd, zs, ppos);
  else tne_edge_impl<bf16>((const bf16*)eattr, src, dst, z, pos,
      (const bf16*)dp1_w, (const bf16*)dp1_b, (const bf16*)dp2_w, (const bf16*)dp2_b,
      (const bf16*)dp3_w, (const bf16*)dp3_b, (const bf16*)emb2_b, P1z, P2z, gC, eabuf, attr, zd, zs, ppos);
}

// ---------------- TNE scatter + LN: writes sm10 bf16 and ln bf16 ----------------
template<typename T>
__device__ __forceinline__ void tne_scat_impl(
  const int* offsets, const float* gVp, const bf16* eabuf,
  const T* ln_g, const T* ln_b, bf16* sm10, bf16* lnO, float* red)
{
  int n0 = blockIdx.x*NB, h = threadIdx.x;
  float tnv[NB];
  #pragma unroll
  for (int nn=0;nn<NB;++nn){
    int n = n0+nn;
    float a=0, v0=0,v1=0,v2=0, s0=0,s1=0,s2=0,s3=0,s4=0,s5=0;
    int beg = offsets[n], end = offsets[n+1];
    int i = beg;
    for (; i+4 <= end; i += 4){
      float c1[4],c2[4],c3[4],vx[4],vy[4],vz[4];
      #pragma unroll
      for (int u=0;u<4;++u){
        const bf16* p = eabuf + (size_t)(i+u)*384;
        c1[u]=b2f(p[h]); c2[u]=b2f(p[128+h]); c3[u]=b2f(p[256+h]);
        vx[u]=gVp[(i+u)*3+0]; vy[u]=gVp[(i+u)*3+1]; vz[u]=gVp[(i+u)*3+2];
      }
      #pragma unroll
      for (int u=0;u<4;++u){
        float tr3 = (vx[u]*vx[u]+vy[u]*vy[u]+vz[u]*vz[u])*(1.0f/3.0f);
        a  += c1[u];
        v0 += c2[u]*vx[u]; v1 += c2[u]*vy[u]; v2 += c2[u]*vz[u];
        s0 += c3[u]*(vx[u]*vx[u] - tr3); s1 += c3[u]*vx[u]*vy[u]; s2 += c3[u]*vx[u]*vz[u];
        s3 += c3[u]*(vy[u]*vy[u] - tr3); s4 += c3[u]*vy[u]*vz[u]; s5 += c3[u]*(vz[u]*vz[u] - tr3);
      }
    }
    for (; i<end; ++i){
      const bf16* p = eabuf + (size_t)i*384;
      float c1 = b2f(p[h]), c2 = b2f(p[128+h]), c3 = b2f(p[256+h]);
      float vx = gVp[i*3+0], vy = gVp[i*3+1], vz = gVp[i*3+2];
      float tr3 = (vx*vx+vy*vy+vz*vz)*(1.0f/3.0f);
      a  += c1;
      v0 += c2*vx; v1 += c2*vy; v2 += c2*vz;
      s0 += c3*(vx*vx - tr3); s1 += c3*vx*vy;          s2 += c3*vx*vz;
      s3 += c3*(vy*vy - tr3); s4 += c3*vy*vz;          s5 += c3*(vz*vz - tr3);
    }
    bf16* sp = sm10 + (size_t)n*1280;
    sp[0*128+h]=__float2bfloat16(a);
    sp[1*128+h]=__float2bfloat16(v0); sp[2*128+h]=__float2bfloat16(v1); sp[3*128+h]=__float2bfloat16(v2);
    sp[4*128+h]=__float2bfloat16(s0); sp[5*128+h]=__float2bfloat16(s1); sp[6*128+h]=__float2bfloat16(s2);
    sp[7*128+h]=__float2bfloat16(s3); sp[8*128+h]=__float2bfloat16(s4); sp[9*128+h]=__float2bfloat16(s5);
    tnv[nn] = 3.0f*a*a + 2.0f*(v0*v0+v1*v1+v2*v2)
            + s0*s0 + s3*s3 + s5*s5 + 2.0f*(s1*s1 + s2*s2 + s4*s4);
  }
  float gg = ldf(ln_g,h), bb = ldf(ln_b,h);
  #pragma unroll
  for (int nn=0;nn<NB;++nn){
    __syncthreads();
    red[h] = tnv[nn]; __syncthreads();
    for (int off=64; off>=1; off>>=1){ if (h<off) red[h]+=red[h+off]; __syncthreads(); }
    float mean = red[0]*(1.0f/128.0f);
    __syncthreads();
    float dm = tnv[nn] - mean;
    red[h] = dm*dm; __syncthreads();
    for (int off=64; off>=1; off>>=1){ if (h<off) red[h]+=red[h+off]; __syncthreads(); }
    float var = red[0]*(1.0f/128.0f);
    lnO[(size_t)(n0+nn)*128 + h] = __float2bfloat16(dm*rsqrtf(var+1e-5f)*gg + bb);
  }
}
__global__ void __launch_bounds__(128) k_tne_scat(
  const int* __restrict__ offsets, const float* __restrict__ gVp, const bf16* __restrict__ eabuf,
  const void* ln_g, const void* ln_b, bf16* __restrict__ sm10, bf16* __restrict__ lnO,
  const int* __restrict__ flag)
{
  __shared__ float red[128];
  if (flag[0]) tne_scat_impl<float>(offsets, gVp, eabuf, (const float*)ln_g, (const float*)ln_b, sm10, lnO, red);
  else         tne_scat_impl<bf16 >(offsets, gVp, eabuf, (const bf16* )ln_g, (const bf16* )ln_b, sm10, lnO, red);
}

// ---------------- node fsc MLP via MFMA (r17-validated) ----------------
template<typename T>
__device__ __forceinline__ void node_mlp_impl(
  const bf16* lnO, const unsigned short* ps0, const unsigned short* ps1,
  const T* b0, const T* b1, bf16* fsc3, unsigned short* h2p)
{
  int wid  = threadIdx.x >> 6;
  int lane = threadIdx.x & 63;
  int n0 = blockIdx.x*16;
  int m = lane & 15, g = lane >> 4;
  short8v aln[4];
  #pragma unroll
  for (int ks=0; ks<4; ++ks)
    aln[ks] = *reinterpret_cast<const short8v*>((const unsigned short*)lnO + (size_t)(n0+m)*128 + ks*32 + g*8);
  for (int nt=wid; nt<16; nt+=4){
    float bias = ldf(b0, nt*16+m);
    f32x4 acc = {bias,bias,bias,bias};
    #pragma unroll
    for (int ks=0; ks<4; ++ks){
      short8v b = *reinterpret_cast<const short8v*>(ps0 + ((size_t)(nt*4+ks)*64 + lane)*8);
      acc = __builtin_amdgcn_mfma_f32_16x16x32_bf16(aln[ks], b, acc, 0,0,0);
    }
    #pragma unroll
    for (int r=0;r<4;++r){
      int n = nt*16 + m, row = g*4 + r;
      h2p[(n>>5)*512 + (((n>>3)&3)*16+row)*8 + (n&7)] = f2bu(siluf(acc[r]));
    }
  }
  __syncthreads();
  short8v a3[8];
  #pragma unroll
  for (int ks=0; ks<8; ++ks) a3[ks] = *reinterpret_cast<const short8v*>(&h2p[ks*512 + lane*8]);
  for (int nt=wid; nt<24; nt+=4){
    float bias = ldf(b1, nt*16+m);
    f32x4 acc = {bias,bias,bias,bias};
    #pragma unroll
    for (int ks=0; ks<8; ++ks){
      short8v b = *reinterpret_cast<const short8v*>(ps1 + ((size_t)(nt*8+ks)*64 + lane)*8);
      acc = __builtin_amdgcn_mfma_f32_16x16x32_bf16(a3[ks], b, acc, 0,0,0);
    }
    #pragma unroll
    for (int r=0;r<4;++r){
      int n = nt*16 + m, row = g*4 + r;
      ((unsigned short*)fsc3)[(size_t)(n0+row)*384 + (n%3)*128 + (n/3)] = f2bu(siluf(acc[r]));
    }
  }
}
__global__ void __launch_bounds__(256) k_node_mlp(
  const bf16* __restrict__ lnO, const unsigned short* __restrict__ ps0,
  const unsigned short* __restrict__ ps1,
  const void* b0, const void* b1, bf16* __restrict__ fsc3, const int* __restrict__ flag)
{
  __shared__ __align__(16) unsigned short h2p[4096];
  if (flag[0]) node_mlp_impl<float>(lnO, ps0, ps1, (const float*)b0, (const float*)b1, fsc3, h2p);
  else         node_mlp_impl<bf16 >(lnO, ps0, ps1, (const bf16* )b0, (const bf16* )b1, fsc3, h2p);
}

// ---------------- tne cmix via MFMA + fsc combine -> X9 (r17-validated) ----------------
__global__ void __launch_bounds__(256) k_tne_cmix(
  const bf16* __restrict__ sm10, const unsigned short* __restrict__ pwlt,
  const bf16* __restrict__ fsc3, float* __restrict__ X9)
{
  int wid  = threadIdx.x >> 6;
  int lane = threadIdx.x & 63;
  int n0 = blockIdx.x*16;
  int m = lane & 15, g = lane >> 4;
  f32x4 acc[10][2];
  #pragma unroll
  for (int c=0;c<10;++c){ acc[c][0]=(f32x4){0,0,0,0}; acc[c][1]=(f32x4){0,0,0,0}; }
  #pragma unroll
  for (int c=0;c<10;++c){
    int mat = (c==0) ? 0 : (c<4) ? 1 : 2;
    const unsigned short* bw = pwlt + (size_t)mat*16384;
    short8v af[4];
    #pragma unroll
    for (int ks=0; ks<4; ++ks)
      af[ks] = *reinterpret_cast<const short8v*>((const unsigned short*)sm10 + (size_t)(n0+m)*1280 + c*128 + ks*32 + g*8);
    #pragma unroll
    for (int t=0;t<2;++t){
      int nt = wid + t*4;
      #pragma unroll
      for (int ks=0; ks<4; ++ks){
        short8v b = *reinterpret_cast<const short8v*>(bw + ((size_t)(nt*4+ks)*64 + lane)*8);
        acc[c][t] = __builtin_amdgcn_mfma_f32_16x16x32_bf16(af[ks], b, acc[c][t], 0,0,0);
      }
    }
  }
  #pragma unroll
  for (int t=0;t<2;++t){
    int nt = wid + t*4;
    int h = nt*16 + m;
    #pragma unroll
    for (int r=0;r<4;++r){
      int node = n0 + g*4 + r;
      float am  = acc[0][t][r];
      float wm0 = acc[1][t][r], wm1 = acc[2][t][r], wm2 = acc[3][t][r];
      float t0 = acc[4][t][r], t1 = acc[5][t][r], t2 = acc[6][t][r];
      float t3 = acc[7][t][r], t4 = acc[8][t][r], t5 = acc[9][t][r];
      float f0 = b2f(fsc3[(size_t)node*384 + h]);
      float f1 = b2f(fsc3[(size_t)node*384 + 128 + h]);
      float f2 = b2f(fsc3[(size_t)node*384 + 256 + h]);
      float* xp = X9 + (size_t)node*1152;
      xp[0*128+h] = f0*am + f2*t0;
      xp[1*128+h] = -f1*wm2 + f2*t1;
      xp[2*128+h] =  f1*wm1 + f2*t2;
      xp[3*128+h] =  f1*wm2 + f2*t1;
      xp[4*128+h] = f0*am + f2*t3;
      xp[5*128+h] = -f1*wm0 + f2*t4;
      xp[6*128+h] = -f1*wm1 + f2*t2;
      xp[7*128+h] =  f1*wm0 + f2*t4;
      xp[8*128+h] = f0*am + f2*t5;
    }
  }
}

// ---------------- FUSED: normalize X (16 nodes) + cmix(lx) via MFMA -> Y10 ----------------
__global__ void __launch_bounds__(256) k_cmix_norm(
  float* __restrict__ X9, const unsigned short* __restrict__ pw, bf16* __restrict__ Y10)
{
  __shared__ __align__(16) unsigned short sst[16*1280];   // 40 KB
  int n0 = blockIdx.x*16;
  int tid = threadIdx.x;
  #pragma unroll
  for (int it=0; it<8; ++it){
    int idx = it*256 + tid;          // 0..2047
    int nn = idx >> 7, h = idx & 127;
    float* xp = X9 + (size_t)(n0+nn)*1152;
    float x00=xp[0*128+h], x01=xp[1*128+h], x02=xp[2*128+h];
    float x10=xp[3*128+h], x11=xp[4*128+h], x12=xp[5*128+h];
    float x20=xp[6*128+h], x21=xp[7*128+h], x22=xp[8*128+h];
    float tn = x00*x00+x01*x01+x02*x02+x10*x10+x11*x11+x12*x12+x20*x20+x21*x21+x22*x22;
    float inv = 1.0f/(tn+1.0f);
    x00*=inv; x01*=inv; x02*=inv; x10*=inv; x11*=inv; x12*=inv; x20*=inv; x21*=inv; x22*=inv;
    xp[0*128+h]=x00; xp[1*128+h]=x01; xp[2*128+h]=x02;
    xp[3*128+h]=x10; xp[4*128+h]=x11; xp[5*128+h]=x12;
    xp[6*128+h]=x20; xp[7*128+h]=x21; xp[8*128+h]=x22;
    float a = (x00+x11+x22)*(1.0f/3.0f);
    unsigned short* sp = sst + (size_t)nn*1280;
    sp[0*128+h]=f2bu(a);
    sp[1*128+h]=f2bu(0.5f*(x21-x12));
    sp[2*128+h]=f2bu(0.5f*(x02-x20));
    sp[3*128+h]=f2bu(0.5f*(x10-x01));
    sp[4*128+h]=f2bu(x00-a);
    sp[5*128+h]=f2bu(0.5f*(x01+x10));
    sp[6*128+h]=f2bu(0.5f*(x02+x20));
    sp[7*128+h]=f2bu(x11-a);
    sp[8*128+h]=f2bu(0.5f*(x12+x21));
    sp[9*128+h]=f2bu(x22-a);
  }
  __syncthreads();
  int wid  = tid >> 6;
  int lane = tid & 63;
  int m = lane & 15, g = lane >> 4;
  f32x4 acc[10][2];
  #pragma unroll
  for (int c=0;c<10;++c){ acc[c][0]=(f32x4){0,0,0,0}; acc[c][1]=(f32x4){0,0,0,0}; }
  #pragma unroll
  for (int c=0;c<10;++c){
    int mat = (c==0) ? 0 : (c<4) ? 1 : 2;
    const unsigned short* bw = pw + (size_t)mat*16384;
    short8v af[4];
    #pragma unroll
    for (int ks=0; ks<4; ++ks)
      af[ks] = *reinterpret_cast<const short8v*>(&sst[(size_t)m*1280 + c*128 + ks*32 + g*8]);
    #pragma unroll
    for (int t=0;t<2;++t){
      int nt = wid + t*4;
      #pragma unroll
      for (int ks=0; ks<4; ++ks){
        short8v b = *reinterpret_cast<const short8v*>(bw + ((size_t)(nt*4+ks)*64 + lane)*8);
        acc[c][t] = __builtin_amdgcn_mfma_f32_16x16x32_bf16(af[ks], b, acc[c][t], 0,0,0);
      }
    }
  }
  #pragma unroll
  for (int t=0;t<2;++t){
    int nt = wid + t*4;
    int h = nt*16 + m;
    #pragma unroll
    for (int r=0;r<4;++r){
      int node = n0 + g*4 + r;
      unsigned short* op = (unsigned short*)Y10 + (size_t)node*1280;
      #pragma unroll
      for (int c=0;c<10;++c) op[c*128 + h] = f2bu(acc[c][t][r]);
    }
  }
}

// ---------------- msg edge MLP via MFMA: 16 edges/block, both layers (blockIdx.y),
// LDS output staging (seg stride 136, row stride 408 — bank de-aliased) ----------------
// Per-tile MFMA math identical to r16/r21/r22 => same values bit-for-bit.
template<typename T>
__device__ __forceinline__ void mfma_impl(
  const unsigned short* eattr_c, const float* gC, const int* pos,
  const unsigned short* p0, const unsigned short* p1, const unsigned short* p2,
  const T* b0, const T* b1, const T* b2,
  unsigned short* eabuf, unsigned short* buf, int* spos)
{
  int wid  = threadIdx.x >> 6;
  int lane = threadIdx.x & 63;
  int e0 = blockIdx.x*16;
  int m = lane & 15, g = lane >> 4;
  if (threadIdx.x < 16) spos[threadIdx.x] = pos[e0 + threadIdx.x];
  float cc[4];
  #pragma unroll
  for (int r=0;r<4;++r) cc[r] = gC[e0 + g*4 + r];
  unsigned short* h1p = buf;
  unsigned short* h2p = buf + 2048;
  short8v a1 = *reinterpret_cast<const short8v*>(eattr_c + (size_t)(e0+m)*32 + g*8);
  // l0: 8 nt tiles, 2 per wave
  for (int nt=wid; nt<8; nt+=4){
    float bias = ldf(b0, nt*16+m);
    f32x4 acc = {bias,bias,bias,bias};
    short8v b = *reinterpret_cast<const short8v*>(p0 + ((size_t)nt*64 + lane)*8);
    acc = __builtin_amdgcn_mfma_f32_16x16x32_bf16(a1, b, acc, 0,0,0);
    #pragma unroll
    for (int r=0;r<4;++r){
      int n = nt*16 + m, row = g*4 + r;
      h1p[(n>>5)*512 + (((n>>3)&3)*16+row)*8 + (n&7)] = f2bu(siluf(acc[r]));
    }
  }
  __syncthreads();
  short8v a2[4];
  #pragma unroll
  for (int ks=0; ks<4; ++ks) a2[ks] = *reinterpret_cast<const short8v*>(&h1p[ks*512 + lane*8]);
  // l1: 16 nt tiles, 4 per wave
  for (int nt=wid; nt<16; nt+=4){
    float bias = ldf(b1, nt*16+m);
    f32x4 acc = {bias,bias,bias,bias};
    #pragma unroll
    for (int ks=0; ks<4; ++ks){
      short8v b = *reinterpret_cast<const short8v*>(p1 + ((size_t)(nt*4+ks)*64 + lane)*8);
      acc = __builtin_amdgcn_mfma_f32_16x16x32_bf16(a2[ks], b, acc, 0,0,0);
    }
    #pragma unroll
    for (int r=0;r<4;++r){
      int n = nt*16 + m, row = g*4 + r;
      h2p[(n>>5)*512 + (((n>>3)&3)*16+row)*8 + (n&7)] = f2bu(siluf(acc[r]));
    }
  }
  __syncthreads();
  short8v a3[8];
  #pragma unroll
  for (int ks=0; ks<8; ++ks) a3[ks] = *reinterpret_cast<const short8v*>(&h2p[ks*512 + lane*8]);
  __syncthreads();   // all waves hold a3 in regs; buf is now free for ostage
  // l2: 24 nt tiles, 6 per wave -> ostage (row stride 408, seg stride 136)
  for (int nt=wid; nt<24; nt+=4){
    float bias = ldf(b2, nt*16+m);
    f32x4 acc = {bias,bias,bias,bias};
    #pragma unroll
    for (int ks=0; ks<8; ++ks){
      short8v b = *reinterpret_cast<const short8v*>(p2 + ((size_t)(nt*8+ks)*64 + lane)*8);
      acc = __builtin_amdgcn_mfma_f32_16x16x32_bf16(a3[ks], b, acc, 0,0,0);
    }
    #pragma unroll
    for (int r=0;r<4;++r){
      int n = nt*16 + m, row = g*4 + r;
      float v = siluf(acc[r]) * cc[r];
      buf[row*408 + (n%3)*136 + (n/3)] = f2bu(v);
    }
  }
  __syncthreads();
  // coalesced write-out: 16 threads per row, 3 segments x uint4 each (768B/row)
  int r  = threadIdx.x >> 4;
  int ch = threadIdx.x & 15;
  size_t base = (size_t)spos[r]*384;
  #pragma unroll
  for (int seg=0; seg<3; ++seg){
    uint4 v = *reinterpret_cast<const uint4*>(&buf[r*408 + seg*136 + ch*8]);
    *reinterpret_cast<uint4*>(eabuf + base + (size_t)(seg*128 + ch*8)) = v;
  }
}
__global__ void __launch_bounds__(256) k_msg_edge_mfma(
  const unsigned short* __restrict__ eattr_c, const float* __restrict__ gC,
  const int* __restrict__ pos,
  const unsigned short* __restrict__ p0a, const unsigned short* __restrict__ p0b,
  const unsigned short* __restrict__ p1a, const unsigned short* __restrict__ p1b,
  const unsigned short* __restrict__ p2a, const unsigned short* __restrict__ p2b,
  const void* b0, const void* b1, const void* b2,
  unsigned short* __restrict__ eabuf_msg, const int* __restrict__ flag)
{
  __shared__ __align__(16) unsigned short buf[6528];   // max(h1p+h2p=6144, ostage 16*408=6528)
  __shared__ int spos[16];
  int l = blockIdx.y;
  const unsigned short* p0 = l ? p0b : p0a;
  const unsigned short* p1 = l ? p1b : p1a;
  const unsigned short* p2 = l ? p2b : p2a;
  unsigned short* eabuf = eabuf_msg + (size_t)l*NE*384;
  if (flag[0]) mfma_impl<float>(eattr_c, gC, pos, p0, p1, p2,
      (const float*)b0 + (long)l*128, (const float*)b1 + (long)l*256, (const float*)b2 + (long)l*384,
      eabuf, buf, spos);
  else mfma_impl<bf16>(eattr_c, gC, pos, p0, p1, p2,
      (const bf16*)b0 + (long)l*128, (const bf16*)b1 + (long)l*256, (const bf16*)b2 + (long)l*384,
      eabuf, buf, spos);
}

// ---------------- msg scatter + AB + decompose -> smb bf16 ----------------
__global__ void __launch_bounds__(128) k_msg_sab(
  const int* __restrict__ offsets, const int* __restrict__ csrc,
  const bf16* __restrict__ eabuf, const bf16* __restrict__ Y10, bf16* __restrict__ smb)
{
  int n0 = blockIdx.x*NB, h = threadIdx.x;
  #pragma unroll
  for (int nn=0;nn<NB;++nn){
    int n = n0+nn;
    float am=0, vm0=0,vm1=0,vm2=0, smm0=0,smm1=0,smm2=0,smm3=0,smm4=0,smm5=0;
    int beg = offsets[n], end = offsets[n+1];
    int i = beg;
    for (; i+4 <= end; i += 4){
      int ss[4];
      #pragma unroll
      for (int u=0;u<4;++u){ ss[u] = csrc[i+u]; }
      float e0a[4], e1a[4], e2a[4];
      float y0[4],y1[4],y2[4],y3[4],y4[4],y5[4],y6[4],y7[4],y8[4],y9[4];
      #pragma unroll
      for (int u=0;u<4;++u){
        const bf16* ep = eabuf + (size_t)(i+u)*384;
        e0a[u]=b2f(ep[h]); e1a[u]=b2f(ep[128+h]); e2a[u]=b2f(ep[256+h]);
        const bf16* yp = Y10 + (size_t)ss[u]*1280;
        y0[u]=b2f(yp[0*128+h]); y1[u]=b2f(yp[1*128+h]); y2[u]=b2f(yp[2*128+h]);
        y3[u]=b2f(yp[3*128+h]); y4[u]=b2f(yp[4*128+h]); y5[u]=b2f(yp[5*128+h]);
        y6[u]=b2f(yp[6*128+h]); y7[u]=b2f(yp[7*128+h]); y8[u]=b2f(yp[8*128+h]);
        y9[u]=b2f(yp[9*128+h]);
      }
      #pragma unroll
      for (int u=0;u<4;++u){
        am   += e0a[u]*y0[u];
        vm0  += e1a[u]*y1[u]; vm1 += e1a[u]*y2[u]; vm2 += e1a[u]*y3[u];
        smm0 += e2a[u]*y4[u]; smm1 += e2a[u]*y5[u]; smm2 += e2a[u]*y6[u];
        smm3 += e2a[u]*y7[u]; smm4 += e2a[u]*y8[u]; smm5 += e2a[u]*y9[u];
      }
    }
    for (; i<end; ++i){
      int s = csrc[i];
      const bf16* ep = eabuf + (size_t)i*384;
      float e0 = b2f(ep[h]), e1 = b2f(ep[128+h]), e2 = b2f(ep[256+h]);
      const bf16* yp = Y10 + (size_t)s*1280;
      am   += e0*b2f(yp[0*128+h]);
      vm0  += e1*b2f(yp[1*128+h]); vm1 += e1*b2f(yp[2*128+h]); vm2 += e1*b2f(yp[3*128+h]);
      smm0 += e2*b2f(yp[4*128+h]); smm1 += e2*b2f(yp[5*128+h]); smm2 += e2*b2f(yp[6*128+h]);
      smm3 += e2*b2f(yp[7*128+h]); smm4 += e2*b2f(yp[8*128+h]); smm5 += e2*b2f(yp[9*128+h]);
    }
    const bf16* yp = Y10 + (size_t)n*1280;
    float aY=b2f(yp[0*128+h]), u0=b2f(yp[1*128+h]), u1=b2f(yp[2*128+h]), u2=b2f(yp[3*128+h]);
    float q0=b2f(yp[4*128+h]), q1=b2f(yp[5*128+h]), q2=b2f(yp[6*128+h]);
    float q3=b2f(yp[7*128+h]), q4=b2f(yp[8*128+h]), q5=b2f(yp[9*128+h]);
    float m00=am+smm0,   m01=-vm2+smm1, m02= vm1+smm2;
    float m10= vm2+smm1, m11=am+smm3,  m12=-vm0+smm4;
    float m20=-vm1+smm2, m21= vm0+smm4, m22=am+smm5;
    float y00=aY+q0,  y01=-u2+q1, y02= u1+q2;
    float y10= u2+q1, y11=aY+q3,  y12=-u0+q4;
    float y20=-u1+q2, y21= u0+q4, y22=aY+q5;
    float ab00 = m00*y00+m01*y10+m02*y20 + y00*m00+y01*m10+y02*m20;
    float ab01 = m00*y01+m01*y11+m02*y21 + y00*m01+y01*m11+y02*m21;
    float ab02 = m00*y02+m01*y12+m02*y22 + y00*m02+y01*m12+y02*m22;
    float ab10 = m10*y00+m11*y10+m12*y20 + y10*m00+y11*m10+y12*m20;
    float ab11 = m10*y01+m11*y11+m12*y21 + y10*m01+y11*m11+y12*m21;
    float ab12 = m10*y02+m11*y12+m12*y22 + y10*m02+y11*m12+y12*m22;
    float ab20 = m20*y00+m21*y10+m22*y20 + y20*m00+y21*m10+y22*m20;
    float ab21 = m20*y01+m21*y11+m22*y21 + y20*m01+y21*m11+y22*m21;
    float ab22 = m20*y02+m21*y12+m22*y22 + y20*m02+y21*m12+y22*m22;
    float a2 = (ab00+ab11+ab22)*(1.0f/3.0f);
    float w0 = 0.5f*(ab21-ab12), w1 = 0.5f*(ab02-ab20), w2 = 0.5f*(ab10-ab01);
    float t0 = ab00-a2, t1 = 0.5f*(ab01+ab10), t2 = 0.5f*(ab02+ab20);
    float t3 = ab11-a2, t4 = 0.5f*(ab12+ab21), t5 = ab22-a2;
    float dnm = ab00*ab00+ab01*ab01+ab02*ab02+ab10*ab10+ab11*ab11+ab12*ab12
              + ab20*ab20+ab21*ab21+ab22*ab22 + 1.0f;
    float inv = 1.0f/dnm;
    bf16* sp = smb + (size_t)n*1280;
    sp[0*128+h]=__float2bfloat16(a2*inv);
    sp[1*128+h]=__float2bfloat16(w0*inv); sp[2*128+h]=__float2bfloat16(w1*inv); sp[3*128+h]=__float2bfloat16(w2*inv);
    sp[4*128+h]=__float2bfloat16(t0*inv); sp[5*128+h]=__float2bfloat16(t1*inv); sp[6*128+h]=__float2bfloat16(t2*inv);
    sp[7*128+h]=__float2bfloat16(t3*inv); sp[8*128+h]=__float2bfloat16(t4*inv); sp[9*128+h]=__float2bfloat16(t5*inv);
  }
}

// ---------------- FUSED: cmix(lt) via MFMA + dX+dX^2 + X update / output ----------------
template<typename T>
__device__ __forceinline__ void cmix_fin_impl(
  const bf16* smb, const unsigned short* pw, float* X9, T* out, int write_out)
{
  int wid  = threadIdx.x >> 6;
  int lane = threadIdx.x & 63;
  int n0 = blockIdx.x*16;
  int m = lane & 15, g = lane >> 4;
  f32x4 acc[10][2];
  #pragma unroll
  for (int c=0;c<10;++c){ acc[c][0]=(f32x4){0,0,0,0}; acc[c][1]=(f32x4){0,0,0,0}; }
  #pragma unroll
  for (int c=0;c<10;++c){
    int mat = (c==0) ? 0 : (c<4) ? 1 : 2;
    const unsigned short* bw = pw + (size_t)mat*16384;
    short8v af[4];
    #pragma unroll
    for (int ks=0; ks<4; ++ks)
      af[ks] = *reinterpret_cast<const short8v*>((const unsigned short*)smb + (size_t)(n0+m)*1280 + c*128 + ks*32 + g*8);
    #pragma unroll
    for (int t=0;t<2;++t){
      int nt = wid + t*4;
      #pragma unroll
      for (int ks=0; ks<4; ++ks){
        short8v b = *reinterpret_cast<const short8v*>(bw + ((size_t)(nt*4+ks)*64 + lane)*8);
        acc[c][t] = __builtin_amdgcn_mfma_f32_16x16x32_bf16(af[ks], b, acc[c][t], 0,0,0);
      }
    }
  }
  #pragma unroll
  for (int t=0;t<2;++t){
    int nt = wid + t*4;
    int h = nt*16 + m;
    #pragma unroll
    for (int r=0;r<4;++r){
      int node = n0 + g*4 + r;
      float at  = bround(acc[0][t][r]);
      float vt0 = bround(acc[1][t][r]), vt1 = bround(acc[2][t][r]), vt2 = bround(acc[3][t][r]);
      float st0 = bround(acc[4][t][r]), st1 = bround(acc[5][t][r]), st2 = bround(acc[6][t][r]);
      float st3 = bround(acc[7][t][r]), st4 = bround(acc[8][t][r]), st5 = bround(acc[9][t][r]);
      float d00=at+st0,   d01=-vt2+st1, d02= vt1+st2;
      float d10= vt2+st1, d11=at+st3,  d12=-vt0+st4;
      float d20=-vt1+st2, d21= vt0+st4, d22=at+st5;
      float g00 = d00 + d00*d00+d01*d10+d02*d20;
      float g01 = d01 + d00*d01+d01*d11+d02*d21;
      float g02 = d02 + d00*d02+d01*d12+d02*d22;
      float g10 = d10 + d10*d00+d11*d10+d12*d20;
      float g11 = d11 + d10*d01+d11*d11+d12*d21;
      float g12 = d12 + d10*d02+d11*d12+d12*d22;
      float g20 = d20 + d20*d00+d21*d10+d22*d20;
      float g21 = d21 + d20*d01+d21*d11+d22*d21;
      float g22 = d22 + d20*d02+d21*d12+d22*d22;
      float* xp = X9 + (size_t)node*1152;
      float x00=xp[0*128+h]+g00, x01=xp[1*128+h]+g01, x02=xp[2*128+h]+g02;
      float x10=xp[3*128+h]+g10, x11=xp[4*128+h]+g11, x12=xp[5*128+h]+g12;
      float x20=xp[6*128+h]+g20, x21=xp[7*128+h]+g21, x22=xp[8*128+h]+g22;
      if (write_out){
        if (sizeof(T)==4){
          float* of = (float*)out + ((size_t)node*128 + h)*9;
          of[0]=x00; of[1]=x01; of[2]=x02; of[3]=x10; of[4]=x11; of[5]=x12; of[6]=x20; of[7]=x21; of[8]=x22;
        } else {
          bf16* ob = (bf16*)out + ((size_t)node*128 + h)*9;
          ob[0]=__float2bfloat16(x00); ob[1]=__float2bfloat16(x01); ob[2]=__float2bfloat16(x02);
          ob[3]=__float2bfloat16(x10); ob[4]=__float2bfloat16(x11); ob[5]=__float2bfloat16(x12);
          ob[6]=__float2bfloat16(x20); ob[7]=__float2bfloat16(x21); ob[8]=__float2bfloat16(x22);
        }
      } else {
        xp[0*128+h]=x00; xp[1*128+h]=x01; xp[2*128+h]=x02;
        xp[3*128+h]=x10; xp[4*128+h]=x11; xp[5*128+h]=x12;
        xp[6*128+h]=x20; xp[7*128+h]=x21; xp[8*128+h]=x22;
      }
    }
  }
}
__global__ void __launch_bounds__(256) k_cmix_fin(
  const bf16* __restrict__ smb, const unsigned short* __restrict__ pw,
  float* __restrict__ X9, void* __restrict__ out,
  const int* __restrict__ flag, int write_out)
{
  if (flag[0]) cmix_fin_impl<float>(smb, pw, X9, (float*)out, write_out);
  else         cmix_fin_impl<bf16 >(smb, pw, X9, (bf16* )out, write_out);
}

extern "C" void kernel_launch(void* const* d_in, const int* in_sizes, int n_in,
                              void* d_out, int out_size, void* d_ws, size_t ws_size,
                              hipStream_t stream)
{
  (void)in_sizes; (void)n_in; (void)out_size; (void)ws_size;
  const int* z    = (const int*)d_in[0];
  const int* eidx = (const int*)d_in[1];
  const int* src  = eidx;
  const int* dst  = eidx + NE;

  // Workspace ~160 MB (ws_size ~256 MB per r19 fillBuffer evidence).
  char* w = (char*)d_ws;
  int* flag    = (int*)w;   w += 64;
  int* counts  = (int*)w;   w += (size_t)NN*4;
  int* offsets = (int*)w;   w += (size_t)(NN+1)*4 + 60;
  int* cursor  = (int*)w;   w += (size_t)NN*4;
  int* pos     = (int*)w;   w += (size_t)NE*4;
  int* csrc    = (int*)w;   w += (size_t)NE*4;
  float* gC    = (float*)w; w += (size_t)NE*4;
  float* gVp   = (float*)w; w += (size_t)NE*12;
  float* P1z   = (float*)w; w += (size_t)MAXZ*HH*4;
  float* P2z   = (float*)w; w += (size_t)MAXZ*HH*4;
  bf16* eabuf  = (bf16*)w;  w += (size_t)NE*384*2;          // tne coefficients
  bf16* eabuf_msg = (bf16*)w; w += (size_t)2*NE*384*2;      // msg edge MLP, both layers
  float* X9    = (float*)w; w += (size_t)NN*1152*4;
  bf16* Y10    = (bf16*)w;  w += (size_t)NN*1280*2;
  bf16* smb    = (bf16*)w;  w += (size_t)NN*1280*2;
  unsigned short* eattr_c = (unsigned short*)w; w += (size_t)NE*32*2;
  unsigned short* pw0[2]; unsigned short* pw1[2]; unsigned short* pw2[2];
  for (int l=0;l<2;++l){
    pw0[l] = (unsigned short*)w; w += 8*64*8*2;
    pw1[l] = (unsigned short*)w; w += 64*64*8*2;
    pw2[l] = (unsigned short*)w; w += 192*64*8*2;
  }
  unsigned short* pw_s0 = (unsigned short*)w; w += 64*64*8*2;
  unsigned short* pw_s1 = (unsigned short*)w; w += 192*64*8*2;
  unsigned short* pwlt  = (unsigned short*)w; w += 3*32*64*8*2;
  unsigned short* pwlx2 = (unsigned short*)w; w += 2*3*32*64*8*2;
  unsigned short* pwlt2 = (unsigned short*)w; w += 2*3*32*64*8*2;
  bf16* lnO    = (bf16*)w;  w += (size_t)NN*128*2;
  bf16* fsc3   = (bf16*)w;  w += (size_t)NN*384*2;
  bf16* sm10   = Y10;   // tne alias: dead until msg cmix_norm overwrites Y10

  k_detect<<<1, 256, 0, stream>>>((const unsigned int*)d_in[4], flag);
  hipMemsetAsync(counts, 0, (size_t)NN*4, stream);
  k_count<<<NE/256, 256, 0, stream>>>(dst, counts);
  k_scan<<<1, 1024, 0, stream>>>(counts, offsets, cursor);
  k_fill<<<NE/256, 256, 0, stream>>>(dst, src, cursor, pos, csrc);
  k_geom<<<NE/256, 256, 0, stream>>>(d_in[2], d_in[3], src, dst, pos, gC, gVp, flag);
  k_zemb<<<MAXZ, 128, 0, stream>>>(d_in[5], d_in[12], P1z, P2z, flag);
  k_cvt_attr<<<NE*32/256, 256, 0, stream>>>(d_in[4], eattr_c, flag);

  PackDescs pd;
  for (int l=0;l<2;++l){
    pd.base[l*3+0] = d_in[21]; pd.eoff[l*3+0] = (long)l*32*128;
    pd.base[l*3+1] = d_in[23]; pd.eoff[l*3+1] = (long)l*128*256;
    pd.base[l*3+2] = d_in[25]; pd.eoff[l*3+2] = (long)l*256*384;
    pd.out[l*3+0] = pw0[l]; pd.K[l*3+0]=32;  pd.N[l*3+0]=128;
    pd.out[l*3+1] = pw1[l]; pd.K[l*3+1]=128; pd.N[l*3+1]=256;
    pd.out[l*3+2] = pw2[l]; pd.K[l*3+2]=256; pd.N[l*3+2]=384;
  }
  pd.base[6] = d_in[15]; pd.eoff[6] = 0; pd.out[6] = pw_s0; pd.K[6]=128; pd.N[6]=256;
  pd.base[7] = d_in[17]; pd.eoff[7] = 0; pd.out[7] = pw_s1; pd.K[7]=256; pd.N[7]=384;
  for (int c=0;c<3;++c){
    pd.base[8+c] = d_in[14]; pd.eoff[8+c] = (long)c*16384;
    pd.out[8+c] = pwlt + (size_t)c*16384; pd.K[8+c]=128; pd.N[8+c]=128;
  }
  for (int l=0;l<2;++l)
    for (int c=0;c<3;++c){
      pd.base[11+l*3+c] = d_in[27]; pd.eoff[11+l*3+c] = (long)(l*3+c)*16384;
      pd.out[11+l*3+c] = pwlx2 + (size_t)(l*3+c)*16384; pd.K[11+l*3+c]=128; pd.N[11+l*3+c]=128;
      pd.base[17+l*3+c] = d_in[28]; pd.eoff[17+l*3+c] = (long)(l*3+c)*16384;
      pd.out[17+l*3+c] = pwlt2 + (size_t)(l*3+c)*16384; pd.K[17+l*3+c]=128; pd.N[17+l*3+c]=128;
    }
  k_pack<<<dim3(48, 23), 256, 0, stream>>>(pd, flag);

  // Both layers' edge MLPs in one dispatch (edge MLP is X-independent).
  k_msg_edge_mfma<<<dim3(NE/16, 2), 256, 0, stream>>>(eattr_c, gC, pos,
      pw0[0], pw0[1], pw1[0], pw1[1], pw2[0], pw2[1],
      d_in[22], d_in[24], d_in[26],
      (unsigned short*)eabuf_msg, flag);

  k_tne_edge<<<NE/TPB, 128, 0, stream>>>(d_in[4], src, dst, z, pos,
      d_in[6], d_in[7], d_in[8], d_in[9], d_in[10], d_in[11], d_in[13],
      P1z, P2z, gC, eabuf, flag);
  k_tne_scat<<<NN/NB, 128, 0, stream>>>(offsets, gVp, eabuf,
      d_in[19], d_in[20], sm10, lnO, flag);
  k_node_mlp<<<NN/16, 256, 0, stream>>>(lnO, pw_s0, pw_s1, d_in[16], d_in[18], fsc3, flag);
  k_tne_cmix<<<NN/16, 256, 0, stream>>>(sm10, pwlt, fsc3, X9);

  for (int l=0; l<2; ++l){
    k_cmix_norm<<<NN/16, 256, 0, stream>>>(X9, pwlx2 + (size_t)l*3*16384, Y10);
    k_msg_sab<<<NN/NB, 128, 0, stream>>>(offsets, csrc,
        eabuf_msg + (size_t)l*NE*384, Y10, smb);
    k_cmix_fin<<<NN/16, 256, 0, stream>>>(smb, pwlt2 + (size_t)l*3*16384, X9, d_out,
        flag, (l==1)?1:0);
  }
}